// Round 1
// baseline (1503.426 us; speedup 1.0000x reference)
//
#include <hip/hip_runtime.h>
#include <hip/hip_fp16.h>

#define EPS 1e-5f

// ---------------- helpers ----------------
__device__ __forceinline__ float blockSum256(float v, float* red){
  #pragma unroll
  for(int o=32;o>0;o>>=1) v += __shfl_down(v,o,64);
  int wid = threadIdx.x>>6;
  if((threadIdx.x&63)==0) red[wid]=v;
  __syncthreads();
  if(threadIdx.x==0) red[0]=red[0]+red[1]+red[2]+red[3];
  __syncthreads();
  float r = red[0];
  __syncthreads();
  return r;
}

// ---------------- K1: EmbedT  TEmx[b][t][n] = LN_n(x[b,n,0,t] + posT[t,n]) ----------------
__global__ __launch_bounds__(256) void k1_embedT(const float* __restrict__ x, const float* __restrict__ posT,
    const float* __restrict__ gT, const float* __restrict__ bT, float* __restrict__ TEmx){
  int bt=blockIdx.x; int b=bt/12, t=bt-b*12;
  int tid=threadIdx.x;
  __shared__ float red[4];
  float v[4]; float s=0.f;
  #pragma unroll
  for(int i=0;i<4;i++){ int n=tid+i*256; v[i]=x[(b*1024+n)*12+t]+posT[t*1024+n]; s+=v[i]; }
  s = blockSum256(s, red);
  float mu = s*(1.f/1024.f);
  float q=0.f;
  #pragma unroll
  for(int i=0;i<4;i++){ float d=v[i]-mu; q+=d*d; }
  q = blockSum256(q, red);
  float rstd = rsqrtf(q*(1.f/1024.f)+EPS);
  #pragma unroll
  for(int i=0;i<4;i++){ int n=tid+i*256; TEmx[bt*1024+n]=(v[i]-mu)*rstd*gT[n]+bT[n]; }
}

// ---------------- K2: QKV  qkv[b][t][0:96 Q |96:192 K |192:288 V] ----------------
__global__ __launch_bounds__(320) void k2_qkv(const float* __restrict__ TEmx, const float* __restrict__ wq,
    const float* __restrict__ wk, const float* __restrict__ wv, float* __restrict__ qkv){
  int bt=blockIdx.x; int tid=threadIdx.x;
  __shared__ float row[1024];
  for(int i=tid;i<1024;i+=320) row[i]=TEmx[bt*1024+i];
  __syncthreads();
  if(tid<288){
    int m=tid/96, col=tid-m*96;
    const float* w = (m==0)?wq:((m==1)?wk:wv);
    float acc=0.f;
    #pragma unroll 4
    for(int n=0;n<1024;n++) acc += row[n]*w[n*96+col];
    qkv[bt*288+tid]=acc;
  }
}

// ---------------- K3: temporal attn: scores (output!), softmax over q (axis=3), ctx ----------------
__global__ __launch_bounds__(512) void k3_attn(const float* __restrict__ qkv, const float* __restrict__ res_att,
    float* __restrict__ scores_out, float* __restrict__ ctx){
  int b=blockIdx.x; int tid=threadIdx.x;
  __shared__ float sS[432];
  __shared__ float sA[432];
  if(tid<432){
    int h=tid/144; int r=tid-h*144; int q=r/12; int k2=r-q*12;
    const float* Qr=&qkv[(b*12+q)*288 + h*32];
    const float* Kr=&qkv[(b*12+k2)*288 + 96 + h*32];
    float acc=0.f;
    #pragma unroll
    for(int d=0;d<32;d++) acc+=Qr[d]*Kr[d];
    acc = acc*0.17677669529663687f + res_att[(b*3+h)*144 + q*12 + k2];
    sS[h*144+q*12+k2]=acc;
    scores_out[(b*3+h)*144 + q*12 + k2]=acc;
  }
  __syncthreads();
  if(tid<36){ // (h,k2) pairs; softmax over q
    int h=tid/12, k2=tid-(tid/12)*12;
    float mx=-1e30f;
    for(int q=0;q<12;q++) mx=fmaxf(mx,sS[h*144+q*12+k2]);
    float sum=0.f;
    for(int q=0;q<12;q++){ float e=__expf(sS[h*144+q*12+k2]-mx); sA[h*144+q*12+k2]=e; sum+=e; }
    float inv=1.f/sum;
    for(int q=0;q<12;q++) sA[h*144+q*12+k2]*=inv;
  }
  __syncthreads();
  // ctx[b][t=q][h*32+d] = sum_k2 attn[h,q,k2] * V[b,k2,h*32+d]
  for(int o=tid;o<1152;o+=512){
    int h=o/384; int r=o-h*384; int q=r/32; int d=r-q*32;
    float acc=0.f;
    #pragma unroll
    for(int k2=0;k2<12;k2++) acc += sA[h*144+q*12+k2]*qkv[(b*12+k2)*288+192+h*32+d];
    ctx[(b*12+q)*96 + h*32 + d]=acc;
  }
}

// ---------------- K4: TATout[b][t][n] = LN_n(ctx@fc + TEmx)  (no affine) ----------------
__global__ __launch_bounds__(256) void k4_tat(const float* __restrict__ ctx, const float* __restrict__ fcW,
    const float* __restrict__ TEmx, float* __restrict__ TAT){
  int bt=blockIdx.x; int tid=threadIdx.x;
  __shared__ float c96[96];
  __shared__ float red[4];
  if(tid<96) c96[tid]=ctx[bt*96+tid];
  __syncthreads();
  float v[4]; float s=0.f;
  #pragma unroll
  for(int i=0;i<4;i++){
    int n=tid+i*256;
    float acc=TEmx[bt*1024+n];
    #pragma unroll 4
    for(int j=0;j<96;j++) acc += c96[j]*fcW[j*1024+n];
    v[i]=acc; s+=acc;
  }
  s=blockSum256(s,red);
  float mu=s*(1.f/1024.f);
  float q=0.f;
  #pragma unroll
  for(int i=0;i<4;i++){float d=v[i]-mu;q+=d*d;}
  q=blockSum256(q,red);
  float rstd=rsqrtf(q*(1.f/1024.f)+EPS);
  #pragma unroll
  for(int i=0;i<4;i++){int n=tid+i*256; TAT[bt*1024+n]=(v[i]-mu)*rstd;}
}

// ---------------- K5: x_TAt + pos_S, LN over DM=512 -> SEmx[b][n][512] ----------------
__global__ __launch_bounds__(256) void k5_semx(const float* __restrict__ TAT, const float* __restrict__ pre_w,
    const float* __restrict__ pre_b, const float* __restrict__ posS, const float* __restrict__ gS,
    const float* __restrict__ bS, float* __restrict__ SEmx){
  int bn=blockIdx.x; int b=bn>>10, n=bn&1023; int tid=threadIdx.x;
  __shared__ float tv[12];
  __shared__ float red[4];
  if(tid<12) tv[tid]=TAT[(b*12+tid)*1024+n];
  __syncthreads();
  float v[2]; float s=0.f;
  #pragma unroll
  for(int i=0;i<2;i++){
    int d=tid+i*256;
    float acc=pre_b[d]+posS[n*512+d];
    #pragma unroll
    for(int t=0;t<12;t++) acc += tv[t]*pre_w[d*12+t];
    v[i]=acc; s+=acc;
  }
  s=blockSum256(s,red);
  float mu=s*(1.f/512.f);
  float q=0.f;
  #pragma unroll
  for(int i=0;i<2;i++){float d2=v[i]-mu;q+=d2*d2;}
  q=blockSum256(q,red);
  float rstd=rsqrtf(q*(1.f/512.f)+EPS);
  #pragma unroll
  for(int i=0;i<2;i++){int d=tid+i*256; SEmx[bn*512+d]=(v[i]-mu)*rstd*gS[d]+bS[d];}
}

// ---------------- K6: SQ/SK[b][k][n][32] = SEmx@swq/swk ; 8 rows per block ----------------
__global__ __launch_bounds__(256) void k6_sqk(const float* __restrict__ SEmx, const float* __restrict__ swq,
    const float* __restrict__ swk, float* __restrict__ SQ, float* __restrict__ SK){
  int bn0=blockIdx.x*8; int tid=threadIdx.x;
  __shared__ float rows[8][512];
  for(int i=tid;i<8*512;i+=256){ int r=i>>9, j=i&511; rows[r][j]=SEmx[(bn0+r)*512+j]; }
  __syncthreads();
  if(tid<192){
    int m=tid/96, col=tid-(tid/96)*96; int k=col>>5, d=col&31;
    const float* w = m? swk:swq;
    float acc[8];
    #pragma unroll
    for(int r=0;r<8;r++) acc[r]=0.f;
    for(int j=0;j<512;j++){
      float wv2=w[j*96+col];
      #pragma unroll
      for(int r=0;r<8;r++) acc[r]+=rows[r][j]*wv2;
    }
    float* dst = m? SK:SQ;
    #pragma unroll
    for(int r=0;r<8;r++){
      int bn=bn0+r; int b=bn>>10, n=bn&1023;
      dst[((b*3+k)*1024+n)*32+d]=acc[r];
    }
  }
}

// ---------------- K7: fused spatial attention + graph conv ----------------
// per block: (b,k, 16 m's). col[n] = SQ[n].SK[m]/sqrt32 + adj[n,m]*cmask[k,n,m];
// softmax over n; p *= cheb[k,n,m]; rhs[b,k,m,t] = sum_n p*x[b,n,t]
#define MT 16
__global__ __launch_bounds__(256) void k7_spatial(const float* __restrict__ SQ, const float* __restrict__ SK,
    const float* __restrict__ adj, const float* __restrict__ cmask, const float* __restrict__ cheb,
    const float* __restrict__ x, float* __restrict__ rhs){
  int blk=blockIdx.x;
  int m0=(blk&63)*MT;
  int bk=blk>>6;             // b*3+k
  int k=bk%3, b=bk/3;
  int tid=threadIdx.x;
  __shared__ __half sbuf[1024*MT];
  __shared__ float skt[MT*32];
  __shared__ float red2[256];
  __shared__ float M_[MT], S_[MT];
  for(int i=tid;i<MT*32;i+=256) skt[i]=SK[bk*32768 + m0*32 + i];
  __syncthreads();
  const float* sqb=&SQ[bk*32768];
  const float* cm=&cmask[k*1048576];
  #pragma unroll
  for(int i=0;i<4;i++){
    int n=tid+i*256;
    float4 q4[8];
    const float4* qp=(const float4*)(sqb+n*32);
    #pragma unroll
    for(int j=0;j<8;j++) q4[j]=qp[j];
    const float* arow=&adj[n*1024+m0];
    const float* crow=&cm[n*1024+m0];
    #pragma unroll
    for(int mm=0;mm<MT;mm++){
      const float* sm=&skt[mm*32];
      float acc=0.f;
      #pragma unroll
      for(int j=0;j<8;j++)
        acc+=q4[j].x*sm[j*4+0]+q4[j].y*sm[j*4+1]+q4[j].z*sm[j*4+2]+q4[j].w*sm[j*4+3];
      acc=acc*0.17677669529663687f + arow[mm]*crow[mm];
      sbuf[n*MT+mm]=__float2half(acc);
    }
  }
  __syncthreads();
  int mc=tid&(MT-1), sub=tid>>4;  // 16 subs x 64 n each
  float mx=-1e30f;
  for(int n=sub*64;n<sub*64+64;n++) mx=fmaxf(mx,__half2float(sbuf[n*MT+mc]));
  red2[tid]=mx;
  __syncthreads();
  if(tid<MT){ float mm=-1e30f; for(int s2=0;s2<16;s2++) mm=fmaxf(mm,red2[s2*MT+tid]); M_[tid]=mm; }
  __syncthreads();
  float Mm=M_[mc];
  float sm2=0.f;
  for(int n=sub*64;n<sub*64+64;n++) sm2+=__expf(__half2float(sbuf[n*MT+mc])-Mm);
  red2[tid]=sm2;
  __syncthreads();
  if(tid<MT){ float ss=0.f; for(int s2=0;s2<16;s2++) ss+=red2[s2*MT+tid]; S_[tid]=ss; }
  __syncthreads();
  const float* chb=&cheb[k*1048576];
  #pragma unroll
  for(int i=0;i<4;i++){
    int n=tid+i*256;
    const float* crow=&chb[n*1024+m0];
    #pragma unroll
    for(int mm=0;mm<MT;mm++){
      float sv=__half2float(sbuf[n*MT+mm]);
      float p=__expf(sv-M_[mm])/S_[mm]*crow[mm];
      sbuf[n*MT+mm]=__float2half(p);
    }
  }
  __syncthreads();
  const float* xb=&x[b*12288];
  for(int o=tid;o<MT*12;o+=256){
    int mo=o/12, t=o-mo*12;
    float acc=0.f;
    for(int n=0;n<1024;n++) acc+=__half2float(sbuf[n*MT+mo])*xb[n*12+t];
    rhs[(bk*1024+m0+mo)*12+t]=acc;
  }
}

// ---------------- K9: theta-contract + GTU convs + fc + residual + final LN ----------------
// 8 (b,n) pairs per block. XP padded stride 772 (=768+4) to avoid LDS bank conflicts across g.
__global__ __launch_bounds__(256) void k9_final(const float* __restrict__ rhs, const float* __restrict__ theta,
    const float* __restrict__ g3w, const float* __restrict__ g3b,
    const float* __restrict__ g5w, const float* __restrict__ g5b,
    const float* __restrict__ g7w, const float* __restrict__ g7b,
    const float* __restrict__ fcw, const float* __restrict__ fcb,
    const float* __restrict__ rw, const float* __restrict__ rb,
    const float* __restrict__ gln, const float* __restrict__ bln,
    const float* __restrict__ x, float* __restrict__ out){
  int bn0=blockIdx.x*8;
  int tid=threadIdx.x;
  __shared__ float XP[8][772];      // [g][c*12+t] (X, later pre-LN values)
  __shared__ __half tcb[8][1544];   // [g][c*24+j]
  __shared__ float mu8[8][12], rs8[8][12];
  // phase0: X = relu(sum_k rhs*theta)
  for(int o=tid;o<8*768;o+=256){
    int g=o/768; int ct=o-g*768; int c=ct/12; int t=ct-c*12;
    int bn=bn0+g; int b=bn>>10, n=bn&1023;
    float a=0.f;
    #pragma unroll
    for(int k=0;k<3;k++) a+=rhs[((b*3+k)*1024+n)*12+t]*theta[k*64+c];
    XP[g][c*12+t]=fmaxf(a,0.f);
  }
  __syncthreads();
  // phase1: the three gated convs -> tcb  (c outer, g inner => weight addresses shared 8-wide)
  for(int o=tid;o<512;o+=256){
    int c=o>>3, g=o&7;
    { // kernel 3, tau 0..9 -> j 0..9
      float ya[10],yb[10];
      float b0=g3b[c], b1=g3b[c+64];
      #pragma unroll
      for(int t2=0;t2<10;t2++){ya[t2]=b0;yb[t2]=b1;}
      for(int ic=0;ic<64;ic++){
        float xr[12];
        #pragma unroll
        for(int t2=0;t2<12;t2++) xr[t2]=XP[g][ic*12+t2];
        const float* wa=&g3w[(c*64+ic)*3];
        const float* wb=&g3w[((c+64)*64+ic)*3];
        float wa0=wa[0],wa1=wa[1],wa2=wa[2];
        float wb0=wb[0],wb1=wb[1],wb2=wb[2];
        #pragma unroll
        for(int t2=0;t2<10;t2++){
          ya[t2]+=xr[t2]*wa0+xr[t2+1]*wa1+xr[t2+2]*wa2;
          yb[t2]+=xr[t2]*wb0+xr[t2+1]*wb1+xr[t2+2]*wb2;
        }
      }
      #pragma unroll
      for(int t2=0;t2<10;t2++)
        tcb[g][c*24+t2]=__float2half(tanhf(ya[t2])/(1.f+__expf(-yb[t2])));
    }
    { // kernel 5, tau 0..7 -> j 10..17
      float ya[8],yb[8];
      float b0=g5b[c], b1=g5b[c+64];
      #pragma unroll
      for(int t2=0;t2<8;t2++){ya[t2]=b0;yb[t2]=b1;}
      for(int ic=0;ic<64;ic++){
        float xr[12];
        #pragma unroll
        for(int t2=0;t2<12;t2++) xr[t2]=XP[g][ic*12+t2];
        const float* wa=&g5w[(c*64+ic)*5];
        const float* wb=&g5w[((c+64)*64+ic)*5];
        float wav[5],wbv[5];
        #pragma unroll
        for(int dt=0;dt<5;dt++){wav[dt]=wa[dt];wbv[dt]=wb[dt];}
        #pragma unroll
        for(int t2=0;t2<8;t2++){
          #pragma unroll
          for(int dt=0;dt<5;dt++){ ya[t2]+=xr[t2+dt]*wav[dt]; yb[t2]+=xr[t2+dt]*wbv[dt]; }
        }
      }
      #pragma unroll
      for(int t2=0;t2<8;t2++)
        tcb[g][c*24+10+t2]=__float2half(tanhf(ya[t2])/(1.f+__expf(-yb[t2])));
    }
    { // kernel 7, tau 0..5 -> j 18..23
      float ya[6],yb[6];
      float b0=g7b[c], b1=g7b[c+64];
      #pragma unroll
      for(int t2=0;t2<6;t2++){ya[t2]=b0;yb[t2]=b1;}
      for(int ic=0;ic<64;ic++){
        float xr[12];
        #pragma unroll
        for(int t2=0;t2<12;t2++) xr[t2]=XP[g][ic*12+t2];
        const float* wa=&g7w[(c*64+ic)*7];
        const float* wb=&g7w[((c+64)*64+ic)*7];
        float wav[7],wbv[7];
        #pragma unroll
        for(int dt=0;dt<7;dt++){wav[dt]=wa[dt];wbv[dt]=wb[dt];}
        #pragma unroll
        for(int t2=0;t2<6;t2++){
          #pragma unroll
          for(int dt=0;dt<7;dt++){ ya[t2]+=xr[t2+dt]*wav[dt]; yb[t2]+=xr[t2+dt]*wbv[dt]; }
        }
      }
      #pragma unroll
      for(int t2=0;t2<6;t2++)
        tcb[g][c*24+18+t2]=__float2half(tanhf(ya[t2])/(1.f+__expf(-yb[t2])));
    }
  }
  __syncthreads();
  // phase2: time_conv = relu(tc@fcw + fcb); pre = relu(x*rw + rb + time_conv) -> XP
  for(int o=tid;o<8*768;o+=256){
    int g=o/768; int ct=o-g*768; int c=ct/12; int t=ct-c*12;
    float acc=fcb[t];
    #pragma unroll
    for(int j=0;j<24;j++) acc+=__half2float(tcb[g][c*24+j])*fcw[j*12+t];
    acc=fmaxf(acc,0.f);
    int bn=bn0+g;
    float xres=x[bn*12+t]*rw[c]+rb[c];
    XP[g][c*12+t]=fmaxf(xres+acc,0.f);
  }
  __syncthreads();
  // phase3: LN over c per (g,t)
  if(tid<96){
    int g=tid/12, t=tid-(tid/12)*12;
    float s=0.f;
    for(int c=0;c<64;c++) s+=XP[g][c*12+t];
    float mu=s*(1.f/64.f);
    float q=0.f;
    for(int c=0;c<64;c++){float d=XP[g][c*12+t]-mu;q+=d*d;}
    mu8[g][t]=mu; rs8[g][t]=rsqrtf(q*(1.f/64.f)+EPS);
  }
  __syncthreads();
  for(int o=tid;o<8*768;o+=256){
    int g=o/768; int ct=o-g*768; int c=ct/12; int t=ct-c*12;
    out[(long)(bn0+g)*768 + ct]=(XP[g][c*12+t]-mu8[g][t])*rs8[g][t]*gln[c]+bln[c];
  }
}

// ---------------- launch ----------------
extern "C" void kernel_launch(void* const* d_in, const int* in_sizes, int n_in,
                              void* d_out, int out_size, void* d_ws, size_t ws_size,
                              hipStream_t stream){
  const float* x    =(const float*)d_in[0];
  const float* res  =(const float*)d_in[1];
  const float* posT =(const float*)d_in[2];
  const float* gT   =(const float*)d_in[3];
  const float* bT   =(const float*)d_in[4];
  const float* wq   =(const float*)d_in[5];
  const float* wk   =(const float*)d_in[6];
  const float* wv   =(const float*)d_in[7];
  const float* fcW  =(const float*)d_in[8];
  const float* prw  =(const float*)d_in[9];
  const float* prb  =(const float*)d_in[10];
  const float* posS =(const float*)d_in[11];
  const float* gS   =(const float*)d_in[12];
  const float* bS   =(const float*)d_in[13];
  const float* swq  =(const float*)d_in[14];
  const float* swk  =(const float*)d_in[15];
  const float* cheb =(const float*)d_in[16];
  const float* adj  =(const float*)d_in[17];
  const float* cmask=(const float*)d_in[18];
  const float* theta=(const float*)d_in[19];
  const float* g3w=(const float*)d_in[20]; const float* g3b=(const float*)d_in[21];
  const float* g5w=(const float*)d_in[22]; const float* g5b=(const float*)d_in[23];
  const float* g7w=(const float*)d_in[24]; const float* g7b=(const float*)d_in[25];
  const float* fcw=(const float*)d_in[26]; const float* fcb=(const float*)d_in[27];
  const float* rw =(const float*)d_in[28]; const float* rb =(const float*)d_in[29];
  const float* gln=(const float*)d_in[30]; const float* bln=(const float*)d_in[31];

  float* outp=(float*)d_out;
  float* scores = outp + 12582912;          // (B,1,H,T,T) after (B,N,C,T)

  float* wsf=(float*)d_ws;
  float* TEmx = wsf;                        // 196608
  float* qkv  = TEmx + 196608;              // 55296
  float* ctx  = qkv + 55296;                // 18432
  float* TAT  = ctx + 18432;                // 196608
  float* SEmx = TAT + 196608;               // 8388608
  float* SQ   = SEmx + 8388608;             // 1572864
  float* SK   = SQ + 1572864;               // 1572864
  float* rhs  = SK + 1572864;               // 589824

  k1_embedT<<<dim3(192),dim3(256),0,stream>>>(x,posT,gT,bT,TEmx);
  k2_qkv<<<dim3(192),dim3(320),0,stream>>>(TEmx,wq,wk,wv,qkv);
  k3_attn<<<dim3(16),dim3(512),0,stream>>>(qkv,res,scores,ctx);
  k4_tat<<<dim3(192),dim3(256),0,stream>>>(ctx,fcW,TEmx,TAT);
  k5_semx<<<dim3(16384),dim3(256),0,stream>>>(TAT,prw,prb,posS,gS,bS,SEmx);
  k6_sqk<<<dim3(2048),dim3(256),0,stream>>>(SEmx,swq,swk,SQ,SK);
  k7_spatial<<<dim3(3072),dim3(256),0,stream>>>(SQ,SK,adj,cmask,cheb,x,rhs);
  k9_final<<<dim3(2048),dim3(256),0,stream>>>(rhs,theta,g3w,g3b,g5w,g5b,g7w,g7b,
                                              fcw,fcb,rw,rb,gln,bln,x,outp);
}

// Round 2
// 891.522 us; speedup vs baseline: 1.6864x; 1.6864x over previous
//
#include <hip/hip_runtime.h>
#include <hip/hip_fp16.h>

#define EPS 1e-5f

typedef float f32x4 __attribute__((ext_vector_type(4)));
typedef short bf16x8 __attribute__((ext_vector_type(8)));
typedef short bf16x4 __attribute__((ext_vector_type(4)));

__device__ __forceinline__ unsigned short f2b(float f){
  unsigned u=__float_as_uint(f);
  return (unsigned short)((u + 0x7fffu + ((u>>16)&1u))>>16);
}
__device__ __forceinline__ float b2f(unsigned short h){
  return __uint_as_float(((unsigned)h)<<16);
}

// ---------------- helpers ----------------
__device__ __forceinline__ float blockSum256(float v, float* red){
  #pragma unroll
  for(int o=32;o>0;o>>=1) v += __shfl_down(v,o,64);
  int wid = threadIdx.x>>6;
  if((threadIdx.x&63)==0) red[wid]=v;
  __syncthreads();
  if(threadIdx.x==0) red[0]=red[0]+red[1]+red[2]+red[3];
  __syncthreads();
  float r = red[0];
  __syncthreads();
  return r;
}

// ---------------- K0: pack mask/cheb:  mc = bf16(cheb)<<16 | bf16(adj*cmask) ----------------
__global__ __launch_bounds__(256) void k0_prep(const float* __restrict__ adj, const float* __restrict__ cmask,
    const float* __restrict__ cheb, unsigned* __restrict__ mc){
  int i = blockIdx.x*256 + threadIdx.x;           // 3*1024*1024 total
  int nm = i & 1048575;
  mc[i] = (((unsigned)f2b(cheb[i]))<<16) | (unsigned)f2b(adj[nm]*cmask[i]);
}

// ---------------- K1: EmbedT  TEmx[b][t][n] = LN_n(x[b,n,0,t] + posT[t,n]) ----------------
__global__ __launch_bounds__(256) void k1_embedT(const float* __restrict__ x, const float* __restrict__ posT,
    const float* __restrict__ gT, const float* __restrict__ bT, float* __restrict__ TEmx){
  int bt=blockIdx.x; int b=bt/12, t=bt-b*12;
  int tid=threadIdx.x;
  __shared__ float red[4];
  float v[4]; float s=0.f;
  #pragma unroll
  for(int i=0;i<4;i++){ int n=tid+i*256; v[i]=x[(b*1024+n)*12+t]+posT[t*1024+n]; s+=v[i]; }
  s = blockSum256(s, red);
  float mu = s*(1.f/1024.f);
  float q=0.f;
  #pragma unroll
  for(int i=0;i<4;i++){ float d=v[i]-mu; q+=d*d; }
  q = blockSum256(q, red);
  float rstd = rsqrtf(q*(1.f/1024.f)+EPS);
  #pragma unroll
  for(int i=0;i<4;i++){ int n=tid+i*256; TEmx[bt*1024+n]=(v[i]-mu)*rstd*gT[n]+bT[n]; }
}

// ---------------- K2: QKV ----------------
__global__ __launch_bounds__(320) void k2_qkv(const float* __restrict__ TEmx, const float* __restrict__ wq,
    const float* __restrict__ wk, const float* __restrict__ wv, float* __restrict__ qkv){
  int bt=blockIdx.x; int tid=threadIdx.x;
  __shared__ float row[1024];
  for(int i=tid;i<1024;i+=320) row[i]=TEmx[bt*1024+i];
  __syncthreads();
  if(tid<288){
    int m=tid/96, col=tid-m*96;
    const float* w = (m==0)?wq:((m==1)?wk:wv);
    float acc=0.f;
    #pragma unroll 4
    for(int n=0;n<1024;n++) acc += row[n]*w[n*96+col];
    qkv[bt*288+tid]=acc;
  }
}

// ---------------- K3: temporal attn ----------------
__global__ __launch_bounds__(512) void k3_attn(const float* __restrict__ qkv, const float* __restrict__ res_att,
    float* __restrict__ scores_out, float* __restrict__ ctx){
  int b=blockIdx.x; int tid=threadIdx.x;
  __shared__ float sS[432];
  __shared__ float sA[432];
  if(tid<432){
    int h=tid/144; int r=tid-h*144; int q=r/12; int k2=r-q*12;
    const float* Qr=&qkv[(b*12+q)*288 + h*32];
    const float* Kr=&qkv[(b*12+k2)*288 + 96 + h*32];
    float acc=0.f;
    #pragma unroll
    for(int d=0;d<32;d++) acc+=Qr[d]*Kr[d];
    acc = acc*0.17677669529663687f + res_att[(b*3+h)*144 + q*12 + k2];
    sS[h*144+q*12+k2]=acc;
    scores_out[(b*3+h)*144 + q*12 + k2]=acc;
  }
  __syncthreads();
  if(tid<36){
    int h=tid/12, k2=tid-(tid/12)*12;
    float mx=-1e30f;
    for(int q=0;q<12;q++) mx=fmaxf(mx,sS[h*144+q*12+k2]);
    float sum=0.f;
    for(int q=0;q<12;q++){ float e=__expf(sS[h*144+q*12+k2]-mx); sA[h*144+q*12+k2]=e; sum+=e; }
    float inv=1.f/sum;
    for(int q=0;q<12;q++) sA[h*144+q*12+k2]*=inv;
  }
  __syncthreads();
  for(int o=tid;o<1152;o+=512){
    int h=o/384; int r=o-h*384; int q=r/32; int d=r-q*32;
    float acc=0.f;
    #pragma unroll
    for(int k2=0;k2<12;k2++) acc += sA[h*144+q*12+k2]*qkv[(b*12+k2)*288+192+h*32+d];
    ctx[(b*12+q)*96 + h*32 + d]=acc;
  }
}

// ---------------- K4: TATout ----------------
__global__ __launch_bounds__(256) void k4_tat(const float* __restrict__ ctx, const float* __restrict__ fcW,
    const float* __restrict__ TEmx, float* __restrict__ TAT){
  int bt=blockIdx.x; int tid=threadIdx.x;
  __shared__ float c96[96];
  __shared__ float red[4];
  if(tid<96) c96[tid]=ctx[bt*96+tid];
  __syncthreads();
  float v[4]; float s=0.f;
  #pragma unroll
  for(int i=0;i<4;i++){
    int n=tid+i*256;
    float acc=TEmx[bt*1024+n];
    #pragma unroll 4
    for(int j=0;j<96;j++) acc += c96[j]*fcW[j*1024+n];
    v[i]=acc; s+=acc;
  }
  s=blockSum256(s,red);
  float mu=s*(1.f/1024.f);
  float q=0.f;
  #pragma unroll
  for(int i=0;i<4;i++){float d=v[i]-mu;q+=d*d;}
  q=blockSum256(q,red);
  float rstd=rsqrtf(q*(1.f/1024.f)+EPS);
  #pragma unroll
  for(int i=0;i<4;i++){int n=tid+i*256; TAT[bt*1024+n]=(v[i]-mu)*rstd;}
}

// ---------------- K5: SEmx (bf16 out) ----------------
__global__ __launch_bounds__(256) void k5_semx(const float* __restrict__ TAT, const float* __restrict__ pre_w,
    const float* __restrict__ pre_b, const float* __restrict__ posS, const float* __restrict__ gS,
    const float* __restrict__ bS, unsigned short* __restrict__ SEb){
  int bn=blockIdx.x; int b=bn>>10, n=bn&1023; int tid=threadIdx.x;
  __shared__ float tv[12];
  __shared__ float red[4];
  if(tid<12) tv[tid]=TAT[(b*12+tid)*1024+n];
  __syncthreads();
  float v[2]; float s=0.f;
  #pragma unroll
  for(int i=0;i<2;i++){
    int d=tid+i*256;
    float acc=pre_b[d]+posS[n*512+d];
    #pragma unroll
    for(int t=0;t<12;t++) acc += tv[t]*pre_w[d*12+t];
    v[i]=acc; s+=acc;
  }
  s=blockSum256(s,red);
  float mu=s*(1.f/512.f);
  float q=0.f;
  #pragma unroll
  for(int i=0;i<2;i++){float d2=v[i]-mu;q+=d2*d2;}
  q=blockSum256(q,red);
  float rstd=rsqrtf(q*(1.f/512.f)+EPS);
  #pragma unroll
  for(int i=0;i<2;i++){int d=tid+i*256; SEb[bn*512+d]=f2b((v[i]-mu)*rstd*gS[d]+bS[d]);}
}

// ---------------- K6: SQ/SK (bf16 in/out) ----------------
__global__ __launch_bounds__(256) void k6_sqk(const unsigned short* __restrict__ SEb, const float* __restrict__ swq,
    const float* __restrict__ swk, unsigned short* __restrict__ SQb, unsigned short* __restrict__ SKb){
  int bn0=blockIdx.x*8; int tid=threadIdx.x;
  __shared__ float rows[8][512];
  for(int i=tid;i<1024;i+=256){
    int r=i>>7, j=(i&127)*4;
    const unsigned short* p=&SEb[(bn0+r)*512+j];
    rows[r][j]=b2f(p[0]); rows[r][j+1]=b2f(p[1]); rows[r][j+2]=b2f(p[2]); rows[r][j+3]=b2f(p[3]);
  }
  __syncthreads();
  if(tid<192){
    int m=tid/96, col=tid-(tid/96)*96; int k=col>>5, d=col&31;
    const float* w = m? swk:swq;
    float acc[8];
    #pragma unroll
    for(int r=0;r<8;r++) acc[r]=0.f;
    for(int j=0;j<512;j++){
      float wv2=w[j*96+col];
      #pragma unroll
      for(int r=0;r<8;r++) acc[r]+=rows[r][j]*wv2;
    }
    unsigned short* dst = m? SKb:SQb;
    #pragma unroll
    for(int r=0;r<8;r++){
      int bn=bn0+r; int b=bn>>10, n=bn&1023;
      dst[((b*3+k)*1024+n)*32+d]=f2b(acc[r]);
    }
  }
}

// ---------------- K7: fused spatial attention + graph conv, MFMA flash style ----------------
// block = (b,k, 64 m's); 4 waves, each owns a 16-m strip.
// S[n][m] = SQ[n]·SK[m]*scale + mask ; col-softmax over n (online, per 128-n chunk);
// O^T[t][m] += x^T · (exp(S-M)*cheb)  accumulated via MFMA with in-register P fragments.
#define SCALE7 0.17677669529663687f
__global__ __launch_bounds__(256) void k7_spatial(const unsigned short* __restrict__ SQb,
    const unsigned short* __restrict__ SKb, const unsigned* __restrict__ mc,
    const float* __restrict__ x, float* __restrict__ rhsT){
  const int blk=blockIdx.x;
  const int mt=blk&15, bk=blk>>4;
  const int k=bk%3, b=bk/3;
  const int m0=mt*64;
  const int tid=threadIdx.x;
  const int w=tid>>6, lane=tid&63, g=lane>>4, col=lane&15;

  __shared__ unsigned short xs[16*128];   // x^T chunk, bf16, XOR-swizzled rows

  const int m_glob = m0 + w*16 + col;
  bf16x8 bfrag = *(const bf16x8*)&SKb[((bk<<10)+m_glob)*32 + g*8];   // B: SK row m, d=g*8..+7

  f32x4 O = {0.f,0.f,0.f,0.f};
  float mrun=-1e30f, lrun=0.f;

  const float* xb = x + b*12288;
  const unsigned* mck = mc + k*1048576;
  const int swz = (col&7)<<3;   // PV A-frag row t == col

  // zero pad rows t=12..15 once
  for(int i=tid;i<512;i+=256){ int t=12+(i>>7), n=i&127; xs[t*128 + (n ^ ((t&7)<<3))]=0; }

  for(int ch=0; ch<8; ++ch){
    const int n0 = ch<<7;
    __syncthreads();
    for(int i=tid;i<1536;i+=256){
      int n=i/12, t=i-n*12;
      xs[t*128 + (n ^ ((t&7)<<3))] = f2b(xb[n0*12 + i]);
    }
    __syncthreads();

    // QK: 8 n-tiles
    f32x4 acc[8];
    #pragma unroll
    for(int nt=0;nt<8;nt++){
      bf16x8 afrag = *(const bf16x8*)&SQb[((bk<<10) + n0 + nt*16 + col)*32 + g*8];
      f32x4 z = {0.f,0.f,0.f,0.f};
      acc[nt] = __builtin_amdgcn_mfma_f32_16x16x32_bf16(afrag, bfrag, z, 0,0,0);
    }
    // packed mask/cheb loads (coalesced over m)
    unsigned mcv[8][4];
    #pragma unroll
    for(int nt=0;nt<8;nt++){
      int nbase = n0 + nt*16 + g*4;
      #pragma unroll
      for(int r=0;r<4;r++) mcv[nt][r] = mck[(nbase+r)*1024 + m_glob];
    }
    float cmax = -1e30f;
    #pragma unroll
    for(int nt=0;nt<8;nt++){
      #pragma unroll
      for(int r=0;r<4;r++){
        float s = acc[nt][r]*SCALE7 + __uint_as_float(mcv[nt][r]<<16);
        acc[nt][r]=s;
        cmax=fmaxf(cmax,s);
      }
    }
    cmax = fmaxf(cmax, __shfl_xor(cmax,16,64));
    cmax = fmaxf(cmax, __shfl_xor(cmax,32,64));
    float mnew = fmaxf(mrun, cmax);
    float alpha = __expf(mrun - mnew);
    float lsum = 0.f;
    unsigned short pb[8][4];
    #pragma unroll
    for(int nt=0;nt<8;nt++){
      #pragma unroll
      for(int r=0;r<4;r++){
        float e = __expf(acc[nt][r] - mnew);
        lsum += e;
        pb[nt][r] = f2b(e * __uint_as_float(mcv[nt][r] & 0xffff0000u));
      }
    }
    lsum += __shfl_xor(lsum,16,64);
    lsum += __shfl_xor(lsum,32,64);
    lrun = lrun*alpha + lsum;
    mrun = mnew;
    O[0]*=alpha; O[1]*=alpha; O[2]*=alpha; O[3]*=alpha;

    // PV: O^T[t][m] += x^T · P  (k-slot permutation consistent in A and B)
    #pragma unroll
    for(int c=0;c<4;c++){
      bf16x8 pf;
      #pragma unroll
      for(int j=0;j<4;j++){ pf[j]=(short)pb[2*c][j]; pf[j+4]=(short)pb[2*c+1][j]; }
      int nlo = c*32 + g*4;
      bf16x4 lo = *(const bf16x4*)&xs[col*128 + (nlo ^ swz)];
      bf16x4 hi = *(const bf16x4*)&xs[col*128 + ((nlo+16) ^ swz)];
      bf16x8 ax;
      #pragma unroll
      for(int j=0;j<4;j++){ ax[j]=lo[j]; ax[j+4]=hi[j]; }
      O = __builtin_amdgcn_mfma_f32_16x16x32_bf16(ax, pf, O, 0,0,0);
    }
  }
  float inv = 1.f/lrun;
  #pragma unroll
  for(int r=0;r<4;r++){
    int t = g*4+r;
    if(t<12) rhsT[((bk*12+t)<<10) + m_glob] = O[r]*inv;
  }
}

// ---------------- K9: theta-contract + GTU convs + fc + residual + final LN ----------------
__global__ __launch_bounds__(256) void k9_final(const float* __restrict__ rhsT, const float* __restrict__ theta,
    const float* __restrict__ g3w, const float* __restrict__ g3b,
    const float* __restrict__ g5w, const float* __restrict__ g5b,
    const float* __restrict__ g7w, const float* __restrict__ g7b,
    const float* __restrict__ fcw, const float* __restrict__ fcb,
    const float* __restrict__ rw, const float* __restrict__ rb,
    const float* __restrict__ gln, const float* __restrict__ bln,
    const float* __restrict__ x, float* __restrict__ out){
  int bn0=blockIdx.x*8;
  int tid=threadIdx.x;
  __shared__ float XP[8][772];
  __shared__ __half tcb[8][1544];
  __shared__ float mu8[8][12], rs8[8][12];
  __shared__ float rstage[3][12][8];
  const int b=bn0>>10, nloc=bn0&1023;
  for(int i=tid;i<288;i+=256){
    int kk=i/96; int rem=i-kk*96; int t=rem>>3; int g=rem&7;
    rstage[kk][t][g]=rhsT[((b*3+kk)*12+t)*1024 + nloc + g];
  }
  __syncthreads();
  // phase0: X = relu(sum_k rhs*theta)
  for(int o=tid;o<8*768;o+=256){
    int g=o/768; int ct=o-g*768; int c=ct/12; int t=ct-c*12;
    float a=0.f;
    #pragma unroll
    for(int kk=0;kk<3;kk++) a+=rstage[kk][t][g]*theta[kk*64+c];
    XP[g][c*12+t]=fmaxf(a,0.f);
  }
  __syncthreads();
  // phase1: gated convs
  for(int o=tid;o<512;o+=256){
    int c=o>>3, g=o&7;
    {
      float ya[10],yb[10];
      float b0=g3b[c], b1=g3b[c+64];
      #pragma unroll
      for(int t2=0;t2<10;t2++){ya[t2]=b0;yb[t2]=b1;}
      for(int ic=0;ic<64;ic++){
        float xr[12];
        #pragma unroll
        for(int t2=0;t2<12;t2++) xr[t2]=XP[g][ic*12+t2];
        const float* wa=&g3w[(c*64+ic)*3];
        const float* wb=&g3w[((c+64)*64+ic)*3];
        float wa0=wa[0],wa1=wa[1],wa2=wa[2];
        float wb0=wb[0],wb1=wb[1],wb2=wb[2];
        #pragma unroll
        for(int t2=0;t2<10;t2++){
          ya[t2]+=xr[t2]*wa0+xr[t2+1]*wa1+xr[t2+2]*wa2;
          yb[t2]+=xr[t2]*wb0+xr[t2+1]*wb1+xr[t2+2]*wb2;
        }
      }
      #pragma unroll
      for(int t2=0;t2<10;t2++)
        tcb[g][c*24+t2]=__float2half(tanhf(ya[t2])/(1.f+__expf(-yb[t2])));
    }
    {
      float ya[8],yb[8];
      float b0=g5b[c], b1=g5b[c+64];
      #pragma unroll
      for(int t2=0;t2<8;t2++){ya[t2]=b0;yb[t2]=b1;}
      for(int ic=0;ic<64;ic++){
        float xr[12];
        #pragma unroll
        for(int t2=0;t2<12;t2++) xr[t2]=XP[g][ic*12+t2];
        const float* wa=&g5w[(c*64+ic)*5];
        const float* wb=&g5w[((c+64)*64+ic)*5];
        float wav[5],wbv[5];
        #pragma unroll
        for(int dt=0;dt<5;dt++){wav[dt]=wa[dt];wbv[dt]=wb[dt];}
        #pragma unroll
        for(int t2=0;t2<8;t2++){
          #pragma unroll
          for(int dt=0;dt<5;dt++){ ya[t2]+=xr[t2+dt]*wav[dt]; yb[t2]+=xr[t2+dt]*wbv[dt]; }
        }
      }
      #pragma unroll
      for(int t2=0;t2<8;t2++)
        tcb[g][c*24+10+t2]=__float2half(tanhf(ya[t2])/(1.f+__expf(-yb[t2])));
    }
    {
      float ya[6],yb[6];
      float b0=g7b[c], b1=g7b[c+64];
      #pragma unroll
      for(int t2=0;t2<6;t2++){ya[t2]=b0;yb[t2]=b1;}
      for(int ic=0;ic<64;ic++){
        float xr[12];
        #pragma unroll
        for(int t2=0;t2<12;t2++) xr[t2]=XP[g][ic*12+t2];
        const float* wa=&g7w[(c*64+ic)*7];
        const float* wb=&g7w[((c+64)*64+ic)*7];
        float wav[7],wbv[7];
        #pragma unroll
        for(int dt=0;dt<7;dt++){wav[dt]=wa[dt];wbv[dt]=wb[dt];}
        #pragma unroll
        for(int t2=0;t2<6;t2++){
          #pragma unroll
          for(int dt=0;dt<7;dt++){ ya[t2]+=xr[t2+dt]*wav[dt]; yb[t2]+=xr[t2+dt]*wbv[dt]; }
        }
      }
      #pragma unroll
      for(int t2=0;t2<6;t2++)
        tcb[g][c*24+18+t2]=__float2half(tanhf(ya[t2])/(1.f+__expf(-yb[t2])));
    }
  }
  __syncthreads();
  // phase2: fc + residual + relu
  for(int o=tid;o<8*768;o+=256){
    int g=o/768; int ct=o-g*768; int c=ct/12; int t=ct-c*12;
    float acc=fcb[t];
    #pragma unroll
    for(int j=0;j<24;j++) acc+=__half2float(tcb[g][c*24+j])*fcw[j*12+t];
    acc=fmaxf(acc,0.f);
    int bn=bn0+g;
    float xres=x[bn*12+t]*rw[c]+rb[c];
    XP[g][c*12+t]=fmaxf(xres+acc,0.f);
  }
  __syncthreads();
  // phase3: LN over c
  if(tid<96){
    int g=tid/12, t=tid-(tid/12)*12;
    float s=0.f;
    for(int c=0;c<64;c++) s+=XP[g][c*12+t];
    float mu=s*(1.f/64.f);
    float q=0.f;
    for(int c=0;c<64;c++){float d=XP[g][c*12+t]-mu;q+=d*d;}
    mu8[g][t]=mu; rs8[g][t]=rsqrtf(q*(1.f/64.f)+EPS);
  }
  __syncthreads();
  for(int o=tid;o<8*768;o+=256){
    int g=o/768; int ct=o-g*768; int c=ct/12; int t=ct-c*12;
    out[(long)(bn0+g)*768 + ct]=(XP[g][c*12+t]-mu8[g][t])*rs8[g][t]*gln[c]+bln[c];
  }
}

// ---------------- launch ----------------
extern "C" void kernel_launch(void* const* d_in, const int* in_sizes, int n_in,
                              void* d_out, int out_size, void* d_ws, size_t ws_size,
                              hipStream_t stream){
  const float* x    =(const float*)d_in[0];
  const float* res  =(const float*)d_in[1];
  const float* posT =(const float*)d_in[2];
  const float* gT   =(const float*)d_in[3];
  const float* bT   =(const float*)d_in[4];
  const float* wq   =(const float*)d_in[5];
  const float* wk   =(const float*)d_in[6];
  const float* wv   =(const float*)d_in[7];
  const float* fcW  =(const float*)d_in[8];
  const float* prw  =(const float*)d_in[9];
  const float* prb  =(const float*)d_in[10];
  const float* posS =(const float*)d_in[11];
  const float* gS   =(const float*)d_in[12];
  const float* bS   =(const float*)d_in[13];
  const float* swq  =(const float*)d_in[14];
  const float* swk  =(const float*)d_in[15];
  const float* cheb =(const float*)d_in[16];
  const float* adj  =(const float*)d_in[17];
  const float* cmask=(const float*)d_in[18];
  const float* theta=(const float*)d_in[19];
  const float* g3w=(const float*)d_in[20]; const float* g3b=(const float*)d_in[21];
  const float* g5w=(const float*)d_in[22]; const float* g5b=(const float*)d_in[23];
  const float* g7w=(const float*)d_in[24]; const float* g7b=(const float*)d_in[25];
  const float* fcw=(const float*)d_in[26]; const float* fcb=(const float*)d_in[27];
  const float* rw =(const float*)d_in[28]; const float* rb =(const float*)d_in[29];
  const float* gln=(const float*)d_in[30]; const float* bln=(const float*)d_in[31];

  float* outp=(float*)d_out;
  float* scores = outp + 12582912;

  float* wsf=(float*)d_ws;
  float* TEmx = wsf;                          // 196608 f
  float* qkv  = TEmx + 196608;                // 55296 f
  float* ctx  = qkv + 55296;                  // 18432 f
  float* TAT  = ctx + 18432;                  // 196608 f
  unsigned short* SEb = (unsigned short*)(TAT + 196608);       // 8388608 u16 = 4194304 f
  unsigned short* SQb = (unsigned short*)((float*)SEb + 4194304); // 1572864 u16 = 786432 f
  unsigned short* SKb = (unsigned short*)((float*)SQb + 786432);  // 1572864 u16 = 786432 f
  unsigned* mc = (unsigned*)((float*)SKb + 786432);            // 3145728 u32
  float* rhsT  = (float*)mc + 3145728;                         // 589824 f

  k0_prep<<<dim3(12288),dim3(256),0,stream>>>(adj,cmask,cheb,mc);
  k1_embedT<<<dim3(192),dim3(256),0,stream>>>(x,posT,gT,bT,TEmx);
  k2_qkv<<<dim3(192),dim3(320),0,stream>>>(TEmx,wq,wk,wv,qkv);
  k3_attn<<<dim3(16),dim3(512),0,stream>>>(qkv,res,scores,ctx);
  k4_tat<<<dim3(192),dim3(256),0,stream>>>(ctx,fcW,TEmx,TAT);
  k5_semx<<<dim3(16384),dim3(256),0,stream>>>(TAT,prw,prb,posS,gS,bS,SEb);
  k6_sqk<<<dim3(2048),dim3(256),0,stream>>>(SEb,swq,swk,SQb,SKb);
  k7_spatial<<<dim3(768),dim3(256),0,stream>>>(SQb,SKb,mc,x,rhsT);
  k9_final<<<dim3(2048),dim3(256),0,stream>>>(rhsT,theta,g3w,g3b,g5w,g5b,g7w,g7b,
                                              fcw,fcb,rw,rb,gln,bln,x,outp);
}

// Round 3
// 469.505 us; speedup vs baseline: 3.2022x; 1.8989x over previous
//
#include <hip/hip_runtime.h>
#include <hip/hip_fp16.h>

#define EPS 1e-5f

typedef float f32x4 __attribute__((ext_vector_type(4)));
typedef short bf16x8 __attribute__((ext_vector_type(8)));
typedef short bf16x4 __attribute__((ext_vector_type(4)));

__device__ __forceinline__ unsigned short f2b(float f){
  unsigned u=__float_as_uint(f);
  return (unsigned short)((u + 0x7fffu + ((u>>16)&1u))>>16);
}
__device__ __forceinline__ float b2f(unsigned short h){
  return __uint_as_float(((unsigned)h)<<16);
}

// ---------------- helpers ----------------
__device__ __forceinline__ float blockSum256(float v, float* red){
  #pragma unroll
  for(int o=32;o>0;o>>=1) v += __shfl_down(v,o,64);
  int wid = threadIdx.x>>6;
  if((threadIdx.x&63)==0) red[wid]=v;
  __syncthreads();
  if(threadIdx.x==0) red[0]=red[0]+red[1]+red[2]+red[3];
  __syncthreads();
  float r = red[0];
  __syncthreads();
  return r;
}

// ---------------- K0: pack mask/cheb ----------------
__global__ __launch_bounds__(256) void k0_prep(const float* __restrict__ adj, const float* __restrict__ cmask,
    const float* __restrict__ cheb, unsigned* __restrict__ mc){
  int i = blockIdx.x*256 + threadIdx.x;
  int nm = i & 1048575;
  mc[i] = (((unsigned)f2b(cheb[i]))<<16) | (unsigned)f2b(adj[nm]*cmask[i]);
}

// ---------------- K1: EmbedT ----------------
__global__ __launch_bounds__(256) void k1_embedT(const float* __restrict__ x, const float* __restrict__ posT,
    const float* __restrict__ gT, const float* __restrict__ bT, float* __restrict__ TEmx){
  int bt=blockIdx.x; int b=bt/12, t=bt-b*12;
  int tid=threadIdx.x;
  __shared__ float red[4];
  float v[4]; float s=0.f;
  #pragma unroll
  for(int i=0;i<4;i++){ int n=tid+i*256; v[i]=x[(b*1024+n)*12+t]+posT[t*1024+n]; s+=v[i]; }
  s = blockSum256(s, red);
  float mu = s*(1.f/1024.f);
  float q=0.f;
  #pragma unroll
  for(int i=0;i<4;i++){ float d=v[i]-mu; q+=d*d; }
  q = blockSum256(q, red);
  float rstd = rsqrtf(q*(1.f/1024.f)+EPS);
  #pragma unroll
  for(int i=0;i<4;i++){ int n=tid+i*256; TEmx[bt*1024+n]=(v[i]-mu)*rstd*gT[n]+bT[n]; }
}

// ---------------- K2: QKV ----------------
__global__ __launch_bounds__(320) void k2_qkv(const float* __restrict__ TEmx, const float* __restrict__ wq,
    const float* __restrict__ wk, const float* __restrict__ wv, float* __restrict__ qkv){
  int bt=blockIdx.x; int tid=threadIdx.x;
  __shared__ float row[1024];
  for(int i=tid;i<1024;i+=320) row[i]=TEmx[bt*1024+i];
  __syncthreads();
  if(tid<288){
    int m=tid/96, col=tid-m*96;
    const float* w = (m==0)?wq:((m==1)?wk:wv);
    float acc=0.f;
    #pragma unroll 4
    for(int n=0;n<1024;n++) acc += row[n]*w[n*96+col];
    qkv[bt*288+tid]=acc;
  }
}

// ---------------- K3: temporal attn ----------------
__global__ __launch_bounds__(512) void k3_attn(const float* __restrict__ qkv, const float* __restrict__ res_att,
    float* __restrict__ scores_out, float* __restrict__ ctx){
  int b=blockIdx.x; int tid=threadIdx.x;
  __shared__ float sS[432];
  __shared__ float sA[432];
  if(tid<432){
    int h=tid/144; int r=tid-h*144; int q=r/12; int k2=r-q*12;
    const float* Qr=&qkv[(b*12+q)*288 + h*32];
    const float* Kr=&qkv[(b*12+k2)*288 + 96 + h*32];
    float acc=0.f;
    #pragma unroll
    for(int d=0;d<32;d++) acc+=Qr[d]*Kr[d];
    acc = acc*0.17677669529663687f + res_att[(b*3+h)*144 + q*12 + k2];
    sS[h*144+q*12+k2]=acc;
    scores_out[(b*3+h)*144 + q*12 + k2]=acc;
  }
  __syncthreads();
  if(tid<36){
    int h=tid/12, k2=tid-(tid/12)*12;
    float mx=-1e30f;
    for(int q=0;q<12;q++) mx=fmaxf(mx,sS[h*144+q*12+k2]);
    float sum=0.f;
    for(int q=0;q<12;q++){ float e=__expf(sS[h*144+q*12+k2]-mx); sA[h*144+q*12+k2]=e; sum+=e; }
    float inv=1.f/sum;
    for(int q=0;q<12;q++) sA[h*144+q*12+k2]*=inv;
  }
  __syncthreads();
  for(int o=tid;o<1152;o+=512){
    int h=o/384; int r=o-h*384; int q=r/32; int d=r-q*32;
    float acc=0.f;
    #pragma unroll
    for(int k2=0;k2<12;k2++) acc += sA[h*144+q*12+k2]*qkv[(b*12+k2)*288+192+h*32+d];
    ctx[(b*12+q)*96 + h*32 + d]=acc;
  }
}

// ---------------- K4: TATout ----------------
__global__ __launch_bounds__(256) void k4_tat(const float* __restrict__ ctx, const float* __restrict__ fcW,
    const float* __restrict__ TEmx, float* __restrict__ TAT){
  int bt=blockIdx.x; int tid=threadIdx.x;
  __shared__ float c96[96];
  __shared__ float red[4];
  if(tid<96) c96[tid]=ctx[bt*96+tid];
  __syncthreads();
  float v[4]; float s=0.f;
  #pragma unroll
  for(int i=0;i<4;i++){
    int n=tid+i*256;
    float acc=TEmx[bt*1024+n];
    #pragma unroll 4
    for(int j=0;j<96;j++) acc += c96[j]*fcW[j*1024+n];
    v[i]=acc; s+=acc;
  }
  s=blockSum256(s,red);
  float mu=s*(1.f/1024.f);
  float q=0.f;
  #pragma unroll
  for(int i=0;i<4;i++){float d=v[i]-mu;q+=d*d;}
  q=blockSum256(q,red);
  float rstd=rsqrtf(q*(1.f/1024.f)+EPS);
  #pragma unroll
  for(int i=0;i<4;i++){int n=tid+i*256; TAT[bt*1024+n]=(v[i]-mu)*rstd;}
}

// ---------------- K5: SEmx (bf16 out) ----------------
__global__ __launch_bounds__(256) void k5_semx(const float* __restrict__ TAT, const float* __restrict__ pre_w,
    const float* __restrict__ pre_b, const float* __restrict__ posS, const float* __restrict__ gS,
    const float* __restrict__ bS, unsigned short* __restrict__ SEb){
  int bn=blockIdx.x; int b=bn>>10, n=bn&1023; int tid=threadIdx.x;
  __shared__ float tv[12];
  __shared__ float red[4];
  if(tid<12) tv[tid]=TAT[(b*12+tid)*1024+n];
  __syncthreads();
  float v[2]; float s=0.f;
  #pragma unroll
  for(int i=0;i<2;i++){
    int d=tid+i*256;
    float acc=pre_b[d]+posS[n*512+d];
    #pragma unroll
    for(int t=0;t<12;t++) acc += tv[t]*pre_w[d*12+t];
    v[i]=acc; s+=acc;
  }
  s=blockSum256(s,red);
  float mu=s*(1.f/512.f);
  float q=0.f;
  #pragma unroll
  for(int i=0;i<2;i++){float d2=v[i]-mu;q+=d2*d2;}
  q=blockSum256(q,red);
  float rstd=rsqrtf(q*(1.f/512.f)+EPS);
  #pragma unroll
  for(int i=0;i<2;i++){int d=tid+i*256; SEb[bn*512+d]=f2b((v[i]-mu)*rstd*gS[d]+bS[d]);}
}

// ---------------- K6: SQ/SK (bf16 in/out) ----------------
__global__ __launch_bounds__(256) void k6_sqk(const unsigned short* __restrict__ SEb, const float* __restrict__ swq,
    const float* __restrict__ swk, unsigned short* __restrict__ SQb, unsigned short* __restrict__ SKb){
  int bn0=blockIdx.x*8; int tid=threadIdx.x;
  __shared__ float rows[8][512];
  for(int i=tid;i<1024;i+=256){
    int r=i>>7, j=(i&127)*4;
    const unsigned short* p=&SEb[(bn0+r)*512+j];
    rows[r][j]=b2f(p[0]); rows[r][j+1]=b2f(p[1]); rows[r][j+2]=b2f(p[2]); rows[r][j+3]=b2f(p[3]);
  }
  __syncthreads();
  if(tid<192){
    int m=tid/96, col=tid-(tid/96)*96; int k=col>>5, d=col&31;
    const float* w = m? swk:swq;
    float acc[8];
    #pragma unroll
    for(int r=0;r<8;r++) acc[r]=0.f;
    for(int j=0;j<512;j++){
      float wv2=w[j*96+col];
      #pragma unroll
      for(int r=0;r<8;r++) acc[r]+=rows[r][j]*wv2;
    }
    unsigned short* dst = m? SKb:SQb;
    #pragma unroll
    for(int r=0;r<8;r++){
      int bn=bn0+r; int b=bn>>10, n=bn&1023;
      dst[((b*3+k)*1024+n)*32+d]=f2b(acc[r]);
    }
  }
}

// ---------------- K7: fused spatial attention + graph conv (MFMA flash) ----------------
#define SCALE7 0.17677669529663687f
__global__ __launch_bounds__(256) void k7_spatial(const unsigned short* __restrict__ SQb,
    const unsigned short* __restrict__ SKb, const unsigned* __restrict__ mc,
    const float* __restrict__ x, float* __restrict__ rhsT){
  const int blk=blockIdx.x;
  const int mt=blk&15, bk=blk>>4;
  const int k=bk%3, b=bk/3;
  const int m0=mt*64;
  const int tid=threadIdx.x;
  const int w=tid>>6, lane=tid&63, g=lane>>4, col=lane&15;

  __shared__ unsigned short xs[16*128];

  const int m_glob = m0 + w*16 + col;
  bf16x8 bfrag = *(const bf16x8*)&SKb[((bk<<10)+m_glob)*32 + g*8];

  f32x4 O = {0.f,0.f,0.f,0.f};
  float mrun=-1e30f, lrun=0.f;

  const float* xb = x + b*12288;
  const unsigned* mck = mc + k*1048576;
  const int swz = (col&7)<<3;

  for(int i=tid;i<512;i+=256){ int t=12+(i>>7), n=i&127; xs[t*128 + (n ^ ((t&7)<<3))]=0; }

  for(int ch=0; ch<8; ++ch){
    const int n0 = ch<<7;
    __syncthreads();
    for(int i=tid;i<1536;i+=256){
      int n=i/12, t=i-n*12;
      xs[t*128 + (n ^ ((t&7)<<3))] = f2b(xb[n0*12 + i]);
    }
    __syncthreads();

    f32x4 acc[8];
    #pragma unroll
    for(int nt=0;nt<8;nt++){
      bf16x8 afrag = *(const bf16x8*)&SQb[((bk<<10) + n0 + nt*16 + col)*32 + g*8];
      f32x4 z = {0.f,0.f,0.f,0.f};
      acc[nt] = __builtin_amdgcn_mfma_f32_16x16x32_bf16(afrag, bfrag, z, 0,0,0);
    }
    unsigned mcv[8][4];
    #pragma unroll
    for(int nt=0;nt<8;nt++){
      int nbase = n0 + nt*16 + g*4;
      #pragma unroll
      for(int r=0;r<4;r++) mcv[nt][r] = mck[(nbase+r)*1024 + m_glob];
    }
    float cmax = -1e30f;
    #pragma unroll
    for(int nt=0;nt<8;nt++){
      #pragma unroll
      for(int r=0;r<4;r++){
        float s = acc[nt][r]*SCALE7 + __uint_as_float(mcv[nt][r]<<16);
        acc[nt][r]=s;
        cmax=fmaxf(cmax,s);
      }
    }
    cmax = fmaxf(cmax, __shfl_xor(cmax,16,64));
    cmax = fmaxf(cmax, __shfl_xor(cmax,32,64));
    float mnew = fmaxf(mrun, cmax);
    float alpha = __expf(mrun - mnew);
    float lsum = 0.f;
    unsigned short pb[8][4];
    #pragma unroll
    for(int nt=0;nt<8;nt++){
      #pragma unroll
      for(int r=0;r<4;r++){
        float e = __expf(acc[nt][r] - mnew);
        lsum += e;
        pb[nt][r] = f2b(e * __uint_as_float(mcv[nt][r] & 0xffff0000u));
      }
    }
    lsum += __shfl_xor(lsum,16,64);
    lsum += __shfl_xor(lsum,32,64);
    lrun = lrun*alpha + lsum;
    mrun = mnew;
    O[0]*=alpha; O[1]*=alpha; O[2]*=alpha; O[3]*=alpha;

    #pragma unroll
    for(int c=0;c<4;c++){
      bf16x8 pf;
      #pragma unroll
      for(int j=0;j<4;j++){ pf[j]=(short)pb[2*c][j]; pf[j+4]=(short)pb[2*c+1][j]; }
      int nlo = c*32 + g*4;
      bf16x4 lo = *(const bf16x4*)&xs[col*128 + (nlo ^ swz)];
      bf16x4 hi = *(const bf16x4*)&xs[col*128 + ((nlo+16) ^ swz)];
      bf16x8 ax;
      #pragma unroll
      for(int j=0;j<4;j++){ ax[j]=lo[j]; ax[j+4]=hi[j]; }
      O = __builtin_amdgcn_mfma_f32_16x16x32_bf16(ax, pf, O, 0,0,0);
    }
  }
  float inv = 1.f/lrun;
  #pragma unroll
  for(int r=0;r<4;r++){
    int t = g*4+r;
    if(t<12) rhsT[((bk*12+t)<<10) + m_glob] = O[r]*inv;
  }
}

// ---------------- K8: pack conv weights into MFMA A-fragment layout ----------------
// Apack[frag][lane][8] bf16 ; frag = conv_off + rt*ks + s ; k-order = dt*64+ic
__global__ __launch_bounds__(256) void k8_prep(const float* __restrict__ g3w, const float* __restrict__ g5w,
    const float* __restrict__ g7w, unsigned short* __restrict__ Apack){
  int idx = blockIdx.x*256+threadIdx.x;      // 240*64 = 15360
  if(idx>=15360) return;
  int frag=idx>>6, lane=idx&63;
  int rt, s, kappa; const float* W;
  if(frag<48){ rt=frag/6; s=frag-rt*6; kappa=3; W=g3w; }
  else if(frag<128){ int f=frag-48; rt=f/10; s=f-rt*10; kappa=5; W=g5w; }
  else { int f=frag-128; rt=f/14; s=f-rt*14; kappa=7; W=g7w; }
  int c = rt*16 + (lane&15);
  int dt = s>>1, ic0=(s&1)*32 + (lane>>4)*8;
  #pragma unroll
  for(int j=0;j<8;j++) Apack[idx*8+j]=f2b(W[(c*64+ic0+j)*kappa + dt]);
}

// ---------------- K9: theta-contract + MFMA GTU convs + fc + residual + final LN ----------------
// 8 (b,n) per block, 4 waves. Wave w owns channel row-tiles {w, w+4} = (c, c+64) pairs.
// Cols = (tau2, g). B-frags from swizzled LDS Xl[t][g][ic]; A-frags from Apack (L2).
__global__ __launch_bounds__(256) void k9_final(const float* __restrict__ rhsT, const float* __restrict__ theta,
    const unsigned short* __restrict__ Apack,
    const float* __restrict__ g3b, const float* __restrict__ g5b, const float* __restrict__ g7b,
    const float* __restrict__ fcw, const float* __restrict__ fcb,
    const float* __restrict__ rw, const float* __restrict__ rb,
    const float* __restrict__ gln, const float* __restrict__ bln,
    const float* __restrict__ x, float* __restrict__ out){
  int bn0=blockIdx.x*8;
  int tid=threadIdx.x;
  const int b=bn0>>10, n0=bn0&1023;

  __shared__ union {
    struct { unsigned short Xl[12*8*64]; float rstage[3][12][8]; } p0;
    float XP[8][772];
  } U;
  __shared__ __half G[64*24*8];
  __shared__ float xres[8][12];
  __shared__ float mu8[8][12], rs8[8][12];

  for(int i=tid;i<288;i+=256){
    int kk=i/96; int rem=i-kk*96; int t=rem>>3; int g=rem&7;
    U.p0.rstage[kk][t][g]=rhsT[((b*3+kk)*12+t)*1024 + n0 + g];
  }
  for(int i=tid;i<96;i+=256){ int g=i/12, t=i-(i/12)*12; xres[g][t]=x[(bn0+g)*12+t]; }
  __syncthreads();

  // phase0: Xl[t][g][ic] = bf16(relu(sum_kk rstage*theta)), g-XOR-swizzled, ic-pairs
  {
    int g=tid>>5, icp=tid&31;
    float th0[3], th1[3];
    #pragma unroll
    for(int kk=0;kk<3;kk++){ th0[kk]=theta[kk*64+2*icp]; th1[kk]=theta[kk*64+2*icp+1]; }
    #pragma unroll
    for(int t=0;t<12;t++){
      float r0=U.p0.rstage[0][t][g], r1=U.p0.rstage[1][t][g], r2=U.p0.rstage[2][t][g];
      float a0=fmaxf(r0*th0[0]+r1*th0[1]+r2*th0[2],0.f);
      float a1=fmaxf(r0*th1[0]+r1*th1[1]+r2*th1[2],0.f);
      unsigned pack = (((unsigned)f2b(a1))<<16)|(unsigned)f2b(a0);
      *(unsigned*)((char*)U.p0.Xl + ((t*8+g)<<7) + ((icp*4) ^ (g<<4))) = pack;
    }
  }
  __syncthreads();

  const int w=tid>>6, lane=tid&63, halfk=lane>>4, colq=lane&15;
  const int gg=colq&7, tau2=colq>>3;
  const int ca = w*16 + halfk*4;          // tanh channel base; sigmoid = 64+ca

  f32x4 acA[12], acB[12];
  #pragma unroll
  for(int j=0;j<5;j++){
    #pragma unroll
    for(int r=0;r<4;r++){ acA[j][r]=g3b[ca+r]; acB[j][r]=g3b[64+ca+r]; }
  }
  #pragma unroll
  for(int j=5;j<9;j++){
    #pragma unroll
    for(int r=0;r<4;r++){ acA[j][r]=g5b[ca+r]; acB[j][r]=g5b[64+ca+r]; }
  }
  #pragma unroll
  for(int j=9;j<12;j++){
    #pragma unroll
    for(int r=0;r<4;r++){ acA[j][r]=g7b[ca+r]; acB[j][r]=g7b[64+ca+r]; }
  }

  const char* xlb = (const char*)U.p0.Xl;
  // g3: frags 0..47 (rt*6+s), 5 col-tiles
  #pragma unroll
  for(int s=0;s<6;s++){
    bf16x8 a0 = *(const bf16x8*)&Apack[((w  )*6 + s)*512 + lane*8];
    bf16x8 a1 = *(const bf16x8*)&Apack[((w+4)*6 + s)*512 + lane*8];
    int dt=s>>1;
    int sl = ((((s&1)*32 + halfk*8)*2) ^ (gg<<4));
    #pragma unroll
    for(int j=0;j<5;j++){
      int t=2*j+tau2+dt;
      bf16x8 bf = *(const bf16x8*)(xlb + ((t*8+gg)<<7) + sl);
      acA[j] = __builtin_amdgcn_mfma_f32_16x16x32_bf16(a0, bf, acA[j], 0,0,0);
      acB[j] = __builtin_amdgcn_mfma_f32_16x16x32_bf16(a1, bf, acB[j], 0,0,0);
    }
  }
  // g5: frags 48..127 (48 + rt*10+s), 4 col-tiles
  #pragma unroll
  for(int s=0;s<10;s++){
    bf16x8 a0 = *(const bf16x8*)&Apack[(48 + (w  )*10 + s)*512 + lane*8];
    bf16x8 a1 = *(const bf16x8*)&Apack[(48 + (w+4)*10 + s)*512 + lane*8];
    int dt=s>>1;
    int sl = ((((s&1)*32 + halfk*8)*2) ^ (gg<<4));
    #pragma unroll
    for(int j=0;j<4;j++){
      int t=2*j+tau2+dt;
      bf16x8 bf = *(const bf16x8*)(xlb + ((t*8+gg)<<7) + sl);
      acA[5+j] = __builtin_amdgcn_mfma_f32_16x16x32_bf16(a0, bf, acA[5+j], 0,0,0);
      acB[5+j] = __builtin_amdgcn_mfma_f32_16x16x32_bf16(a1, bf, acB[5+j], 0,0,0);
    }
  }
  // g7: frags 128..239 (128 + rt*14+s), 3 col-tiles
  #pragma unroll
  for(int s=0;s<14;s++){
    bf16x8 a0 = *(const bf16x8*)&Apack[(128 + (w  )*14 + s)*512 + lane*8];
    bf16x8 a1 = *(const bf16x8*)&Apack[(128 + (w+4)*14 + s)*512 + lane*8];
    int dt=s>>1;
    int sl = ((((s&1)*32 + halfk*8)*2) ^ (gg<<4));
    #pragma unroll
    for(int j=0;j<3;j++){
      int t=2*j+tau2+dt;
      bf16x8 bf = *(const bf16x8*)(xlb + ((t*8+gg)<<7) + sl);
      acA[9+j] = __builtin_amdgcn_mfma_f32_16x16x32_bf16(a0, bf, acA[9+j], 0,0,0);
      acB[9+j] = __builtin_amdgcn_mfma_f32_16x16x32_bf16(a1, bf, acB[9+j], 0,0,0);
    }
  }

  // gated = tanh(ya)*sigmoid(yb), in-register pairing; write to G[c][tau][g]
  #pragma unroll
  for(int j=0;j<12;j++){
    int tb = (j<5)? 2*j : ((j<9)? 10+2*(j-5) : 18+2*(j-9));
    int tau = tb + tau2;
    #pragma unroll
    for(int r=0;r<4;r++){
      float ya=acA[j][r], yb=acB[j][r];
      float e2=__expf(2.f*ya);
      float th=1.f - 2.f/(e2+1.f);
      float sg=1.f/(1.f+__expf(-yb));
      G[((ca+r)*24+tau)*8+gg]=__float2half(th*sg);
    }
  }
  __syncthreads();

  // phase2: time_conv + residual + relu -> XP (re-uses Xl/rstage LDS)
  for(int o=tid;o<8*768;o+=256){
    int g=o/768; int ct=o-g*768; int c=ct/12; int t=ct-c*12;
    float acc=fcb[t];
    #pragma unroll
    for(int j=0;j<24;j++) acc+=__half2float(G[(c*24+j)*8+g])*fcw[j*12+t];
    acc=fmaxf(acc,0.f);
    float xr=xres[g][t]*rw[c]+rb[c];
    U.XP[g][c*12+t]=fmaxf(xr+acc,0.f);
  }
  __syncthreads();
  // phase3: LN over c
  if(tid<96){
    int g=tid/12, t=tid-(tid/12)*12;
    float s=0.f;
    for(int c=0;c<64;c++) s+=U.XP[g][c*12+t];
    float mu=s*(1.f/64.f);
    float q=0.f;
    for(int c=0;c<64;c++){float d=U.XP[g][c*12+t]-mu;q+=d*d;}
    mu8[g][t]=mu; rs8[g][t]=rsqrtf(q*(1.f/64.f)+EPS);
  }
  __syncthreads();
  for(int o=tid;o<8*768;o+=256){
    int g=o/768; int ct=o-g*768; int c=ct/12; int t=ct-c*12;
    out[(long)(bn0+g)*768 + ct]=(U.XP[g][c*12+t]-mu8[g][t])*rs8[g][t]*gln[c]+bln[c];
  }
}

// ---------------- launch ----------------
extern "C" void kernel_launch(void* const* d_in, const int* in_sizes, int n_in,
                              void* d_out, int out_size, void* d_ws, size_t ws_size,
                              hipStream_t stream){
  const float* x    =(const float*)d_in[0];
  const float* res  =(const float*)d_in[1];
  const float* posT =(const float*)d_in[2];
  const float* gT   =(const float*)d_in[3];
  const float* bT   =(const float*)d_in[4];
  const float* wq   =(const float*)d_in[5];
  const float* wk   =(const float*)d_in[6];
  const float* wv   =(const float*)d_in[7];
  const float* fcW  =(const float*)d_in[8];
  const float* prw  =(const float*)d_in[9];
  const float* prb  =(const float*)d_in[10];
  const float* posS =(const float*)d_in[11];
  const float* gS   =(const float*)d_in[12];
  const float* bS   =(const float*)d_in[13];
  const float* swq  =(const float*)d_in[14];
  const float* swk  =(const float*)d_in[15];
  const float* cheb =(const float*)d_in[16];
  const float* adj  =(const float*)d_in[17];
  const float* cmask=(const float*)d_in[18];
  const float* theta=(const float*)d_in[19];
  const float* g3w=(const float*)d_in[20]; const float* g3b=(const float*)d_in[21];
  const float* g5w=(const float*)d_in[22]; const float* g5b=(const float*)d_in[23];
  const float* g7w=(const float*)d_in[24]; const float* g7b=(const float*)d_in[25];
  const float* fcw=(const float*)d_in[26]; const float* fcb=(const float*)d_in[27];
  const float* rw =(const float*)d_in[28]; const float* rb =(const float*)d_in[29];
  const float* gln=(const float*)d_in[30]; const float* bln=(const float*)d_in[31];

  float* outp=(float*)d_out;
  float* scores = outp + 12582912;

  float* wsf=(float*)d_ws;
  float* TEmx = wsf;                          // 196608 f
  float* qkv  = TEmx + 196608;                // 55296 f
  float* ctx  = qkv + 55296;                  // 18432 f
  float* TAT  = ctx + 18432;                  // 196608 f
  unsigned short* SEb = (unsigned short*)(TAT + 196608);          // 4194304 f
  unsigned short* SQb = (unsigned short*)((float*)SEb + 4194304); // 786432 f
  unsigned short* SKb = (unsigned short*)((float*)SQb + 786432);  // 786432 f
  unsigned* mc = (unsigned*)((float*)SKb + 786432);               // 3145728 f
  float* rhsT  = (float*)mc + 3145728;                            // 589824 f
  unsigned short* Apack = (unsigned short*)(rhsT + 589824);       // 122880 u16

  k0_prep<<<dim3(12288),dim3(256),0,stream>>>(adj,cmask,cheb,mc);
  k8_prep<<<dim3(60),dim3(256),0,stream>>>(g3w,g5w,g7w,Apack);
  k1_embedT<<<dim3(192),dim3(256),0,stream>>>(x,posT,gT,bT,TEmx);
  k2_qkv<<<dim3(192),dim3(320),0,stream>>>(TEmx,wq,wk,wv,qkv);
  k3_attn<<<dim3(16),dim3(512),0,stream>>>(qkv,res,scores,ctx);
  k4_tat<<<dim3(192),dim3(256),0,stream>>>(ctx,fcW,TEmx,TAT);
  k5_semx<<<dim3(16384),dim3(256),0,stream>>>(TAT,prw,prb,posS,gS,bS,SEb);
  k6_sqk<<<dim3(2048),dim3(256),0,stream>>>(SEb,swq,swk,SQb,SKb);
  k7_spatial<<<dim3(768),dim3(256),0,stream>>>(SQb,SKb,mc,x,rhsT);
  k9_final<<<dim3(2048),dim3(256),0,stream>>>(rhsT,theta,Apack,g3b,g5b,g7b,
                                              fcw,fcb,rw,rb,gln,bln,x,outp);
}

// Round 4
// 356.697 us; speedup vs baseline: 4.2149x; 1.3163x over previous
//
#include <hip/hip_runtime.h>
#include <hip/hip_fp16.h>

#define EPS 1e-5f

typedef float f32x4 __attribute__((ext_vector_type(4)));
typedef short bf16x8 __attribute__((ext_vector_type(8)));
typedef short bf16x4 __attribute__((ext_vector_type(4)));

__device__ __forceinline__ unsigned short f2b(float f){
  unsigned u=__float_as_uint(f);
  return (unsigned short)((u + 0x7fffu + ((u>>16)&1u))>>16);
}
__device__ __forceinline__ float b2f(unsigned short h){
  return __uint_as_float(((unsigned)h)<<16);
}

// ---------------- helpers ----------------
__device__ __forceinline__ float blockSum256(float v, float* red){
  #pragma unroll
  for(int o=32;o>0;o>>=1) v += __shfl_down(v,o,64);
  int wid = threadIdx.x>>6;
  if((threadIdx.x&63)==0) red[wid]=v;
  __syncthreads();
  if(threadIdx.x==0) red[0]=red[0]+red[1]+red[2]+red[3];
  __syncthreads();
  float r = red[0];
  __syncthreads();
  return r;
}

// ---------------- K0: pack mask/cheb ----------------
__global__ __launch_bounds__(256) void k0_prep(const float* __restrict__ adj, const float* __restrict__ cmask,
    const float* __restrict__ cheb, unsigned* __restrict__ mc){
  int i = blockIdx.x*256 + threadIdx.x;
  int nm = i & 1048575;
  mc[i] = (((unsigned)f2b(cheb[i]))<<16) | (unsigned)f2b(adj[nm]*cmask[i]);
}

// ---------------- K1: EmbedT ----------------
__global__ __launch_bounds__(256) void k1_embedT(const float* __restrict__ x, const float* __restrict__ posT,
    const float* __restrict__ gT, const float* __restrict__ bT, float* __restrict__ TEmx){
  int bt=blockIdx.x; int b=bt/12, t=bt-b*12;
  int tid=threadIdx.x;
  __shared__ float red[4];
  float v[4]; float s=0.f;
  #pragma unroll
  for(int i=0;i<4;i++){ int n=tid+i*256; v[i]=x[(b*1024+n)*12+t]+posT[t*1024+n]; s+=v[i]; }
  s = blockSum256(s, red);
  float mu = s*(1.f/1024.f);
  float q=0.f;
  #pragma unroll
  for(int i=0;i<4;i++){ float d=v[i]-mu; q+=d*d; }
  q = blockSum256(q, red);
  float rstd = rsqrtf(q*(1.f/1024.f)+EPS);
  #pragma unroll
  for(int i=0;i<4;i++){ int n=tid+i*256; TEmx[bt*1024+n]=(v[i]-mu)*rstd*gT[n]+bT[n]; }
}

// ---------------- K2: QKV ----------------
__global__ __launch_bounds__(320) void k2_qkv(const float* __restrict__ TEmx, const float* __restrict__ wq,
    const float* __restrict__ wk, const float* __restrict__ wv, float* __restrict__ qkv){
  int bt=blockIdx.x; int tid=threadIdx.x;
  __shared__ float row[1024];
  for(int i=tid;i<1024;i+=320) row[i]=TEmx[bt*1024+i];
  __syncthreads();
  if(tid<288){
    int m=tid/96, col=tid-m*96;
    const float* w = (m==0)?wq:((m==1)?wk:wv);
    float acc=0.f;
    #pragma unroll 4
    for(int n=0;n<1024;n++) acc += row[n]*w[n*96+col];
    qkv[bt*288+tid]=acc;
  }
}

// ---------------- K3: temporal attn ----------------
__global__ __launch_bounds__(512) void k3_attn(const float* __restrict__ qkv, const float* __restrict__ res_att,
    float* __restrict__ scores_out, float* __restrict__ ctx){
  int b=blockIdx.x; int tid=threadIdx.x;
  __shared__ float sS[432];
  __shared__ float sA[432];
  if(tid<432){
    int h=tid/144; int r=tid-h*144; int q=r/12; int k2=r-q*12;
    const float* Qr=&qkv[(b*12+q)*288 + h*32];
    const float* Kr=&qkv[(b*12+k2)*288 + 96 + h*32];
    float acc=0.f;
    #pragma unroll
    for(int d=0;d<32;d++) acc+=Qr[d]*Kr[d];
    acc = acc*0.17677669529663687f + res_att[(b*3+h)*144 + q*12 + k2];
    sS[h*144+q*12+k2]=acc;
    scores_out[(b*3+h)*144 + q*12 + k2]=acc;
  }
  __syncthreads();
  if(tid<36){
    int h=tid/12, k2=tid-(tid/12)*12;
    float mx=-1e30f;
    for(int q=0;q<12;q++) mx=fmaxf(mx,sS[h*144+q*12+k2]);
    float sum=0.f;
    for(int q=0;q<12;q++){ float e=__expf(sS[h*144+q*12+k2]-mx); sA[h*144+q*12+k2]=e; sum+=e; }
    float inv=1.f/sum;
    for(int q=0;q<12;q++) sA[h*144+q*12+k2]*=inv;
  }
  __syncthreads();
  for(int o=tid;o<1152;o+=512){
    int h=o/384; int r=o-h*384; int q=r/32; int d=r-q*32;
    float acc=0.f;
    #pragma unroll
    for(int k2=0;k2<12;k2++) acc += sA[h*144+q*12+k2]*qkv[(b*12+k2)*288+192+h*32+d];
    ctx[(b*12+q)*96 + h*32 + d]=acc;
  }
}

// ---------------- K4: TATout ----------------
__global__ __launch_bounds__(256) void k4_tat(const float* __restrict__ ctx, const float* __restrict__ fcW,
    const float* __restrict__ TEmx, float* __restrict__ TAT){
  int bt=blockIdx.x; int tid=threadIdx.x;
  __shared__ float c96[96];
  __shared__ float red[4];
  if(tid<96) c96[tid]=ctx[bt*96+tid];
  __syncthreads();
  float v[4]; float s=0.f;
  #pragma unroll
  for(int i=0;i<4;i++){
    int n=tid+i*256;
    float acc=TEmx[bt*1024+n];
    #pragma unroll 4
    for(int j=0;j<96;j++) acc += c96[j]*fcW[j*1024+n];
    v[i]=acc; s+=acc;
  }
  s=blockSum256(s,red);
  float mu=s*(1.f/1024.f);
  float q=0.f;
  #pragma unroll
  for(int i=0;i<4;i++){float d=v[i]-mu;q+=d*d;}
  q=blockSum256(q,red);
  float rstd=rsqrtf(q*(1.f/1024.f)+EPS);
  #pragma unroll
  for(int i=0;i<4;i++){int n=tid+i*256; TAT[bt*1024+n]=(v[i]-mu)*rstd;}
}

// ---------------- K5: SEmx (bf16 out) ----------------
__global__ __launch_bounds__(256) void k5_semx(const float* __restrict__ TAT, const float* __restrict__ pre_w,
    const float* __restrict__ pre_b, const float* __restrict__ posS, const float* __restrict__ gS,
    const float* __restrict__ bS, unsigned short* __restrict__ SEb){
  int bn=blockIdx.x; int b=bn>>10, n=bn&1023; int tid=threadIdx.x;
  __shared__ float tv[12];
  __shared__ float red[4];
  if(tid<12) tv[tid]=TAT[(b*12+tid)*1024+n];
  __syncthreads();
  float v[2]; float s=0.f;
  #pragma unroll
  for(int i=0;i<2;i++){
    int d=tid+i*256;
    float acc=pre_b[d]+posS[n*512+d];
    #pragma unroll
    for(int t=0;t<12;t++) acc += tv[t]*pre_w[d*12+t];
    v[i]=acc; s+=acc;
  }
  s=blockSum256(s,red);
  float mu=s*(1.f/512.f);
  float q=0.f;
  #pragma unroll
  for(int i=0;i<2;i++){float d2=v[i]-mu;q+=d2*d2;}
  q=blockSum256(q,red);
  float rstd=rsqrtf(q*(1.f/512.f)+EPS);
  #pragma unroll
  for(int i=0;i<2;i++){int d=tid+i*256; SEb[bn*512+d]=f2b((v[i]-mu)*rstd*gS[d]+bS[d]);}
}

// ---------------- KW: pack swq/swk into MFMA B-fragment layout ----------------
// Wpack[frag=ct*16+ks][lane][8] : value = W[ks*32+(lane>>4)*8+j][(ct%6)*16+(lane&15)]
__global__ __launch_bounds__(256) void kw_prep(const float* __restrict__ swq, const float* __restrict__ swk,
    unsigned short* __restrict__ Wpack){
  int idx = blockIdx.x*256+threadIdx.x;  // 12*16*64 = 12288
  if(idx>=12288) return;
  int frag=idx>>6, lane=idx&63;
  int ct=frag>>4, ks=frag&15;
  const float* W = (ct<6)? swq : swk;
  int c = ((ct<6)? ct : ct-6)*16 + (lane&15);
  int k0 = ks*32 + (lane>>4)*8;
  #pragma unroll
  for(int j=0;j<8;j++) Wpack[idx*8+j]=f2b(W[(k0+j)*96 + c]);
}

// ---------------- K6: SQ/SK via MFMA GEMM (16384x512 @ 512x192) ----------------
// 4 waves/block; wave owns 16 rows; 16 K-steps x 12 col-tiles.
__global__ __launch_bounds__(256) void k6_sqk(const unsigned short* __restrict__ SEb,
    const unsigned short* __restrict__ Wpack,
    unsigned short* __restrict__ SQb, unsigned short* __restrict__ SKb){
  int tid=threadIdx.x; int w=tid>>6, lane=tid&63;
  const int hi=lane>>4, lo=lane&15;
  const int row0 = blockIdx.x*64 + w*16;
  f32x4 acc[12];
  #pragma unroll
  for(int i=0;i<12;i++){ acc[i][0]=0.f; acc[i][1]=0.f; acc[i][2]=0.f; acc[i][3]=0.f; }
  for(int ks=0;ks<16;ks++){
    bf16x8 af = *(const bf16x8*)&SEb[(row0+lo)*512 + ks*32 + hi*8];
    #pragma unroll
    for(int ct=0;ct<12;ct++){
      bf16x8 bf = *(const bf16x8*)&Wpack[((ct*16+ks)<<9) + lane*8];
      acc[ct] = __builtin_amdgcn_mfma_f32_16x16x32_bf16(af, bf, acc[ct], 0,0,0);
    }
  }
  #pragma unroll
  for(int ct=0;ct<12;ct++){
    int c96 = ((ct<6)? ct : ct-6)*16 + lo;
    int kq = c96>>5, d = c96&31;
    unsigned short* dst = (ct<6)? SQb : SKb;
    #pragma unroll
    for(int r=0;r<4;r++){
      int n = row0 + hi*4 + r;
      int b = n>>10, nl = n&1023;
      dst[((b*3+kq)*1024+nl)*32 + d] = f2b(acc[ct][r]);
    }
  }
}

// ---------------- K7: fused spatial attention + graph conv (MFMA flash) ----------------
#define SCALE7 0.17677669529663687f
__global__ __launch_bounds__(256) void k7_spatial(const unsigned short* __restrict__ SQb,
    const unsigned short* __restrict__ SKb, const unsigned* __restrict__ mc,
    const float* __restrict__ x, float* __restrict__ rhsT){
  const int blk=blockIdx.x;
  const int mt=blk&15, bk=blk>>4;
  const int k=bk%3, b=bk/3;
  const int m0=mt*64;
  const int tid=threadIdx.x;
  const int w=tid>>6, lane=tid&63, g=lane>>4, col=lane&15;

  __shared__ unsigned short xs[16*128];

  const int m_glob = m0 + w*16 + col;
  bf16x8 bfrag = *(const bf16x8*)&SKb[((bk<<10)+m_glob)*32 + g*8];

  f32x4 O = {0.f,0.f,0.f,0.f};
  float mrun=-1e30f, lrun=0.f;

  const float* xb = x + b*12288;
  const unsigned* mck = mc + k*1048576;
  const int swz = (col&7)<<3;

  for(int i=tid;i<512;i+=256){ int t=12+(i>>7), n=i&127; xs[t*128 + (n ^ ((t&7)<<3))]=0; }

  for(int ch=0; ch<8; ++ch){
    const int n0 = ch<<7;
    __syncthreads();
    for(int i=tid;i<1536;i+=256){
      int n=i/12, t=i-n*12;
      xs[t*128 + (n ^ ((t&7)<<3))] = f2b(xb[n0*12 + i]);
    }
    __syncthreads();

    f32x4 acc[8];
    #pragma unroll
    for(int nt=0;nt<8;nt++){
      bf16x8 afrag = *(const bf16x8*)&SQb[((bk<<10) + n0 + nt*16 + col)*32 + g*8];
      f32x4 z = {0.f,0.f,0.f,0.f};
      acc[nt] = __builtin_amdgcn_mfma_f32_16x16x32_bf16(afrag, bfrag, z, 0,0,0);
    }
    unsigned mcv[8][4];
    #pragma unroll
    for(int nt=0;nt<8;nt++){
      int nbase = n0 + nt*16 + g*4;
      #pragma unroll
      for(int r=0;r<4;r++) mcv[nt][r] = mck[(nbase+r)*1024 + m_glob];
    }
    float cmax = -1e30f;
    #pragma unroll
    for(int nt=0;nt<8;nt++){
      #pragma unroll
      for(int r=0;r<4;r++){
        float s = acc[nt][r]*SCALE7 + __uint_as_float(mcv[nt][r]<<16);
        acc[nt][r]=s;
        cmax=fmaxf(cmax,s);
      }
    }
    cmax = fmaxf(cmax, __shfl_xor(cmax,16,64));
    cmax = fmaxf(cmax, __shfl_xor(cmax,32,64));
    float mnew = fmaxf(mrun, cmax);
    float alpha = __expf(mrun - mnew);
    float lsum = 0.f;
    unsigned short pb[8][4];
    #pragma unroll
    for(int nt=0;nt<8;nt++){
      #pragma unroll
      for(int r=0;r<4;r++){
        float e = __expf(acc[nt][r] - mnew);
        lsum += e;
        pb[nt][r] = f2b(e * __uint_as_float(mcv[nt][r] & 0xffff0000u));
      }
    }
    lsum += __shfl_xor(lsum,16,64);
    lsum += __shfl_xor(lsum,32,64);
    lrun = lrun*alpha + lsum;
    mrun = mnew;
    O[0]*=alpha; O[1]*=alpha; O[2]*=alpha; O[3]*=alpha;

    #pragma unroll
    for(int c=0;c<4;c++){
      bf16x8 pf;
      #pragma unroll
      for(int j=0;j<4;j++){ pf[j]=(short)pb[2*c][j]; pf[j+4]=(short)pb[2*c+1][j]; }
      int nlo = c*32 + g*4;
      bf16x4 lo = *(const bf16x4*)&xs[col*128 + (nlo ^ swz)];
      bf16x4 hi = *(const bf16x4*)&xs[col*128 + ((nlo+16) ^ swz)];
      bf16x8 ax;
      #pragma unroll
      for(int j=0;j<4;j++){ ax[j]=lo[j]; ax[j+4]=hi[j]; }
      O = __builtin_amdgcn_mfma_f32_16x16x32_bf16(ax, pf, O, 0,0,0);
    }
  }
  float inv = 1.f/lrun;
  #pragma unroll
  for(int r=0;r<4;r++){
    int t = g*4+r;
    if(t<12) rhsT[((bk*12+t)<<10) + m_glob] = O[r]*inv;
  }
}

// ---------------- K8: pack conv weights into MFMA A-fragment layout ----------------
__global__ __launch_bounds__(256) void k8_prep(const float* __restrict__ g3w, const float* __restrict__ g5w,
    const float* __restrict__ g7w, unsigned short* __restrict__ Apack){
  int idx = blockIdx.x*256+threadIdx.x;      // 240*64 = 15360
  if(idx>=15360) return;
  int frag=idx>>6, lane=idx&63;
  int rt, s, kappa; const float* W;
  if(frag<48){ rt=frag/6; s=frag-rt*6; kappa=3; W=g3w; }
  else if(frag<128){ int f=frag-48; rt=f/10; s=f-rt*10; kappa=5; W=g5w; }
  else { int f=frag-128; rt=f/14; s=f-rt*14; kappa=7; W=g7w; }
  int c = rt*16 + (lane&15);
  int dt = s>>1, ic0=(s&1)*32 + (lane>>4)*8;
  #pragma unroll
  for(int j=0;j<8;j++) Apack[idx*8+j]=f2b(W[(c*64+ic0+j)*kappa + dt]);
}

// ---------------- K9: theta-contract + MFMA GTU convs + fc + residual + final LN ----------------
__global__ __launch_bounds__(256) void k9_final(const float* __restrict__ rhsT, const float* __restrict__ theta,
    const unsigned short* __restrict__ Apack,
    const float* __restrict__ g3b, const float* __restrict__ g5b, const float* __restrict__ g7b,
    const float* __restrict__ fcw, const float* __restrict__ fcb,
    const float* __restrict__ rw, const float* __restrict__ rb,
    const float* __restrict__ gln, const float* __restrict__ bln,
    const float* __restrict__ x, float* __restrict__ out){
  int bn0=blockIdx.x*8;
  int tid=threadIdx.x;
  const int b=bn0>>10, n0=bn0&1023;

  __shared__ union {
    struct { unsigned short Xl[12*8*64]; float rstage[3][12][8]; } p0;
    float XP[8][772];
  } U;
  __shared__ __half G[64*24*8];
  __shared__ float xres[8][12];
  __shared__ float mu8[8][12], rs8[8][12];

  for(int i=tid;i<288;i+=256){
    int kk=i/96; int rem=i-kk*96; int t=rem>>3; int g=rem&7;
    U.p0.rstage[kk][t][g]=rhsT[((b*3+kk)*12+t)*1024 + n0 + g];
  }
  for(int i=tid;i<96;i+=256){ int g=i/12, t=i-(i/12)*12; xres[g][t]=x[(bn0+g)*12+t]; }
  __syncthreads();

  {
    int g=tid>>5, icp=tid&31;
    float th0[3], th1[3];
    #pragma unroll
    for(int kk=0;kk<3;kk++){ th0[kk]=theta[kk*64+2*icp]; th1[kk]=theta[kk*64+2*icp+1]; }
    #pragma unroll
    for(int t=0;t<12;t++){
      float r0=U.p0.rstage[0][t][g], r1=U.p0.rstage[1][t][g], r2=U.p0.rstage[2][t][g];
      float a0=fmaxf(r0*th0[0]+r1*th0[1]+r2*th0[2],0.f);
      float a1=fmaxf(r0*th1[0]+r1*th1[1]+r2*th1[2],0.f);
      unsigned pack = (((unsigned)f2b(a1))<<16)|(unsigned)f2b(a0);
      *(unsigned*)((char*)U.p0.Xl + ((t*8+g)<<7) + ((icp*4) ^ (g<<4))) = pack;
    }
  }
  __syncthreads();

  const int w=tid>>6, lane=tid&63, halfk=lane>>4, colq=lane&15;
  const int gg=colq&7, tau2=colq>>3;
  const int ca = w*16 + halfk*4;

  f32x4 acA[12], acB[12];
  #pragma unroll
  for(int j=0;j<5;j++){
    #pragma unroll
    for(int r=0;r<4;r++){ acA[j][r]=g3b[ca+r]; acB[j][r]=g3b[64+ca+r]; }
  }
  #pragma unroll
  for(int j=5;j<9;j++){
    #pragma unroll
    for(int r=0;r<4;r++){ acA[j][r]=g5b[ca+r]; acB[j][r]=g5b[64+ca+r]; }
  }
  #pragma unroll
  for(int j=9;j<12;j++){
    #pragma unroll
    for(int r=0;r<4;r++){ acA[j][r]=g7b[ca+r]; acB[j][r]=g7b[64+ca+r]; }
  }

  const char* xlb = (const char*)U.p0.Xl;
  #pragma unroll
  for(int s=0;s<6;s++){
    bf16x8 a0 = *(const bf16x8*)&Apack[((w  )*6 + s)*512 + lane*8];
    bf16x8 a1 = *(const bf16x8*)&Apack[((w+4)*6 + s)*512 + lane*8];
    int dt=s>>1;
    int sl = ((((s&1)*32 + halfk*8)*2) ^ (gg<<4));
    #pragma unroll
    for(int j=0;j<5;j++){
      int t=2*j+tau2+dt;
      bf16x8 bf = *(const bf16x8*)(xlb + ((t*8+gg)<<7) + sl);
      acA[j] = __builtin_amdgcn_mfma_f32_16x16x32_bf16(a0, bf, acA[j], 0,0,0);
      acB[j] = __builtin_amdgcn_mfma_f32_16x16x32_bf16(a1, bf, acB[j], 0,0,0);
    }
  }
  #pragma unroll
  for(int s=0;s<10;s++){
    bf16x8 a0 = *(const bf16x8*)&Apack[(48 + (w  )*10 + s)*512 + lane*8];
    bf16x8 a1 = *(const bf16x8*)&Apack[(48 + (w+4)*10 + s)*512 + lane*8];
    int dt=s>>1;
    int sl = ((((s&1)*32 + halfk*8)*2) ^ (gg<<4));
    #pragma unroll
    for(int j=0;j<4;j++){
      int t=2*j+tau2+dt;
      bf16x8 bf = *(const bf16x8*)(xlb + ((t*8+gg)<<7) + sl);
      acA[5+j] = __builtin_amdgcn_mfma_f32_16x16x32_bf16(a0, bf, acA[5+j], 0,0,0);
      acB[5+j] = __builtin_amdgcn_mfma_f32_16x16x32_bf16(a1, bf, acB[5+j], 0,0,0);
    }
  }
  #pragma unroll
  for(int s=0;s<14;s++){
    bf16x8 a0 = *(const bf16x8*)&Apack[(128 + (w  )*14 + s)*512 + lane*8];
    bf16x8 a1 = *(const bf16x8*)&Apack[(128 + (w+4)*14 + s)*512 + lane*8];
    int dt=s>>1;
    int sl = ((((s&1)*32 + halfk*8)*2) ^ (gg<<4));
    #pragma unroll
    for(int j=0;j<3;j++){
      int t=2*j+tau2+dt;
      bf16x8 bf = *(const bf16x8*)(xlb + ((t*8+gg)<<7) + sl);
      acA[9+j] = __builtin_amdgcn_mfma_f32_16x16x32_bf16(a0, bf, acA[9+j], 0,0,0);
      acB[9+j] = __builtin_amdgcn_mfma_f32_16x16x32_bf16(a1, bf, acB[9+j], 0,0,0);
    }
  }

  #pragma unroll
  for(int j=0;j<12;j++){
    int tb = (j<5)? 2*j : ((j<9)? 10+2*(j-5) : 18+2*(j-9));
    int tau = tb + tau2;
    #pragma unroll
    for(int r=0;r<4;r++){
      float ya=acA[j][r], yb=acB[j][r];
      float e2=__expf(2.f*ya);
      float th=1.f - 2.f/(e2+1.f);
      float sg=1.f/(1.f+__expf(-yb));
      G[((ca+r)*24+tau)*8+gg]=__float2half(th*sg);
    }
  }
  __syncthreads();

  for(int o=tid;o<8*768;o+=256){
    int g=o/768; int ct=o-g*768; int c=ct/12; int t=ct-c*12;
    float acc=fcb[t];
    #pragma unroll
    for(int j=0;j<24;j++) acc+=__half2float(G[(c*24+j)*8+g])*fcw[j*12+t];
    acc=fmaxf(acc,0.f);
    float xr=xres[g][t]*rw[c]+rb[c];
    U.XP[g][c*12+t]=fmaxf(xr+acc,0.f);
  }
  __syncthreads();
  if(tid<96){
    int g=tid/12, t=tid-(tid/12)*12;
    float s=0.f;
    for(int c=0;c<64;c++) s+=U.XP[g][c*12+t];
    float mu=s*(1.f/64.f);
    float q=0.f;
    for(int c=0;c<64;c++){float d=U.XP[g][c*12+t]-mu;q+=d*d;}
    mu8[g][t]=mu; rs8[g][t]=rsqrtf(q*(1.f/64.f)+EPS);
  }
  __syncthreads();
  for(int o=tid;o<8*768;o+=256){
    int g=o/768; int ct=o-g*768; int c=ct/12; int t=ct-c*12;
    out[(long)(bn0+g)*768 + ct]=(U.XP[g][c*12+t]-mu8[g][t])*rs8[g][t]*gln[c]+bln[c];
  }
}

// ---------------- launch ----------------
extern "C" void kernel_launch(void* const* d_in, const int* in_sizes, int n_in,
                              void* d_out, int out_size, void* d_ws, size_t ws_size,
                              hipStream_t stream){
  const float* x    =(const float*)d_in[0];
  const float* res  =(const float*)d_in[1];
  const float* posT =(const float*)d_in[2];
  const float* gT   =(const float*)d_in[3];
  const float* bT   =(const float*)d_in[4];
  const float* wq   =(const float*)d_in[5];
  const float* wk   =(const float*)d_in[6];
  const float* wv   =(const float*)d_in[7];
  const float* fcW  =(const float*)d_in[8];
  const float* prw  =(const float*)d_in[9];
  const float* prb  =(const float*)d_in[10];
  const float* posS =(const float*)d_in[11];
  const float* gS   =(const float*)d_in[12];
  const float* bS   =(const float*)d_in[13];
  const float* swq  =(const float*)d_in[14];
  const float* swk  =(const float*)d_in[15];
  const float* cheb =(const float*)d_in[16];
  const float* adj  =(const float*)d_in[17];
  const float* cmask=(const float*)d_in[18];
  const float* theta=(const float*)d_in[19];
  const float* g3w=(const float*)d_in[20]; const float* g3b=(const float*)d_in[21];
  const float* g5w=(const float*)d_in[22]; const float* g5b=(const float*)d_in[23];
  const float* g7w=(const float*)d_in[24]; const float* g7b=(const float*)d_in[25];
  const float* fcw=(const float*)d_in[26]; const float* fcb=(const float*)d_in[27];
  const float* rw =(const float*)d_in[28]; const float* rb =(const float*)d_in[29];
  const float* gln=(const float*)d_in[30]; const float* bln=(const float*)d_in[31];

  float* outp=(float*)d_out;
  float* scores = outp + 12582912;

  float* wsf=(float*)d_ws;
  float* TEmx = wsf;                          // 196608 f
  float* qkv  = TEmx + 196608;                // 55296 f
  float* ctx  = qkv + 55296;                  // 18432 f
  float* TAT  = ctx + 18432;                  // 196608 f
  unsigned short* SEb = (unsigned short*)(TAT + 196608);          // 4194304 f
  unsigned short* SQb = (unsigned short*)((float*)SEb + 4194304); // 786432 f
  unsigned short* SKb = (unsigned short*)((float*)SQb + 786432);  // 786432 f
  unsigned* mc = (unsigned*)((float*)SKb + 786432);               // 3145728 f
  float* rhsT  = (float*)mc + 3145728;                            // 589824 f
  unsigned short* Apack = (unsigned short*)(rhsT + 589824);       // 122880 u16
  unsigned short* Wpack = Apack + 122880;                         // 98304 u16

  k0_prep<<<dim3(12288),dim3(256),0,stream>>>(adj,cmask,cheb,mc);
  k8_prep<<<dim3(60),dim3(256),0,stream>>>(g3w,g5w,g7w,Apack);
  kw_prep<<<dim3(48),dim3(256),0,stream>>>(swq,swk,Wpack);
  k1_embedT<<<dim3(192),dim3(256),0,stream>>>(x,posT,gT,bT,TEmx);
  k2_qkv<<<dim3(192),dim3(320),0,stream>>>(TEmx,wq,wk,wv,qkv);
  k3_attn<<<dim3(16),dim3(512),0,stream>>>(qkv,res,scores,ctx);
  k4_tat<<<dim3(192),dim3(256),0,stream>>>(ctx,fcW,TEmx,TAT);
  k5_semx<<<dim3(16384),dim3(256),0,stream>>>(TAT,prw,prb,posS,gS,bS,SEb);
  k6_sqk<<<dim3(256),dim3(256),0,stream>>>(SEb,Wpack,SQb,SKb);
  k7_spatial<<<dim3(768),dim3(256),0,stream>>>(SQb,SKb,mc,x,rhsT);
  k9_final<<<dim3(2048),dim3(256),0,stream>>>(rhsT,theta,Apack,g3b,g5b,g7b,
                                              fcw,fcb,rw,rb,gln,bln,x,outp);
}

// Round 5
// 350.439 us; speedup vs baseline: 4.2901x; 1.0179x over previous
//
#include <hip/hip_runtime.h>
#include <hip/hip_fp16.h>

#define EPS 1e-5f

typedef float f32x4 __attribute__((ext_vector_type(4)));
typedef short bf16x8 __attribute__((ext_vector_type(8)));
typedef short bf16x4 __attribute__((ext_vector_type(4)));

__device__ __forceinline__ unsigned short f2b(float f){
  unsigned u=__float_as_uint(f);
  return (unsigned short)((u + 0x7fffu + ((u>>16)&1u))>>16);
}
__device__ __forceinline__ float b2f(unsigned short h){
  return __uint_as_float(((unsigned)h)<<16);
}

// ---------------- helpers ----------------
__device__ __forceinline__ float blockSum256(float v, float* red){
  #pragma unroll
  for(int o=32;o>0;o>>=1) v += __shfl_down(v,o,64);
  int wid = threadIdx.x>>6;
  if((threadIdx.x&63)==0) red[wid]=v;
  __syncthreads();
  if(threadIdx.x==0) red[0]=red[0]+red[1]+red[2]+red[3];
  __syncthreads();
  float r = red[0];
  __syncthreads();
  return r;
}

// ---------------- K0: pack mask/cheb ----------------
__global__ __launch_bounds__(256) void k0_prep(const float* __restrict__ adj, const float* __restrict__ cmask,
    const float* __restrict__ cheb, unsigned* __restrict__ mc){
  int i = blockIdx.x*256 + threadIdx.x;
  int nm = i & 1048575;
  mc[i] = (((unsigned)f2b(cheb[i]))<<16) | (unsigned)f2b(adj[nm]*cmask[i]);
}

// ---------------- K1: EmbedT ----------------
__global__ __launch_bounds__(256) void k1_embedT(const float* __restrict__ x, const float* __restrict__ posT,
    const float* __restrict__ gT, const float* __restrict__ bT, float* __restrict__ TEmx){
  int bt=blockIdx.x; int b=bt/12, t=bt-b*12;
  int tid=threadIdx.x;
  __shared__ float red[4];
  float v[4]; float s=0.f;
  #pragma unroll
  for(int i=0;i<4;i++){ int n=tid+i*256; v[i]=x[(b*1024+n)*12+t]+posT[t*1024+n]; s+=v[i]; }
  s = blockSum256(s, red);
  float mu = s*(1.f/1024.f);
  float q=0.f;
  #pragma unroll
  for(int i=0;i<4;i++){ float d=v[i]-mu; q+=d*d; }
  q = blockSum256(q, red);
  float rstd = rsqrtf(q*(1.f/1024.f)+EPS);
  #pragma unroll
  for(int i=0;i<4;i++){ int n=tid+i*256; TEmx[bt*1024+n]=(v[i]-mu)*rstd*gT[n]+bT[n]; }
}

// ---------------- K2: QKV ----------------
__global__ __launch_bounds__(320) void k2_qkv(const float* __restrict__ TEmx, const float* __restrict__ wq,
    const float* __restrict__ wk, const float* __restrict__ wv, float* __restrict__ qkv){
  int bt=blockIdx.x; int tid=threadIdx.x;
  __shared__ float row[1024];
  for(int i=tid;i<1024;i+=320) row[i]=TEmx[bt*1024+i];
  __syncthreads();
  if(tid<288){
    int m=tid/96, col=tid-m*96;
    const float* w = (m==0)?wq:((m==1)?wk:wv);
    float acc=0.f;
    #pragma unroll 4
    for(int n=0;n<1024;n++) acc += row[n]*w[n*96+col];
    qkv[bt*288+tid]=acc;
  }
}

// ---------------- K3: temporal attn ----------------
__global__ __launch_bounds__(512) void k3_attn(const float* __restrict__ qkv, const float* __restrict__ res_att,
    float* __restrict__ scores_out, float* __restrict__ ctx){
  int b=blockIdx.x; int tid=threadIdx.x;
  __shared__ float sS[432];
  __shared__ float sA[432];
  if(tid<432){
    int h=tid/144; int r=tid-h*144; int q=r/12; int k2=r-q*12;
    const float* Qr=&qkv[(b*12+q)*288 + h*32];
    const float* Kr=&qkv[(b*12+k2)*288 + 96 + h*32];
    float acc=0.f;
    #pragma unroll
    for(int d=0;d<32;d++) acc+=Qr[d]*Kr[d];
    acc = acc*0.17677669529663687f + res_att[(b*3+h)*144 + q*12 + k2];
    sS[h*144+q*12+k2]=acc;
    scores_out[(b*3+h)*144 + q*12 + k2]=acc;
  }
  __syncthreads();
  if(tid<36){
    int h=tid/12, k2=tid-(tid/12)*12;
    float mx=-1e30f;
    for(int q=0;q<12;q++) mx=fmaxf(mx,sS[h*144+q*12+k2]);
    float sum=0.f;
    for(int q=0;q<12;q++){ float e=__expf(sS[h*144+q*12+k2]-mx); sA[h*144+q*12+k2]=e; sum+=e; }
    float inv=1.f/sum;
    for(int q=0;q<12;q++) sA[h*144+q*12+k2]*=inv;
  }
  __syncthreads();
  for(int o=tid;o<1152;o+=512){
    int h=o/384; int r=o-h*384; int q=r/32; int d=r-q*32;
    float acc=0.f;
    #pragma unroll
    for(int k2=0;k2<12;k2++) acc += sA[h*144+q*12+k2]*qkv[(b*12+k2)*288+192+h*32+d];
    ctx[(b*12+q)*96 + h*32 + d]=acc;
  }
}

// ---------------- K4: TATout ----------------
__global__ __launch_bounds__(256) void k4_tat(const float* __restrict__ ctx, const float* __restrict__ fcW,
    const float* __restrict__ TEmx, float* __restrict__ TAT){
  int bt=blockIdx.x; int tid=threadIdx.x;
  __shared__ float c96[96];
  __shared__ float red[4];
  if(tid<96) c96[tid]=ctx[bt*96+tid];
  __syncthreads();
  float v[4]; float s=0.f;
  #pragma unroll
  for(int i=0;i<4;i++){
    int n=tid+i*256;
    float acc=TEmx[bt*1024+n];
    #pragma unroll 4
    for(int j=0;j<96;j++) acc += c96[j]*fcW[j*1024+n];
    v[i]=acc; s+=acc;
  }
  s=blockSum256(s,red);
  float mu=s*(1.f/1024.f);
  float q=0.f;
  #pragma unroll
  for(int i=0;i<4;i++){float d=v[i]-mu;q+=d*d;}
  q=blockSum256(q,red);
  float rstd=rsqrtf(q*(1.f/1024.f)+EPS);
  #pragma unroll
  for(int i=0;i<4;i++){int n=tid+i*256; TAT[bt*1024+n]=(v[i]-mu)*rstd;}
}

// ---------------- K5: SEmx (bf16 out) ----------------
__global__ __launch_bounds__(256) void k5_semx(const float* __restrict__ TAT, const float* __restrict__ pre_w,
    const float* __restrict__ pre_b, const float* __restrict__ posS, const float* __restrict__ gS,
    const float* __restrict__ bS, unsigned short* __restrict__ SEb){
  int bn=blockIdx.x; int b=bn>>10, n=bn&1023; int tid=threadIdx.x;
  __shared__ float tv[12];
  __shared__ float red[4];
  if(tid<12) tv[tid]=TAT[(b*12+tid)*1024+n];
  __syncthreads();
  float v[2]; float s=0.f;
  #pragma unroll
  for(int i=0;i<2;i++){
    int d=tid+i*256;
    float acc=pre_b[d]+posS[n*512+d];
    #pragma unroll
    for(int t=0;t<12;t++) acc += tv[t]*pre_w[d*12+t];
    v[i]=acc; s+=acc;
  }
  s=blockSum256(s,red);
  float mu=s*(1.f/512.f);
  float q=0.f;
  #pragma unroll
  for(int i=0;i<2;i++){float d2=v[i]-mu;q+=d2*d2;}
  q=blockSum256(q,red);
  float rstd=rsqrtf(q*(1.f/512.f)+EPS);
  #pragma unroll
  for(int i=0;i<2;i++){int d=tid+i*256; SEb[bn*512+d]=f2b((v[i]-mu)*rstd*gS[d]+bS[d]);}
}

// ---------------- KW: pack swq/swk into MFMA B-fragment layout ----------------
__global__ __launch_bounds__(256) void kw_prep(const float* __restrict__ swq, const float* __restrict__ swk,
    unsigned short* __restrict__ Wpack){
  int idx = blockIdx.x*256+threadIdx.x;  // 12*16*64 = 12288
  if(idx>=12288) return;
  int frag=idx>>6, lane=idx&63;
  int ct=frag>>4, ks=frag&15;
  const float* W = (ct<6)? swq : swk;
  int c = ((ct<6)? ct : ct-6)*16 + (lane&15);
  int k0 = ks*32 + (lane>>4)*8;
  #pragma unroll
  for(int j=0;j<8;j++) Wpack[idx*8+j]=f2b(W[(k0+j)*96 + c]);
}

// ---------------- K6: SQ/SK via MFMA GEMM ----------------
__global__ __launch_bounds__(256) void k6_sqk(const unsigned short* __restrict__ SEb,
    const unsigned short* __restrict__ Wpack,
    unsigned short* __restrict__ SQb, unsigned short* __restrict__ SKb){
  int tid=threadIdx.x; int w=tid>>6, lane=tid&63;
  const int hi=lane>>4, lo=lane&15;
  const int row0 = blockIdx.x*64 + w*16;
  f32x4 acc[12];
  #pragma unroll
  for(int i=0;i<12;i++){ acc[i][0]=0.f; acc[i][1]=0.f; acc[i][2]=0.f; acc[i][3]=0.f; }
  for(int ks=0;ks<16;ks++){
    bf16x8 af = *(const bf16x8*)&SEb[(row0+lo)*512 + ks*32 + hi*8];
    #pragma unroll
    for(int ct=0;ct<12;ct++){
      bf16x8 bf = *(const bf16x8*)&Wpack[((ct*16+ks)<<9) + lane*8];
      acc[ct] = __builtin_amdgcn_mfma_f32_16x16x32_bf16(af, bf, acc[ct], 0,0,0);
    }
  }
  #pragma unroll
  for(int ct=0;ct<12;ct++){
    int c96 = ((ct<6)? ct : ct-6)*16 + lo;
    int kq = c96>>5, d = c96&31;
    unsigned short* dst = (ct<6)? SQb : SKb;
    #pragma unroll
    for(int r=0;r<4;r++){
      int n = row0 + hi*4 + r;
      int b = n>>10, nl = n&1023;
      dst[((b*3+kq)*1024+nl)*32 + d] = f2b(acc[ct][r]);
    }
  }
}

// ---------------- K7: fused spatial attention + graph conv (MFMA flash) ----------------
#define SCALE7 0.17677669529663687f
__global__ __launch_bounds__(256) void k7_spatial(const unsigned short* __restrict__ SQb,
    const unsigned short* __restrict__ SKb, const unsigned* __restrict__ mc,
    const float* __restrict__ x, float* __restrict__ rhsT){
  const int blk=blockIdx.x;
  const int mt=blk&15, bk=blk>>4;
  const int k=bk%3, b=bk/3;
  const int m0=mt*64;
  const int tid=threadIdx.x;
  const int w=tid>>6, lane=tid&63, g=lane>>4, col=lane&15;

  __shared__ unsigned short xs[16*128];

  const int m_glob = m0 + w*16 + col;
  bf16x8 bfrag = *(const bf16x8*)&SKb[((bk<<10)+m_glob)*32 + g*8];

  f32x4 O = {0.f,0.f,0.f,0.f};
  float mrun=-1e30f, lrun=0.f;

  const float* xb = x + b*12288;
  const unsigned* mck = mc + k*1048576;
  const int swz = (col&7)<<3;

  for(int i=tid;i<512;i+=256){ int t=12+(i>>7), n=i&127; xs[t*128 + (n ^ ((t&7)<<3))]=0; }

  for(int ch=0; ch<8; ++ch){
    const int n0 = ch<<7;
    __syncthreads();
    for(int i=tid;i<1536;i+=256){
      int n=i/12, t=i-n*12;
      xs[t*128 + (n ^ ((t&7)<<3))] = f2b(xb[n0*12 + i]);
    }
    __syncthreads();

    f32x4 acc[8];
    #pragma unroll
    for(int nt=0;nt<8;nt++){
      bf16x8 afrag = *(const bf16x8*)&SQb[((bk<<10) + n0 + nt*16 + col)*32 + g*8];
      f32x4 z = {0.f,0.f,0.f,0.f};
      acc[nt] = __builtin_amdgcn_mfma_f32_16x16x32_bf16(afrag, bfrag, z, 0,0,0);
    }
    unsigned mcv[8][4];
    #pragma unroll
    for(int nt=0;nt<8;nt++){
      int nbase = n0 + nt*16 + g*4;
      #pragma unroll
      for(int r=0;r<4;r++) mcv[nt][r] = mck[(nbase+r)*1024 + m_glob];
    }
    float cmax = -1e30f;
    #pragma unroll
    for(int nt=0;nt<8;nt++){
      #pragma unroll
      for(int r=0;r<4;r++){
        float s = acc[nt][r]*SCALE7 + __uint_as_float(mcv[nt][r]<<16);
        acc[nt][r]=s;
        cmax=fmaxf(cmax,s);
      }
    }
    cmax = fmaxf(cmax, __shfl_xor(cmax,16,64));
    cmax = fmaxf(cmax, __shfl_xor(cmax,32,64));
    float mnew = fmaxf(mrun, cmax);
    float alpha = __expf(mrun - mnew);
    float lsum = 0.f;
    unsigned short pb[8][4];
    #pragma unroll
    for(int nt=0;nt<8;nt++){
      #pragma unroll
      for(int r=0;r<4;r++){
        float e = __expf(acc[nt][r] - mnew);
        lsum += e;
        pb[nt][r] = f2b(e * __uint_as_float(mcv[nt][r] & 0xffff0000u));
      }
    }
    lsum += __shfl_xor(lsum,16,64);
    lsum += __shfl_xor(lsum,32,64);
    lrun = lrun*alpha + lsum;
    mrun = mnew;
    O[0]*=alpha; O[1]*=alpha; O[2]*=alpha; O[3]*=alpha;

    #pragma unroll
    for(int c=0;c<4;c++){
      bf16x8 pf;
      #pragma unroll
      for(int j=0;j<4;j++){ pf[j]=(short)pb[2*c][j]; pf[j+4]=(short)pb[2*c+1][j]; }
      int nlo = c*32 + g*4;
      bf16x4 lo = *(const bf16x4*)&xs[col*128 + (nlo ^ swz)];
      bf16x4 hi = *(const bf16x4*)&xs[col*128 + ((nlo+16) ^ swz)];
      bf16x8 ax;
      #pragma unroll
      for(int j=0;j<4;j++){ ax[j]=lo[j]; ax[j+4]=hi[j]; }
      O = __builtin_amdgcn_mfma_f32_16x16x32_bf16(ax, pf, O, 0,0,0);
    }
  }
  float inv = 1.f/lrun;
  #pragma unroll
  for(int r=0;r<4;r++){
    int t = g*4+r;
    if(t<12) rhsT[((bk*12+t)<<10) + m_glob] = O[r]*inv;
  }
}

// ---------------- K8: pack conv weights into MFMA A-fragment layout ----------------
__global__ __launch_bounds__(256) void k8_prep(const float* __restrict__ g3w, const float* __restrict__ g5w,
    const float* __restrict__ g7w, unsigned short* __restrict__ Apack){
  int idx = blockIdx.x*256+threadIdx.x;      // 240*64 = 15360
  if(idx>=15360) return;
  int frag=idx>>6, lane=idx&63;
  int rt, s, kappa; const float* W;
  if(frag<48){ rt=frag/6; s=frag-rt*6; kappa=3; W=g3w; }
  else if(frag<128){ int f=frag-48; rt=f/10; s=f-rt*10; kappa=5; W=g5w; }
  else { int f=frag-128; rt=f/14; s=f-rt*14; kappa=7; W=g7w; }
  int c = rt*16 + (lane&15);
  int dt = s>>1, ic0=(s&1)*32 + (lane>>4)*8;
  #pragma unroll
  for(int j=0;j<8;j++) Apack[idx*8+j]=f2b(W[(c*64+ic0+j)*kappa + dt]);
}

// ---------------- K9: theta-contract + MFMA GTU convs + in-register fc + residual + LN ----------------
// 8 (b,n) per block, 4 waves. Wave w owns channel rows {w*16..w*16+15} as (c, c+64) pairs.
// Gated values stay in registers; fc contraction done per-lane + one shfl_xor(8) reduce
// (partner lane holds the other tau2-half). No G LDS tile -> no 32-way conflicts.
__global__ __launch_bounds__(256) void k9_final(const float* __restrict__ rhsT, const float* __restrict__ theta,
    const unsigned short* __restrict__ Apack,
    const float* __restrict__ g3b, const float* __restrict__ g5b, const float* __restrict__ g7b,
    const float* __restrict__ fcw, const float* __restrict__ fcb,
    const float* __restrict__ rw, const float* __restrict__ rb,
    const float* __restrict__ gln, const float* __restrict__ bln,
    const float* __restrict__ x, float* __restrict__ out){
  int bn0=blockIdx.x*8;
  int tid=threadIdx.x;
  const int b=bn0>>10, n0=bn0&1023;

  __shared__ union {
    struct { unsigned short Xl[12*8*64]; float rstage[3][12][8]; } p0;
    float XP[8][772];
  } U;
  __shared__ float xres[8][12];
  __shared__ float mu8[8][12], rs8[8][12];

  for(int i=tid;i<288;i+=256){
    int kk=i/96; int rem=i-kk*96; int t=rem>>3; int g=rem&7;
    U.p0.rstage[kk][t][g]=rhsT[((b*3+kk)*12+t)*1024 + n0 + g];
  }
  for(int i=tid;i<96;i+=256){ int g=i/12, t=i-(i/12)*12; xres[g][t]=x[(bn0+g)*12+t]; }
  __syncthreads();

  // phase0: Xl[t][g][ic] = bf16(relu(sum_kk rstage*theta)), g-XOR-swizzled, ic-pairs
  {
    int g=tid>>5, icp=tid&31;
    float th0[3], th1[3];
    #pragma unroll
    for(int kk=0;kk<3;kk++){ th0[kk]=theta[kk*64+2*icp]; th1[kk]=theta[kk*64+2*icp+1]; }
    #pragma unroll
    for(int t=0;t<12;t++){
      float r0=U.p0.rstage[0][t][g], r1=U.p0.rstage[1][t][g], r2=U.p0.rstage[2][t][g];
      float a0=fmaxf(r0*th0[0]+r1*th0[1]+r2*th0[2],0.f);
      float a1=fmaxf(r0*th1[0]+r1*th1[1]+r2*th1[2],0.f);
      unsigned pack = (((unsigned)f2b(a1))<<16)|(unsigned)f2b(a0);
      *(unsigned*)((char*)U.p0.Xl + ((t*8+g)<<7) + ((icp*4) ^ (g<<4))) = pack;
    }
  }
  __syncthreads();

  const int w=tid>>6, lane=tid&63, halfk=lane>>4, colq=lane&15;
  const int gg=colq&7, tau2=colq>>3;
  const int ca = w*16 + halfk*4;

  f32x4 acA[12], acB[12];
  #pragma unroll
  for(int j=0;j<5;j++){
    #pragma unroll
    for(int r=0;r<4;r++){ acA[j][r]=g3b[ca+r]; acB[j][r]=g3b[64+ca+r]; }
  }
  #pragma unroll
  for(int j=5;j<9;j++){
    #pragma unroll
    for(int r=0;r<4;r++){ acA[j][r]=g5b[ca+r]; acB[j][r]=g5b[64+ca+r]; }
  }
  #pragma unroll
  for(int j=9;j<12;j++){
    #pragma unroll
    for(int r=0;r<4;r++){ acA[j][r]=g7b[ca+r]; acB[j][r]=g7b[64+ca+r]; }
  }

  const char* xlb = (const char*)U.p0.Xl;
  #pragma unroll
  for(int s=0;s<6;s++){
    bf16x8 a0 = *(const bf16x8*)&Apack[((w  )*6 + s)*512 + lane*8];
    bf16x8 a1 = *(const bf16x8*)&Apack[((w+4)*6 + s)*512 + lane*8];
    int dt=s>>1;
    int sl = ((((s&1)*32 + halfk*8)*2) ^ (gg<<4));
    #pragma unroll
    for(int j=0;j<5;j++){
      int t=2*j+tau2+dt;
      bf16x8 bf = *(const bf16x8*)(xlb + ((t*8+gg)<<7) + sl);
      acA[j] = __builtin_amdgcn_mfma_f32_16x16x32_bf16(a0, bf, acA[j], 0,0,0);
      acB[j] = __builtin_amdgcn_mfma_f32_16x16x32_bf16(a1, bf, acB[j], 0,0,0);
    }
  }
  #pragma unroll
  for(int s=0;s<10;s++){
    bf16x8 a0 = *(const bf16x8*)&Apack[(48 + (w  )*10 + s)*512 + lane*8];
    bf16x8 a1 = *(const bf16x8*)&Apack[(48 + (w+4)*10 + s)*512 + lane*8];
    int dt=s>>1;
    int sl = ((((s&1)*32 + halfk*8)*2) ^ (gg<<4));
    #pragma unroll
    for(int j=0;j<4;j++){
      int t=2*j+tau2+dt;
      bf16x8 bf = *(const bf16x8*)(xlb + ((t*8+gg)<<7) + sl);
      acA[5+j] = __builtin_amdgcn_mfma_f32_16x16x32_bf16(a0, bf, acA[5+j], 0,0,0);
      acB[5+j] = __builtin_amdgcn_mfma_f32_16x16x32_bf16(a1, bf, acB[5+j], 0,0,0);
    }
  }
  #pragma unroll
  for(int s=0;s<14;s++){
    bf16x8 a0 = *(const bf16x8*)&Apack[(128 + (w  )*14 + s)*512 + lane*8];
    bf16x8 a1 = *(const bf16x8*)&Apack[(128 + (w+4)*14 + s)*512 + lane*8];
    int dt=s>>1;
    int sl = ((((s&1)*32 + halfk*8)*2) ^ (gg<<4));
    #pragma unroll
    for(int j=0;j<3;j++){
      int t=2*j+tau2+dt;
      bf16x8 bf = *(const bf16x8*)(xlb + ((t*8+gg)<<7) + sl);
      acA[9+j] = __builtin_amdgcn_mfma_f32_16x16x32_bf16(a0, bf, acA[9+j], 0,0,0);
      acB[9+j] = __builtin_amdgcn_mfma_f32_16x16x32_bf16(a1, bf, acB[9+j], 0,0,0);
    }
  }

  // gating -> registers (lane holds c=ca+r, tau=tb+tau2, g=gg)
  float gv[12][4];
  #pragma unroll
  for(int j=0;j<12;j++){
    #pragma unroll
    for(int r=0;r<4;r++){
      float ya=acA[j][r], yb=acB[j][r];
      float e2=__expf(2.f*ya);
      float th=1.f - 2.f/(e2+1.f);
      float sg=1.f/(1.f+__expf(-yb));
      gv[j][r]=th*sg;
    }
  }
  __syncthreads();   // all waves done reading Xl; XP (union) becomes writable

  // phase2: per-lane partial fc over this lane's 12 taus, all 12 t
  float acc[4][12];
  #pragma unroll
  for(int r=0;r<4;r++)
    #pragma unroll
    for(int t=0;t<12;t++) acc[r][t]=0.f;
  #pragma unroll
  for(int j=0;j<12;j++){
    int tb = (j<5)? 2*j : ((j<9)? 10+2*(j-5) : 18+2*(j-9));
    int tau = tb + tau2;
    const float4* fr = (const float4*)&fcw[tau*12];
    float4 f0=fr[0], f1=fr[1], f2=fr[2];
    float fv[12]={f0.x,f0.y,f0.z,f0.w, f1.x,f1.y,f1.z,f1.w, f2.x,f2.y,f2.z,f2.w};
    #pragma unroll
    for(int r=0;r<4;r++){
      float g0=gv[j][r];
      #pragma unroll
      for(int t=0;t<12;t++) acc[r][t] += g0*fv[t];
    }
  }
  // combine tau2 halves (partner lane = colq^8)
  #pragma unroll
  for(int r=0;r<4;r++)
    #pragma unroll
    for(int t=0;t<12;t++) acc[r][t] += __shfl_xor(acc[r][t], 8, 64);

  // write this lane's half of t, fused residual + relu
  {
    float rwa[4], rba[4];
    #pragma unroll
    for(int r=0;r<4;r++){ rwa[r]=rw[ca+r]; rba[r]=rb[ca+r]; }
    int t0 = tau2*6;
    #pragma unroll
    for(int tt=0;tt<6;tt++){
      int t=t0+tt;
      float fb=fcb[t];
      float xv=xres[gg][t];
      #pragma unroll
      for(int r=0;r<4;r++){
        float tv = fmaxf(acc[r][t]+fb, 0.f);
        float xr = xv*rwa[r]+rba[r];
        U.XP[gg][(ca+r)*12+t] = fmaxf(xr+tv, 0.f);
      }
    }
  }
  __syncthreads();

  // phase3: LN over c
  if(tid<96){
    int g=tid/12, t=tid-(tid/12)*12;
    float s=0.f;
    for(int c=0;c<64;c++) s+=U.XP[g][c*12+t];
    float mu=s*(1.f/64.f);
    float q=0.f;
    for(int c=0;c<64;c++){float d=U.XP[g][c*12+t]-mu;q+=d*d;}
    mu8[g][t]=mu; rs8[g][t]=rsqrtf(q*(1.f/64.f)+EPS);
  }
  __syncthreads();
  for(int o=tid;o<8*768;o+=256){
    int g=o/768; int ct=o-g*768; int c=ct/12; int t=ct-c*12;
    out[(long)(bn0+g)*768 + ct]=(U.XP[g][c*12+t]-mu8[g][t])*rs8[g][t]*gln[c]+bln[c];
  }
}

// ---------------- launch ----------------
extern "C" void kernel_launch(void* const* d_in, const int* in_sizes, int n_in,
                              void* d_out, int out_size, void* d_ws, size_t ws_size,
                              hipStream_t stream){
  const float* x    =(const float*)d_in[0];
  const float* res  =(const float*)d_in[1];
  const float* posT =(const float*)d_in[2];
  const float* gT   =(const float*)d_in[3];
  const float* bT   =(const float*)d_in[4];
  const float* wq   =(const float*)d_in[5];
  const float* wk   =(const float*)d_in[6];
  const float* wv   =(const float*)d_in[7];
  const float* fcW  =(const float*)d_in[8];
  const float* prw  =(const float*)d_in[9];
  const float* prb  =(const float*)d_in[10];
  const float* posS =(const float*)d_in[11];
  const float* gS   =(const float*)d_in[12];
  const float* bS   =(const float*)d_in[13];
  const float* swq  =(const float*)d_in[14];
  const float* swk  =(const float*)d_in[15];
  const float* cheb =(const float*)d_in[16];
  const float* adj  =(const float*)d_in[17];
  const float* cmask=(const float*)d_in[18];
  const float* theta=(const float*)d_in[19];
  const float* g3w=(const float*)d_in[20]; const float* g3b=(const float*)d_in[21];
  const float* g5w=(const float*)d_in[22]; const float* g5b=(const float*)d_in[23];
  const float* g7w=(const float*)d_in[24]; const float* g7b=(const float*)d_in[25];
  const float* fcw=(const float*)d_in[26]; const float* fcb=(const float*)d_in[27];
  const float* rw =(const float*)d_in[28]; const float* rb =(const float*)d_in[29];
  const float* gln=(const float*)d_in[30]; const float* bln=(const float*)d_in[31];

  float* outp=(float*)d_out;
  float* scores = outp + 12582912;

  float* wsf=(float*)d_ws;
  float* TEmx = wsf;                          // 196608 f
  float* qkv  = TEmx + 196608;                // 55296 f
  float* ctx  = qkv + 55296;                  // 18432 f
  float* TAT  = ctx + 18432;                  // 196608 f
  unsigned short* SEb = (unsigned short*)(TAT + 196608);          // 4194304 f
  unsigned short* SQb = (unsigned short*)((float*)SEb + 4194304); // 786432 f
  unsigned short* SKb = (unsigned short*)((float*)SQb + 786432);  // 786432 f
  unsigned* mc = (unsigned*)((float*)SKb + 786432);               // 3145728 f
  float* rhsT  = (float*)mc + 3145728;                            // 589824 f
  unsigned short* Apack = (unsigned short*)(rhsT + 589824);       // 122880 u16
  unsigned short* Wpack = Apack + 122880;                         // 98304 u16

  k0_prep<<<dim3(12288),dim3(256),0,stream>>>(adj,cmask,cheb,mc);
  k8_prep<<<dim3(60),dim3(256),0,stream>>>(g3w,g5w,g7w,Apack);
  kw_prep<<<dim3(48),dim3(256),0,stream>>>(swq,swk,Wpack);
  k1_embedT<<<dim3(192),dim3(256),0,stream>>>(x,posT,gT,bT,TEmx);
  k2_qkv<<<dim3(192),dim3(320),0,stream>>>(TEmx,wq,wk,wv,qkv);
  k3_attn<<<dim3(16),dim3(512),0,stream>>>(qkv,res,scores,ctx);
  k4_tat<<<dim3(192),dim3(256),0,stream>>>(ctx,fcW,TEmx,TAT);
  k5_semx<<<dim3(16384),dim3(256),0,stream>>>(TAT,prw,prb,posS,gS,bS,SEb);
  k6_sqk<<<dim3(256),dim3(256),0,stream>>>(SEb,Wpack,SQb,SKb);
  k7_spatial<<<dim3(768),dim3(256),0,stream>>>(SQb,SKb,mc,x,rhsT);
  k9_final<<<dim3(2048),dim3(256),0,stream>>>(rhsT,theta,Apack,g3b,g5b,g7b,
                                              fcw,fcb,rw,rb,gln,bln,x,outp);
}

// Round 6
// 295.830 us; speedup vs baseline: 5.0821x; 1.1846x over previous
//
#include <hip/hip_runtime.h>
#include <hip/hip_fp16.h>

#define EPS 1e-5f

typedef float f32x4 __attribute__((ext_vector_type(4)));
typedef short bf16x8 __attribute__((ext_vector_type(8)));
typedef short bf16x4 __attribute__((ext_vector_type(4)));

__device__ __forceinline__ unsigned short f2b(float f){
  unsigned u=__float_as_uint(f);
  return (unsigned short)((u + 0x7fffu + ((u>>16)&1u))>>16);
}
__device__ __forceinline__ float b2f(unsigned short h){
  return __uint_as_float(((unsigned)h)<<16);
}

// ---------------- helpers ----------------
__device__ __forceinline__ float blockSum256(float v, float* red){
  #pragma unroll
  for(int o=32;o>0;o>>=1) v += __shfl_down(v,o,64);
  int wid = threadIdx.x>>6;
  if((threadIdx.x&63)==0) red[wid]=v;
  __syncthreads();
  if(threadIdx.x==0) red[0]=red[0]+red[1]+red[2]+red[3];
  __syncthreads();
  float r = red[0];
  __syncthreads();
  return r;
}

// ---------------- K0: pack mask/cheb ----------------
__global__ __launch_bounds__(256) void k0_prep(const float* __restrict__ adj, const float* __restrict__ cmask,
    const float* __restrict__ cheb, unsigned* __restrict__ mc){
  int i = blockIdx.x*256 + threadIdx.x;
  int nm = i & 1048575;
  mc[i] = (((unsigned)f2b(cheb[i]))<<16) | (unsigned)f2b(adj[nm]*cmask[i]);
}

// ---------------- K1: EmbedT ----------------
__global__ __launch_bounds__(256) void k1_embedT(const float* __restrict__ x, const float* __restrict__ posT,
    const float* __restrict__ gT, const float* __restrict__ bT, float* __restrict__ TEmx){
  int bt=blockIdx.x; int b=bt/12, t=bt-b*12;
  int tid=threadIdx.x;
  __shared__ float red[4];
  float v[4]; float s=0.f;
  #pragma unroll
  for(int i=0;i<4;i++){ int n=tid+i*256; v[i]=x[(b*1024+n)*12+t]+posT[t*1024+n]; s+=v[i]; }
  s = blockSum256(s, red);
  float mu = s*(1.f/1024.f);
  float q=0.f;
  #pragma unroll
  for(int i=0;i<4;i++){ float d=v[i]-mu; q+=d*d; }
  q = blockSum256(q, red);
  float rstd = rsqrtf(q*(1.f/1024.f)+EPS);
  #pragma unroll
  for(int i=0;i<4;i++){ int n=tid+i*256; TEmx[bt*1024+n]=(v[i]-mu)*rstd*gT[n]+bT[n]; }
}

// ---------------- K2: QKV ----------------
__global__ __launch_bounds__(320) void k2_qkv(const float* __restrict__ TEmx, const float* __restrict__ wq,
    const float* __restrict__ wk, const float* __restrict__ wv, float* __restrict__ qkv){
  int bt=blockIdx.x; int tid=threadIdx.x;
  __shared__ float row[1024];
  for(int i=tid;i<1024;i+=320) row[i]=TEmx[bt*1024+i];
  __syncthreads();
  if(tid<288){
    int m=tid/96, col=tid-m*96;
    const float* w = (m==0)?wq:((m==1)?wk:wv);
    float acc=0.f;
    #pragma unroll 4
    for(int n=0;n<1024;n++) acc += row[n]*w[n*96+col];
    qkv[bt*288+tid]=acc;
  }
}

// ---------------- K3: temporal attn ----------------
__global__ __launch_bounds__(512) void k3_attn(const float* __restrict__ qkv, const float* __restrict__ res_att,
    float* __restrict__ scores_out, float* __restrict__ ctx){
  int b=blockIdx.x; int tid=threadIdx.x;
  __shared__ float sS[432];
  __shared__ float sA[432];
  if(tid<432){
    int h=tid/144; int r=tid-h*144; int q=r/12; int k2=r-q*12;
    const float* Qr=&qkv[(b*12+q)*288 + h*32];
    const float* Kr=&qkv[(b*12+k2)*288 + 96 + h*32];
    float acc=0.f;
    #pragma unroll
    for(int d=0;d<32;d++) acc+=Qr[d]*Kr[d];
    acc = acc*0.17677669529663687f + res_att[(b*3+h)*144 + q*12 + k2];
    sS[h*144+q*12+k2]=acc;
    scores_out[(b*3+h)*144 + q*12 + k2]=acc;
  }
  __syncthreads();
  if(tid<36){
    int h=tid/12, k2=tid-(tid/12)*12;
    float mx=-1e30f;
    for(int q=0;q<12;q++) mx=fmaxf(mx,sS[h*144+q*12+k2]);
    float sum=0.f;
    for(int q=0;q<12;q++){ float e=__expf(sS[h*144+q*12+k2]-mx); sA[h*144+q*12+k2]=e; sum+=e; }
    float inv=1.f/sum;
    for(int q=0;q<12;q++) sA[h*144+q*12+k2]*=inv;
  }
  __syncthreads();
  for(int o=tid;o<1152;o+=512){
    int h=o/384; int r=o-h*384; int q=r/32; int d=r-q*32;
    float acc=0.f;
    #pragma unroll
    for(int k2=0;k2<12;k2++) acc += sA[h*144+q*12+k2]*qkv[(b*12+k2)*288+192+h*32+d];
    ctx[(b*12+q)*96 + h*32 + d]=acc;
  }
}

// ---------------- K4: TATout ----------------
__global__ __launch_bounds__(256) void k4_tat(const float* __restrict__ ctx, const float* __restrict__ fcW,
    const float* __restrict__ TEmx, float* __restrict__ TAT){
  int bt=blockIdx.x; int tid=threadIdx.x;
  __shared__ float c96[96];
  __shared__ float red[4];
  if(tid<96) c96[tid]=ctx[bt*96+tid];
  __syncthreads();
  float v[4]; float s=0.f;
  #pragma unroll
  for(int i=0;i<4;i++){
    int n=tid+i*256;
    float acc=TEmx[bt*1024+n];
    #pragma unroll 4
    for(int j=0;j<96;j++) acc += c96[j]*fcW[j*1024+n];
    v[i]=acc; s+=acc;
  }
  s=blockSum256(s,red);
  float mu=s*(1.f/1024.f);
  float q=0.f;
  #pragma unroll
  for(int i=0;i<4;i++){float d=v[i]-mu;q+=d*d;}
  q=blockSum256(q,red);
  float rstd=rsqrtf(q*(1.f/1024.f)+EPS);
  #pragma unroll
  for(int i=0;i<4;i++){int n=tid+i*256; TAT[bt*1024+n]=(v[i]-mu)*rstd;}
}

// ---------------- K5: SEmx (bf16 out) ----------------
__global__ __launch_bounds__(256) void k5_semx(const float* __restrict__ TAT, const float* __restrict__ pre_w,
    const float* __restrict__ pre_b, const float* __restrict__ posS, const float* __restrict__ gS,
    const float* __restrict__ bS, unsigned short* __restrict__ SEb){
  int bn=blockIdx.x; int b=bn>>10, n=bn&1023; int tid=threadIdx.x;
  __shared__ float tv[12];
  __shared__ float red[4];
  if(tid<12) tv[tid]=TAT[(b*12+tid)*1024+n];
  __syncthreads();
  float v[2]; float s=0.f;
  #pragma unroll
  for(int i=0;i<2;i++){
    int d=tid+i*256;
    float acc=pre_b[d]+posS[n*512+d];
    #pragma unroll
    for(int t=0;t<12;t++) acc += tv[t]*pre_w[d*12+t];
    v[i]=acc; s+=acc;
  }
  s=blockSum256(s,red);
  float mu=s*(1.f/512.f);
  float q=0.f;
  #pragma unroll
  for(int i=0;i<2;i++){float d2=v[i]-mu;q+=d2*d2;}
  q=blockSum256(q,red);
  float rstd=rsqrtf(q*(1.f/512.f)+EPS);
  #pragma unroll
  for(int i=0;i<2;i++){int d=tid+i*256; SEb[bn*512+d]=f2b((v[i]-mu)*rstd*gS[d]+bS[d]);}
}

// ---------------- KW: pack swq/swk into MFMA B-fragment layout ----------------
__global__ __launch_bounds__(256) void kw_prep(const float* __restrict__ swq, const float* __restrict__ swk,
    unsigned short* __restrict__ Wpack){
  int idx = blockIdx.x*256+threadIdx.x;  // 12*16*64 = 12288
  if(idx>=12288) return;
  int frag=idx>>6, lane=idx&63;
  int ct=frag>>4, ks=frag&15;
  const float* W = (ct<6)? swq : swk;
  int c = ((ct<6)? ct : ct-6)*16 + (lane&15);
  int k0 = ks*32 + (lane>>4)*8;
  #pragma unroll
  for(int j=0;j<8;j++) Wpack[idx*8+j]=f2b(W[(k0+j)*96 + c]);
}

// ---------------- K6: SQ/SK via MFMA GEMM ----------------
__global__ __launch_bounds__(256) void k6_sqk(const unsigned short* __restrict__ SEb,
    const unsigned short* __restrict__ Wpack,
    unsigned short* __restrict__ SQb, unsigned short* __restrict__ SKb){
  int tid=threadIdx.x; int w=tid>>6, lane=tid&63;
  const int hi=lane>>4, lo=lane&15;
  const int row0 = blockIdx.x*64 + w*16;
  f32x4 acc[12];
  #pragma unroll
  for(int i=0;i<12;i++){ acc[i][0]=0.f; acc[i][1]=0.f; acc[i][2]=0.f; acc[i][3]=0.f; }
  for(int ks=0;ks<16;ks++){
    bf16x8 af = *(const bf16x8*)&SEb[(row0+lo)*512 + ks*32 + hi*8];
    #pragma unroll
    for(int ct=0;ct<12;ct++){
      bf16x8 bf = *(const bf16x8*)&Wpack[((ct*16+ks)<<9) + lane*8];
      acc[ct] = __builtin_amdgcn_mfma_f32_16x16x32_bf16(af, bf, acc[ct], 0,0,0);
    }
  }
  #pragma unroll
  for(int ct=0;ct<12;ct++){
    int c96 = ((ct<6)? ct : ct-6)*16 + lo;
    int kq = c96>>5, d = c96&31;
    unsigned short* dst = (ct<6)? SQb : SKb;
    #pragma unroll
    for(int r=0;r<4;r++){
      int n = row0 + hi*4 + r;
      int b = n>>10, nl = n&1023;
      dst[((b*3+kq)*1024+nl)*32 + d] = f2b(acc[ct][r]);
    }
  }
}

// ---------------- K7: fused spatial attention + graph conv (MFMA flash) ----------------
#define SCALE7 0.17677669529663687f
__global__ __launch_bounds__(256) void k7_spatial(const unsigned short* __restrict__ SQb,
    const unsigned short* __restrict__ SKb, const unsigned* __restrict__ mc,
    const float* __restrict__ x, float* __restrict__ rhsT){
  const int blk=blockIdx.x;
  const int mt=blk&15, bk=blk>>4;
  const int k=bk%3, b=bk/3;
  const int m0=mt*64;
  const int tid=threadIdx.x;
  const int w=tid>>6, lane=tid&63, g=lane>>4, col=lane&15;

  __shared__ unsigned short xs[16*128];

  const int m_glob = m0 + w*16 + col;
  bf16x8 bfrag = *(const bf16x8*)&SKb[((bk<<10)+m_glob)*32 + g*8];

  f32x4 O = {0.f,0.f,0.f,0.f};
  float mrun=-1e30f, lrun=0.f;

  const float* xb = x + b*12288;
  const unsigned* mck = mc + k*1048576;
  const int swz = (col&7)<<3;

  for(int i=tid;i<512;i+=256){ int t=12+(i>>7), n=i&127; xs[t*128 + (n ^ ((t&7)<<3))]=0; }

  for(int ch=0; ch<8; ++ch){
    const int n0 = ch<<7;
    __syncthreads();
    for(int i=tid;i<1536;i+=256){
      int n=i/12, t=i-n*12;
      xs[t*128 + (n ^ ((t&7)<<3))] = f2b(xb[n0*12 + i]);
    }
    __syncthreads();

    f32x4 acc[8];
    #pragma unroll
    for(int nt=0;nt<8;nt++){
      bf16x8 afrag = *(const bf16x8*)&SQb[((bk<<10) + n0 + nt*16 + col)*32 + g*8];
      f32x4 z = {0.f,0.f,0.f,0.f};
      acc[nt] = __builtin_amdgcn_mfma_f32_16x16x32_bf16(afrag, bfrag, z, 0,0,0);
    }
    unsigned mcv[8][4];
    #pragma unroll
    for(int nt=0;nt<8;nt++){
      int nbase = n0 + nt*16 + g*4;
      #pragma unroll
      for(int r=0;r<4;r++) mcv[nt][r] = mck[(nbase+r)*1024 + m_glob];
    }
    float cmax = -1e30f;
    #pragma unroll
    for(int nt=0;nt<8;nt++){
      #pragma unroll
      for(int r=0;r<4;r++){
        float s = acc[nt][r]*SCALE7 + __uint_as_float(mcv[nt][r]<<16);
        acc[nt][r]=s;
        cmax=fmaxf(cmax,s);
      }
    }
    cmax = fmaxf(cmax, __shfl_xor(cmax,16,64));
    cmax = fmaxf(cmax, __shfl_xor(cmax,32,64));
    float mnew = fmaxf(mrun, cmax);
    float alpha = __expf(mrun - mnew);
    float lsum = 0.f;
    unsigned short pb[8][4];
    #pragma unroll
    for(int nt=0;nt<8;nt++){
      #pragma unroll
      for(int r=0;r<4;r++){
        float e = __expf(acc[nt][r] - mnew);
        lsum += e;
        pb[nt][r] = f2b(e * __uint_as_float(mcv[nt][r] & 0xffff0000u));
      }
    }
    lsum += __shfl_xor(lsum,16,64);
    lsum += __shfl_xor(lsum,32,64);
    lrun = lrun*alpha + lsum;
    mrun = mnew;
    O[0]*=alpha; O[1]*=alpha; O[2]*=alpha; O[3]*=alpha;

    #pragma unroll
    for(int c=0;c<4;c++){
      bf16x8 pf;
      #pragma unroll
      for(int j=0;j<4;j++){ pf[j]=(short)pb[2*c][j]; pf[j+4]=(short)pb[2*c+1][j]; }
      int nlo = c*32 + g*4;
      bf16x4 lo = *(const bf16x4*)&xs[col*128 + (nlo ^ swz)];
      bf16x4 hi = *(const bf16x4*)&xs[col*128 + ((nlo+16) ^ swz)];
      bf16x8 ax;
      #pragma unroll
      for(int j=0;j<4;j++){ ax[j]=lo[j]; ax[j+4]=hi[j]; }
      O = __builtin_amdgcn_mfma_f32_16x16x32_bf16(ax, pf, O, 0,0,0);
    }
  }
  float inv = 1.f/lrun;
  #pragma unroll
  for(int r=0;r<4;r++){
    int t = g*4+r;
    if(t<12) rhsT[((bk*12+t)<<10) + m_glob] = O[r]*inv;
  }
}

// ---------------- K8: pack conv weights into MFMA A-fragment layout ----------------
__global__ __launch_bounds__(256) void k8_prep(const float* __restrict__ g3w, const float* __restrict__ g5w,
    const float* __restrict__ g7w, unsigned short* __restrict__ Apack){
  int idx = blockIdx.x*256+threadIdx.x;      // 240*64 = 15360
  if(idx>=15360) return;
  int frag=idx>>6, lane=idx&63;
  int rt, s, kappa; const float* W;
  if(frag<48){ rt=frag/6; s=frag-rt*6; kappa=3; W=g3w; }
  else if(frag<128){ int f=frag-48; rt=f/10; s=f-rt*10; kappa=5; W=g5w; }
  else { int f=frag-128; rt=f/14; s=f-rt*14; kappa=7; W=g7w; }
  int c = rt*16 + (lane&15);
  int dt = s>>1, ic0=(s&1)*32 + (lane>>4)*8;
  #pragma unroll
  for(int j=0;j<8;j++) Apack[idx*8+j]=f2b(W[(c*64+ic0+j)*kappa + dt]);
}

// ---------------- K9: theta-contract + MFMA GTU convs (grouped) + in-reg fc + residual + LN ----
// Register-pressure-shaped: each conv group's accumulators live only within its scope;
// gating + fc folding happen immediately after each group. fc acc = facc[6][4] (lane's
// own t-half); partner's tau2-half contribution via per-j shfl_xor(gv,8).
__global__ __launch_bounds__(256) void k9_final(const float* __restrict__ rhsT, const float* __restrict__ theta,
    const unsigned short* __restrict__ Apack,
    const float* __restrict__ g3b, const float* __restrict__ g5b, const float* __restrict__ g7b,
    const float* __restrict__ fcw, const float* __restrict__ fcb,
    const float* __restrict__ rw, const float* __restrict__ rb,
    const float* __restrict__ gln, const float* __restrict__ bln,
    const float* __restrict__ x, float* __restrict__ out){
  int bn0=blockIdx.x*8;
  int tid=threadIdx.x;
  const int b=bn0>>10, n0=bn0&1023;

  __shared__ union {
    struct { unsigned short Xl[12*8*64]; float rstage[3][12][8]; } p0;
    float XP[8][772];
  } U;
  __shared__ float xres[8][12];
  __shared__ float mu8[8][12], rs8[8][12];

  for(int i=tid;i<288;i+=256){
    int kk=i/96; int rem=i-kk*96; int t=rem>>3; int g=rem&7;
    U.p0.rstage[kk][t][g]=rhsT[((b*3+kk)*12+t)*1024 + n0 + g];
  }
  for(int i=tid;i<96;i+=256){ int g=i/12, t=i-(i/12)*12; xres[g][t]=x[(bn0+g)*12+t]; }
  __syncthreads();

  // phase0: Xl[t][g][ic] = bf16(relu(sum_kk rstage*theta)), g-XOR-swizzled, ic-pairs
  {
    int g=tid>>5, icp=tid&31;
    float th0[3], th1[3];
    #pragma unroll
    for(int kk=0;kk<3;kk++){ th0[kk]=theta[kk*64+2*icp]; th1[kk]=theta[kk*64+2*icp+1]; }
    #pragma unroll
    for(int t=0;t<12;t++){
      float r0=U.p0.rstage[0][t][g], r1=U.p0.rstage[1][t][g], r2=U.p0.rstage[2][t][g];
      float a0=fmaxf(r0*th0[0]+r1*th0[1]+r2*th0[2],0.f);
      float a1=fmaxf(r0*th1[0]+r1*th1[1]+r2*th1[2],0.f);
      unsigned pack = (((unsigned)f2b(a1))<<16)|(unsigned)f2b(a0);
      *(unsigned*)((char*)U.p0.Xl + ((t*8+g)<<7) + ((icp*4) ^ (g<<4))) = pack;
    }
  }
  __syncthreads();

  const int w=tid>>6, lane=tid&63, halfk=lane>>4, colq=lane&15;
  const int gg=colq&7, tau2=colq>>3;
  const int ca = w*16 + halfk*4;
  const int t0 = tau2*6;
  const char* xlb = (const char*)U.p0.Xl;

  float facc[6][4];
  #pragma unroll
  for(int tt=0;tt<6;tt++)
    #pragma unroll
    for(int r=0;r<4;r++) facc[tt][r]=0.f;

  // ---- group kappa=3: 5 col-tiles, 6 K-steps ----
  {
    f32x4 acA[5], acB[5];
    #pragma unroll
    for(int j=0;j<5;j++)
      #pragma unroll
      for(int r=0;r<4;r++){ acA[j][r]=g3b[ca+r]; acB[j][r]=g3b[64+ca+r]; }
    #pragma unroll
    for(int s=0;s<6;s++){
      bf16x8 a0 = *(const bf16x8*)&Apack[((w  )*6 + s)*512 + lane*8];
      bf16x8 a1 = *(const bf16x8*)&Apack[((w+4)*6 + s)*512 + lane*8];
      int dt=s>>1;
      int sl = ((((s&1)*32 + halfk*8)*2) ^ (gg<<4));
      #pragma unroll
      for(int j=0;j<5;j++){
        int t=2*j+tau2+dt;
        bf16x8 bf = *(const bf16x8*)(xlb + ((t*8+gg)<<7) + sl);
        acA[j] = __builtin_amdgcn_mfma_f32_16x16x32_bf16(a0, bf, acA[j], 0,0,0);
        acB[j] = __builtin_amdgcn_mfma_f32_16x16x32_bf16(a1, bf, acB[j], 0,0,0);
      }
    }
    #pragma unroll
    for(int j=0;j<5;j++){
      int tb=2*j;
      float gv[4], gvp[4];
      #pragma unroll
      for(int r=0;r<4;r++){
        float ya=acA[j][r], yb=acB[j][r];
        float e2=__expf(2.f*ya);
        float th=1.f - 2.f/(e2+1.f);
        float sg=1.f/(1.f+__expf(-yb));
        gv[r]=th*sg;
      }
      #pragma unroll
      for(int r=0;r<4;r++) gvp[r]=__shfl_xor(gv[r],8,64);
      const float* fo=&fcw[(tb+tau2)*12 + t0];
      const float* fp=&fcw[(tb+(tau2^1))*12 + t0];
      #pragma unroll
      for(int tt=0;tt<6;tt++){
        float a=fo[tt], p=fp[tt];
        #pragma unroll
        for(int r=0;r<4;r++) facc[tt][r] += gv[r]*a + gvp[r]*p;
      }
    }
  }
  // ---- group kappa=5: 4 col-tiles, 10 K-steps ----
  {
    f32x4 acA[4], acB[4];
    #pragma unroll
    for(int j=0;j<4;j++)
      #pragma unroll
      for(int r=0;r<4;r++){ acA[j][r]=g5b[ca+r]; acB[j][r]=g5b[64+ca+r]; }
    #pragma unroll
    for(int s=0;s<10;s++){
      bf16x8 a0 = *(const bf16x8*)&Apack[(48 + (w  )*10 + s)*512 + lane*8];
      bf16x8 a1 = *(const bf16x8*)&Apack[(48 + (w+4)*10 + s)*512 + lane*8];
      int dt=s>>1;
      int sl = ((((s&1)*32 + halfk*8)*2) ^ (gg<<4));
      #pragma unroll
      for(int j=0;j<4;j++){
        int t=2*j+tau2+dt;
        bf16x8 bf = *(const bf16x8*)(xlb + ((t*8+gg)<<7) + sl);
        acA[j] = __builtin_amdgcn_mfma_f32_16x16x32_bf16(a0, bf, acA[j], 0,0,0);
        acB[j] = __builtin_amdgcn_mfma_f32_16x16x32_bf16(a1, bf, acB[j], 0,0,0);
      }
    }
    #pragma unroll
    for(int j=0;j<4;j++){
      int tb=10+2*j;
      float gv[4], gvp[4];
      #pragma unroll
      for(int r=0;r<4;r++){
        float ya=acA[j][r], yb=acB[j][r];
        float e2=__expf(2.f*ya);
        float th=1.f - 2.f/(e2+1.f);
        float sg=1.f/(1.f+__expf(-yb));
        gv[r]=th*sg;
      }
      #pragma unroll
      for(int r=0;r<4;r++) gvp[r]=__shfl_xor(gv[r],8,64);
      const float* fo=&fcw[(tb+tau2)*12 + t0];
      const float* fp=&fcw[(tb+(tau2^1))*12 + t0];
      #pragma unroll
      for(int tt=0;tt<6;tt++){
        float a=fo[tt], p=fp[tt];
        #pragma unroll
        for(int r=0;r<4;r++) facc[tt][r] += gv[r]*a + gvp[r]*p;
      }
    }
  }
  // ---- group kappa=7: 3 col-tiles, 14 K-steps ----
  {
    f32x4 acA[3], acB[3];
    #pragma unroll
    for(int j=0;j<3;j++)
      #pragma unroll
      for(int r=0;r<4;r++){ acA[j][r]=g7b[ca+r]; acB[j][r]=g7b[64+ca+r]; }
    #pragma unroll
    for(int s=0;s<14;s++){
      bf16x8 a0 = *(const bf16x8*)&Apack[(128 + (w  )*14 + s)*512 + lane*8];
      bf16x8 a1 = *(const bf16x8*)&Apack[(128 + (w+4)*14 + s)*512 + lane*8];
      int dt=s>>1;
      int sl = ((((s&1)*32 + halfk*8)*2) ^ (gg<<4));
      #pragma unroll
      for(int j=0;j<3;j++){
        int t=2*j+tau2+dt;
        bf16x8 bf = *(const bf16x8*)(xlb + ((t*8+gg)<<7) + sl);
        acA[j] = __builtin_amdgcn_mfma_f32_16x16x32_bf16(a0, bf, acA[j], 0,0,0);
        acB[j] = __builtin_amdgcn_mfma_f32_16x16x32_bf16(a1, bf, acB[j], 0,0,0);
      }
    }
    #pragma unroll
    for(int j=0;j<3;j++){
      int tb=18+2*j;
      float gv[4], gvp[4];
      #pragma unroll
      for(int r=0;r<4;r++){
        float ya=acA[j][r], yb=acB[j][r];
        float e2=__expf(2.f*ya);
        float th=1.f - 2.f/(e2+1.f);
        float sg=1.f/(1.f+__expf(-yb));
        gv[r]=th*sg;
      }
      #pragma unroll
      for(int r=0;r<4;r++) gvp[r]=__shfl_xor(gv[r],8,64);
      const float* fo=&fcw[(tb+tau2)*12 + t0];
      const float* fp=&fcw[(tb+(tau2^1))*12 + t0];
      #pragma unroll
      for(int tt=0;tt<6;tt++){
        float a=fo[tt], p=fp[tt];
        #pragma unroll
        for(int r=0;r<4;r++) facc[tt][r] += gv[r]*a + gvp[r]*p;
      }
    }
  }

  __syncthreads();   // all waves done reading Xl; XP (union) becomes writable

  // write this lane's t-half, fused fc-bias + residual + relu
  {
    float rwa[4], rba[4];
    #pragma unroll
    for(int r=0;r<4;r++){ rwa[r]=rw[ca+r]; rba[r]=rb[ca+r]; }
    #pragma unroll
    for(int tt=0;tt<6;tt++){
      int t=t0+tt;
      float fb=fcb[t];
      float xv=xres[gg][t];
      #pragma unroll
      for(int r=0;r<4;r++){
        float tv = fmaxf(facc[tt][r]+fb, 0.f);
        float xr = xv*rwa[r]+rba[r];
        U.XP[gg][(ca+r)*12+t] = fmaxf(xr+tv, 0.f);
      }
    }
  }
  __syncthreads();

  // phase3: LN over c
  if(tid<96){
    int g=tid/12, t=tid-(tid/12)*12;
    float s=0.f;
    for(int c=0;c<64;c++) s+=U.XP[g][c*12+t];
    float mu=s*(1.f/64.f);
    float q=0.f;
    for(int c=0;c<64;c++){float d=U.XP[g][c*12+t]-mu;q+=d*d;}
    mu8[g][t]=mu; rs8[g][t]=rsqrtf(q*(1.f/64.f)+EPS);
  }
  __syncthreads();
  for(int o=tid;o<8*768;o+=256){
    int g=o/768; int ct=o-g*768; int c=ct/12; int t=ct-c*12;
    out[(long)(bn0+g)*768 + ct]=(U.XP[g][c*12+t]-mu8[g][t])*rs8[g][t]*gln[c]+bln[c];
  }
}

// ---------------- launch ----------------
extern "C" void kernel_launch(void* const* d_in, const int* in_sizes, int n_in,
                              void* d_out, int out_size, void* d_ws, size_t ws_size,
                              hipStream_t stream){
  const float* x    =(const float*)d_in[0];
  const float* res  =(const float*)d_in[1];
  const float* posT =(const float*)d_in[2];
  const float* gT   =(const float*)d_in[3];
  const float* bT   =(const float*)d_in[4];
  const float* wq   =(const float*)d_in[5];
  const float* wk   =(const float*)d_in[6];
  const float* wv   =(const float*)d_in[7];
  const float* fcW  =(const float*)d_in[8];
  const float* prw  =(const float*)d_in[9];
  const float* prb  =(const float*)d_in[10];
  const float* posS =(const float*)d_in[11];
  const float* gS   =(const float*)d_in[12];
  const float* bS   =(const float*)d_in[13];
  const float* swq  =(const float*)d_in[14];
  const float* swk  =(const float*)d_in[15];
  const float* cheb =(const float*)d_in[16];
  const float* adj  =(const float*)d_in[17];
  const float* cmask=(const float*)d_in[18];
  const float* theta=(const float*)d_in[19];
  const float* g3w=(const float*)d_in[20]; const float* g3b=(const float*)d_in[21];
  const float* g5w=(const float*)d_in[22]; const float* g5b=(const float*)d_in[23];
  const float* g7w=(const float*)d_in[24]; const float* g7b=(const float*)d_in[25];
  const float* fcw=(const float*)d_in[26]; const float* fcb=(const float*)d_in[27];
  const float* rw =(const float*)d_in[28]; const float* rb =(const float*)d_in[29];
  const float* gln=(const float*)d_in[30]; const float* bln=(const float*)d_in[31];

  float* outp=(float*)d_out;
  float* scores = outp + 12582912;

  float* wsf=(float*)d_ws;
  float* TEmx = wsf;                          // 196608 f
  float* qkv  = TEmx + 196608;                // 55296 f
  float* ctx  = qkv + 55296;                  // 18432 f
  float* TAT  = ctx + 18432;                  // 196608 f
  unsigned short* SEb = (unsigned short*)(TAT + 196608);          // 4194304 f
  unsigned short* SQb = (unsigned short*)((float*)SEb + 4194304); // 786432 f
  unsigned short* SKb = (unsigned short*)((float*)SQb + 786432);  // 786432 f
  unsigned* mc = (unsigned*)((float*)SKb + 786432);               // 3145728 f
  float* rhsT  = (float*)mc + 3145728;                            // 589824 f
  unsigned short* Apack = (unsigned short*)(rhsT + 589824);       // 122880 u16
  unsigned short* Wpack = Apack + 122880;                         // 98304 u16

  k0_prep<<<dim3(12288),dim3(256),0,stream>>>(adj,cmask,cheb,mc);
  k8_prep<<<dim3(60),dim3(256),0,stream>>>(g3w,g5w,g7w,Apack);
  kw_prep<<<dim3(48),dim3(256),0,stream>>>(swq,swk,Wpack);
  k1_embedT<<<dim3(192),dim3(256),0,stream>>>(x,posT,gT,bT,TEmx);
  k2_qkv<<<dim3(192),dim3(320),0,stream>>>(TEmx,wq,wk,wv,qkv);
  k3_attn<<<dim3(16),dim3(512),0,stream>>>(qkv,res,scores,ctx);
  k4_tat<<<dim3(192),dim3(256),0,stream>>>(ctx,fcW,TEmx,TAT);
  k5_semx<<<dim3(16384),dim3(256),0,stream>>>(TAT,prw,prb,posS,gS,bS,SEb);
  k6_sqk<<<dim3(256),dim3(256),0,stream>>>(SEb,Wpack,SQb,SKb);
  k7_spatial<<<dim3(768),dim3(256),0,stream>>>(SQb,SKb,mc,x,rhsT);
  k9_final<<<dim3(2048),dim3(256),0,stream>>>(rhsT,theta,Apack,g3b,g5b,g7b,
                                              fcw,fcb,rw,rb,gln,bln,x,outp);
}

// Round 7
// 234.895 us; speedup vs baseline: 6.4004x; 1.2594x over previous
//
#include <hip/hip_runtime.h>
#include <hip/hip_fp16.h>

#define EPS 1e-5f

typedef float f32x4 __attribute__((ext_vector_type(4)));
typedef short bf16x8 __attribute__((ext_vector_type(8)));
typedef short bf16x4 __attribute__((ext_vector_type(4)));

__device__ __forceinline__ unsigned short f2b(float f){
  unsigned u=__float_as_uint(f);
  return (unsigned short)((u + 0x7fffu + ((u>>16)&1u))>>16);
}
__device__ __forceinline__ float b2f(unsigned short h){
  return __uint_as_float(((unsigned)h)<<16);
}

// ---------------- helpers ----------------
__device__ __forceinline__ float blockSum256(float v, float* red){
  #pragma unroll
  for(int o=32;o>0;o>>=1) v += __shfl_down(v,o,64);
  int wid = threadIdx.x>>6;
  if((threadIdx.x&63)==0) red[wid]=v;
  __syncthreads();
  if(threadIdx.x==0) red[0]=red[0]+red[1]+red[2]+red[3];
  __syncthreads();
  float r = red[0];
  __syncthreads();
  return r;
}

// ---------------- K0: pack mask/cheb ----------------
__global__ __launch_bounds__(256) void k0_prep(const float* __restrict__ adj, const float* __restrict__ cmask,
    const float* __restrict__ cheb, unsigned* __restrict__ mc){
  int i = blockIdx.x*256 + threadIdx.x;
  int nm = i & 1048575;
  mc[i] = (((unsigned)f2b(cheb[i]))<<16) | (unsigned)f2b(adj[nm]*cmask[i]);
}

// ---------------- K1: EmbedT (fp32 + bf16 outputs) ----------------
__global__ __launch_bounds__(256) void k1_embedT(const float* __restrict__ x, const float* __restrict__ posT,
    const float* __restrict__ gT, const float* __restrict__ bT, float* __restrict__ TEmx,
    unsigned short* __restrict__ TEb){
  int bt=blockIdx.x; int b=bt/12, t=bt-b*12;
  int tid=threadIdx.x;
  __shared__ float red[4];
  float v[4]; float s=0.f;
  #pragma unroll
  for(int i=0;i<4;i++){ int n=tid+i*256; v[i]=x[(b*1024+n)*12+t]+posT[t*1024+n]; s+=v[i]; }
  s = blockSum256(s, red);
  float mu = s*(1.f/1024.f);
  float q=0.f;
  #pragma unroll
  for(int i=0;i<4;i++){ float d=v[i]-mu; q+=d*d; }
  q = blockSum256(q, red);
  float rstd = rsqrtf(q*(1.f/1024.f)+EPS);
  #pragma unroll
  for(int i=0;i<4;i++){
    int n=tid+i*256;
    float val=(v[i]-mu)*rstd*gT[n]+bT[n];
    TEmx[bt*1024+n]=val;
    TEb[bt*1024+n]=f2b(val);
  }
}

// ---------------- KW2: pack [wq|wk|wv] into MFMA B-fragment layout ----------------
// Wpack2[frag=ct*32+ks][lane][8] : value = W[ks*32+(lane>>4)*8+j][ct*16+(lane&15)]
__global__ __launch_bounds__(256) void kw2_prep(const float* __restrict__ wq, const float* __restrict__ wk,
    const float* __restrict__ wv, unsigned short* __restrict__ Wpack2){
  int idx = blockIdx.x*256+threadIdx.x;   // 576*64 = 36864
  if(idx>=36864) return;
  int frag=idx>>6, lane=idx&63;
  int ct=frag>>5, ks=frag&31;
  int cg = ct*16 + (lane&15);
  const float* W; int c;
  if(cg<96){ W=wq; c=cg; } else if(cg<192){ W=wk; c=cg-96; } else { W=wv; c=cg-192; }
  int k0 = ks*32 + (lane>>4)*8;
  #pragma unroll
  for(int j=0;j<8;j++) Wpack2[idx*8+j]=f2b(W[(k0+j)*96 + c]);
}

// ---------------- K2: QKV via MFMA split-K GEMM (192x1024 @ 1024x288) ----------------
// grid = 12 row-tiles x 18 col-tiles; 4 waves, wave w = K-slice [256w,256w+256)
__global__ __launch_bounds__(256) void k2_qkv(const unsigned short* __restrict__ TEb,
    const unsigned short* __restrict__ Wpack2, float* __restrict__ qkv){
  int tid=threadIdx.x; int w=tid>>6, lane=tid&63;
  const int hi=lane>>4, lo=lane&15;
  const int rt=blockIdx.x/18, ct=blockIdx.x-rt*18;
  __shared__ float red[4][16][16];
  f32x4 acc={0.f,0.f,0.f,0.f};
  #pragma unroll
  for(int s=0;s<8;s++){
    int ks=w*8+s;
    bf16x8 af = *(const bf16x8*)&TEb[(rt*16+lo)*1024 + ks*32 + hi*8];
    bf16x8 bf = *(const bf16x8*)&Wpack2[((ct*32+ks)<<9) + lane*8];
    acc = __builtin_amdgcn_mfma_f32_16x16x32_bf16(af, bf, acc, 0,0,0);
  }
  #pragma unroll
  for(int r=0;r<4;r++) red[w][hi*4+r][lo]=acc[r];
  __syncthreads();
  int r16=tid>>4, c16=tid&15;
  float s = red[0][r16][c16]+red[1][r16][c16]+red[2][r16][c16]+red[3][r16][c16];
  qkv[(rt*16+r16)*288 + ct*16 + c16] = s;
}

// ---------------- K3: temporal attn ----------------
__global__ __launch_bounds__(512) void k3_attn(const float* __restrict__ qkv, const float* __restrict__ res_att,
    float* __restrict__ scores_out, float* __restrict__ ctx){
  int b=blockIdx.x; int tid=threadIdx.x;
  __shared__ float sS[432];
  __shared__ float sA[432];
  if(tid<432){
    int h=tid/144; int r=tid-h*144; int q=r/12; int k2=r-q*12;
    const float* Qr=&qkv[(b*12+q)*288 + h*32];
    const float* Kr=&qkv[(b*12+k2)*288 + 96 + h*32];
    float acc=0.f;
    #pragma unroll
    for(int d=0;d<32;d++) acc+=Qr[d]*Kr[d];
    acc = acc*0.17677669529663687f + res_att[(b*3+h)*144 + q*12 + k2];
    sS[h*144+q*12+k2]=acc;
    scores_out[(b*3+h)*144 + q*12 + k2]=acc;
  }
  __syncthreads();
  if(tid<36){
    int h=tid/12, k2=tid-(tid/12)*12;
    float mx=-1e30f;
    for(int q=0;q<12;q++) mx=fmaxf(mx,sS[h*144+q*12+k2]);
    float sum=0.f;
    for(int q=0;q<12;q++){ float e=__expf(sS[h*144+q*12+k2]-mx); sA[h*144+q*12+k2]=e; sum+=e; }
    float inv=1.f/sum;
    for(int q=0;q<12;q++) sA[h*144+q*12+k2]*=inv;
  }
  __syncthreads();
  for(int o=tid;o<1152;o+=512){
    int h=o/384; int r=o-h*384; int q=r/32; int d=r-q*32;
    float acc=0.f;
    #pragma unroll
    for(int k2=0;k2<12;k2++) acc += sA[h*144+q*12+k2]*qkv[(b*12+k2)*288+192+h*32+d];
    ctx[(b*12+q)*96 + h*32 + d]=acc;
  }
}

// ---------------- K4: TATout ----------------
__global__ __launch_bounds__(256) void k4_tat(const float* __restrict__ ctx, const float* __restrict__ fcW,
    const float* __restrict__ TEmx, float* __restrict__ TAT){
  int bt=blockIdx.x; int tid=threadIdx.x;
  __shared__ float c96[96];
  __shared__ float red[4];
  if(tid<96) c96[tid]=ctx[bt*96+tid];
  __syncthreads();
  float v[4]; float s=0.f;
  #pragma unroll
  for(int i=0;i<4;i++){
    int n=tid+i*256;
    float acc=TEmx[bt*1024+n];
    #pragma unroll 4
    for(int j=0;j<96;j++) acc += c96[j]*fcW[j*1024+n];
    v[i]=acc; s+=acc;
  }
  s=blockSum256(s,red);
  float mu=s*(1.f/1024.f);
  float q=0.f;
  #pragma unroll
  for(int i=0;i<4;i++){float d=v[i]-mu;q+=d*d;}
  q=blockSum256(q,red);
  float rstd=rsqrtf(q*(1.f/1024.f)+EPS);
  #pragma unroll
  for(int i=0;i<4;i++){int n=tid+i*256; TAT[bt*1024+n]=(v[i]-mu)*rstd;}
}

// ---------------- K5: SEmx (bf16 out) ----------------
__global__ __launch_bounds__(256) void k5_semx(const float* __restrict__ TAT, const float* __restrict__ pre_w,
    const float* __restrict__ pre_b, const float* __restrict__ posS, const float* __restrict__ gS,
    const float* __restrict__ bS, unsigned short* __restrict__ SEb){
  int bn=blockIdx.x; int b=bn>>10, n=bn&1023; int tid=threadIdx.x;
  __shared__ float tv[12];
  __shared__ float red[4];
  if(tid<12) tv[tid]=TAT[(b*12+tid)*1024+n];
  __syncthreads();
  float v[2]; float s=0.f;
  #pragma unroll
  for(int i=0;i<2;i++){
    int d=tid+i*256;
    float acc=pre_b[d]+posS[n*512+d];
    #pragma unroll
    for(int t=0;t<12;t++) acc += tv[t]*pre_w[d*12+t];
    v[i]=acc; s+=acc;
  }
  s=blockSum256(s,red);
  float mu=s*(1.f/512.f);
  float q=0.f;
  #pragma unroll
  for(int i=0;i<2;i++){float d2=v[i]-mu;q+=d2*d2;}
  q=blockSum256(q,red);
  float rstd=rsqrtf(q*(1.f/512.f)+EPS);
  #pragma unroll
  for(int i=0;i<2;i++){int d=tid+i*256; SEb[bn*512+d]=f2b((v[i]-mu)*rstd*gS[d]+bS[d]);}
}

// ---------------- KW: pack swq/swk into MFMA B-fragment layout ----------------
__global__ __launch_bounds__(256) void kw_prep(const float* __restrict__ swq, const float* __restrict__ swk,
    unsigned short* __restrict__ Wpack){
  int idx = blockIdx.x*256+threadIdx.x;  // 12*16*64 = 12288
  if(idx>=12288) return;
  int frag=idx>>6, lane=idx&63;
  int ct=frag>>4, ks=frag&15;
  const float* W = (ct<6)? swq : swk;
  int c = ((ct<6)? ct : ct-6)*16 + (lane&15);
  int k0 = ks*32 + (lane>>4)*8;
  #pragma unroll
  for(int j=0;j<8;j++) Wpack[idx*8+j]=f2b(W[(k0+j)*96 + c]);
}

// ---------------- K6: SQ/SK via MFMA GEMM ----------------
__global__ __launch_bounds__(256) void k6_sqk(const unsigned short* __restrict__ SEb,
    const unsigned short* __restrict__ Wpack,
    unsigned short* __restrict__ SQb, unsigned short* __restrict__ SKb){
  int tid=threadIdx.x; int w=tid>>6, lane=tid&63;
  const int hi=lane>>4, lo=lane&15;
  const int row0 = blockIdx.x*64 + w*16;
  f32x4 acc[12];
  #pragma unroll
  for(int i=0;i<12;i++){ acc[i][0]=0.f; acc[i][1]=0.f; acc[i][2]=0.f; acc[i][3]=0.f; }
  for(int ks=0;ks<16;ks++){
    bf16x8 af = *(const bf16x8*)&SEb[(row0+lo)*512 + ks*32 + hi*8];
    #pragma unroll
    for(int ct=0;ct<12;ct++){
      bf16x8 bf = *(const bf16x8*)&Wpack[((ct*16+ks)<<9) + lane*8];
      acc[ct] = __builtin_amdgcn_mfma_f32_16x16x32_bf16(af, bf, acc[ct], 0,0,0);
    }
  }
  #pragma unroll
  for(int ct=0;ct<12;ct++){
    int c96 = ((ct<6)? ct : ct-6)*16 + lo;
    int kq = c96>>5, d = c96&31;
    unsigned short* dst = (ct<6)? SQb : SKb;
    #pragma unroll
    for(int r=0;r<4;r++){
      int n = row0 + hi*4 + r;
      int b = n>>10, nl = n&1023;
      dst[((b*3+kq)*1024+nl)*32 + d] = f2b(acc[ct][r]);
    }
  }
}

// ---------------- K7: fused spatial attention + graph conv (MFMA flash) ----------------
#define SCALE7 0.17677669529663687f
__global__ __launch_bounds__(256) void k7_spatial(const unsigned short* __restrict__ SQb,
    const unsigned short* __restrict__ SKb, const unsigned* __restrict__ mc,
    const float* __restrict__ x, float* __restrict__ rhsT){
  const int blk=blockIdx.x;
  const int mt=blk&15, bk=blk>>4;
  const int k=bk%3, b=bk/3;
  const int m0=mt*64;
  const int tid=threadIdx.x;
  const int w=tid>>6, lane=tid&63, g=lane>>4, col=lane&15;

  __shared__ unsigned short xs[16*128];

  const int m_glob = m0 + w*16 + col;
  bf16x8 bfrag = *(const bf16x8*)&SKb[((bk<<10)+m_glob)*32 + g*8];

  f32x4 O = {0.f,0.f,0.f,0.f};
  float mrun=-1e30f, lrun=0.f;

  const float* xb = x + b*12288;
  const unsigned* mck = mc + k*1048576;
  const int swz = (col&7)<<3;

  for(int i=tid;i<512;i+=256){ int t=12+(i>>7), n=i&127; xs[t*128 + (n ^ ((t&7)<<3))]=0; }

  for(int ch=0; ch<8; ++ch){
    const int n0 = ch<<7;
    __syncthreads();
    for(int i=tid;i<1536;i+=256){
      int n=i/12, t=i-n*12;
      xs[t*128 + (n ^ ((t&7)<<3))] = f2b(xb[n0*12 + i]);
    }
    __syncthreads();

    f32x4 acc[8];
    #pragma unroll
    for(int nt=0;nt<8;nt++){
      bf16x8 afrag = *(const bf16x8*)&SQb[((bk<<10) + n0 + nt*16 + col)*32 + g*8];
      f32x4 z = {0.f,0.f,0.f,0.f};
      acc[nt] = __builtin_amdgcn_mfma_f32_16x16x32_bf16(afrag, bfrag, z, 0,0,0);
    }
    unsigned mcv[8][4];
    #pragma unroll
    for(int nt=0;nt<8;nt++){
      int nbase = n0 + nt*16 + g*4;
      #pragma unroll
      for(int r=0;r<4;r++) mcv[nt][r] = mck[(nbase+r)*1024 + m_glob];
    }
    float cmax = -1e30f;
    #pragma unroll
    for(int nt=0;nt<8;nt++){
      #pragma unroll
      for(int r=0;r<4;r++){
        float s = acc[nt][r]*SCALE7 + __uint_as_float(mcv[nt][r]<<16);
        acc[nt][r]=s;
        cmax=fmaxf(cmax,s);
      }
    }
    cmax = fmaxf(cmax, __shfl_xor(cmax,16,64));
    cmax = fmaxf(cmax, __shfl_xor(cmax,32,64));
    float mnew = fmaxf(mrun, cmax);
    float alpha = __expf(mrun - mnew);
    float lsum = 0.f;
    unsigned short pb[8][4];
    #pragma unroll
    for(int nt=0;nt<8;nt++){
      #pragma unroll
      for(int r=0;r<4;r++){
        float e = __expf(acc[nt][r] - mnew);
        lsum += e;
        pb[nt][r] = f2b(e * __uint_as_float(mcv[nt][r] & 0xffff0000u));
      }
    }
    lsum += __shfl_xor(lsum,16,64);
    lsum += __shfl_xor(lsum,32,64);
    lrun = lrun*alpha + lsum;
    mrun = mnew;
    O[0]*=alpha; O[1]*=alpha; O[2]*=alpha; O[3]*=alpha;

    #pragma unroll
    for(int c=0;c<4;c++){
      bf16x8 pf;
      #pragma unroll
      for(int j=0;j<4;j++){ pf[j]=(short)pb[2*c][j]; pf[j+4]=(short)pb[2*c+1][j]; }
      int nlo = c*32 + g*4;
      bf16x4 lo = *(const bf16x4*)&xs[col*128 + (nlo ^ swz)];
      bf16x4 hi = *(const bf16x4*)&xs[col*128 + ((nlo+16) ^ swz)];
      bf16x8 ax;
      #pragma unroll
      for(int j=0;j<4;j++){ ax[j]=lo[j]; ax[j+4]=hi[j]; }
      O = __builtin_amdgcn_mfma_f32_16x16x32_bf16(ax, pf, O, 0,0,0);
    }
  }
  float inv = 1.f/lrun;
  #pragma unroll
  for(int r=0;r<4;r++){
    int t = g*4+r;
    if(t<12) rhsT[((bk*12+t)<<10) + m_glob] = O[r]*inv;
  }
}

// ---------------- K8: pack conv weights into MFMA A-fragment layout ----------------
__global__ __launch_bounds__(256) void k8_prep(const float* __restrict__ g3w, const float* __restrict__ g5w,
    const float* __restrict__ g7w, unsigned short* __restrict__ Apack){
  int idx = blockIdx.x*256+threadIdx.x;      // 240*64 = 15360
  if(idx>=15360) return;
  int frag=idx>>6, lane=idx&63;
  int rt, s, kappa; const float* W;
  if(frag<48){ rt=frag/6; s=frag-rt*6; kappa=3; W=g3w; }
  else if(frag<128){ int f=frag-48; rt=f/10; s=f-rt*10; kappa=5; W=g5w; }
  else { int f=frag-128; rt=f/14; s=f-rt*14; kappa=7; W=g7w; }
  int c = rt*16 + (lane&15);
  int dt = s>>1, ic0=(s&1)*32 + (lane>>4)*8;
  #pragma unroll
  for(int j=0;j<8;j++) Apack[idx*8+j]=f2b(W[(c*64+ic0+j)*kappa + dt]);
}

// ---------------- K9: theta-contract + MFMA GTU convs (grouped) + in-reg fc + residual + LN ----
__global__ __launch_bounds__(256) void k9_final(const float* __restrict__ rhsT, const float* __restrict__ theta,
    const unsigned short* __restrict__ Apack,
    const float* __restrict__ g3b, const float* __restrict__ g5b, const float* __restrict__ g7b,
    const float* __restrict__ fcw, const float* __restrict__ fcb,
    const float* __restrict__ rw, const float* __restrict__ rb,
    const float* __restrict__ gln, const float* __restrict__ bln,
    const float* __restrict__ x, float* __restrict__ out){
  int bn0=blockIdx.x*8;
  int tid=threadIdx.x;
  const int b=bn0>>10, n0=bn0&1023;

  __shared__ union {
    struct { unsigned short Xl[12*8*64]; float rstage[3][12][8]; } p0;
    float XP[8][772];
  } U;
  __shared__ float xres[8][12];
  __shared__ float mu8[8][12], rs8[8][12];

  for(int i=tid;i<288;i+=256){
    int kk=i/96; int rem=i-kk*96; int t=rem>>3; int g=rem&7;
    U.p0.rstage[kk][t][g]=rhsT[((b*3+kk)*12+t)*1024 + n0 + g];
  }
  for(int i=tid;i<96;i+=256){ int g=i/12, t=i-(i/12)*12; xres[g][t]=x[(bn0+g)*12+t]; }
  __syncthreads();

  {
    int g=tid>>5, icp=tid&31;
    float th0[3], th1[3];
    #pragma unroll
    for(int kk=0;kk<3;kk++){ th0[kk]=theta[kk*64+2*icp]; th1[kk]=theta[kk*64+2*icp+1]; }
    #pragma unroll
    for(int t=0;t<12;t++){
      float r0=U.p0.rstage[0][t][g], r1=U.p0.rstage[1][t][g], r2=U.p0.rstage[2][t][g];
      float a0=fmaxf(r0*th0[0]+r1*th0[1]+r2*th0[2],0.f);
      float a1=fmaxf(r0*th1[0]+r1*th1[1]+r2*th1[2],0.f);
      unsigned pack = (((unsigned)f2b(a1))<<16)|(unsigned)f2b(a0);
      *(unsigned*)((char*)U.p0.Xl + ((t*8+g)<<7) + ((icp*4) ^ (g<<4))) = pack;
    }
  }
  __syncthreads();

  const int w=tid>>6, lane=tid&63, halfk=lane>>4, colq=lane&15;
  const int gg=colq&7, tau2=colq>>3;
  const int ca = w*16 + halfk*4;
  const int t0 = tau2*6;
  const char* xlb = (const char*)U.p0.Xl;

  float facc[6][4];
  #pragma unroll
  for(int tt=0;tt<6;tt++)
    #pragma unroll
    for(int r=0;r<4;r++) facc[tt][r]=0.f;

  // ---- group kappa=3 ----
  {
    f32x4 acA[5], acB[5];
    #pragma unroll
    for(int j=0;j<5;j++)
      #pragma unroll
      for(int r=0;r<4;r++){ acA[j][r]=g3b[ca+r]; acB[j][r]=g3b[64+ca+r]; }
    #pragma unroll
    for(int s=0;s<6;s++){
      bf16x8 a0 = *(const bf16x8*)&Apack[((w  )*6 + s)*512 + lane*8];
      bf16x8 a1 = *(const bf16x8*)&Apack[((w+4)*6 + s)*512 + lane*8];
      int dt=s>>1;
      int sl = ((((s&1)*32 + halfk*8)*2) ^ (gg<<4));
      #pragma unroll
      for(int j=0;j<5;j++){
        int t=2*j+tau2+dt;
        bf16x8 bf = *(const bf16x8*)(xlb + ((t*8+gg)<<7) + sl);
        acA[j] = __builtin_amdgcn_mfma_f32_16x16x32_bf16(a0, bf, acA[j], 0,0,0);
        acB[j] = __builtin_amdgcn_mfma_f32_16x16x32_bf16(a1, bf, acB[j], 0,0,0);
      }
    }
    #pragma unroll
    for(int j=0;j<5;j++){
      int tb=2*j;
      float gv[4], gvp[4];
      #pragma unroll
      for(int r=0;r<4;r++){
        float ya=acA[j][r], yb=acB[j][r];
        float e2=__expf(2.f*ya);
        float th=1.f - 2.f/(e2+1.f);
        float sg=1.f/(1.f+__expf(-yb));
        gv[r]=th*sg;
      }
      #pragma unroll
      for(int r=0;r<4;r++) gvp[r]=__shfl_xor(gv[r],8,64);
      const float* fo=&fcw[(tb+tau2)*12 + t0];
      const float* fp=&fcw[(tb+(tau2^1))*12 + t0];
      #pragma unroll
      for(int tt=0;tt<6;tt++){
        float a=fo[tt], p=fp[tt];
        #pragma unroll
        for(int r=0;r<4;r++) facc[tt][r] += gv[r]*a + gvp[r]*p;
      }
    }
  }
  // ---- group kappa=5 ----
  {
    f32x4 acA[4], acB[4];
    #pragma unroll
    for(int j=0;j<4;j++)
      #pragma unroll
      for(int r=0;r<4;r++){ acA[j][r]=g5b[ca+r]; acB[j][r]=g5b[64+ca+r]; }
    #pragma unroll
    for(int s=0;s<10;s++){
      bf16x8 a0 = *(const bf16x8*)&Apack[(48 + (w  )*10 + s)*512 + lane*8];
      bf16x8 a1 = *(const bf16x8*)&Apack[(48 + (w+4)*10 + s)*512 + lane*8];
      int dt=s>>1;
      int sl = ((((s&1)*32 + halfk*8)*2) ^ (gg<<4));
      #pragma unroll
      for(int j=0;j<4;j++){
        int t=2*j+tau2+dt;
        bf16x8 bf = *(const bf16x8*)(xlb + ((t*8+gg)<<7) + sl);
        acA[j] = __builtin_amdgcn_mfma_f32_16x16x32_bf16(a0, bf, acA[j], 0,0,0);
        acB[j] = __builtin_amdgcn_mfma_f32_16x16x32_bf16(a1, bf, acB[j], 0,0,0);
      }
    }
    #pragma unroll
    for(int j=0;j<4;j++){
      int tb=10+2*j;
      float gv[4], gvp[4];
      #pragma unroll
      for(int r=0;r<4;r++){
        float ya=acA[j][r], yb=acB[j][r];
        float e2=__expf(2.f*ya);
        float th=1.f - 2.f/(e2+1.f);
        float sg=1.f/(1.f+__expf(-yb));
        gv[r]=th*sg;
      }
      #pragma unroll
      for(int r=0;r<4;r++) gvp[r]=__shfl_xor(gv[r],8,64);
      const float* fo=&fcw[(tb+tau2)*12 + t0];
      const float* fp=&fcw[(tb+(tau2^1))*12 + t0];
      #pragma unroll
      for(int tt=0;tt<6;tt++){
        float a=fo[tt], p=fp[tt];
        #pragma unroll
        for(int r=0;r<4;r++) facc[tt][r] += gv[r]*a + gvp[r]*p;
      }
    }
  }
  // ---- group kappa=7 ----
  {
    f32x4 acA[3], acB[3];
    #pragma unroll
    for(int j=0;j<3;j++)
      #pragma unroll
      for(int r=0;r<4;r++){ acA[j][r]=g7b[ca+r]; acB[j][r]=g7b[64+ca+r]; }
    #pragma unroll
    for(int s=0;s<14;s++){
      bf16x8 a0 = *(const bf16x8*)&Apack[(128 + (w  )*14 + s)*512 + lane*8];
      bf16x8 a1 = *(const bf16x8*)&Apack[(128 + (w+4)*14 + s)*512 + lane*8];
      int dt=s>>1;
      int sl = ((((s&1)*32 + halfk*8)*2) ^ (gg<<4));
      #pragma unroll
      for(int j=0;j<3;j++){
        int t=2*j+tau2+dt;
        bf16x8 bf = *(const bf16x8*)(xlb + ((t*8+gg)<<7) + sl);
        acA[j] = __builtin_amdgcn_mfma_f32_16x16x32_bf16(a0, bf, acA[j], 0,0,0);
        acB[j] = __builtin_amdgcn_mfma_f32_16x16x32_bf16(a1, bf, acB[j], 0,0,0);
      }
    }
    #pragma unroll
    for(int j=0;j<3;j++){
      int tb=18+2*j;
      float gv[4], gvp[4];
      #pragma unroll
      for(int r=0;r<4;r++){
        float ya=acA[j][r], yb=acB[j][r];
        float e2=__expf(2.f*ya);
        float th=1.f - 2.f/(e2+1.f);
        float sg=1.f/(1.f+__expf(-yb));
        gv[r]=th*sg;
      }
      #pragma unroll
      for(int r=0;r<4;r++) gvp[r]=__shfl_xor(gv[r],8,64);
      const float* fo=&fcw[(tb+tau2)*12 + t0];
      const float* fp=&fcw[(tb+(tau2^1))*12 + t0];
      #pragma unroll
      for(int tt=0;tt<6;tt++){
        float a=fo[tt], p=fp[tt];
        #pragma unroll
        for(int r=0;r<4;r++) facc[tt][r] += gv[r]*a + gvp[r]*p;
      }
    }
  }

  __syncthreads();

  {
    float rwa[4], rba[4];
    #pragma unroll
    for(int r=0;r<4;r++){ rwa[r]=rw[ca+r]; rba[r]=rb[ca+r]; }
    #pragma unroll
    for(int tt=0;tt<6;tt++){
      int t=t0+tt;
      float fb=fcb[t];
      float xv=xres[gg][t];
      #pragma unroll
      for(int r=0;r<4;r++){
        float tv = fmaxf(facc[tt][r]+fb, 0.f);
        float xr = xv*rwa[r]+rba[r];
        U.XP[gg][(ca+r)*12+t] = fmaxf(xr+tv, 0.f);
      }
    }
  }
  __syncthreads();

  if(tid<96){
    int g=tid/12, t=tid-(tid/12)*12;
    float s=0.f;
    for(int c=0;c<64;c++) s+=U.XP[g][c*12+t];
    float mu=s*(1.f/64.f);
    float q=0.f;
    for(int c=0;c<64;c++){float d=U.XP[g][c*12+t]-mu;q+=d*d;}
    mu8[g][t]=mu; rs8[g][t]=rsqrtf(q*(1.f/64.f)+EPS);
  }
  __syncthreads();
  for(int o=tid;o<8*768;o+=256){
    int g=o/768; int ct=o-g*768; int c=ct/12; int t=ct-c*12;
    out[(long)(bn0+g)*768 + ct]=(U.XP[g][c*12+t]-mu8[g][t])*rs8[g][t]*gln[c]+bln[c];
  }
}

// ---------------- launch ----------------
extern "C" void kernel_launch(void* const* d_in, const int* in_sizes, int n_in,
                              void* d_out, int out_size, void* d_ws, size_t ws_size,
                              hipStream_t stream){
  const float* x    =(const float*)d_in[0];
  const float* res  =(const float*)d_in[1];
  const float* posT =(const float*)d_in[2];
  const float* gT   =(const float*)d_in[3];
  const float* bT   =(const float*)d_in[4];
  const float* wq   =(const float*)d_in[5];
  const float* wk   =(const float*)d_in[6];
  const float* wv   =(const float*)d_in[7];
  const float* fcW  =(const float*)d_in[8];
  const float* prw  =(const float*)d_in[9];
  const float* prb  =(const float*)d_in[10];
  const float* posS =(const float*)d_in[11];
  const float* gS   =(const float*)d_in[12];
  const float* bS   =(const float*)d_in[13];
  const float* swq  =(const float*)d_in[14];
  const float* swk  =(const float*)d_in[15];
  const float* cheb =(const float*)d_in[16];
  const float* adj  =(const float*)d_in[17];
  const float* cmask=(const float*)d_in[18];
  const float* theta=(const float*)d_in[19];
  const float* g3w=(const float*)d_in[20]; const float* g3b=(const float*)d_in[21];
  const float* g5w=(const float*)d_in[22]; const float* g5b=(const float*)d_in[23];
  const float* g7w=(const float*)d_in[24]; const float* g7b=(const float*)d_in[25];
  const float* fcw=(const float*)d_in[26]; const float* fcb=(const float*)d_in[27];
  const float* rw =(const float*)d_in[28]; const float* rb =(const float*)d_in[29];
  const float* gln=(const float*)d_in[30]; const float* bln=(const float*)d_in[31];

  float* outp=(float*)d_out;
  float* scores = outp + 12582912;

  float* wsf=(float*)d_ws;
  float* TEmx = wsf;                          // 196608 f
  float* qkv  = TEmx + 196608;                // 55296 f
  float* ctx  = qkv + 55296;                  // 18432 f
  float* TAT  = ctx + 18432;                  // 196608 f
  unsigned short* SEb = (unsigned short*)(TAT + 196608);          // 4194304 f
  unsigned short* SQb = (unsigned short*)((float*)SEb + 4194304); // 786432 f
  unsigned short* SKb = (unsigned short*)((float*)SQb + 786432);  // 786432 f
  unsigned* mc = (unsigned*)((float*)SKb + 786432);               // 3145728 f
  float* rhsT  = (float*)mc + 3145728;                            // 589824 f
  unsigned short* Apack = (unsigned short*)(rhsT + 589824);       // 122880 u16
  unsigned short* Wpack = Apack + 122880;                         // 98304 u16
  unsigned short* Wpack2 = Wpack + 98304;                         // 294912 u16
  unsigned short* TEb = Wpack2 + 294912;                          // 196608 u16

  k0_prep<<<dim3(12288),dim3(256),0,stream>>>(adj,cmask,cheb,mc);
  k8_prep<<<dim3(60),dim3(256),0,stream>>>(g3w,g5w,g7w,Apack);
  kw_prep<<<dim3(48),dim3(256),0,stream>>>(swq,swk,Wpack);
  kw2_prep<<<dim3(144),dim3(256),0,stream>>>(wq,wk,wv,Wpack2);
  k1_embedT<<<dim3(192),dim3(256),0,stream>>>(x,posT,gT,bT,TEmx,TEb);
  k2_qkv<<<dim3(216),dim3(256),0,stream>>>(TEb,Wpack2,qkv);
  k3_attn<<<dim3(16),dim3(512),0,stream>>>(qkv,res,scores,ctx);
  k4_tat<<<dim3(192),dim3(256),0,stream>>>(ctx,fcW,TEmx,TAT);
  k5_semx<<<dim3(16384),dim3(256),0,stream>>>(TAT,prw,prb,posS,gS,bS,SEb);
  k6_sqk<<<dim3(256),dim3(256),0,stream>>>(SEb,Wpack,SQb,SKb);
  k7_spatial<<<dim3(768),dim3(256),0,stream>>>(SQb,SKb,mc,x,rhsT);
  k9_final<<<dim3(2048),dim3(256),0,stream>>>(rhsT,theta,Apack,g3b,g5b,g7b,
                                              fcw,fcb,rw,rb,gln,bln,x,outp);
}

// Round 8
// 219.893 us; speedup vs baseline: 6.8371x; 1.0682x over previous
//
#include <hip/hip_runtime.h>
#include <hip/hip_fp16.h>

#define EPS 1e-5f

typedef float f32x4 __attribute__((ext_vector_type(4)));
typedef short bf16x8 __attribute__((ext_vector_type(8)));
typedef short bf16x4 __attribute__((ext_vector_type(4)));

__device__ __forceinline__ unsigned short f2b(float f){
  unsigned u=__float_as_uint(f);
  return (unsigned short)((u + 0x7fffu + ((u>>16)&1u))>>16);
}
__device__ __forceinline__ float b2f(unsigned short h){
  return __uint_as_float(((unsigned)h)<<16);
}

// ---------------- helpers ----------------
__device__ __forceinline__ float blockSum256(float v, float* red){
  #pragma unroll
  for(int o=32;o>0;o>>=1) v += __shfl_down(v,o,64);
  int wid = threadIdx.x>>6;
  if((threadIdx.x&63)==0) red[wid]=v;
  __syncthreads();
  if(threadIdx.x==0) red[0]=red[0]+red[1]+red[2]+red[3];
  __syncthreads();
  float r = red[0];
  __syncthreads();
  return r;
}

// ---------------- K0: pack mask/cheb ----------------
__global__ __launch_bounds__(256) void k0_prep(const float* __restrict__ adj, const float* __restrict__ cmask,
    const float* __restrict__ cheb, unsigned* __restrict__ mc){
  int i = blockIdx.x*256 + threadIdx.x;
  int nm = i & 1048575;
  mc[i] = (((unsigned)f2b(cheb[i]))<<16) | (unsigned)f2b(adj[nm]*cmask[i]);
}

// ---------------- K1: EmbedT (fp32 + bf16 outputs) ----------------
__global__ __launch_bounds__(256) void k1_embedT(const float* __restrict__ x, const float* __restrict__ posT,
    const float* __restrict__ gT, const float* __restrict__ bT, float* __restrict__ TEmx,
    unsigned short* __restrict__ TEb){
  int bt=blockIdx.x; int b=bt/12, t=bt-b*12;
  int tid=threadIdx.x;
  __shared__ float red[4];
  float v[4]; float s=0.f;
  #pragma unroll
  for(int i=0;i<4;i++){ int n=tid+i*256; v[i]=x[(b*1024+n)*12+t]+posT[t*1024+n]; s+=v[i]; }
  s = blockSum256(s, red);
  float mu = s*(1.f/1024.f);
  float q=0.f;
  #pragma unroll
  for(int i=0;i<4;i++){ float d=v[i]-mu; q+=d*d; }
  q = blockSum256(q, red);
  float rstd = rsqrtf(q*(1.f/1024.f)+EPS);
  #pragma unroll
  for(int i=0;i<4;i++){
    int n=tid+i*256;
    float val=(v[i]-mu)*rstd*gT[n]+bT[n];
    TEmx[bt*1024+n]=val;
    TEb[bt*1024+n]=f2b(val);
  }
}

// ---------------- KW2: pack [wq|wk|wv] into MFMA B-fragment layout ----------------
__global__ __launch_bounds__(256) void kw2_prep(const float* __restrict__ wq, const float* __restrict__ wk,
    const float* __restrict__ wv, unsigned short* __restrict__ Wpack2){
  int idx = blockIdx.x*256+threadIdx.x;   // 576*64 = 36864
  if(idx>=36864) return;
  int frag=idx>>6, lane=idx&63;
  int ct=frag>>5, ks=frag&31;
  int cg = ct*16 + (lane&15);
  const float* W; int c;
  if(cg<96){ W=wq; c=cg; } else if(cg<192){ W=wk; c=cg-96; } else { W=wv; c=cg-192; }
  int k0 = ks*32 + (lane>>4)*8;
  #pragma unroll
  for(int j=0;j<8;j++) Wpack2[idx*8+j]=f2b(W[(k0+j)*96 + c]);
}

// ---------------- KFC: pack fcw into one MFMA B-fragment (K=24 pad 32, 12 cols) ----------------
__global__ __launch_bounds__(64) void kfc_prep(const float* __restrict__ fcw, unsigned short* __restrict__ fcwB){
  int lane = threadIdx.x;
  int t = lane&15, hq = lane>>4;
  #pragma unroll
  for(int j=0;j<8;j++){
    int tau = hq*8+j;
    fcwB[lane*8+j] = (tau<24 && t<12) ? f2b(fcw[tau*12+t]) : (unsigned short)0;
  }
}

// ---------------- K2: QKV via MFMA split-K GEMM ----------------
__global__ __launch_bounds__(256) void k2_qkv(const unsigned short* __restrict__ TEb,
    const unsigned short* __restrict__ Wpack2, float* __restrict__ qkv){
  int tid=threadIdx.x; int w=tid>>6, lane=tid&63;
  const int hi=lane>>4, lo=lane&15;
  const int rt=blockIdx.x/18, ct=blockIdx.x-rt*18;
  __shared__ float red[4][16][16];
  f32x4 acc={0.f,0.f,0.f,0.f};
  #pragma unroll
  for(int s=0;s<8;s++){
    int ks=w*8+s;
    bf16x8 af = *(const bf16x8*)&TEb[(rt*16+lo)*1024 + ks*32 + hi*8];
    bf16x8 bf = *(const bf16x8*)&Wpack2[((ct*32+ks)<<9) + lane*8];
    acc = __builtin_amdgcn_mfma_f32_16x16x32_bf16(af, bf, acc, 0,0,0);
  }
  #pragma unroll
  for(int r=0;r<4;r++) red[w][hi*4+r][lo]=acc[r];
  __syncthreads();
  int r16=tid>>4, c16=tid&15;
  float s = red[0][r16][c16]+red[1][r16][c16]+red[2][r16][c16]+red[3][r16][c16];
  qkv[(rt*16+r16)*288 + ct*16 + c16] = s;
}

// ---------------- K3: temporal attn ----------------
__global__ __launch_bounds__(512) void k3_attn(const float* __restrict__ qkv, const float* __restrict__ res_att,
    float* __restrict__ scores_out, float* __restrict__ ctx){
  int b=blockIdx.x; int tid=threadIdx.x;
  __shared__ float sS[432];
  __shared__ float sA[432];
  if(tid<432){
    int h=tid/144; int r=tid-h*144; int q=r/12; int k2=r-q*12;
    const float* Qr=&qkv[(b*12+q)*288 + h*32];
    const float* Kr=&qkv[(b*12+k2)*288 + 96 + h*32];
    float acc=0.f;
    #pragma unroll
    for(int d=0;d<32;d++) acc+=Qr[d]*Kr[d];
    acc = acc*0.17677669529663687f + res_att[(b*3+h)*144 + q*12 + k2];
    sS[h*144+q*12+k2]=acc;
    scores_out[(b*3+h)*144 + q*12 + k2]=acc;
  }
  __syncthreads();
  if(tid<36){
    int h=tid/12, k2=tid-(tid/12)*12;
    float mx=-1e30f;
    for(int q=0;q<12;q++) mx=fmaxf(mx,sS[h*144+q*12+k2]);
    float sum=0.f;
    for(int q=0;q<12;q++){ float e=__expf(sS[h*144+q*12+k2]-mx); sA[h*144+q*12+k2]=e; sum+=e; }
    float inv=1.f/sum;
    for(int q=0;q<12;q++) sA[h*144+q*12+k2]*=inv;
  }
  __syncthreads();
  for(int o=tid;o<1152;o+=512){
    int h=o/384; int r=o-h*384; int q=r/32; int d=r-q*32;
    float acc=0.f;
    #pragma unroll
    for(int k2=0;k2<12;k2++) acc += sA[h*144+q*12+k2]*qkv[(b*12+k2)*288+192+h*32+d];
    ctx[(b*12+q)*96 + h*32 + d]=acc;
  }
}

// ---------------- K4: TATout ----------------
__global__ __launch_bounds__(256) void k4_tat(const float* __restrict__ ctx, const float* __restrict__ fcW,
    const float* __restrict__ TEmx, float* __restrict__ TAT){
  int bt=blockIdx.x; int tid=threadIdx.x;
  __shared__ float c96[96];
  __shared__ float red[4];
  if(tid<96) c96[tid]=ctx[bt*96+tid];
  __syncthreads();
  float v[4]; float s=0.f;
  #pragma unroll
  for(int i=0;i<4;i++){
    int n=tid+i*256;
    float acc=TEmx[bt*1024+n];
    #pragma unroll 4
    for(int j=0;j<96;j++) acc += c96[j]*fcW[j*1024+n];
    v[i]=acc; s+=acc;
  }
  s=blockSum256(s,red);
  float mu=s*(1.f/1024.f);
  float q=0.f;
  #pragma unroll
  for(int i=0;i<4;i++){float d=v[i]-mu;q+=d*d;}
  q=blockSum256(q,red);
  float rstd=rsqrtf(q*(1.f/1024.f)+EPS);
  #pragma unroll
  for(int i=0;i<4;i++){int n=tid+i*256; TAT[bt*1024+n]=(v[i]-mu)*rstd;}
}

// ---------------- K5: SEmx (bf16 out) ----------------
__global__ __launch_bounds__(256) void k5_semx(const float* __restrict__ TAT, const float* __restrict__ pre_w,
    const float* __restrict__ pre_b, const float* __restrict__ posS, const float* __restrict__ gS,
    const float* __restrict__ bS, unsigned short* __restrict__ SEb){
  int bn=blockIdx.x; int b=bn>>10, n=bn&1023; int tid=threadIdx.x;
  __shared__ float tv[12];
  __shared__ float red[4];
  if(tid<12) tv[tid]=TAT[(b*12+tid)*1024+n];
  __syncthreads();
  float v[2]; float s=0.f;
  #pragma unroll
  for(int i=0;i<2;i++){
    int d=tid+i*256;
    float acc=pre_b[d]+posS[n*512+d];
    #pragma unroll
    for(int t=0;t<12;t++) acc += tv[t]*pre_w[d*12+t];
    v[i]=acc; s+=acc;
  }
  s=blockSum256(s,red);
  float mu=s*(1.f/512.f);
  float q=0.f;
  #pragma unroll
  for(int i=0;i<2;i++){float d2=v[i]-mu;q+=d2*d2;}
  q=blockSum256(q,red);
  float rstd=rsqrtf(q*(1.f/512.f)+EPS);
  #pragma unroll
  for(int i=0;i<2;i++){int d=tid+i*256; SEb[bn*512+d]=f2b((v[i]-mu)*rstd*gS[d]+bS[d]);}
}

// ---------------- KW: pack swq/swk into MFMA B-fragment layout ----------------
__global__ __launch_bounds__(256) void kw_prep(const float* __restrict__ swq, const float* __restrict__ swk,
    unsigned short* __restrict__ Wpack){
  int idx = blockIdx.x*256+threadIdx.x;  // 12*16*64 = 12288
  if(idx>=12288) return;
  int frag=idx>>6, lane=idx&63;
  int ct=frag>>4, ks=frag&15;
  const float* W = (ct<6)? swq : swk;
  int c = ((ct<6)? ct : ct-6)*16 + (lane&15);
  int k0 = ks*32 + (lane>>4)*8;
  #pragma unroll
  for(int j=0;j<8;j++) Wpack[idx*8+j]=f2b(W[(k0+j)*96 + c]);
}

// ---------------- K6: SQ/SK via MFMA GEMM ----------------
__global__ __launch_bounds__(256) void k6_sqk(const unsigned short* __restrict__ SEb,
    const unsigned short* __restrict__ Wpack,
    unsigned short* __restrict__ SQb, unsigned short* __restrict__ SKb){
  int tid=threadIdx.x; int w=tid>>6, lane=tid&63;
  const int hi=lane>>4, lo=lane&15;
  const int row0 = blockIdx.x*64 + w*16;
  f32x4 acc[12];
  #pragma unroll
  for(int i=0;i<12;i++){ acc[i][0]=0.f; acc[i][1]=0.f; acc[i][2]=0.f; acc[i][3]=0.f; }
  for(int ks=0;ks<16;ks++){
    bf16x8 af = *(const bf16x8*)&SEb[(row0+lo)*512 + ks*32 + hi*8];
    #pragma unroll
    for(int ct=0;ct<12;ct++){
      bf16x8 bf = *(const bf16x8*)&Wpack[((ct*16+ks)<<9) + lane*8];
      acc[ct] = __builtin_amdgcn_mfma_f32_16x16x32_bf16(af, bf, acc[ct], 0,0,0);
    }
  }
  #pragma unroll
  for(int ct=0;ct<12;ct++){
    int c96 = ((ct<6)? ct : ct-6)*16 + lo;
    int kq = c96>>5, d = c96&31;
    unsigned short* dst = (ct<6)? SQb : SKb;
    #pragma unroll
    for(int r=0;r<4;r++){
      int n = row0 + hi*4 + r;
      int b = n>>10, nl = n&1023;
      dst[((b*3+kq)*1024+nl)*32 + d] = f2b(acc[ct][r]);
    }
  }
}

// ---------------- K7: fused spatial attention + graph conv (MFMA flash) ----------------
#define SCALE7 0.17677669529663687f
__global__ __launch_bounds__(256) void k7_spatial(const unsigned short* __restrict__ SQb,
    const unsigned short* __restrict__ SKb, const unsigned* __restrict__ mc,
    const float* __restrict__ x, float* __restrict__ rhsT){
  const int blk=blockIdx.x;
  const int mt=blk&15, bk=blk>>4;
  const int k=bk%3, b=bk/3;
  const int m0=mt*64;
  const int tid=threadIdx.x;
  const int w=tid>>6, lane=tid&63, g=lane>>4, col=lane&15;

  __shared__ unsigned short xs[16*128];

  const int m_glob = m0 + w*16 + col;
  bf16x8 bfrag = *(const bf16x8*)&SKb[((bk<<10)+m_glob)*32 + g*8];

  f32x4 O = {0.f,0.f,0.f,0.f};
  float mrun=-1e30f, lrun=0.f;

  const float* xb = x + b*12288;
  const unsigned* mck = mc + k*1048576;
  const int swz = (col&7)<<3;

  for(int i=tid;i<512;i+=256){ int t=12+(i>>7), n=i&127; xs[t*128 + (n ^ ((t&7)<<3))]=0; }

  for(int ch=0; ch<8; ++ch){
    const int n0 = ch<<7;
    __syncthreads();
    for(int i=tid;i<1536;i+=256){
      int n=i/12, t=i-n*12;
      xs[t*128 + (n ^ ((t&7)<<3))] = f2b(xb[n0*12 + i]);
    }
    __syncthreads();

    f32x4 acc[8];
    #pragma unroll
    for(int nt=0;nt<8;nt++){
      bf16x8 afrag = *(const bf16x8*)&SQb[((bk<<10) + n0 + nt*16 + col)*32 + g*8];
      f32x4 z = {0.f,0.f,0.f,0.f};
      acc[nt] = __builtin_amdgcn_mfma_f32_16x16x32_bf16(afrag, bfrag, z, 0,0,0);
    }
    unsigned mcv[8][4];
    #pragma unroll
    for(int nt=0;nt<8;nt++){
      int nbase = n0 + nt*16 + g*4;
      #pragma unroll
      for(int r=0;r<4;r++) mcv[nt][r] = mck[(nbase+r)*1024 + m_glob];
    }
    float cmax = -1e30f;
    #pragma unroll
    for(int nt=0;nt<8;nt++){
      #pragma unroll
      for(int r=0;r<4;r++){
        float s = acc[nt][r]*SCALE7 + __uint_as_float(mcv[nt][r]<<16);
        acc[nt][r]=s;
        cmax=fmaxf(cmax,s);
      }
    }
    cmax = fmaxf(cmax, __shfl_xor(cmax,16,64));
    cmax = fmaxf(cmax, __shfl_xor(cmax,32,64));
    float mnew = fmaxf(mrun, cmax);
    float alpha = __expf(mrun - mnew);
    float lsum = 0.f;
    unsigned short pb[8][4];
    #pragma unroll
    for(int nt=0;nt<8;nt++){
      #pragma unroll
      for(int r=0;r<4;r++){
        float e = __expf(acc[nt][r] - mnew);
        lsum += e;
        pb[nt][r] = f2b(e * __uint_as_float(mcv[nt][r] & 0xffff0000u));
      }
    }
    lsum += __shfl_xor(lsum,16,64);
    lsum += __shfl_xor(lsum,32,64);
    lrun = lrun*alpha + lsum;
    mrun = mnew;
    O[0]*=alpha; O[1]*=alpha; O[2]*=alpha; O[3]*=alpha;

    #pragma unroll
    for(int c=0;c<4;c++){
      bf16x8 pf;
      #pragma unroll
      for(int j=0;j<4;j++){ pf[j]=(short)pb[2*c][j]; pf[j+4]=(short)pb[2*c+1][j]; }
      int nlo = c*32 + g*4;
      bf16x4 lo = *(const bf16x4*)&xs[col*128 + (nlo ^ swz)];
      bf16x4 hi = *(const bf16x4*)&xs[col*128 + ((nlo+16) ^ swz)];
      bf16x8 ax;
      #pragma unroll
      for(int j=0;j<4;j++){ ax[j]=lo[j]; ax[j+4]=hi[j]; }
      O = __builtin_amdgcn_mfma_f32_16x16x32_bf16(ax, pf, O, 0,0,0);
    }
  }
  float inv = 1.f/lrun;
  #pragma unroll
  for(int r=0;r<4;r++){
    int t = g*4+r;
    if(t<12) rhsT[((bk*12+t)<<10) + m_glob] = O[r]*inv;
  }
}

// ---------------- K8: pack conv weights into MFMA A-fragment layout ----------------
__global__ __launch_bounds__(256) void k8_prep(const float* __restrict__ g3w, const float* __restrict__ g5w,
    const float* __restrict__ g7w, unsigned short* __restrict__ Apack){
  int idx = blockIdx.x*256+threadIdx.x;      // 240*64 = 15360
  if(idx>=15360) return;
  int frag=idx>>6, lane=idx&63;
  int rt, s, kappa; const float* W;
  if(frag<48){ rt=frag/6; s=frag-rt*6; kappa=3; W=g3w; }
  else if(frag<128){ int f=frag-48; rt=f/10; s=f-rt*10; kappa=5; W=g5w; }
  else { int f=frag-128; rt=f/14; s=f-rt*14; kappa=7; W=g7w; }
  int c = rt*16 + (lane&15);
  int dt = s>>1, ic0=(s&1)*32 + (lane>>4)*8;
  #pragma unroll
  for(int j=0;j<8;j++) Apack[idx*8+j]=f2b(W[(c*64+ic0+j)*kappa + dt]);
}

// ---------------- K9 v3: conv MFMA -> gated bf16 LDS tile -> fc via MFMA -> residual+LN ----
// Wave w owns c-rows [w*16,w*16+16). Gated values: Gl[w][c_loc][g^(c_loc&7)][tau] (bf16).
// fc contraction: per g one mfma(A2=Gl rows, B2=fcwB) -> D2(row=c,col=t) -> epilogue.
__global__ __launch_bounds__(256) void k9_final(const float* __restrict__ rhsT, const float* __restrict__ theta,
    const unsigned short* __restrict__ Apack, const unsigned short* __restrict__ fcwB,
    const float* __restrict__ g3b, const float* __restrict__ g5b, const float* __restrict__ g7b,
    const float* __restrict__ fcb,
    const float* __restrict__ rw, const float* __restrict__ rb,
    const float* __restrict__ gln, const float* __restrict__ bln,
    const float* __restrict__ x, float* __restrict__ out){
  int bn0=blockIdx.x*8;
  int tid=threadIdx.x;
  const int b=bn0>>10, n0=bn0&1023;

  __shared__ struct { unsigned short Xl[12*8*64]; float rstage[3][12][8]; } P0;
  __shared__ union {
    unsigned short Gl[4*16*8*24];   // [wave][c_loc][g'][tau]  24576 B
    float XP[8][772];               // 24704 B
  } U;
  __shared__ float xres[8][12];
  __shared__ float mu8[8][12], rs8[8][12];

  for(int i=tid;i<288;i+=256){
    int kk=i/96; int rem=i-kk*96; int t=rem>>3; int g=rem&7;
    P0.rstage[kk][t][g]=rhsT[((b*3+kk)*12+t)*1024 + n0 + g];
  }
  for(int i=tid;i<96;i+=256){ int g=i/12, t=i-(i/12)*12; xres[g][t]=x[(bn0+g)*12+t]; }
  __syncthreads();

  // phase0: Xl[t][g][ic] = bf16(relu(sum_kk rstage*theta)), g-XOR-swizzled, ic-pairs
  {
    int g=tid>>5, icp=tid&31;
    float th0[3], th1[3];
    #pragma unroll
    for(int kk=0;kk<3;kk++){ th0[kk]=theta[kk*64+2*icp]; th1[kk]=theta[kk*64+2*icp+1]; }
    #pragma unroll
    for(int t=0;t<12;t++){
      float r0=P0.rstage[0][t][g], r1=P0.rstage[1][t][g], r2=P0.rstage[2][t][g];
      float a0=fmaxf(r0*th0[0]+r1*th0[1]+r2*th0[2],0.f);
      float a1=fmaxf(r0*th1[0]+r1*th1[1]+r2*th1[2],0.f);
      unsigned pack = (((unsigned)f2b(a1))<<16)|(unsigned)f2b(a0);
      *(unsigned*)((char*)P0.Xl + ((t*8+g)<<7) + ((icp*4) ^ (g<<4))) = pack;
    }
  }
  __syncthreads();

  const int w=tid>>6, lane=tid&63, halfk=lane>>4, colq=lane&15;
  const int gg=colq&7, tau2=colq>>3;
  const int ca = w*16 + halfk*4;
  const char* xlb = (const char*)P0.Xl;
  unsigned short* Glw = &U.Gl[w*3072];

  // gating helper: write 4 gated values for col-tile with tau base tb
  #define GATE_STORE(ACCA, ACCB, TB) { \
    _Pragma("unroll") \
    for(int r=0;r<4;r++){ \
      float ya=(ACCA)[r], yb=(ACCB)[r]; \
      float e2=__expf(2.f*ya), eb=__expf(yb); \
      float gval=(e2-1.f)*eb*__frcp_rn((e2+1.f)*(eb+1.f)); \
      int c_loc=halfk*4+r; \
      Glw[c_loc*192 + ((gg ^ (c_loc&7))*24) + (TB)+tau2] = f2b(gval); \
    } }

  // ---- group kappa=3: 5 col-tiles, 6 K-steps ----
  {
    f32x4 acA[5], acB[5];
    #pragma unroll
    for(int j=0;j<5;j++)
      #pragma unroll
      for(int r=0;r<4;r++){ acA[j][r]=g3b[ca+r]; acB[j][r]=g3b[64+ca+r]; }
    #pragma unroll
    for(int s=0;s<6;s++){
      bf16x8 a0 = *(const bf16x8*)&Apack[((w  )*6 + s)*512 + lane*8];
      bf16x8 a1 = *(const bf16x8*)&Apack[((w+4)*6 + s)*512 + lane*8];
      int dt=s>>1;
      int sl = ((((s&1)*32 + halfk*8)*2) ^ (gg<<4));
      #pragma unroll
      for(int j=0;j<5;j++){
        int t=2*j+tau2+dt;
        bf16x8 bf = *(const bf16x8*)(xlb + ((t*8+gg)<<7) + sl);
        acA[j] = __builtin_amdgcn_mfma_f32_16x16x32_bf16(a0, bf, acA[j], 0,0,0);
        acB[j] = __builtin_amdgcn_mfma_f32_16x16x32_bf16(a1, bf, acB[j], 0,0,0);
      }
    }
    #pragma unroll
    for(int j=0;j<5;j++) GATE_STORE(acA[j], acB[j], 2*j)
  }
  // ---- group kappa=5: 4 col-tiles, 10 K-steps ----
  {
    f32x4 acA[4], acB[4];
    #pragma unroll
    for(int j=0;j<4;j++)
      #pragma unroll
      for(int r=0;r<4;r++){ acA[j][r]=g5b[ca+r]; acB[j][r]=g5b[64+ca+r]; }
    #pragma unroll
    for(int s=0;s<10;s++){
      bf16x8 a0 = *(const bf16x8*)&Apack[(48 + (w  )*10 + s)*512 + lane*8];
      bf16x8 a1 = *(const bf16x8*)&Apack[(48 + (w+4)*10 + s)*512 + lane*8];
      int dt=s>>1;
      int sl = ((((s&1)*32 + halfk*8)*2) ^ (gg<<4));
      #pragma unroll
      for(int j=0;j<4;j++){
        int t=2*j+tau2+dt;
        bf16x8 bf = *(const bf16x8*)(xlb + ((t*8+gg)<<7) + sl);
        acA[j] = __builtin_amdgcn_mfma_f32_16x16x32_bf16(a0, bf, acA[j], 0,0,0);
        acB[j] = __builtin_amdgcn_mfma_f32_16x16x32_bf16(a1, bf, acB[j], 0,0,0);
      }
    }
    #pragma unroll
    for(int j=0;j<4;j++) GATE_STORE(acA[j], acB[j], 10+2*j)
  }
  // ---- group kappa=7: 3 col-tiles, 14 K-steps ----
  {
    f32x4 acA[3], acB[3];
    #pragma unroll
    for(int j=0;j<3;j++)
      #pragma unroll
      for(int r=0;r<4;r++){ acA[j][r]=g7b[ca+r]; acB[j][r]=g7b[64+ca+r]; }
    #pragma unroll
    for(int s=0;s<14;s++){
      bf16x8 a0 = *(const bf16x8*)&Apack[(128 + (w  )*14 + s)*512 + lane*8];
      bf16x8 a1 = *(const bf16x8*)&Apack[(128 + (w+4)*14 + s)*512 + lane*8];
      int dt=s>>1;
      int sl = ((((s&1)*32 + halfk*8)*2) ^ (gg<<4));
      #pragma unroll
      for(int j=0;j<3;j++){
        int t=2*j+tau2+dt;
        bf16x8 bf = *(const bf16x8*)(xlb + ((t*8+gg)<<7) + sl);
        acA[j] = __builtin_amdgcn_mfma_f32_16x16x32_bf16(a0, bf, acA[j], 0,0,0);
        acB[j] = __builtin_amdgcn_mfma_f32_16x16x32_bf16(a1, bf, acB[j], 0,0,0);
      }
    }
    #pragma unroll
    for(int j=0;j<3;j++) GATE_STORE(acA[j], acB[j], 18+2*j)
  }
  #undef GATE_STORE

  // ---- fc via MFMA: per g, D2[c][t] = Gl(A2) x fcwB(B2), K=24 pad 32 ----
  const int tcol = lane&15, hq = lane>>4;
  const int hm = (hq==3)? 0 : hq;            // hi=3 rows of B2 are zero -> A2 values irrelevant
  bf16x8 b2 = *(const bf16x8*)&fcwB[lane*8];
  float fcbv = (tcol<12)? fcb[tcol] : 0.f;
  f32x4 d2[8];
  #pragma unroll
  for(int g=0; g<8; g++){
    bf16x8 a2 = *(const bf16x8*)&Glw[tcol*192 + ((g ^ (tcol&7))*24) + hm*8];
    f32x4 ini = {fcbv, fcbv, fcbv, fcbv};
    d2[g] = __builtin_amdgcn_mfma_f32_16x16x32_bf16(a2, b2, ini, 0,0,0);
  }
  __syncthreads();   // all Gl reads done; XP (union) becomes writable

  // epilogue: relu(time_conv) + residual + relu -> XP  (row c = w*16+hq*4+r, col t = tcol)
  if(tcol<12){
    float rwa[4], rba[4];
    #pragma unroll
    for(int r=0;r<4;r++){ int c=w*16+hq*4+r; rwa[r]=rw[c]; rba[r]=rb[c]; }
    #pragma unroll
    for(int g=0; g<8; g++){
      float xv=xres[g][tcol];
      #pragma unroll
      for(int r=0;r<4;r++){
        int c=w*16+hq*4+r;
        float tv = fmaxf(d2[g][r], 0.f);
        float xr = xv*rwa[r]+rba[r];
        U.XP[g][c*12+tcol] = fmaxf(xr+tv, 0.f);
      }
    }
  }
  __syncthreads();

  // LN over c (192 threads, split c-range, shfl combine)
  if(tid<192){
    int p=tid>>1, h=tid&1;
    int g=p/12, t=p-(p/12)*12;
    float s=0.f;
    for(int c=h*32;c<h*32+32;c++) s+=U.XP[g][c*12+t];
    s += __shfl_xor(s,1,64);
    float mu=s*(1.f/64.f);
    float q=0.f;
    for(int c=h*32;c<h*32+32;c++){float d=U.XP[g][c*12+t]-mu;q+=d*d;}
    q += __shfl_xor(q,1,64);
    if(h==0){ mu8[g][t]=mu; rs8[g][t]=rsqrtf(q*(1.f/64.f)+EPS); }
  }
  __syncthreads();
  for(int o=tid;o<8*768;o+=256){
    int g=o/768; int ct=o-g*768; int c=ct/12; int t=ct-c*12;
    out[(long)(bn0+g)*768 + ct]=(U.XP[g][c*12+t]-mu8[g][t])*rs8[g][t]*gln[c]+bln[c];
  }
}

// ---------------- launch ----------------
extern "C" void kernel_launch(void* const* d_in, const int* in_sizes, int n_in,
                              void* d_out, int out_size, void* d_ws, size_t ws_size,
                              hipStream_t stream){
  const float* x    =(const float*)d_in[0];
  const float* res  =(const float*)d_in[1];
  const float* posT =(const float*)d_in[2];
  const float* gT   =(const float*)d_in[3];
  const float* bT   =(const float*)d_in[4];
  const float* wq   =(const float*)d_in[5];
  const float* wk   =(const float*)d_in[6];
  const float* wv   =(const float*)d_in[7];
  const float* fcW  =(const float*)d_in[8];
  const float* prw  =(const float*)d_in[9];
  const float* prb  =(const float*)d_in[10];
  const float* posS =(const float*)d_in[11];
  const float* gS   =(const float*)d_in[12];
  const float* bS   =(const float*)d_in[13];
  const float* swq  =(const float*)d_in[14];
  const float* swk  =(const float*)d_in[15];
  const float* cheb =(const float*)d_in[16];
  const float* adj  =(const float*)d_in[17];
  const float* cmask=(const float*)d_in[18];
  const float* theta=(const float*)d_in[19];
  const float* g3w=(const float*)d_in[20]; const float* g3b=(const float*)d_in[21];
  const float* g5w=(const float*)d_in[22]; const float* g5b=(const float*)d_in[23];
  const float* g7w=(const float*)d_in[24]; const float* g7b=(const float*)d_in[25];
  const float* fcw=(const float*)d_in[26]; const float* fcb=(const float*)d_in[27];
  const float* rw =(const float*)d_in[28]; const float* rb =(const float*)d_in[29];
  const float* gln=(const float*)d_in[30]; const float* bln=(const float*)d_in[31];

  float* outp=(float*)d_out;
  float* scores = outp + 12582912;

  float* wsf=(float*)d_ws;
  float* TEmx = wsf;                          // 196608 f
  float* qkv  = TEmx + 196608;                // 55296 f
  float* ctx  = qkv + 55296;                  // 18432 f
  float* TAT  = ctx + 18432;                  // 196608 f
  unsigned short* SEb = (unsigned short*)(TAT + 196608);          // 4194304 f
  unsigned short* SQb = (unsigned short*)((float*)SEb + 4194304); // 786432 f
  unsigned short* SKb = (unsigned short*)((float*)SQb + 786432);  // 786432 f
  unsigned* mc = (unsigned*)((float*)SKb + 786432);               // 3145728 f
  float* rhsT  = (float*)mc + 3145728;                            // 589824 f
  unsigned short* Apack = (unsigned short*)(rhsT + 589824);       // 122880 u16
  unsigned short* Wpack = Apack + 122880;                         // 98304 u16
  unsigned short* Wpack2 = Wpack + 98304;                         // 294912 u16
  unsigned short* TEb = Wpack2 + 294912;                          // 196608 u16
  unsigned short* fcwB = TEb + 196608;                            // 512 u16

  k0_prep<<<dim3(12288),dim3(256),0,stream>>>(adj,cmask,cheb,mc);
  k8_prep<<<dim3(60),dim3(256),0,stream>>>(g3w,g5w,g7w,Apack);
  kw_prep<<<dim3(48),dim3(256),0,stream>>>(swq,swk,Wpack);
  kw2_prep<<<dim3(144),dim3(256),0,stream>>>(wq,wk,wv,Wpack2);
  kfc_prep<<<dim3(1),dim3(64),0,stream>>>(fcw,fcwB);
  k1_embedT<<<dim3(192),dim3(256),0,stream>>>(x,posT,gT,bT,TEmx,TEb);
  k2_qkv<<<dim3(216),dim3(256),0,stream>>>(TEb,Wpack2,qkv);
  k3_attn<<<dim3(16),dim3(512),0,stream>>>(qkv,res,scores,ctx);
  k4_tat<<<dim3(192),dim3(256),0,stream>>>(ctx,fcW,TEmx,TAT);
  k5_semx<<<dim3(16384),dim3(256),0,stream>>>(TAT,prw,prb,posS,gS,bS,SEb);
  k6_sqk<<<dim3(256),dim3(256),0,stream>>>(SEb,Wpack,SQb,SKb);
  k7_spatial<<<dim3(768),dim3(256),0,stream>>>(SQb,SKb,mc,x,rhsT);
  k9_final<<<dim3(2048),dim3(256),0,stream>>>(rhsT,theta,Apack,fcwB,g3b,g5b,g7b,
                                              fcb,rw,rb,gln,bln,x,outp);
}

// Round 9
// 207.132 us; speedup vs baseline: 7.2583x; 1.0616x over previous
//
#include <hip/hip_runtime.h>
#include <hip/hip_fp16.h>

#define EPS 1e-5f

typedef float f32x4 __attribute__((ext_vector_type(4)));
typedef short bf16x8 __attribute__((ext_vector_type(8)));
typedef short bf16x4 __attribute__((ext_vector_type(4)));

__device__ __forceinline__ unsigned short f2b(float f){
  unsigned u=__float_as_uint(f);
  return (unsigned short)((u + 0x7fffu + ((u>>16)&1u))>>16);
}
__device__ __forceinline__ float b2f(unsigned short h){
  return __uint_as_float(((unsigned)h)<<16);
}

// ---------------- helpers ----------------
__device__ __forceinline__ float blockSum256(float v, float* red){
  #pragma unroll
  for(int o=32;o>0;o>>=1) v += __shfl_down(v,o,64);
  int wid = threadIdx.x>>6;
  if((threadIdx.x&63)==0) red[wid]=v;
  __syncthreads();
  if(threadIdx.x==0) red[0]=red[0]+red[1]+red[2]+red[3];
  __syncthreads();
  float r = red[0];
  __syncthreads();
  return r;
}

// ---------------- KB0: pack mask/cheb TRANSPOSED: mcT[k][m][n] ----------------
// 64x64 tiles via LDS; reads coalesced in m, writes coalesced in n.
__global__ __launch_bounds__(256) void kb0_prep(const float* __restrict__ adj, const float* __restrict__ cmask,
    const float* __restrict__ cheb, unsigned* __restrict__ mcT){
  int blk=blockIdx.x;                 // k*256 + tn*16 + tm
  int k=blk>>8; int rem=blk&255; int tn=rem>>4, tm=rem&15;
  int tid=threadIdx.x;
  __shared__ unsigned tile[64][65];
  const float* chk = cheb + k*1048576;
  const float* cmk = cmask + k*1048576;
  for(int i=tid;i<4096;i+=256){
    int ln=i>>6, lm=i&63;
    int n=tn*64+ln, m=tm*64+lm;
    int nm=n*1024+m;
    tile[ln][lm] = (((unsigned)f2b(chk[nm]))<<16) | (unsigned)f2b(adj[nm]*cmk[nm]);
  }
  __syncthreads();
  unsigned* dst = mcT + k*1048576;
  for(int i=tid;i<4096;i+=256){
    int lm=i>>6, ln=i&63;
    dst[(tm*64+lm)*1024 + tn*64+ln] = tile[ln][lm];
  }
}

// ---------------- KPREP: fused weight packing (Apack | Wpack | Wpack2 | fcwB) ----------------
__global__ __launch_bounds__(256) void kprep(const float* __restrict__ g3w, const float* __restrict__ g5w,
    const float* __restrict__ g7w, const float* __restrict__ swq, const float* __restrict__ swk,
    const float* __restrict__ wq, const float* __restrict__ wk, const float* __restrict__ wv,
    const float* __restrict__ fcw,
    unsigned short* __restrict__ Apack, unsigned short* __restrict__ Wpack,
    unsigned short* __restrict__ Wpack2, unsigned short* __restrict__ fcwB){
  int idx = blockIdx.x*256+threadIdx.x;
  if(idx<15360){                                   // Apack (conv A-frags)
    int frag=idx>>6, lane=idx&63;
    int rt, s, kappa; const float* W;
    if(frag<48){ rt=frag/6; s=frag-rt*6; kappa=3; W=g3w; }
    else if(frag<128){ int f=frag-48; rt=f/10; s=f-rt*10; kappa=5; W=g5w; }
    else { int f=frag-128; rt=f/14; s=f-rt*14; kappa=7; W=g7w; }
    int c = rt*16 + (lane&15);
    int dt = s>>1, ic0=(s&1)*32 + (lane>>4)*8;
    #pragma unroll
    for(int j=0;j<8;j++) Apack[idx*8+j]=f2b(W[(c*64+ic0+j)*kappa + dt]);
  } else if(idx<27648){                            // Wpack (swq/swk B-frags)
    int id2=idx-15360;
    int frag=id2>>6, lane=id2&63;
    int ct=frag>>4, ks=frag&15;
    const float* W = (ct<6)? swq : swk;
    int c = ((ct<6)? ct : ct-6)*16 + (lane&15);
    int k0 = ks*32 + (lane>>4)*8;
    #pragma unroll
    for(int j=0;j<8;j++) Wpack[id2*8+j]=f2b(W[(k0+j)*96 + c]);
  } else if(idx<64512){                            // Wpack2 (wq|wk|wv B-frags)
    int id2=idx-27648;
    int frag=id2>>6, lane=id2&63;
    int ct=frag>>5, ks=frag&31;
    int cg = ct*16 + (lane&15);
    const float* W; int c;
    if(cg<96){ W=wq; c=cg; } else if(cg<192){ W=wk; c=cg-96; } else { W=wv; c=cg-192; }
    int k0 = ks*32 + (lane>>4)*8;
    #pragma unroll
    for(int j=0;j<8;j++) Wpack2[id2*8+j]=f2b(W[(k0+j)*96 + c]);
  } else if(idx<64576){                            // fcwB
    int lane=idx-64512;
    int t=lane&15, hq=lane>>4;
    #pragma unroll
    for(int j=0;j<8;j++){
      int tau=hq*8+j;
      fcwB[lane*8+j] = (tau<24 && t<12) ? f2b(fcw[tau*12+t]) : (unsigned short)0;
    }
  }
}

// ---------------- K1: EmbedT (fp32 + bf16 outputs) ----------------
__global__ __launch_bounds__(256) void k1_embedT(const float* __restrict__ x, const float* __restrict__ posT,
    const float* __restrict__ gT, const float* __restrict__ bT, float* __restrict__ TEmx,
    unsigned short* __restrict__ TEb){
  int bt=blockIdx.x; int b=bt/12, t=bt-b*12;
  int tid=threadIdx.x;
  __shared__ float red[4];
  float v[4]; float s=0.f;
  #pragma unroll
  for(int i=0;i<4;i++){ int n=tid+i*256; v[i]=x[(b*1024+n)*12+t]+posT[t*1024+n]; s+=v[i]; }
  s = blockSum256(s, red);
  float mu = s*(1.f/1024.f);
  float q=0.f;
  #pragma unroll
  for(int i=0;i<4;i++){ float d=v[i]-mu; q+=d*d; }
  q = blockSum256(q, red);
  float rstd = rsqrtf(q*(1.f/1024.f)+EPS);
  #pragma unroll
  for(int i=0;i<4;i++){
    int n=tid+i*256;
    float val=(v[i]-mu)*rstd*gT[n]+bT[n];
    TEmx[bt*1024+n]=val;
    TEb[bt*1024+n]=f2b(val);
  }
}

// ---------------- K2: QKV via MFMA split-K GEMM ----------------
__global__ __launch_bounds__(256) void k2_qkv(const unsigned short* __restrict__ TEb,
    const unsigned short* __restrict__ Wpack2, float* __restrict__ qkv){
  int tid=threadIdx.x; int w=tid>>6, lane=tid&63;
  const int hi=lane>>4, lo=lane&15;
  const int rt=blockIdx.x/18, ct=blockIdx.x-rt*18;
  __shared__ float red[4][16][16];
  f32x4 acc={0.f,0.f,0.f,0.f};
  #pragma unroll
  for(int s=0;s<8;s++){
    int ks=w*8+s;
    bf16x8 af = *(const bf16x8*)&TEb[(rt*16+lo)*1024 + ks*32 + hi*8];
    bf16x8 bf = *(const bf16x8*)&Wpack2[((ct*32+ks)<<9) + lane*8];
    acc = __builtin_amdgcn_mfma_f32_16x16x32_bf16(af, bf, acc, 0,0,0);
  }
  #pragma unroll
  for(int r=0;r<4;r++) red[w][hi*4+r][lo]=acc[r];
  __syncthreads();
  int r16=tid>>4, c16=tid&15;
  float s = red[0][r16][c16]+red[1][r16][c16]+red[2][r16][c16]+red[3][r16][c16];
  qkv[(rt*16+r16)*288 + ct*16 + c16] = s;
}

// ---------------- K3: temporal attn ----------------
__global__ __launch_bounds__(512) void k3_attn(const float* __restrict__ qkv, const float* __restrict__ res_att,
    float* __restrict__ scores_out, float* __restrict__ ctx){
  int b=blockIdx.x; int tid=threadIdx.x;
  __shared__ float sS[432];
  __shared__ float sA[432];
  if(tid<432){
    int h=tid/144; int r=tid-h*144; int q=r/12; int k2=r-q*12;
    const float* Qr=&qkv[(b*12+q)*288 + h*32];
    const float* Kr=&qkv[(b*12+k2)*288 + 96 + h*32];
    float acc=0.f;
    #pragma unroll
    for(int d=0;d<32;d++) acc+=Qr[d]*Kr[d];
    acc = acc*0.17677669529663687f + res_att[(b*3+h)*144 + q*12 + k2];
    sS[h*144+q*12+k2]=acc;
    scores_out[(b*3+h)*144 + q*12 + k2]=acc;
  }
  __syncthreads();
  if(tid<36){
    int h=tid/12, k2=tid-(tid/12)*12;
    float mx=-1e30f;
    for(int q=0;q<12;q++) mx=fmaxf(mx,sS[h*144+q*12+k2]);
    float sum=0.f;
    for(int q=0;q<12;q++){ float e=__expf(sS[h*144+q*12+k2]-mx); sA[h*144+q*12+k2]=e; sum+=e; }
    float inv=1.f/sum;
    for(int q=0;q<12;q++) sA[h*144+q*12+k2]*=inv;
  }
  __syncthreads();
  for(int o=tid;o<1152;o+=512){
    int h=o/384; int r=o-h*384; int q=r/32; int d=r-q*32;
    float acc=0.f;
    #pragma unroll
    for(int k2=0;k2<12;k2++) acc += sA[h*144+q*12+k2]*qkv[(b*12+k2)*288+192+h*32+d];
    ctx[(b*12+q)*96 + h*32 + d]=acc;
  }
}

// ---------------- K4: TATout ----------------
__global__ __launch_bounds__(256) void k4_tat(const float* __restrict__ ctx, const float* __restrict__ fcW,
    const float* __restrict__ TEmx, float* __restrict__ TAT){
  int bt=blockIdx.x; int tid=threadIdx.x;
  __shared__ float c96[96];
  __shared__ float red[4];
  if(tid<96) c96[tid]=ctx[bt*96+tid];
  __syncthreads();
  float v[4]; float s=0.f;
  #pragma unroll
  for(int i=0;i<4;i++){
    int n=tid+i*256;
    float acc=TEmx[bt*1024+n];
    #pragma unroll 4
    for(int j=0;j<96;j++) acc += c96[j]*fcW[j*1024+n];
    v[i]=acc; s+=acc;
  }
  s=blockSum256(s,red);
  float mu=s*(1.f/1024.f);
  float q=0.f;
  #pragma unroll
  for(int i=0;i<4;i++){float d=v[i]-mu;q+=d*d;}
  q=blockSum256(q,red);
  float rstd=rsqrtf(q*(1.f/1024.f)+EPS);
  #pragma unroll
  for(int i=0;i<4;i++){int n=tid+i*256; TAT[bt*1024+n]=(v[i]-mu)*rstd;}
}

// ---------------- K5 v2: SEmx, 8 rows/block; pre_w in regs; one LDS-matrix LN reduce ----------------
__global__ __launch_bounds__(256) void k5_semx(const float* __restrict__ TAT, const float* __restrict__ pre_w,
    const float* __restrict__ pre_b, const float* __restrict__ posS, const float* __restrict__ gS,
    const float* __restrict__ bS, unsigned short* __restrict__ SEb){
  int bn0=blockIdx.x*8; int b=bn0>>10, n0=bn0&1023; int tid=threadIdx.x;
  __shared__ float tv[12][8];
  __shared__ float ps[8][264];
  __shared__ float pq[8][264];
  __shared__ float mur[8], rsr[8];
  if(tid<96){ int r=tid&7, t=tid>>3; tv[t][r]=TAT[(b*12+t)*1024+n0+r]; }
  __syncthreads();
  const int d0=tid, d1=tid+256;
  float w0[12], w1[12];
  {
    const float4* p0=(const float4*)&pre_w[d0*12];
    float4 a=p0[0], bb=p0[1], c=p0[2];
    w0[0]=a.x;w0[1]=a.y;w0[2]=a.z;w0[3]=a.w; w0[4]=bb.x;w0[5]=bb.y;w0[6]=bb.z;w0[7]=bb.w;
    w0[8]=c.x;w0[9]=c.y;w0[10]=c.z;w0[11]=c.w;
    const float4* p1=(const float4*)&pre_w[d1*12];
    float4 d=p1[0], e=p1[1], f=p1[2];
    w1[0]=d.x;w1[1]=d.y;w1[2]=d.z;w1[3]=d.w; w1[4]=e.x;w1[5]=e.y;w1[6]=e.z;w1[7]=e.w;
    w1[8]=f.x;w1[9]=f.y;w1[10]=f.z;w1[11]=f.w;
  }
  float pb0=pre_b[d0], pb1=pre_b[d1];
  float v0[8], v1[8];
  #pragma unroll
  for(int r=0;r<8;r++){
    float acc0=pb0 + posS[(n0+r)*512+d0];
    float acc1=pb1 + posS[(n0+r)*512+d1];
    #pragma unroll
    for(int t=0;t<12;t++){ float tvv=tv[t][r]; acc0+=tvv*w0[t]; acc1+=tvv*w1[t]; }
    v0[r]=acc0; v1[r]=acc1;
    ps[r][tid]=acc0+acc1;
    pq[r][tid]=acc0*acc0+acc1*acc1;
  }
  __syncthreads();
  {
    int row=tid>>5, l32=tid&31;
    float s=0.f, q=0.f;
    #pragma unroll
    for(int j=0;j<8;j++){ s+=ps[row][l32+j*32]; q+=pq[row][l32+j*32]; }
    #pragma unroll
    for(int o=16;o>=1;o>>=1){ s+=__shfl_xor(s,o,64); q+=__shfl_xor(q,o,64); }
    if(l32==0){
      float mu=s*(1.f/512.f);
      float var=q*(1.f/512.f)-mu*mu;
      mur[row]=mu; rsr[row]=rsqrtf(var+EPS);
    }
  }
  __syncthreads();
  float g0=gS[d0], b0v=bS[d0], g1=gS[d1], b1v=bS[d1];
  #pragma unroll
  for(int r=0;r<8;r++){
    float mu=mur[r], rs=rsr[r];
    SEb[(bn0+r)*512 + d0] = f2b((v0[r]-mu)*rs*g0+b0v);
    SEb[(bn0+r)*512 + d1] = f2b((v1[r]-mu)*rs*g1+b1v);
  }
}

// ---------------- K6: SQ/SK via MFMA GEMM ----------------
__global__ __launch_bounds__(256) void k6_sqk(const unsigned short* __restrict__ SEb,
    const unsigned short* __restrict__ Wpack,
    unsigned short* __restrict__ SQb, unsigned short* __restrict__ SKb){
  int tid=threadIdx.x; int w=tid>>6, lane=tid&63;
  const int hi=lane>>4, lo=lane&15;
  const int row0 = blockIdx.x*64 + w*16;
  f32x4 acc[12];
  #pragma unroll
  for(int i=0;i<12;i++){ acc[i][0]=0.f; acc[i][1]=0.f; acc[i][2]=0.f; acc[i][3]=0.f; }
  for(int ks=0;ks<16;ks++){
    bf16x8 af = *(const bf16x8*)&SEb[(row0+lo)*512 + ks*32 + hi*8];
    #pragma unroll
    for(int ct=0;ct<12;ct++){
      bf16x8 bf = *(const bf16x8*)&Wpack[((ct*16+ks)<<9) + lane*8];
      acc[ct] = __builtin_amdgcn_mfma_f32_16x16x32_bf16(af, bf, acc[ct], 0,0,0);
    }
  }
  #pragma unroll
  for(int ct=0;ct<12;ct++){
    int c96 = ((ct<6)? ct : ct-6)*16 + lo;
    int kq = c96>>5, d = c96&31;
    unsigned short* dst = (ct<6)? SQb : SKb;
    #pragma unroll
    for(int r=0;r<4;r++){
      int n = row0 + hi*4 + r;
      int b = n>>10, nl = n&1023;
      dst[((b*3+kq)*1024+nl)*32 + d] = f2b(acc[ct][r]);
    }
  }
}

// ---------------- K7: fused spatial attention + graph conv (MFMA flash, mcT + XCD swizzle) ----------------
#define SCALE7 0.17677669529663687f
__global__ __launch_bounds__(256) void k7_spatial(const unsigned short* __restrict__ SQb,
    const unsigned short* __restrict__ SKb, const unsigned* __restrict__ mcT,
    const float* __restrict__ x, float* __restrict__ rhsT){
  const int blk0=blockIdx.x;
  const int blk=(blk0&7)*96 + (blk0>>3);      // XCD-chunked: 768 = 8*96, bijective
  const int mt=blk&15, bk=blk>>4;
  const int k=bk%3, b=bk/3;
  const int m0=mt*64;
  const int tid=threadIdx.x;
  const int w=tid>>6, lane=tid&63, g=lane>>4, col=lane&15;

  __shared__ unsigned short xs[16*128];

  const int m_glob = m0 + w*16 + col;
  bf16x8 bfrag = *(const bf16x8*)&SKb[((bk<<10)+m_glob)*32 + g*8];

  f32x4 O = {0.f,0.f,0.f,0.f};
  float mrun=-1e30f, lrun=0.f;

  const float* xb = x + b*12288;
  const unsigned* mrow = mcT + k*1048576 + m_glob*1024;
  const int swz = (col&7)<<3;

  for(int i=tid;i<512;i+=256){ int t=12+(i>>7), n=i&127; xs[t*128 + (n ^ ((t&7)<<3))]=0; }

  for(int ch=0; ch<8; ++ch){
    const int n0 = ch<<7;
    __syncthreads();
    for(int i=tid;i<1536;i+=256){
      int n=i/12, t=i-n*12;
      xs[t*128 + (n ^ ((t&7)<<3))] = f2b(xb[n0*12 + i]);
    }
    __syncthreads();

    f32x4 acc[8];
    #pragma unroll
    for(int nt=0;nt<8;nt++){
      bf16x8 afrag = *(const bf16x8*)&SQb[((bk<<10) + n0 + nt*16 + col)*32 + g*8];
      f32x4 z = {0.f,0.f,0.f,0.f};
      acc[nt] = __builtin_amdgcn_mfma_f32_16x16x32_bf16(afrag, bfrag, z, 0,0,0);
    }
    unsigned mcv[8][4];
    #pragma unroll
    for(int nt=0;nt<8;nt++){
      uint4 mv = *(const uint4*)&mrow[n0 + nt*16 + g*4];
      mcv[nt][0]=mv.x; mcv[nt][1]=mv.y; mcv[nt][2]=mv.z; mcv[nt][3]=mv.w;
    }
    float cmax = -1e30f;
    #pragma unroll
    for(int nt=0;nt<8;nt++){
      #pragma unroll
      for(int r=0;r<4;r++){
        float s = acc[nt][r]*SCALE7 + __uint_as_float(mcv[nt][r]<<16);
        acc[nt][r]=s;
        cmax=fmaxf(cmax,s);
      }
    }
    cmax = fmaxf(cmax, __shfl_xor(cmax,16,64));
    cmax = fmaxf(cmax, __shfl_xor(cmax,32,64));
    float mnew = fmaxf(mrun, cmax);
    float alpha = __expf(mrun - mnew);
    float lsum = 0.f;
    unsigned short pb[8][4];
    #pragma unroll
    for(int nt=0;nt<8;nt++){
      #pragma unroll
      for(int r=0;r<4;r++){
        float e = __expf(acc[nt][r] - mnew);
        lsum += e;
        pb[nt][r] = f2b(e * __uint_as_float(mcv[nt][r] & 0xffff0000u));
      }
    }
    lsum += __shfl_xor(lsum,16,64);
    lsum += __shfl_xor(lsum,32,64);
    lrun = lrun*alpha + lsum;
    mrun = mnew;
    O[0]*=alpha; O[1]*=alpha; O[2]*=alpha; O[3]*=alpha;

    #pragma unroll
    for(int c=0;c<4;c++){
      bf16x8 pf;
      #pragma unroll
      for(int j=0;j<4;j++){ pf[j]=(short)pb[2*c][j]; pf[j+4]=(short)pb[2*c+1][j]; }
      int nlo = c*32 + g*4;
      bf16x4 lo = *(const bf16x4*)&xs[col*128 + (nlo ^ swz)];
      bf16x4 hi = *(const bf16x4*)&xs[col*128 + ((nlo+16) ^ swz)];
      bf16x8 ax;
      #pragma unroll
      for(int j=0;j<4;j++){ ax[j]=lo[j]; ax[j+4]=hi[j]; }
      O = __builtin_amdgcn_mfma_f32_16x16x32_bf16(ax, pf, O, 0,0,0);
    }
  }
  float inv = 1.f/lrun;
  #pragma unroll
  for(int r=0;r<4;r++){
    int t = g*4+r;
    if(t<12) rhsT[((bk*12+t)<<10) + m_glob] = O[r]*inv;
  }
}

// ---------------- K9: conv MFMA -> gated bf16 LDS tile -> fc via MFMA -> residual+LN ----
__global__ __launch_bounds__(256) void k9_final(const float* __restrict__ rhsT, const float* __restrict__ theta,
    const unsigned short* __restrict__ Apack, const unsigned short* __restrict__ fcwB,
    const float* __restrict__ g3b, const float* __restrict__ g5b, const float* __restrict__ g7b,
    const float* __restrict__ fcb,
    const float* __restrict__ rw, const float* __restrict__ rb,
    const float* __restrict__ gln, const float* __restrict__ bln,
    const float* __restrict__ x, float* __restrict__ out){
  int bn0=blockIdx.x*8;
  int tid=threadIdx.x;
  const int b=bn0>>10, n0=bn0&1023;

  __shared__ struct { unsigned short Xl[12*8*64]; float rstage[3][12][8]; } P0;
  __shared__ union {
    unsigned short Gl[4*16*8*24];   // [wave][c_loc][g'][tau]
    float XP[8][772];
  } U;
  __shared__ float xres[8][12];
  __shared__ float mu8[8][12], rs8[8][12];

  for(int i=tid;i<288;i+=256){
    int kk=i/96; int rem=i-kk*96; int t=rem>>3; int g=rem&7;
    P0.rstage[kk][t][g]=rhsT[((b*3+kk)*12+t)*1024 + n0 + g];
  }
  for(int i=tid;i<96;i+=256){ int g=i/12, t=i-(i/12)*12; xres[g][t]=x[(bn0+g)*12+t]; }
  __syncthreads();

  {
    int g=tid>>5, icp=tid&31;
    float th0[3], th1[3];
    #pragma unroll
    for(int kk=0;kk<3;kk++){ th0[kk]=theta[kk*64+2*icp]; th1[kk]=theta[kk*64+2*icp+1]; }
    #pragma unroll
    for(int t=0;t<12;t++){
      float r0=P0.rstage[0][t][g], r1=P0.rstage[1][t][g], r2=P0.rstage[2][t][g];
      float a0=fmaxf(r0*th0[0]+r1*th0[1]+r2*th0[2],0.f);
      float a1=fmaxf(r0*th1[0]+r1*th1[1]+r2*th1[2],0.f);
      unsigned pack = (((unsigned)f2b(a1))<<16)|(unsigned)f2b(a0);
      *(unsigned*)((char*)P0.Xl + ((t*8+g)<<7) + ((icp*4) ^ (g<<4))) = pack;
    }
  }
  __syncthreads();

  const int w=tid>>6, lane=tid&63, halfk=lane>>4, colq=lane&15;
  const int gg=colq&7, tau2=colq>>3;
  const int ca = w*16 + halfk*4;
  const char* xlb = (const char*)P0.Xl;
  unsigned short* Glw = &U.Gl[w*3072];

  #define GATE_STORE(ACCA, ACCB, TB) { \
    _Pragma("unroll") \
    for(int r=0;r<4;r++){ \
      float ya=(ACCA)[r], yb=(ACCB)[r]; \
      float e2=__expf(2.f*ya), eb=__expf(yb); \
      float gval=(e2-1.f)*eb*__frcp_rn((e2+1.f)*(eb+1.f)); \
      int c_loc=halfk*4+r; \
      Glw[c_loc*192 + ((gg ^ (c_loc&7))*24) + (TB)+tau2] = f2b(gval); \
    } }

  // ---- group kappa=3 ----
  {
    f32x4 acA[5], acB[5];
    #pragma unroll
    for(int j=0;j<5;j++)
      #pragma unroll
      for(int r=0;r<4;r++){ acA[j][r]=g3b[ca+r]; acB[j][r]=g3b[64+ca+r]; }
    #pragma unroll
    for(int s=0;s<6;s++){
      bf16x8 a0 = *(const bf16x8*)&Apack[((w  )*6 + s)*512 + lane*8];
      bf16x8 a1 = *(const bf16x8*)&Apack[((w+4)*6 + s)*512 + lane*8];
      int dt=s>>1;
      int sl = ((((s&1)*32 + halfk*8)*2) ^ (gg<<4));
      #pragma unroll
      for(int j=0;j<5;j++){
        int t=2*j+tau2+dt;
        bf16x8 bf = *(const bf16x8*)(xlb + ((t*8+gg)<<7) + sl);
        acA[j] = __builtin_amdgcn_mfma_f32_16x16x32_bf16(a0, bf, acA[j], 0,0,0);
        acB[j] = __builtin_amdgcn_mfma_f32_16x16x32_bf16(a1, bf, acB[j], 0,0,0);
      }
    }
    #pragma unroll
    for(int j=0;j<5;j++) GATE_STORE(acA[j], acB[j], 2*j)
  }
  // ---- group kappa=5 ----
  {
    f32x4 acA[4], acB[4];
    #pragma unroll
    for(int j=0;j<4;j++)
      #pragma unroll
      for(int r=0;r<4;r++){ acA[j][r]=g5b[ca+r]; acB[j][r]=g5b[64+ca+r]; }
    #pragma unroll
    for(int s=0;s<10;s++){
      bf16x8 a0 = *(const bf16x8*)&Apack[(48 + (w  )*10 + s)*512 + lane*8];
      bf16x8 a1 = *(const bf16x8*)&Apack[(48 + (w+4)*10 + s)*512 + lane*8];
      int dt=s>>1;
      int sl = ((((s&1)*32 + halfk*8)*2) ^ (gg<<4));
      #pragma unroll
      for(int j=0;j<4;j++){
        int t=2*j+tau2+dt;
        bf16x8 bf = *(const bf16x8*)(xlb + ((t*8+gg)<<7) + sl);
        acA[j] = __builtin_amdgcn_mfma_f32_16x16x32_bf16(a0, bf, acA[j], 0,0,0);
        acB[j] = __builtin_amdgcn_mfma_f32_16x16x32_bf16(a1, bf, acB[j], 0,0,0);
      }
    }
    #pragma unroll
    for(int j=0;j<4;j++) GATE_STORE(acA[j], acB[j], 10+2*j)
  }
  // ---- group kappa=7 ----
  {
    f32x4 acA[3], acB[3];
    #pragma unroll
    for(int j=0;j<3;j++)
      #pragma unroll
      for(int r=0;r<4;r++){ acA[j][r]=g7b[ca+r]; acB[j][r]=g7b[64+ca+r]; }
    #pragma unroll
    for(int s=0;s<14;s++){
      bf16x8 a0 = *(const bf16x8*)&Apack[(128 + (w  )*14 + s)*512 + lane*8];
      bf16x8 a1 = *(const bf16x8*)&Apack[(128 + (w+4)*14 + s)*512 + lane*8];
      int dt=s>>1;
      int sl = ((((s&1)*32 + halfk*8)*2) ^ (gg<<4));
      #pragma unroll
      for(int j=0;j<3;j++){
        int t=2*j+tau2+dt;
        bf16x8 bf = *(const bf16x8*)(xlb + ((t*8+gg)<<7) + sl);
        acA[j] = __builtin_amdgcn_mfma_f32_16x16x32_bf16(a0, bf, acA[j], 0,0,0);
        acB[j] = __builtin_amdgcn_mfma_f32_16x16x32_bf16(a1, bf, acB[j], 0,0,0);
      }
    }
    #pragma unroll
    for(int j=0;j<3;j++) GATE_STORE(acA[j], acB[j], 18+2*j)
  }
  #undef GATE_STORE

  // ---- fc via MFMA ----
  const int tcol = lane&15, hq = lane>>4;
  const int hm = (hq==3)? 0 : hq;
  bf16x8 b2 = *(const bf16x8*)&fcwB[lane*8];
  float fcbv = (tcol<12)? fcb[tcol] : 0.f;
  f32x4 d2[8];
  #pragma unroll
  for(int g=0; g<8; g++){
    bf16x8 a2 = *(const bf16x8*)&Glw[tcol*192 + ((g ^ (tcol&7))*24) + hm*8];
    f32x4 ini = {fcbv, fcbv, fcbv, fcbv};
    d2[g] = __builtin_amdgcn_mfma_f32_16x16x32_bf16(a2, b2, ini, 0,0,0);
  }
  __syncthreads();

  if(tcol<12){
    float rwa[4], rba[4];
    #pragma unroll
    for(int r=0;r<4;r++){ int c=w*16+hq*4+r; rwa[r]=rw[c]; rba[r]=rb[c]; }
    #pragma unroll
    for(int g=0; g<8; g++){
      float xv=xres[g][tcol];
      #pragma unroll
      for(int r=0;r<4;r++){
        int c=w*16+hq*4+r;
        float tv = fmaxf(d2[g][r], 0.f);
        float xr = xv*rwa[r]+rba[r];
        U.XP[g][c*12+tcol] = fmaxf(xr+tv, 0.f);
      }
    }
  }
  __syncthreads();

  if(tid<192){
    int p=tid>>1, h=tid&1;
    int g=p/12, t=p-(p/12)*12;
    float s=0.f;
    for(int c=h*32;c<h*32+32;c++) s+=U.XP[g][c*12+t];
    s += __shfl_xor(s,1,64);
    float mu=s*(1.f/64.f);
    float q=0.f;
    for(int c=h*32;c<h*32+32;c++){float d=U.XP[g][c*12+t]-mu;q+=d*d;}
    q += __shfl_xor(q,1,64);
    if(h==0){ mu8[g][t]=mu; rs8[g][t]=rsqrtf(q*(1.f/64.f)+EPS); }
  }
  __syncthreads();
  // float4 final write: 768 = 64c x 3 quads (t = qb*4..+3, never crossing c)
  for(int o=tid;o<1536;o+=256){
    int g=o/192; int q4=o-g*192;
    int c=q4/3; int tb=(q4-c*3)*4;
    float4 vv = *(const float4*)&U.XP[g][c*12+tb];
    float gl=gln[c], bl=bln[c];
    float4 ov;
    ov.x=(vv.x-mu8[g][tb+0])*rs8[g][tb+0]*gl+bl;
    ov.y=(vv.y-mu8[g][tb+1])*rs8[g][tb+1]*gl+bl;
    ov.z=(vv.z-mu8[g][tb+2])*rs8[g][tb+2]*gl+bl;
    ov.w=(vv.w-mu8[g][tb+3])*rs8[g][tb+3]*gl+bl;
    *(float4*)&out[(long)(bn0+g)*768 + c*12 + tb] = ov;
  }
}

// ---------------- launch ----------------
extern "C" void kernel_launch(void* const* d_in, const int* in_sizes, int n_in,
                              void* d_out, int out_size, void* d_ws, size_t ws_size,
                              hipStream_t stream){
  const float* x    =(const float*)d_in[0];
  const float* res  =(const float*)d_in[1];
  const float* posT =(const float*)d_in[2];
  const float* gT   =(const float*)d_in[3];
  const float* bT   =(const float*)d_in[4];
  const float* wq   =(const float*)d_in[5];
  const float* wk   =(const float*)d_in[6];
  const float* wv   =(const float*)d_in[7];
  const float* fcW  =(const float*)d_in[8];
  const float* prw  =(const float*)d_in[9];
  const float* prb  =(const float*)d_in[10];
  const float* posS =(const float*)d_in[11];
  const float* gS   =(const float*)d_in[12];
  const float* bS   =(const float*)d_in[13];
  const float* swq  =(const float*)d_in[14];
  const float* swk  =(const float*)d_in[15];
  const float* cheb =(const float*)d_in[16];
  const float* adj  =(const float*)d_in[17];
  const float* cmask=(const float*)d_in[18];
  const float* theta=(const float*)d_in[19];
  const float* g3w=(const float*)d_in[20]; const float* g3b=(const float*)d_in[21];
  const float* g5w=(const float*)d_in[22]; const float* g5b=(const float*)d_in[23];
  const float* g7w=(const float*)d_in[24]; const float* g7b=(const float*)d_in[25];
  const float* fcw=(const float*)d_in[26]; const float* fcb=(const float*)d_in[27];
  const float* rw =(const float*)d_in[28]; const float* rb =(const float*)d_in[29];
  const float* gln=(const float*)d_in[30]; const float* bln=(const float*)d_in[31];

  float* outp=(float*)d_out;
  float* scores = outp + 12582912;

  float* wsf=(float*)d_ws;
  float* TEmx = wsf;                          // 196608 f
  float* qkv  = TEmx + 196608;                // 55296 f
  float* ctx  = qkv + 55296;                  // 18432 f
  float* TAT  = ctx + 18432;                  // 196608 f
  unsigned short* SEb = (unsigned short*)(TAT + 196608);          // 4194304 f
  unsigned short* SQb = (unsigned short*)((float*)SEb + 4194304); // 786432 f
  unsigned short* SKb = (unsigned short*)((float*)SQb + 786432);  // 786432 f
  unsigned* mcT = (unsigned*)((float*)SKb + 786432);              // 3145728 f
  float* rhsT  = (float*)mcT + 3145728;                           // 589824 f
  unsigned short* Apack = (unsigned short*)(rhsT + 589824);       // 122880 u16
  unsigned short* Wpack = Apack + 122880;                         // 98304 u16
  unsigned short* Wpack2 = Wpack + 98304;                         // 294912 u16
  unsigned short* TEb = Wpack2 + 294912;                          // 196608 u16
  unsigned short* fcwB = TEb + 196608;                            // 512 u16

  kb0_prep<<<dim3(768),dim3(256),0,stream>>>(adj,cmask,cheb,mcT);
  kprep<<<dim3(253),dim3(256),0,stream>>>(g3w,g5w,g7w,swq,swk,wq,wk,wv,fcw,
                                          Apack,Wpack,Wpack2,fcwB);
  k1_embedT<<<dim3(192),dim3(256),0,stream>>>(x,posT,gT,bT,TEmx,TEb);
  k2_qkv<<<dim3(216),dim3(256),0,stream>>>(TEb,Wpack2,qkv);
  k3_attn<<<dim3(16),dim3(512),0,stream>>>(qkv,res,scores,ctx);
  k4_tat<<<dim3(192),dim3(256),0,stream>>>(ctx,fcW,TEmx,TAT);
  k5_semx<<<dim3(2048),dim3(256),0,stream>>>(TAT,prw,prb,posS,gS,bS,SEb);
  k6_sqk<<<dim3(256),dim3(256),0,stream>>>(SEb,Wpack,SQb,SKb);
  k7_spatial<<<dim3(768),dim3(256),0,stream>>>(SQb,SKb,mcT,x,rhsT);
  k9_final<<<dim3(2048),dim3(256),0,stream>>>(rhsT,theta,Apack,fcwB,g3b,g5b,g7b,
                                              fcb,rw,rb,gln,bln,x,outp);
}

// Round 10
// 174.150 us; speedup vs baseline: 8.6329x; 1.1894x over previous
//
#include <hip/hip_runtime.h>
#include <hip/hip_fp16.h>

#define EPS 1e-5f

typedef float f32x4 __attribute__((ext_vector_type(4)));
typedef short bf16x8 __attribute__((ext_vector_type(8)));
typedef short bf16x4 __attribute__((ext_vector_type(4)));

__device__ __forceinline__ unsigned short f2b(float f){
  unsigned u=__float_as_uint(f);
  return (unsigned short)((u + 0x7fffu + ((u>>16)&1u))>>16);
}
__device__ __forceinline__ float b2f(unsigned short h){
  return __uint_as_float(((unsigned)h)<<16);
}

// ---------------- helpers ----------------
__device__ __forceinline__ float blockSum256(float v, float* red){
  #pragma unroll
  for(int o=32;o>0;o>>=1) v += __shfl_down(v,o,64);
  int wid = threadIdx.x>>6;
  if((threadIdx.x&63)==0) red[wid]=v;
  __syncthreads();
  if(threadIdx.x==0) red[0]=red[0]+red[1]+red[2]+red[3];
  __syncthreads();
  float r = red[0];
  __syncthreads();
  return r;
}

// ---------------- KB0: pack mask/cheb TRANSPOSED: mcT[k][m][n] ----------------
__global__ __launch_bounds__(256) void kb0_prep(const float* __restrict__ adj, const float* __restrict__ cmask,
    const float* __restrict__ cheb, unsigned* __restrict__ mcT){
  int blk=blockIdx.x;                 // k*256 + tn*16 + tm
  int k=blk>>8; int rem=blk&255; int tn=rem>>4, tm=rem&15;
  int tid=threadIdx.x;
  __shared__ unsigned tile[64][65];
  const float* chk = cheb + k*1048576;
  const float* cmk = cmask + k*1048576;
  for(int i=tid;i<4096;i+=256){
    int ln=i>>6, lm=i&63;
    int n=tn*64+ln, m=tm*64+lm;
    int nm=n*1024+m;
    tile[ln][lm] = (((unsigned)f2b(chk[nm]))<<16) | (unsigned)f2b(adj[nm]*cmk[nm]);
  }
  __syncthreads();
  unsigned* dst = mcT + k*1048576;
  for(int i=tid;i<4096;i+=256){
    int lm=i>>6, ln=i&63;
    dst[(tm*64+lm)*1024 + tn*64+ln] = tile[ln][lm];
  }
}

// ---------------- KPREP: fused weight packing (Apack | Wpack | Wpack2 | fcwB) ----------------
__global__ __launch_bounds__(256) void kprep(const float* __restrict__ g3w, const float* __restrict__ g5w,
    const float* __restrict__ g7w, const float* __restrict__ swq, const float* __restrict__ swk,
    const float* __restrict__ wq, const float* __restrict__ wk, const float* __restrict__ wv,
    const float* __restrict__ fcw,
    unsigned short* __restrict__ Apack, unsigned short* __restrict__ Wpack,
    unsigned short* __restrict__ Wpack2, unsigned short* __restrict__ fcwB){
  int idx = blockIdx.x*256+threadIdx.x;
  if(idx<15360){                                   // Apack (conv A-frags)
    int frag=idx>>6, lane=idx&63;
    int rt, s, kappa; const float* W;
    if(frag<48){ rt=frag/6; s=frag-rt*6; kappa=3; W=g3w; }
    else if(frag<128){ int f=frag-48; rt=f/10; s=f-rt*10; kappa=5; W=g5w; }
    else { int f=frag-128; rt=f/14; s=f-rt*14; kappa=7; W=g7w; }
    int c = rt*16 + (lane&15);
    int dt = s>>1, ic0=(s&1)*32 + (lane>>4)*8;
    #pragma unroll
    for(int j=0;j<8;j++) Apack[idx*8+j]=f2b(W[(c*64+ic0+j)*kappa + dt]);
  } else if(idx<27648){                            // Wpack (swq/swk B-frags)
    int id2=idx-15360;
    int frag=id2>>6, lane=id2&63;
    int ct=frag>>4, ks=frag&15;
    const float* W = (ct<6)? swq : swk;
    int c = ((ct<6)? ct : ct-6)*16 + (lane&15);
    int k0 = ks*32 + (lane>>4)*8;
    #pragma unroll
    for(int j=0;j<8;j++) Wpack[id2*8+j]=f2b(W[(k0+j)*96 + c]);
  } else if(idx<64512){                            // Wpack2 (wq|wk|wv B-frags)
    int id2=idx-27648;
    int frag=id2>>6, lane=id2&63;
    int ct=frag>>5, ks=frag&31;
    int cg = ct*16 + (lane&15);
    const float* W; int c;
    if(cg<96){ W=wq; c=cg; } else if(cg<192){ W=wk; c=cg-96; } else { W=wv; c=cg-192; }
    int k0 = ks*32 + (lane>>4)*8;
    #pragma unroll
    for(int j=0;j<8;j++) Wpack2[id2*8+j]=f2b(W[(k0+j)*96 + c]);
  } else if(idx<64576){                            // fcwB
    int lane=idx-64512;
    int t=lane&15, hq=lane>>4;
    #pragma unroll
    for(int j=0;j<8;j++){
      int tau=hq*8+j;
      fcwB[lane*8+j] = (tau<24 && t<12) ? f2b(fcw[tau*12+t]) : (unsigned short)0;
    }
  }
}

// ---------------- K1: EmbedT (fp32 + bf16 outputs) ----------------
__global__ __launch_bounds__(256) void k1_embedT(const float* __restrict__ x, const float* __restrict__ posT,
    const float* __restrict__ gT, const float* __restrict__ bT, float* __restrict__ TEmx,
    unsigned short* __restrict__ TEb){
  int bt=blockIdx.x; int b=bt/12, t=bt-b*12;
  int tid=threadIdx.x;
  __shared__ float red[4];
  float v[4]; float s=0.f;
  #pragma unroll
  for(int i=0;i<4;i++){ int n=tid+i*256; v[i]=x[(b*1024+n)*12+t]+posT[t*1024+n]; s+=v[i]; }
  s = blockSum256(s, red);
  float mu = s*(1.f/1024.f);
  float q=0.f;
  #pragma unroll
  for(int i=0;i<4;i++){ float d=v[i]-mu; q+=d*d; }
  q = blockSum256(q, red);
  float rstd = rsqrtf(q*(1.f/1024.f)+EPS);
  #pragma unroll
  for(int i=0;i<4;i++){
    int n=tid+i*256;
    float val=(v[i]-mu)*rstd*gT[n]+bT[n];
    TEmx[bt*1024+n]=val;
    TEb[bt*1024+n]=f2b(val);
  }
}

// ---------------- K2: QKV via MFMA split-K GEMM ----------------
__global__ __launch_bounds__(256) void k2_qkv(const unsigned short* __restrict__ TEb,
    const unsigned short* __restrict__ Wpack2, float* __restrict__ qkv){
  int tid=threadIdx.x; int w=tid>>6, lane=tid&63;
  const int hi=lane>>4, lo=lane&15;
  const int rt=blockIdx.x/18, ct=blockIdx.x-rt*18;
  __shared__ float red[4][16][16];
  f32x4 acc={0.f,0.f,0.f,0.f};
  #pragma unroll
  for(int s=0;s<8;s++){
    int ks=w*8+s;
    bf16x8 af = *(const bf16x8*)&TEb[(rt*16+lo)*1024 + ks*32 + hi*8];
    bf16x8 bf = *(const bf16x8*)&Wpack2[((ct*32+ks)<<9) + lane*8];
    acc = __builtin_amdgcn_mfma_f32_16x16x32_bf16(af, bf, acc, 0,0,0);
  }
  #pragma unroll
  for(int r=0;r<4;r++) red[w][hi*4+r][lo]=acc[r];
  __syncthreads();
  int r16=tid>>4, c16=tid&15;
  float s = red[0][r16][c16]+red[1][r16][c16]+red[2][r16][c16]+red[3][r16][c16];
  qkv[(rt*16+r16)*288 + ct*16 + c16] = s;
}

// ---------------- K3: temporal attn ----------------
__global__ __launch_bounds__(512) void k3_attn(const float* __restrict__ qkv, const float* __restrict__ res_att,
    float* __restrict__ scores_out, float* __restrict__ ctx){
  int b=blockIdx.x; int tid=threadIdx.x;
  __shared__ float sS[432];
  __shared__ float sA[432];
  if(tid<432){
    int h=tid/144; int r=tid-h*144; int q=r/12; int k2=r-q*12;
    const float* Qr=&qkv[(b*12+q)*288 + h*32];
    const float* Kr=&qkv[(b*12+k2)*288 + 96 + h*32];
    float acc=0.f;
    #pragma unroll
    for(int d=0;d<32;d++) acc+=Qr[d]*Kr[d];
    acc = acc*0.17677669529663687f + res_att[(b*3+h)*144 + q*12 + k2];
    sS[h*144+q*12+k2]=acc;
    scores_out[(b*3+h)*144 + q*12 + k2]=acc;
  }
  __syncthreads();
  if(tid<36){
    int h=tid/12, k2=tid-(tid/12)*12;
    float mx=-1e30f;
    for(int q=0;q<12;q++) mx=fmaxf(mx,sS[h*144+q*12+k2]);
    float sum=0.f;
    for(int q=0;q<12;q++){ float e=__expf(sS[h*144+q*12+k2]-mx); sA[h*144+q*12+k2]=e; sum+=e; }
    float inv=1.f/sum;
    for(int q=0;q<12;q++) sA[h*144+q*12+k2]*=inv;
  }
  __syncthreads();
  for(int o=tid;o<1152;o+=512){
    int h=o/384; int r=o-h*384; int q=r/32; int d=r-q*32;
    float acc=0.f;
    #pragma unroll
    for(int k2=0;k2<12;k2++) acc += sA[h*144+q*12+k2]*qkv[(b*12+k2)*288+192+h*32+d];
    ctx[(b*12+q)*96 + h*32 + d]=acc;
  }
}

// ---------------- K4 v2: TATout, 4 interleaved accumulator chains ----------------
__global__ __launch_bounds__(256) void k4_tat(const float* __restrict__ ctx, const float* __restrict__ fcW,
    const float* __restrict__ TEmx, float* __restrict__ TAT){
  int bt=blockIdx.x; int tid=threadIdx.x;
  __shared__ float c96[96];
  __shared__ float red[4];
  if(tid<96) c96[tid]=ctx[bt*96+tid];
  __syncthreads();
  int n0=tid, n1=tid+256, n2=tid+512, n3=tid+768;
  const float* te=&TEmx[bt*1024];
  float a0=te[n0], a1=te[n1], a2=te[n2], a3=te[n3];
  #pragma unroll 8
  for(int j=0;j<96;j++){
    float cj=c96[j];
    const float* wr=&fcW[j*1024];
    a0+=cj*wr[n0]; a1+=cj*wr[n1]; a2+=cj*wr[n2]; a3+=cj*wr[n3];
  }
  float s=a0+a1+a2+a3;
  s=blockSum256(s,red);
  float mu=s*(1.f/1024.f);
  float q=(a0-mu)*(a0-mu)+(a1-mu)*(a1-mu)+(a2-mu)*(a2-mu)+(a3-mu)*(a3-mu);
  q=blockSum256(q,red);
  float rstd=rsqrtf(q*(1.f/1024.f)+EPS);
  float* dst=&TAT[bt*1024];
  dst[n0]=(a0-mu)*rstd; dst[n1]=(a1-mu)*rstd; dst[n2]=(a2-mu)*rstd; dst[n3]=(a3-mu)*rstd;
}

// ---------------- K5: SEmx, 8 rows/block; pre_w in regs ----------------
__global__ __launch_bounds__(256) void k5_semx(const float* __restrict__ TAT, const float* __restrict__ pre_w,
    const float* __restrict__ pre_b, const float* __restrict__ posS, const float* __restrict__ gS,
    const float* __restrict__ bS, unsigned short* __restrict__ SEb){
  int bn0=blockIdx.x*8; int b=bn0>>10, n0=bn0&1023; int tid=threadIdx.x;
  __shared__ float tv[12][8];
  __shared__ float ps[8][264];
  __shared__ float pq[8][264];
  __shared__ float mur[8], rsr[8];
  if(tid<96){ int r=tid&7, t=tid>>3; tv[t][r]=TAT[(b*12+t)*1024+n0+r]; }
  __syncthreads();
  const int d0=tid, d1=tid+256;
  float w0[12], w1[12];
  {
    const float4* p0=(const float4*)&pre_w[d0*12];
    float4 a=p0[0], bb=p0[1], c=p0[2];
    w0[0]=a.x;w0[1]=a.y;w0[2]=a.z;w0[3]=a.w; w0[4]=bb.x;w0[5]=bb.y;w0[6]=bb.z;w0[7]=bb.w;
    w0[8]=c.x;w0[9]=c.y;w0[10]=c.z;w0[11]=c.w;
    const float4* p1=(const float4*)&pre_w[d1*12];
    float4 d=p1[0], e=p1[1], f=p1[2];
    w1[0]=d.x;w1[1]=d.y;w1[2]=d.z;w1[3]=d.w; w1[4]=e.x;w1[5]=e.y;w1[6]=e.z;w1[7]=e.w;
    w1[8]=f.x;w1[9]=f.y;w1[10]=f.z;w1[11]=f.w;
  }
  float pb0=pre_b[d0], pb1=pre_b[d1];
  float v0[8], v1[8];
  #pragma unroll
  for(int r=0;r<8;r++){
    float acc0=pb0 + posS[(n0+r)*512+d0];
    float acc1=pb1 + posS[(n0+r)*512+d1];
    #pragma unroll
    for(int t=0;t<12;t++){ float tvv=tv[t][r]; acc0+=tvv*w0[t]; acc1+=tvv*w1[t]; }
    v0[r]=acc0; v1[r]=acc1;
    ps[r][tid]=acc0+acc1;
    pq[r][tid]=acc0*acc0+acc1*acc1;
  }
  __syncthreads();
  {
    int row=tid>>5, l32=tid&31;
    float s=0.f, q=0.f;
    #pragma unroll
    for(int j=0;j<8;j++){ s+=ps[row][l32+j*32]; q+=pq[row][l32+j*32]; }
    #pragma unroll
    for(int o=16;o>=1;o>>=1){ s+=__shfl_xor(s,o,64); q+=__shfl_xor(q,o,64); }
    if(l32==0){
      float mu=s*(1.f/512.f);
      float var=q*(1.f/512.f)-mu*mu;
      mur[row]=mu; rsr[row]=rsqrtf(var+EPS);
    }
  }
  __syncthreads();
  float g0=gS[d0], b0v=bS[d0], g1=gS[d1], b1v=bS[d1];
  #pragma unroll
  for(int r=0;r<8;r++){
    float mu=mur[r], rs=rsr[r];
    SEb[(bn0+r)*512 + d0] = f2b((v0[r]-mu)*rs*g0+b0v);
    SEb[(bn0+r)*512 + d1] = f2b((v1[r]-mu)*rs*g1+b1v);
  }
}

// ---------------- K6: SQ/SK via MFMA GEMM ----------------
__global__ __launch_bounds__(256) void k6_sqk(const unsigned short* __restrict__ SEb,
    const unsigned short* __restrict__ Wpack,
    unsigned short* __restrict__ SQb, unsigned short* __restrict__ SKb){
  int tid=threadIdx.x; int w=tid>>6, lane=tid&63;
  const int hi=lane>>4, lo=lane&15;
  const int row0 = blockIdx.x*64 + w*16;
  f32x4 acc[12];
  #pragma unroll
  for(int i=0;i<12;i++){ acc[i][0]=0.f; acc[i][1]=0.f; acc[i][2]=0.f; acc[i][3]=0.f; }
  for(int ks=0;ks<16;ks++){
    bf16x8 af = *(const bf16x8*)&SEb[(row0+lo)*512 + ks*32 + hi*8];
    #pragma unroll
    for(int ct=0;ct<12;ct++){
      bf16x8 bf = *(const bf16x8*)&Wpack[((ct*16+ks)<<9) + lane*8];
      acc[ct] = __builtin_amdgcn_mfma_f32_16x16x32_bf16(af, bf, acc[ct], 0,0,0);
    }
  }
  #pragma unroll
  for(int ct=0;ct<12;ct++){
    int c96 = ((ct<6)? ct : ct-6)*16 + lo;
    int kq = c96>>5, d = c96&31;
    unsigned short* dst = (ct<6)? SQb : SKb;
    #pragma unroll
    for(int r=0;r<4;r++){
      int n = row0 + hi*4 + r;
      int b = n>>10, nl = n&1023;
      dst[((b*3+kq)*1024+nl)*32 + d] = f2b(acc[ct][r]);
    }
  }
}

// ---------------- K7 v3: whole-x LDS stage, barrier-free chunk loop ----------------
#define SCALE7 0.17677669529663687f
__global__ __launch_bounds__(256) void k7_spatial(const unsigned short* __restrict__ SQb,
    const unsigned short* __restrict__ SKb, const unsigned* __restrict__ mcT,
    const float* __restrict__ x, float* __restrict__ rhsT){
  const int blk0=blockIdx.x;
  const int blk=(blk0&7)*96 + (blk0>>3);      // XCD-chunked: 768 = 8*96, bijective
  const int mt=blk&15, bk=blk>>4;
  const int k=bk%3, b=bk/3;
  const int m0=mt*64;
  const int tid=threadIdx.x;
  const int w=tid>>6, lane=tid&63, g=lane>>4, col=lane&15;

  __shared__ unsigned short xs[16*1024];      // x^T for all n, rows t=0..11 (+4 zero rows), swizzled

  const float* xb = x + b*12288;
  // zero rows t=12..15 (u32 granularity, contiguous region)
  for(int i=tid;i<2048;i+=256) ((unsigned*)xs)[12*512 + i] = 0u;
  // stage all of x_b (coalesced read over i = n*12+t)
  for(int i=tid;i<12288;i+=256){
    int n=i/12, t=i-n*12;
    xs[t*1024 + (n ^ ((t&7)<<3))] = f2b(xb[i]);
  }
  __syncthreads();                            // the ONLY barrier

  const int m_glob = m0 + w*16 + col;
  bf16x8 bfrag = *(const bf16x8*)&SKb[((bk<<10)+m_glob)*32 + g*8];

  f32x4 O = {0.f,0.f,0.f,0.f};
  float mrun=-1e30f, lrun=0.f;

  const unsigned* mrow = mcT + k*1048576 + m_glob*1024;
  const int swz = (col&7)<<3;

  for(int ch=0; ch<8; ++ch){
    const int n0 = ch<<7;

    f32x4 acc[8];
    #pragma unroll
    for(int nt=0;nt<8;nt++){
      bf16x8 afrag = *(const bf16x8*)&SQb[((bk<<10) + n0 + nt*16 + col)*32 + g*8];
      f32x4 z = {0.f,0.f,0.f,0.f};
      acc[nt] = __builtin_amdgcn_mfma_f32_16x16x32_bf16(afrag, bfrag, z, 0,0,0);
    }
    unsigned mcv[8][4];
    #pragma unroll
    for(int nt=0;nt<8;nt++){
      uint4 mv = *(const uint4*)&mrow[n0 + nt*16 + g*4];
      mcv[nt][0]=mv.x; mcv[nt][1]=mv.y; mcv[nt][2]=mv.z; mcv[nt][3]=mv.w;
    }
    float cmax = -1e30f;
    #pragma unroll
    for(int nt=0;nt<8;nt++){
      #pragma unroll
      for(int r=0;r<4;r++){
        float s = acc[nt][r]*SCALE7 + __uint_as_float(mcv[nt][r]<<16);
        acc[nt][r]=s;
        cmax=fmaxf(cmax,s);
      }
    }
    cmax = fmaxf(cmax, __shfl_xor(cmax,16,64));
    cmax = fmaxf(cmax, __shfl_xor(cmax,32,64));
    float mnew = fmaxf(mrun, cmax);
    float alpha = __expf(mrun - mnew);
    float lsum = 0.f;
    unsigned short pb[8][4];
    #pragma unroll
    for(int nt=0;nt<8;nt++){
      #pragma unroll
      for(int r=0;r<4;r++){
        float e = __expf(acc[nt][r] - mnew);
        lsum += e;
        pb[nt][r] = f2b(e * __uint_as_float(mcv[nt][r] & 0xffff0000u));
      }
    }
    lsum += __shfl_xor(lsum,16,64);
    lsum += __shfl_xor(lsum,32,64);
    lrun = lrun*alpha + lsum;
    mrun = mnew;
    O[0]*=alpha; O[1]*=alpha; O[2]*=alpha; O[3]*=alpha;

    #pragma unroll
    for(int c=0;c<4;c++){
      bf16x8 pf;
      #pragma unroll
      for(int j=0;j<4;j++){ pf[j]=(short)pb[2*c][j]; pf[j+4]=(short)pb[2*c+1][j]; }
      int nlo = n0 + c*32 + g*4;
      bf16x4 lo = *(const bf16x4*)&xs[col*1024 + (nlo ^ swz)];
      bf16x4 hi = *(const bf16x4*)&xs[col*1024 + ((nlo+16) ^ swz)];
      bf16x8 ax;
      #pragma unroll
      for(int j=0;j<4;j++){ ax[j]=lo[j]; ax[j+4]=hi[j]; }
      O = __builtin_amdgcn_mfma_f32_16x16x32_bf16(ax, pf, O, 0,0,0);
    }
  }
  float inv = 1.f/lrun;
  #pragma unroll
  for(int r=0;r<4;r++){
    int t = g*4+r;
    if(t<12) rhsT[((bk*12+t)<<10) + m_glob] = O[r]*inv;
  }
}

// ---------------- K9: conv MFMA -> gated bf16 LDS tile -> fc via MFMA -> residual+LN ----
__global__ __launch_bounds__(256) void k9_final(const float* __restrict__ rhsT, const float* __restrict__ theta,
    const unsigned short* __restrict__ Apack, const unsigned short* __restrict__ fcwB,
    const float* __restrict__ g3b, const float* __restrict__ g5b, const float* __restrict__ g7b,
    const float* __restrict__ fcb,
    const float* __restrict__ rw, const float* __restrict__ rb,
    const float* __restrict__ gln, const float* __restrict__ bln,
    const float* __restrict__ x, float* __restrict__ out){
  int bn0=blockIdx.x*8;
  int tid=threadIdx.x;
  const int b=bn0>>10, n0=bn0&1023;

  __shared__ struct { unsigned short Xl[12*8*64]; float rstage[3][12][8]; } P0;
  __shared__ union {
    unsigned short Gl[4*16*8*24];   // [wave][c_loc][g'][tau]
    float XP[8][772];
  } U;
  __shared__ float xres[8][12];
  __shared__ float mu8[8][12], rs8[8][12];

  for(int i=tid;i<288;i+=256){
    int kk=i/96; int rem=i-kk*96; int t=rem>>3; int g=rem&7;
    P0.rstage[kk][t][g]=rhsT[((b*3+kk)*12+t)*1024 + n0 + g];
  }
  for(int i=tid;i<96;i+=256){ int g=i/12, t=i-(i/12)*12; xres[g][t]=x[(bn0+g)*12+t]; }
  __syncthreads();

  {
    int g=tid>>5, icp=tid&31;
    float th0[3], th1[3];
    #pragma unroll
    for(int kk=0;kk<3;kk++){ th0[kk]=theta[kk*64+2*icp]; th1[kk]=theta[kk*64+2*icp+1]; }
    #pragma unroll
    for(int t=0;t<12;t++){
      float r0=P0.rstage[0][t][g], r1=P0.rstage[1][t][g], r2=P0.rstage[2][t][g];
      float a0=fmaxf(r0*th0[0]+r1*th0[1]+r2*th0[2],0.f);
      float a1=fmaxf(r0*th1[0]+r1*th1[1]+r2*th1[2],0.f);
      unsigned pack = (((unsigned)f2b(a1))<<16)|(unsigned)f2b(a0);
      *(unsigned*)((char*)P0.Xl + ((t*8+g)<<7) + ((icp*4) ^ (g<<4))) = pack;
    }
  }
  __syncthreads();

  const int w=tid>>6, lane=tid&63, halfk=lane>>4, colq=lane&15;
  const int gg=colq&7, tau2=colq>>3;
  const int ca = w*16 + halfk*4;
  const char* xlb = (const char*)P0.Xl;
  unsigned short* Glw = &U.Gl[w*3072];

  #define GATE_STORE(ACCA, ACCB, TB) { \
    _Pragma("unroll") \
    for(int r=0;r<4;r++){ \
      float ya=(ACCA)[r], yb=(ACCB)[r]; \
      float e2=__expf(2.f*ya), eb=__expf(yb); \
      float gval=(e2-1.f)*eb*__frcp_rn((e2+1.f)*(eb+1.f)); \
      int c_loc=halfk*4+r; \
      Glw[c_loc*192 + ((gg ^ (c_loc&7))*24) + (TB)+tau2] = f2b(gval); \
    } }

  // ---- group kappa=3 ----
  {
    f32x4 acA[5], acB[5];
    #pragma unroll
    for(int j=0;j<5;j++)
      #pragma unroll
      for(int r=0;r<4;r++){ acA[j][r]=g3b[ca+r]; acB[j][r]=g3b[64+ca+r]; }
    #pragma unroll
    for(int s=0;s<6;s++){
      bf16x8 a0 = *(const bf16x8*)&Apack[((w  )*6 + s)*512 + lane*8];
      bf16x8 a1 = *(const bf16x8*)&Apack[((w+4)*6 + s)*512 + lane*8];
      int dt=s>>1;
      int sl = ((((s&1)*32 + halfk*8)*2) ^ (gg<<4));
      #pragma unroll
      for(int j=0;j<5;j++){
        int t=2*j+tau2+dt;
        bf16x8 bf = *(const bf16x8*)(xlb + ((t*8+gg)<<7) + sl);
        acA[j] = __builtin_amdgcn_mfma_f32_16x16x32_bf16(a0, bf, acA[j], 0,0,0);
        acB[j] = __builtin_amdgcn_mfma_f32_16x16x32_bf16(a1, bf, acB[j], 0,0,0);
      }
    }
    #pragma unroll
    for(int j=0;j<5;j++) GATE_STORE(acA[j], acB[j], 2*j)
  }
  // ---- group kappa=5 ----
  {
    f32x4 acA[4], acB[4];
    #pragma unroll
    for(int j=0;j<4;j++)
      #pragma unroll
      for(int r=0;r<4;r++){ acA[j][r]=g5b[ca+r]; acB[j][r]=g5b[64+ca+r]; }
    #pragma unroll
    for(int s=0;s<10;s++){
      bf16x8 a0 = *(const bf16x8*)&Apack[(48 + (w  )*10 + s)*512 + lane*8];
      bf16x8 a1 = *(const bf16x8*)&Apack[(48 + (w+4)*10 + s)*512 + lane*8];
      int dt=s>>1;
      int sl = ((((s&1)*32 + halfk*8)*2) ^ (gg<<4));
      #pragma unroll
      for(int j=0;j<4;j++){
        int t=2*j+tau2+dt;
        bf16x8 bf = *(const bf16x8*)(xlb + ((t*8+gg)<<7) + sl);
        acA[j] = __builtin_amdgcn_mfma_f32_16x16x32_bf16(a0, bf, acA[j], 0,0,0);
        acB[j] = __builtin_amdgcn_mfma_f32_16x16x32_bf16(a1, bf, acB[j], 0,0,0);
      }
    }
    #pragma unroll
    for(int j=0;j<4;j++) GATE_STORE(acA[j], acB[j], 10+2*j)
  }
  // ---- group kappa=7 ----
  {
    f32x4 acA[3], acB[3];
    #pragma unroll
    for(int j=0;j<3;j++)
      #pragma unroll
      for(int r=0;r<4;r++){ acA[j][r]=g7b[ca+r]; acB[j][r]=g7b[64+ca+r]; }
    #pragma unroll
    for(int s=0;s<14;s++){
      bf16x8 a0 = *(const bf16x8*)&Apack[(128 + (w  )*14 + s)*512 + lane*8];
      bf16x8 a1 = *(const bf16x8*)&Apack[(128 + (w+4)*14 + s)*512 + lane*8];
      int dt=s>>1;
      int sl = ((((s&1)*32 + halfk*8)*2) ^ (gg<<4));
      #pragma unroll
      for(int j=0;j<3;j++){
        int t=2*j+tau2+dt;
        bf16x8 bf = *(const bf16x8*)(xlb + ((t*8+gg)<<7) + sl);
        acA[j] = __builtin_amdgcn_mfma_f32_16x16x32_bf16(a0, bf, acA[j], 0,0,0);
        acB[j] = __builtin_amdgcn_mfma_f32_16x16x32_bf16(a1, bf, acB[j], 0,0,0);
      }
    }
    #pragma unroll
    for(int j=0;j<3;j++) GATE_STORE(acA[j], acB[j], 18+2*j)
  }
  #undef GATE_STORE

  // ---- fc via MFMA ----
  const int tcol = lane&15, hq = lane>>4;
  const int hm = (hq==3)? 0 : hq;
  bf16x8 b2 = *(const bf16x8*)&fcwB[lane*8];
  float fcbv = (tcol<12)? fcb[tcol] : 0.f;
  f32x4 d2[8];
  #pragma unroll
  for(int g=0; g<8; g++){
    bf16x8 a2 = *(const bf16x8*)&Glw[tcol*192 + ((g ^ (tcol&7))*24) + hm*8];
    f32x4 ini = {fcbv, fcbv, fcbv, fcbv};
    d2[g] = __builtin_amdgcn_mfma_f32_16x16x32_bf16(a2, b2, ini, 0,0,0);
  }
  __syncthreads();

  if(tcol<12){
    float rwa[4], rba[4];
    #pragma unroll
    for(int r=0;r<4;r++){ int c=w*16+hq*4+r; rwa[r]=rw[c]; rba[r]=rb[c]; }
    #pragma unroll
    for(int g=0; g<8; g++){
      float xv=xres[g][tcol];
      #pragma unroll
      for(int r=0;r<4;r++){
        int c=w*16+hq*4+r;
        float tv = fmaxf(d2[g][r], 0.f);
        float xr = xv*rwa[r]+rba[r];
        U.XP[g][c*12+tcol] = fmaxf(xr+tv, 0.f);
      }
    }
  }
  __syncthreads();

  if(tid<192){
    int p=tid>>1, h=tid&1;
    int g=p/12, t=p-(p/12)*12;
    float s=0.f;
    for(int c=h*32;c<h*32+32;c++) s+=U.XP[g][c*12+t];
    s += __shfl_xor(s,1,64);
    float mu=s*(1.f/64.f);
    float q=0.f;
    for(int c=h*32;c<h*32+32;c++){float d=U.XP[g][c*12+t]-mu;q+=d*d;}
    q += __shfl_xor(q,1,64);
    if(h==0){ mu8[g][t]=mu; rs8[g][t]=rsqrtf(q*(1.f/64.f)+EPS); }
  }
  __syncthreads();
  for(int o=tid;o<1536;o+=256){
    int g=o/192; int q4=o-g*192;
    int c=q4/3; int tb=(q4-c*3)*4;
    float4 vv = *(const float4*)&U.XP[g][c*12+tb];
    float gl=gln[c], bl=bln[c];
    float4 ov;
    ov.x=(vv.x-mu8[g][tb+0])*rs8[g][tb+0]*gl+bl;
    ov.y=(vv.y-mu8[g][tb+1])*rs8[g][tb+1]*gl+bl;
    ov.z=(vv.z-mu8[g][tb+2])*rs8[g][tb+2]*gl+bl;
    ov.w=(vv.w-mu8[g][tb+3])*rs8[g][tb+3]*gl+bl;
    *(float4*)&out[(long)(bn0+g)*768 + c*12 + tb] = ov;
  }
}

// ---------------- launch ----------------
extern "C" void kernel_launch(void* const* d_in, const int* in_sizes, int n_in,
                              void* d_out, int out_size, void* d_ws, size_t ws_size,
                              hipStream_t stream){
  const float* x    =(const float*)d_in[0];
  const float* res  =(const float*)d_in[1];
  const float* posT =(const float*)d_in[2];
  const float* gT   =(const float*)d_in[3];
  const float* bT   =(const float*)d_in[4];
  const float* wq   =(const float*)d_in[5];
  const float* wk   =(const float*)d_in[6];
  const float* wv   =(const float*)d_in[7];
  const float* fcW  =(const float*)d_in[8];
  const float* prw  =(const float*)d_in[9];
  const float* prb  =(const float*)d_in[10];
  const float* posS =(const float*)d_in[11];
  const float* gS   =(const float*)d_in[12];
  const float* bS   =(const float*)d_in[13];
  const float* swq  =(const float*)d_in[14];
  const float* swk  =(const float*)d_in[15];
  const float* cheb =(const float*)d_in[16];
  const float* adj  =(const float*)d_in[17];
  const float* cmask=(const float*)d_in[18];
  const float* theta=(const float*)d_in[19];
  const float* g3w=(const float*)d_in[20]; const float* g3b=(const float*)d_in[21];
  const float* g5w=(const float*)d_in[22]; const float* g5b=(const float*)d_in[23];
  const float* g7w=(const float*)d_in[24]; const float* g7b=(const float*)d_in[25];
  const float* fcw=(const float*)d_in[26]; const float* fcb=(const float*)d_in[27];
  const float* rw =(const float*)d_in[28]; const float* rb =(const float*)d_in[29];
  const float* gln=(const float*)d_in[30]; const float* bln=(const float*)d_in[31];

  float* outp=(float*)d_out;
  float* scores = outp + 12582912;

  float* wsf=(float*)d_ws;
  float* TEmx = wsf;                          // 196608 f
  float* qkv  = TEmx + 196608;                // 55296 f
  float* ctx  = qkv + 55296;                  // 18432 f
  float* TAT  = ctx + 18432;                  // 196608 f
  unsigned short* SEb = (unsigned short*)(TAT + 196608);          // 4194304 f
  unsigned short* SQb = (unsigned short*)((float*)SEb + 4194304); // 786432 f
  unsigned short* SKb = (unsigned short*)((float*)SQb + 786432);  // 786432 f
  unsigned* mcT = (unsigned*)((float*)SKb + 786432);              // 3145728 f
  float* rhsT  = (float*)mcT + 3145728;                           // 589824 f
  unsigned short* Apack = (unsigned short*)(rhsT + 589824);       // 122880 u16
  unsigned short* Wpack = Apack + 122880;                         // 98304 u16
  unsigned short* Wpack2 = Wpack + 98304;                         // 294912 u16
  unsigned short* TEb = Wpack2 + 294912;                          // 196608 u16
  unsigned short* fcwB = TEb + 196608;                            // 512 u16

  kb0_prep<<<dim3(768),dim3(256),0,stream>>>(adj,cmask,cheb,mcT);
  kprep<<<dim3(253),dim3(256),0,stream>>>(g3w,g5w,g7w,swq,swk,wq,wk,wv,fcw,
                                          Apack,Wpack,Wpack2,fcwB);
  k1_embedT<<<dim3(192),dim3(256),0,stream>>>(x,posT,gT,bT,TEmx,TEb);
  k2_qkv<<<dim3(216),dim3(256),0,stream>>>(TEb,Wpack2,qkv);
  k3_attn<<<dim3(16),dim3(512),0,stream>>>(qkv,res,scores,ctx);
  k4_tat<<<dim3(192),dim3(256),0,stream>>>(ctx,fcW,TEmx,TAT);
  k5_semx<<<dim3(2048),dim3(256),0,stream>>>(TAT,prw,prb,posS,gS,bS,SEb);
  k6_sqk<<<dim3(256),dim3(256),0,stream>>>(SEb,Wpack,SQb,SKb);
  k7_spatial<<<dim3(768),dim3(256),0,stream>>>(SQb,SKb,mcT,x,rhsT);
  k9_final<<<dim3(2048),dim3(256),0,stream>>>(rhsT,theta,Apack,fcwB,g3b,g5b,g7b,
                                              fcb,rw,rb,gln,bln,x,outp);
}

// Round 11
// 173.170 us; speedup vs baseline: 8.6818x; 1.0057x over previous
//
#include <hip/hip_runtime.h>
#include <hip/hip_fp16.h>

#define EPS 1e-5f

typedef float f32x4 __attribute__((ext_vector_type(4)));
typedef short bf16x8 __attribute__((ext_vector_type(8)));
typedef short bf16x4 __attribute__((ext_vector_type(4)));
typedef _Float16 f16x8 __attribute__((ext_vector_type(8)));

__device__ __forceinline__ unsigned short f2b(float f){
  unsigned u=__float_as_uint(f);
  return (unsigned short)((u + 0x7fffu + ((u>>16)&1u))>>16);
}
__device__ __forceinline__ float b2f(unsigned short h){
  return __uint_as_float(((unsigned)h)<<16);
}
__device__ __forceinline__ unsigned short f2h(float f){
  return __half_as_ushort(__float2half(f));
}

// ---------------- helpers ----------------
__device__ __forceinline__ float blockSum256(float v, float* red){
  #pragma unroll
  for(int o=32;o>0;o>>=1) v += __shfl_down(v,o,64);
  int wid = threadIdx.x>>6;
  if((threadIdx.x&63)==0) red[wid]=v;
  __syncthreads();
  if(threadIdx.x==0) red[0]=red[0]+red[1]+red[2]+red[3];
  __syncthreads();
  float r = red[0];
  __syncthreads();
  return r;
}

// ---------------- KB0: pack mask/cheb TRANSPOSED: mcT[k][m][n] ----------------
__global__ __launch_bounds__(256) void kb0_prep(const float* __restrict__ adj, const float* __restrict__ cmask,
    const float* __restrict__ cheb, unsigned* __restrict__ mcT){
  int blk=blockIdx.x;                 // k*256 + tn*16 + tm
  int k=blk>>8; int rem=blk&255; int tn=rem>>4, tm=rem&15;
  int tid=threadIdx.x;
  __shared__ unsigned tile[64][65];
  const float* chk = cheb + k*1048576;
  const float* cmk = cmask + k*1048576;
  for(int i=tid;i<4096;i+=256){
    int ln=i>>6, lm=i&63;
    int n=tn*64+ln, m=tm*64+lm;
    int nm=n*1024+m;
    tile[ln][lm] = (((unsigned)f2b(chk[nm]))<<16) | (unsigned)f2b(adj[nm]*cmk[nm]);
  }
  __syncthreads();
  unsigned* dst = mcT + k*1048576;
  for(int i=tid;i<4096;i+=256){
    int lm=i>>6, ln=i&63;
    dst[(tm*64+lm)*1024 + tn*64+ln] = tile[ln][lm];
  }
}

// ---------------- KPREP: fused weight packing (Apack fp16 | Wpack bf16 | Wpack2 bf16 | fcwB fp16) ----------------
__global__ __launch_bounds__(256) void kprep(const float* __restrict__ g3w, const float* __restrict__ g5w,
    const float* __restrict__ g7w, const float* __restrict__ swq, const float* __restrict__ swk,
    const float* __restrict__ wq, const float* __restrict__ wk, const float* __restrict__ wv,
    const float* __restrict__ fcw,
    unsigned short* __restrict__ Apack, unsigned short* __restrict__ Wpack,
    unsigned short* __restrict__ Wpack2, unsigned short* __restrict__ fcwB){
  int idx = blockIdx.x*256+threadIdx.x;
  if(idx<15360){                                   // Apack (conv A-frags, fp16)
    int frag=idx>>6, lane=idx&63;
    int rt, s, kappa; const float* W;
    if(frag<48){ rt=frag/6; s=frag-rt*6; kappa=3; W=g3w; }
    else if(frag<128){ int f=frag-48; rt=f/10; s=f-rt*10; kappa=5; W=g5w; }
    else { int f=frag-128; rt=f/14; s=f-rt*14; kappa=7; W=g7w; }
    int c = rt*16 + (lane&15);
    int dt = s>>1, ic0=(s&1)*32 + (lane>>4)*8;
    #pragma unroll
    for(int j=0;j<8;j++) Apack[idx*8+j]=f2h(W[(c*64+ic0+j)*kappa + dt]);
  } else if(idx<27648){                            // Wpack (swq/swk B-frags, bf16)
    int id2=idx-15360;
    int frag=id2>>6, lane=id2&63;
    int ct=frag>>4, ks=frag&15;
    const float* W = (ct<6)? swq : swk;
    int c = ((ct<6)? ct : ct-6)*16 + (lane&15);
    int k0 = ks*32 + (lane>>4)*8;
    #pragma unroll
    for(int j=0;j<8;j++) Wpack[id2*8+j]=f2b(W[(k0+j)*96 + c]);
  } else if(idx<64512){                            // Wpack2 (wq|wk|wv B-frags, bf16)
    int id2=idx-27648;
    int frag=id2>>6, lane=id2&63;
    int ct=frag>>5, ks=frag&31;
    int cg = ct*16 + (lane&15);
    const float* W; int c;
    if(cg<96){ W=wq; c=cg; } else if(cg<192){ W=wk; c=cg-96; } else { W=wv; c=cg-192; }
    int k0 = ks*32 + (lane>>4)*8;
    #pragma unroll
    for(int j=0;j<8;j++) Wpack2[id2*8+j]=f2b(W[(k0+j)*96 + c]);
  } else if(idx<64576){                            // fcwB (fp16)
    int lane=idx-64512;
    int t=lane&15, hq=lane>>4;
    #pragma unroll
    for(int j=0;j<8;j++){
      int tau=hq*8+j;
      fcwB[lane*8+j] = (tau<24 && t<12) ? f2h(fcw[tau*12+t]) : (unsigned short)0;
    }
  }
}

// ---------------- K1: EmbedT (fp32 + bf16 outputs) ----------------
__global__ __launch_bounds__(256) void k1_embedT(const float* __restrict__ x, const float* __restrict__ posT,
    const float* __restrict__ gT, const float* __restrict__ bT, float* __restrict__ TEmx,
    unsigned short* __restrict__ TEb){
  int bt=blockIdx.x; int b=bt/12, t=bt-b*12;
  int tid=threadIdx.x;
  __shared__ float red[4];
  float v[4]; float s=0.f;
  #pragma unroll
  for(int i=0;i<4;i++){ int n=tid+i*256; v[i]=x[(b*1024+n)*12+t]+posT[t*1024+n]; s+=v[i]; }
  s = blockSum256(s, red);
  float mu = s*(1.f/1024.f);
  float q=0.f;
  #pragma unroll
  for(int i=0;i<4;i++){ float d=v[i]-mu; q+=d*d; }
  q = blockSum256(q, red);
  float rstd = rsqrtf(q*(1.f/1024.f)+EPS);
  #pragma unroll
  for(int i=0;i<4;i++){
    int n=tid+i*256;
    float val=(v[i]-mu)*rstd*gT[n]+bT[n];
    TEmx[bt*1024+n]=val;
    TEb[bt*1024+n]=f2b(val);
  }
}

// ---------------- K2: QKV via MFMA split-K GEMM ----------------
__global__ __launch_bounds__(256) void k2_qkv(const unsigned short* __restrict__ TEb,
    const unsigned short* __restrict__ Wpack2, float* __restrict__ qkv){
  int tid=threadIdx.x; int w=tid>>6, lane=tid&63;
  const int hi=lane>>4, lo=lane&15;
  const int rt=blockIdx.x/18, ct=blockIdx.x-rt*18;
  __shared__ float red[4][16][16];
  f32x4 acc={0.f,0.f,0.f,0.f};
  #pragma unroll
  for(int s=0;s<8;s++){
    int ks=w*8+s;
    bf16x8 af = *(const bf16x8*)&TEb[(rt*16+lo)*1024 + ks*32 + hi*8];
    bf16x8 bf = *(const bf16x8*)&Wpack2[((ct*32+ks)<<9) + lane*8];
    acc = __builtin_amdgcn_mfma_f32_16x16x32_bf16(af, bf, acc, 0,0,0);
  }
  #pragma unroll
  for(int r=0;r<4;r++) red[w][hi*4+r][lo]=acc[r];
  __syncthreads();
  int r16=tid>>4, c16=tid&15;
  float s = red[0][r16][c16]+red[1][r16][c16]+red[2][r16][c16]+red[3][r16][c16];
  qkv[(rt*16+r16)*288 + ct*16 + c16] = s;
}

// ---------------- K3: temporal attn ----------------
__global__ __launch_bounds__(512) void k3_attn(const float* __restrict__ qkv, const float* __restrict__ res_att,
    float* __restrict__ scores_out, float* __restrict__ ctx){
  int b=blockIdx.x; int tid=threadIdx.x;
  __shared__ float sS[432];
  __shared__ float sA[432];
  if(tid<432){
    int h=tid/144; int r=tid-h*144; int q=r/12; int k2=r-q*12;
    const float* Qr=&qkv[(b*12+q)*288 + h*32];
    const float* Kr=&qkv[(b*12+k2)*288 + 96 + h*32];
    float acc=0.f;
    #pragma unroll
    for(int d=0;d<32;d++) acc+=Qr[d]*Kr[d];
    acc = acc*0.17677669529663687f + res_att[(b*3+h)*144 + q*12 + k2];
    sS[h*144+q*12+k2]=acc;
    scores_out[(b*3+h)*144 + q*12 + k2]=acc;
  }
  __syncthreads();
  if(tid<36){
    int h=tid/12, k2=tid-(tid/12)*12;
    float mx=-1e30f;
    for(int q=0;q<12;q++) mx=fmaxf(mx,sS[h*144+q*12+k2]);
    float sum=0.f;
    for(int q=0;q<12;q++){ float e=__expf(sS[h*144+q*12+k2]-mx); sA[h*144+q*12+k2]=e; sum+=e; }
    float inv=1.f/sum;
    for(int q=0;q<12;q++) sA[h*144+q*12+k2]*=inv;
  }
  __syncthreads();
  for(int o=tid;o<1152;o+=512){
    int h=o/384; int r=o-h*384; int q=r/32; int d=r-q*32;
    float acc=0.f;
    #pragma unroll
    for(int k2=0;k2<12;k2++) acc += sA[h*144+q*12+k2]*qkv[(b*12+k2)*288+192+h*32+d];
    ctx[(b*12+q)*96 + h*32 + d]=acc;
  }
}

// ---------------- K4: TATout, 4 interleaved accumulator chains ----------------
__global__ __launch_bounds__(256) void k4_tat(const float* __restrict__ ctx, const float* __restrict__ fcW,
    const float* __restrict__ TEmx, float* __restrict__ TAT){
  int bt=blockIdx.x; int tid=threadIdx.x;
  __shared__ float c96[96];
  __shared__ float red[4];
  if(tid<96) c96[tid]=ctx[bt*96+tid];
  __syncthreads();
  int n0=tid, n1=tid+256, n2=tid+512, n3=tid+768;
  const float* te=&TEmx[bt*1024];
  float a0=te[n0], a1=te[n1], a2=te[n2], a3=te[n3];
  #pragma unroll 8
  for(int j=0;j<96;j++){
    float cj=c96[j];
    const float* wr=&fcW[j*1024];
    a0+=cj*wr[n0]; a1+=cj*wr[n1]; a2+=cj*wr[n2]; a3+=cj*wr[n3];
  }
  float s=a0+a1+a2+a3;
  s=blockSum256(s,red);
  float mu=s*(1.f/1024.f);
  float q=(a0-mu)*(a0-mu)+(a1-mu)*(a1-mu)+(a2-mu)*(a2-mu)+(a3-mu)*(a3-mu);
  q=blockSum256(q,red);
  float rstd=rsqrtf(q*(1.f/1024.f)+EPS);
  float* dst=&TAT[bt*1024];
  dst[n0]=(a0-mu)*rstd; dst[n1]=(a1-mu)*rstd; dst[n2]=(a2-mu)*rstd; dst[n3]=(a3-mu)*rstd;
}

// ---------------- K5: SEmx, 8 rows/block; pre_w in regs ----------------
__global__ __launch_bounds__(256) void k5_semx(const float* __restrict__ TAT, const float* __restrict__ pre_w,
    const float* __restrict__ pre_b, const float* __restrict__ posS, const float* __restrict__ gS,
    const float* __restrict__ bS, unsigned short* __restrict__ SEb){
  int bn0=blockIdx.x*8; int b=bn0>>10, n0=bn0&1023; int tid=threadIdx.x;
  __shared__ float tv[12][8];
  __shared__ float ps[8][264];
  __shared__ float pq[8][264];
  __shared__ float mur[8], rsr[8];
  if(tid<96){ int r=tid&7, t=tid>>3; tv[t][r]=TAT[(b*12+t)*1024+n0+r]; }
  __syncthreads();
  const int d0=tid, d1=tid+256;
  float w0[12], w1[12];
  {
    const float4* p0=(const float4*)&pre_w[d0*12];
    float4 a=p0[0], bb=p0[1], c=p0[2];
    w0[0]=a.x;w0[1]=a.y;w0[2]=a.z;w0[3]=a.w; w0[4]=bb.x;w0[5]=bb.y;w0[6]=bb.z;w0[7]=bb.w;
    w0[8]=c.x;w0[9]=c.y;w0[10]=c.z;w0[11]=c.w;
    const float4* p1=(const float4*)&pre_w[d1*12];
    float4 d=p1[0], e=p1[1], f=p1[2];
    w1[0]=d.x;w1[1]=d.y;w1[2]=d.z;w1[3]=d.w; w1[4]=e.x;w1[5]=e.y;w1[6]=e.z;w1[7]=e.w;
    w1[8]=f.x;w1[9]=f.y;w1[10]=f.z;w1[11]=f.w;
  }
  float pb0=pre_b[d0], pb1=pre_b[d1];
  float v0[8], v1[8];
  #pragma unroll
  for(int r=0;r<8;r++){
    float acc0=pb0 + posS[(n0+r)*512+d0];
    float acc1=pb1 + posS[(n0+r)*512+d1];
    #pragma unroll
    for(int t=0;t<12;t++){ float tvv=tv[t][r]; acc0+=tvv*w0[t]; acc1+=tvv*w1[t]; }
    v0[r]=acc0; v1[r]=acc1;
    ps[r][tid]=acc0+acc1;
    pq[r][tid]=acc0*acc0+acc1*acc1;
  }
  __syncthreads();
  {
    int row=tid>>5, l32=tid&31;
    float s=0.f, q=0.f;
    #pragma unroll
    for(int j=0;j<8;j++){ s+=ps[row][l32+j*32]; q+=pq[row][l32+j*32]; }
    #pragma unroll
    for(int o=16;o>=1;o>>=1){ s+=__shfl_xor(s,o,64); q+=__shfl_xor(q,o,64); }
    if(l32==0){
      float mu=s*(1.f/512.f);
      float var=q*(1.f/512.f)-mu*mu;
      mur[row]=mu; rsr[row]=rsqrtf(var+EPS);
    }
  }
  __syncthreads();
  float g0=gS[d0], b0v=bS[d0], g1=gS[d1], b1v=bS[d1];
  #pragma unroll
  for(int r=0;r<8;r++){
    float mu=mur[r], rs=rsr[r];
    SEb[(bn0+r)*512 + d0] = f2b((v0[r]-mu)*rs*g0+b0v);
    SEb[(bn0+r)*512 + d1] = f2b((v1[r]-mu)*rs*g1+b1v);
  }
}

// ---------------- K6 v2: SQ/SK via MFMA GEMM, 16 rows/block, wave = 3 col-tiles ----------------
__global__ __launch_bounds__(256) void k6_sqk(const unsigned short* __restrict__ SEb,
    const unsigned short* __restrict__ Wpack,
    unsigned short* __restrict__ SQb, unsigned short* __restrict__ SKb){
  int tid=threadIdx.x; int w=tid>>6, lane=tid&63;
  const int hi=lane>>4, lo=lane&15;
  const int row0 = blockIdx.x*16;
  f32x4 acc[3];
  #pragma unroll
  for(int i=0;i<3;i++){ acc[i][0]=0.f; acc[i][1]=0.f; acc[i][2]=0.f; acc[i][3]=0.f; }
  for(int ks=0;ks<16;ks++){
    bf16x8 af = *(const bf16x8*)&SEb[(row0+lo)*512 + ks*32 + hi*8];
    #pragma unroll
    for(int j=0;j<3;j++){
      int ct = w*3+j;
      bf16x8 bf = *(const bf16x8*)&Wpack[((ct*16+ks)<<9) + lane*8];
      acc[j] = __builtin_amdgcn_mfma_f32_16x16x32_bf16(af, bf, acc[j], 0,0,0);
    }
  }
  #pragma unroll
  for(int j=0;j<3;j++){
    int ct = w*3+j;
    int c96 = ((ct<6)? ct : ct-6)*16 + lo;
    int kq = c96>>5, d = c96&31;
    unsigned short* dst = (ct<6)? SQb : SKb;
    #pragma unroll
    for(int r=0;r<4;r++){
      int n = row0 + hi*4 + r;
      int b = n>>10, nl = n&1023;
      dst[((b*3+kq)*1024+nl)*32 + d] = f2b(acc[j][r]);
    }
  }
}

// ---------------- K7: whole-x LDS stage, barrier-free chunk loop ----------------
#define SCALE7 0.17677669529663687f
__global__ __launch_bounds__(256) void k7_spatial(const unsigned short* __restrict__ SQb,
    const unsigned short* __restrict__ SKb, const unsigned* __restrict__ mcT,
    const float* __restrict__ x, float* __restrict__ rhsT){
  const int blk0=blockIdx.x;
  const int blk=(blk0&7)*96 + (blk0>>3);      // XCD-chunked: 768 = 8*96, bijective
  const int mt=blk&15, bk=blk>>4;
  const int k=bk%3, b=bk/3;
  const int m0=mt*64;
  const int tid=threadIdx.x;
  const int w=tid>>6, lane=tid&63, g=lane>>4, col=lane&15;

  __shared__ unsigned short xs[16*1024];

  const float* xb = x + b*12288;
  for(int i=tid;i<2048;i+=256) ((unsigned*)xs)[12*512 + i] = 0u;
  for(int i=tid;i<12288;i+=256){
    int n=i/12, t=i-n*12;
    xs[t*1024 + (n ^ ((t&7)<<3))] = f2b(xb[i]);
  }
  __syncthreads();

  const int m_glob = m0 + w*16 + col;
  bf16x8 bfrag = *(const bf16x8*)&SKb[((bk<<10)+m_glob)*32 + g*8];

  f32x4 O = {0.f,0.f,0.f,0.f};
  float mrun=-1e30f, lrun=0.f;

  const unsigned* mrow = mcT + k*1048576 + m_glob*1024;
  const int swz = (col&7)<<3;

  for(int ch=0; ch<8; ++ch){
    const int n0 = ch<<7;

    f32x4 acc[8];
    #pragma unroll
    for(int nt=0;nt<8;nt++){
      bf16x8 afrag = *(const bf16x8*)&SQb[((bk<<10) + n0 + nt*16 + col)*32 + g*8];
      f32x4 z = {0.f,0.f,0.f,0.f};
      acc[nt] = __builtin_amdgcn_mfma_f32_16x16x32_bf16(afrag, bfrag, z, 0,0,0);
    }
    unsigned mcv[8][4];
    #pragma unroll
    for(int nt=0;nt<8;nt++){
      uint4 mv = *(const uint4*)&mrow[n0 + nt*16 + g*4];
      mcv[nt][0]=mv.x; mcv[nt][1]=mv.y; mcv[nt][2]=mv.z; mcv[nt][3]=mv.w;
    }
    float cmax = -1e30f;
    #pragma unroll
    for(int nt=0;nt<8;nt++){
      #pragma unroll
      for(int r=0;r<4;r++){
        float s = acc[nt][r]*SCALE7 + __uint_as_float(mcv[nt][r]<<16);
        acc[nt][r]=s;
        cmax=fmaxf(cmax,s);
      }
    }
    cmax = fmaxf(cmax, __shfl_xor(cmax,16,64));
    cmax = fmaxf(cmax, __shfl_xor(cmax,32,64));
    float mnew = fmaxf(mrun, cmax);
    float alpha = __expf(mrun - mnew);
    float lsum = 0.f;
    unsigned short pb[8][4];
    #pragma unroll
    for(int nt=0;nt<8;nt++){
      #pragma unroll
      for(int r=0;r<4;r++){
        float e = __expf(acc[nt][r] - mnew);
        lsum += e;
        pb[nt][r] = f2b(e * __uint_as_float(mcv[nt][r] & 0xffff0000u));
      }
    }
    lsum += __shfl_xor(lsum,16,64);
    lsum += __shfl_xor(lsum,32,64);
    lrun = lrun*alpha + lsum;
    mrun = mnew;
    O[0]*=alpha; O[1]*=alpha; O[2]*=alpha; O[3]*=alpha;

    #pragma unroll
    for(int c=0;c<4;c++){
      bf16x8 pf;
      #pragma unroll
      for(int j=0;j<4;j++){ pf[j]=(short)pb[2*c][j]; pf[j+4]=(short)pb[2*c+1][j]; }
      int nlo = n0 + c*32 + g*4;
      bf16x4 lo = *(const bf16x4*)&xs[col*1024 + (nlo ^ swz)];
      bf16x4 hi = *(const bf16x4*)&xs[col*1024 + ((nlo+16) ^ swz)];
      bf16x8 ax;
      #pragma unroll
      for(int j=0;j<4;j++){ ax[j]=lo[j]; ax[j+4]=hi[j]; }
      O = __builtin_amdgcn_mfma_f32_16x16x32_bf16(ax, pf, O, 0,0,0);
    }
  }
  float inv = 1.f/lrun;
  #pragma unroll
  for(int r=0;r<4;r++){
    int t = g*4+r;
    if(t<12) rhsT[((bk*12+t)<<10) + m_glob] = O[r]*inv;
  }
}

// ---------------- K9 v4: fp16 internals (cvt_pkrtz packs), paired u32 Gl writes ----
__global__ __launch_bounds__(256) void k9_final(const float* __restrict__ rhsT, const float* __restrict__ theta,
    const unsigned short* __restrict__ Apack, const unsigned short* __restrict__ fcwB,
    const float* __restrict__ g3b, const float* __restrict__ g5b, const float* __restrict__ g7b,
    const float* __restrict__ fcb,
    const float* __restrict__ rw, const float* __restrict__ rb,
    const float* __restrict__ gln, const float* __restrict__ bln,
    const float* __restrict__ x, float* __restrict__ out){
  int bn0=blockIdx.x*8;
  int tid=threadIdx.x;
  const int b=bn0>>10, n0=bn0&1023;

  __shared__ struct { unsigned short Xl[12*8*64]; float rstage[3][12][8]; } P0;
  __shared__ union {
    unsigned short Gl[4*16*8*24];   // [wave][c_loc][g'][tau]  (fp16 bits)
    float XP[8][772];
  } U;
  __shared__ float xres[8][12];
  __shared__ float mu8[8][12], rs8[8][12];

  for(int i=tid;i<288;i+=256){
    int kk=i/96; int rem=i-kk*96; int t=rem>>3; int g=rem&7;
    P0.rstage[kk][t][g]=rhsT[((b*3+kk)*12+t)*1024 + n0 + g];
  }
  for(int i=tid;i<96;i+=256){ int g=i/12, t=i-(i/12)*12; xres[g][t]=x[(bn0+g)*12+t]; }
  __syncthreads();

  // phase0: Xl[t][g][ic] = fp16(relu(sum_kk rstage*theta)), g-XOR-swizzled, ic-pairs
  {
    int g=tid>>5, icp=tid&31;
    float th0[3], th1[3];
    #pragma unroll
    for(int kk=0;kk<3;kk++){ th0[kk]=theta[kk*64+2*icp]; th1[kk]=theta[kk*64+2*icp+1]; }
    #pragma unroll
    for(int t=0;t<12;t++){
      float r0=P0.rstage[0][t][g], r1=P0.rstage[1][t][g], r2=P0.rstage[2][t][g];
      float a0=fmaxf(r0*th0[0]+r1*th0[1]+r2*th0[2],0.f);
      float a1=fmaxf(r0*th1[0]+r1*th1[1]+r2*th1[2],0.f);
      __half2 hp = __floats2half2_rn(a0,a1);
      *(unsigned*)((char*)P0.Xl + ((t*8+g)<<7) + ((icp*4) ^ (g<<4))) = *(unsigned*)&hp;
    }
  }
  __syncthreads();

  const int w=tid>>6, lane=tid&63, halfk=lane>>4, colq=lane&15;
  const int gg=colq&7, tau2=colq>>3;
  const int ca = w*16 + halfk*4;
  const char* xlb = (const char*)P0.Xl;
  unsigned short* Glw = &U.Gl[w*3072];

  // gate + paired fp16 u32 store: lane tau2 holds tau=TB+tau2; partner lane (^8) the other.
  #define GATE_STORE(ACCA, ACCB, TB) { \
    float gv_[4]; \
    _Pragma("unroll") \
    for(int r=0;r<4;r++){ \
      float ya=(ACCA)[r], yb=(ACCB)[r]; \
      float e2=__expf(2.f*ya), eb=__expf(yb); \
      gv_[r]=(e2-1.f)*eb*__frcp_rn((e2+1.f)*(eb+1.f)); \
    } \
    _Pragma("unroll") \
    for(int r=0;r<4;r++){ \
      float gp_=__shfl_xor(gv_[r],8,64); \
      if((r>>1)==tau2){ \
        float lo_= tau2? gp_:gv_[r], hi_= tau2? gv_[r]:gp_; \
        __half2 hp=__floats2half2_rn(lo_,hi_); \
        int c_loc=halfk*4+r; \
        *(unsigned*)((char*)Glw + c_loc*384 + ((gg ^ (c_loc&7))*48) + (TB)*2) = *(unsigned*)&hp; \
      } \
    } }

  // ---- group kappa=3 ----
  {
    f32x4 acA[5], acB[5];
    #pragma unroll
    for(int j=0;j<5;j++)
      #pragma unroll
      for(int r=0;r<4;r++){ acA[j][r]=g3b[ca+r]; acB[j][r]=g3b[64+ca+r]; }
    #pragma unroll
    for(int s=0;s<6;s++){
      f16x8 a0 = *(const f16x8*)&Apack[((w  )*6 + s)*512 + lane*8];
      f16x8 a1 = *(const f16x8*)&Apack[((w+4)*6 + s)*512 + lane*8];
      int dt=s>>1;
      int sl = ((((s&1)*32 + halfk*8)*2) ^ (gg<<4));
      #pragma unroll
      for(int j=0;j<5;j++){
        int t=2*j+tau2+dt;
        f16x8 bf = *(const f16x8*)(xlb + ((t*8+gg)<<7) + sl);
        acA[j] = __builtin_amdgcn_mfma_f32_16x16x32_f16(a0, bf, acA[j], 0,0,0);
        acB[j] = __builtin_amdgcn_mfma_f32_16x16x32_f16(a1, bf, acB[j], 0,0,0);
      }
    }
    #pragma unroll
    for(int j=0;j<5;j++) GATE_STORE(acA[j], acB[j], 2*j)
  }
  // ---- group kappa=5 ----
  {
    f32x4 acA[4], acB[4];
    #pragma unroll
    for(int j=0;j<4;j++)
      #pragma unroll
      for(int r=0;r<4;r++){ acA[j][r]=g5b[ca+r]; acB[j][r]=g5b[64+ca+r]; }
    #pragma unroll
    for(int s=0;s<10;s++){
      f16x8 a0 = *(const f16x8*)&Apack[(48 + (w  )*10 + s)*512 + lane*8];
      f16x8 a1 = *(const f16x8*)&Apack[(48 + (w+4)*10 + s)*512 + lane*8];
      int dt=s>>1;
      int sl = ((((s&1)*32 + halfk*8)*2) ^ (gg<<4));
      #pragma unroll
      for(int j=0;j<4;j++){
        int t=2*j+tau2+dt;
        f16x8 bf = *(const f16x8*)(xlb + ((t*8+gg)<<7) + sl);
        acA[j] = __builtin_amdgcn_mfma_f32_16x16x32_f16(a0, bf, acA[j], 0,0,0);
        acB[j] = __builtin_amdgcn_mfma_f32_16x16x32_f16(a1, bf, acB[j], 0,0,0);
      }
    }
    #pragma unroll
    for(int j=0;j<4;j++) GATE_STORE(acA[j], acB[j], 10+2*j)
  }
  // ---- group kappa=7 ----
  {
    f32x4 acA[3], acB[3];
    #pragma unroll
    for(int j=0;j<3;j++)
      #pragma unroll
      for(int r=0;r<4;r++){ acA[j][r]=g7b[ca+r]; acB[j][r]=g7b[64+ca+r]; }
    #pragma unroll
    for(int s=0;s<14;s++){
      f16x8 a0 = *(const f16x8*)&Apack[(128 + (w  )*14 + s)*512 + lane*8];
      f16x8 a1 = *(const f16x8*)&Apack[(128 + (w+4)*14 + s)*512 + lane*8];
      int dt=s>>1;
      int sl = ((((s&1)*32 + halfk*8)*2) ^ (gg<<4));
      #pragma unroll
      for(int j=0;j<3;j++){
        int t=2*j+tau2+dt;
        f16x8 bf = *(const f16x8*)(xlb + ((t*8+gg)<<7) + sl);
        acA[j] = __builtin_amdgcn_mfma_f32_16x16x32_f16(a0, bf, acA[j], 0,0,0);
        acB[j] = __builtin_amdgcn_mfma_f32_16x16x32_f16(a1, bf, acB[j], 0,0,0);
      }
    }
    #pragma unroll
    for(int j=0;j<3;j++) GATE_STORE(acA[j], acB[j], 18+2*j)
  }
  #undef GATE_STORE

  // ---- fc via MFMA (fp16) ----
  const int tcol = lane&15, hq = lane>>4;
  const int hm = (hq==3)? 0 : hq;
  f16x8 b2 = *(const f16x8*)&fcwB[lane*8];
  float fcbv = (tcol<12)? fcb[tcol] : 0.f;
  f32x4 d2[8];
  #pragma unroll
  for(int g=0; g<8; g++){
    f16x8 a2 = *(const f16x8*)&Glw[tcol*192 + ((g ^ (tcol&7))*24) + hm*8];
    f32x4 ini = {fcbv, fcbv, fcbv, fcbv};
    d2[g] = __builtin_amdgcn_mfma_f32_16x16x32_f16(a2, b2, ini, 0,0,0);
  }
  __syncthreads();

  if(tcol<12){
    float rwa[4], rba[4];
    #pragma unroll
    for(int r=0;r<4;r++){ int c=w*16+hq*4+r; rwa[r]=rw[c]; rba[r]=rb[c]; }
    #pragma unroll
    for(int g=0; g<8; g++){
      float xv=xres[g][tcol];
      #pragma unroll
      for(int r=0;r<4;r++){
        int c=w*16+hq*4+r;
        float tv = fmaxf(d2[g][r], 0.f);
        float xr = xv*rwa[r]+rba[r];
        U.XP[g][c*12+tcol] = fmaxf(xr+tv, 0.f);
      }
    }
  }
  __syncthreads();

  if(tid<192){
    int p=tid>>1, h=tid&1;
    int g=p/12, t=p-(p/12)*12;
    float s=0.f;
    for(int c=h*32;c<h*32+32;c++) s+=U.XP[g][c*12+t];
    s += __shfl_xor(s,1,64);
    float mu=s*(1.f/64.f);
    float q=0.f;
    for(int c=h*32;c<h*32+32;c++){float d=U.XP[g][c*12+t]-mu;q+=d*d;}
    q += __shfl_xor(q,1,64);
    if(h==0){ mu8[g][t]=mu; rs8[g][t]=rsqrtf(q*(1.f/64.f)+EPS); }
  }
  __syncthreads();
  for(int o=tid;o<1536;o+=256){
    int g=o/192; int q4=o-g*192;
    int c=q4/3; int tb=(q4-c*3)*4;
    float4 vv = *(const float4*)&U.XP[g][c*12+tb];
    float gl=gln[c], bl=bln[c];
    float4 ov;
    ov.x=(vv.x-mu8[g][tb+0])*rs8[g][tb+0]*gl+bl;
    ov.y=(vv.y-mu8[g][tb+1])*rs8[g][tb+1]*gl+bl;
    ov.z=(vv.z-mu8[g][tb+2])*rs8[g][tb+2]*gl+bl;
    ov.w=(vv.w-mu8[g][tb+3])*rs8[g][tb+3]*gl+bl;
    *(float4*)&out[(long)(bn0+g)*768 + c*12 + tb] = ov;
  }
}

// ---------------- launch ----------------
extern "C" void kernel_launch(void* const* d_in, const int* in_sizes, int n_in,
                              void* d_out, int out_size, void* d_ws, size_t ws_size,
                              hipStream_t stream){
  const float* x    =(const float*)d_in[0];
  const float* res  =(const float*)d_in[1];
  const float* posT =(const float*)d_in[2];
  const float* gT   =(const float*)d_in[3];
  const float* bT   =(const float*)d_in[4];
  const float* wq   =(const float*)d_in[5];
  const float* wk   =(const float*)d_in[6];
  const float* wv   =(const float*)d_in[7];
  const float* fcW  =(const float*)d_in[8];
  const float* prw  =(const float*)d_in[9];
  const float* prb  =(const float*)d_in[10];
  const float* posS =(const float*)d_in[11];
  const float* gS   =(const float*)d_in[12];
  const float* bS   =(const float*)d_in[13];
  const float* swq  =(const float*)d_in[14];
  const float* swk  =(const float*)d_in[15];
  const float* cheb =(const float*)d_in[16];
  const float* adj  =(const float*)d_in[17];
  const float* cmask=(const float*)d_in[18];
  const float* theta=(const float*)d_in[19];
  const float* g3w=(const float*)d_in[20]; const float* g3b=(const float*)d_in[21];
  const float* g5w=(const float*)d_in[22]; const float* g5b=(const float*)d_in[23];
  const float* g7w=(const float*)d_in[24]; const float* g7b=(const float*)d_in[25];
  const float* fcw=(const float*)d_in[26]; const float* fcb=(const float*)d_in[27];
  const float* rw =(const float*)d_in[28]; const float* rb =(const float*)d_in[29];
  const float* gln=(const float*)d_in[30]; const float* bln=(const float*)d_in[31];

  float* outp=(float*)d_out;
  float* scores = outp + 12582912;

  float* wsf=(float*)d_ws;
  float* TEmx = wsf;                          // 196608 f
  float* qkv  = TEmx + 196608;                // 55296 f
  float* ctx  = qkv + 55296;                  // 18432 f
  float* TAT  = ctx + 18432;                  // 196608 f
  unsigned short* SEb = (unsigned short*)(TAT + 196608);          // 4194304 f
  unsigned short* SQb = (unsigned short*)((float*)SEb + 4194304); // 786432 f
  unsigned short* SKb = (unsigned short*)((float*)SQb + 786432);  // 786432 f
  unsigned* mcT = (unsigned*)((float*)SKb + 786432);              // 3145728 f
  float* rhsT  = (float*)mcT + 3145728;                           // 589824 f
  unsigned short* Apack = (unsigned short*)(rhsT + 589824);       // 122880 u16
  unsigned short* Wpack = Apack + 122880;                         // 98304 u16
  unsigned short* Wpack2 = Wpack + 98304;                         // 294912 u16
  unsigned short* TEb = Wpack2 + 294912;                          // 196608 u16
  unsigned short* fcwB = TEb + 196608;                            // 512 u16

  kb0_prep<<<dim3(768),dim3(256),0,stream>>>(adj,cmask,cheb,mcT);
  kprep<<<dim3(253),dim3(256),0,stream>>>(g3w,g5w,g7w,swq,swk,wq,wk,wv,fcw,
                                          Apack,Wpack,Wpack2,fcwB);
  k1_embedT<<<dim3(192),dim3(256),0,stream>>>(x,posT,gT,bT,TEmx,TEb);
  k2_qkv<<<dim3(216),dim3(256),0,stream>>>(TEb,Wpack2,qkv);
  k3_attn<<<dim3(16),dim3(512),0,stream>>>(qkv,res,scores,ctx);
  k4_tat<<<dim3(192),dim3(256),0,stream>>>(ctx,fcW,TEmx,TAT);
  k5_semx<<<dim3(2048),dim3(256),0,stream>>>(TAT,prw,prb,posS,gS,bS,SEb);
  k6_sqk<<<dim3(1024),dim3(256),0,stream>>>(SEb,Wpack,SQb,SKb);
  k7_spatial<<<dim3(768),dim3(256),0,stream>>>(SQb,SKb,mcT,x,rhsT);
  k9_final<<<dim3(2048),dim3(256),0,stream>>>(rhsT,theta,Apack,fcwB,g3b,g5b,g7b,
                                              fcb,rw,rb,gln,bln,x,outp);
}

// Round 12
// 157.803 us; speedup vs baseline: 9.5273x; 1.0974x over previous
//
#include <hip/hip_runtime.h>
#include <hip/hip_fp16.h>

#define EPS 1e-5f

typedef float f32x4 __attribute__((ext_vector_type(4)));
typedef short bf16x8 __attribute__((ext_vector_type(8)));
typedef short bf16x4 __attribute__((ext_vector_type(4)));

__device__ __forceinline__ unsigned short f2b(float f){
  unsigned u=__float_as_uint(f);
  return (unsigned short)((u + 0x7fffu + ((u>>16)&1u))>>16);
}
__device__ __forceinline__ float b2f(unsigned short h){
  return __uint_as_float(((unsigned)h)<<16);
}

// ---------------- helpers ----------------
__device__ __forceinline__ float blockSum256(float v, float* red){
  #pragma unroll
  for(int o=32;o>0;o>>=1) v += __shfl_down(v,o,64);
  int wid = threadIdx.x>>6;
  if((threadIdx.x&63)==0) red[wid]=v;
  __syncthreads();
  if(threadIdx.x==0) red[0]=red[0]+red[1]+red[2]+red[3];
  __syncthreads();
  float r = red[0];
  __syncthreads();
  return r;
}

// ---------------- KB0: pack mask/cheb TRANSPOSED: mcT[k][m][n] ----------------
__global__ __launch_bounds__(256) void kb0_prep(const float* __restrict__ adj, const float* __restrict__ cmask,
    const float* __restrict__ cheb, unsigned* __restrict__ mcT){
  int blk=blockIdx.x;                 // k*256 + tn*16 + tm
  int k=blk>>8; int rem=blk&255; int tn=rem>>4, tm=rem&15;
  int tid=threadIdx.x;
  __shared__ unsigned tile[64][65];
  const float* chk = cheb + k*1048576;
  const float* cmk = cmask + k*1048576;
  for(int i=tid;i<4096;i+=256){
    int ln=i>>6, lm=i&63;
    int n=tn*64+ln, m=tm*64+lm;
    int nm=n*1024+m;
    tile[ln][lm] = (((unsigned)f2b(chk[nm]))<<16) | (unsigned)f2b(adj[nm]*cmk[nm]);
  }
  __syncthreads();
  unsigned* dst = mcT + k*1048576;
  for(int i=tid;i<4096;i+=256){
    int lm=i>>6, ln=i&63;
    dst[(tm*64+lm)*1024 + tn*64+ln] = tile[ln][lm];
  }
}

// ---------------- KPREP: fused weight packing (Apack | Wpack | Wpack2 | fcwB | fcWB2) ----------------
__global__ __launch_bounds__(256) void kprep(const float* __restrict__ g3w, const float* __restrict__ g5w,
    const float* __restrict__ g7w, const float* __restrict__ swq, const float* __restrict__ swk,
    const float* __restrict__ wq, const float* __restrict__ wk, const float* __restrict__ wv,
    const float* __restrict__ fcw, const float* __restrict__ fcW,
    unsigned short* __restrict__ Apack, unsigned short* __restrict__ Wpack,
    unsigned short* __restrict__ Wpack2, unsigned short* __restrict__ fcwB,
    unsigned short* __restrict__ fcWB2){
  int idx = blockIdx.x*256+threadIdx.x;
  if(idx<15360){                                   // Apack (conv A-frags, bf16)
    int frag=idx>>6, lane=idx&63;
    int rt, s, kappa; const float* W;
    if(frag<48){ rt=frag/6; s=frag-rt*6; kappa=3; W=g3w; }
    else if(frag<128){ int f=frag-48; rt=f/10; s=f-rt*10; kappa=5; W=g5w; }
    else { int f=frag-128; rt=f/14; s=f-rt*14; kappa=7; W=g7w; }
    int c = rt*16 + (lane&15);
    int dt = s>>1, ic0=(s&1)*32 + (lane>>4)*8;
    #pragma unroll
    for(int j=0;j<8;j++) Apack[idx*8+j]=f2b(W[(c*64+ic0+j)*kappa + dt]);
  } else if(idx<27648){                            // Wpack (swq/swk B-frags)
    int id2=idx-15360;
    int frag=id2>>6, lane=id2&63;
    int ct=frag>>4, ks=frag&15;
    const float* W = (ct<6)? swq : swk;
    int c = ((ct<6)? ct : ct-6)*16 + (lane&15);
    int k0 = ks*32 + (lane>>4)*8;
    #pragma unroll
    for(int j=0;j<8;j++) Wpack[id2*8+j]=f2b(W[(k0+j)*96 + c]);
  } else if(idx<64512){                            // Wpack2 (wq|wk|wv B-frags)
    int id2=idx-27648;
    int frag=id2>>6, lane=id2&63;
    int ct=frag>>5, ks=frag&31;
    int cg = ct*16 + (lane&15);
    const float* W; int c;
    if(cg<96){ W=wq; c=cg; } else if(cg<192){ W=wk; c=cg-96; } else { W=wv; c=cg-192; }
    int k0 = ks*32 + (lane>>4)*8;
    #pragma unroll
    for(int j=0;j<8;j++) Wpack2[id2*8+j]=f2b(W[(k0+j)*96 + c]);
  } else if(idx<64576){                            // fcwB (bf16)
    int lane=idx-64512;
    int t=lane&15, hq=lane>>4;
    #pragma unroll
    for(int j=0;j<8;j++){
      int tau=hq*8+j;
      fcwB[lane*8+j] = (tau<24 && t<12) ? f2b(fcw[tau*12+t]) : (unsigned short)0;
    }
  } else if(idx<76864){                            // fcWB2 (fcW B-frags: 64 ct x 3 ks)
    int id3=idx-64576;
    int frag=id3>>6, lane=id3&63;
    int ct=frag/3, ks=frag-ct*3;
    int c = ct*16 + (lane&15);
    int k0 = ks*32 + (lane>>4)*8;
    #pragma unroll
    for(int j=0;j<8;j++) fcWB2[id3*8+j]=f2b(fcW[(k0+j)*1024 + c]);
  }
}

// ---------------- K1: EmbedT (fp32 + bf16 outputs) ----------------
__global__ __launch_bounds__(256) void k1_embedT(const float* __restrict__ x, const float* __restrict__ posT,
    const float* __restrict__ gT, const float* __restrict__ bT, float* __restrict__ TEmx,
    unsigned short* __restrict__ TEb){
  int bt=blockIdx.x; int b=bt/12, t=bt-b*12;
  int tid=threadIdx.x;
  __shared__ float red[4];
  float v[4]; float s=0.f;
  #pragma unroll
  for(int i=0;i<4;i++){ int n=tid+i*256; v[i]=x[(b*1024+n)*12+t]+posT[t*1024+n]; s+=v[i]; }
  s = blockSum256(s, red);
  float mu = s*(1.f/1024.f);
  float q=0.f;
  #pragma unroll
  for(int i=0;i<4;i++){ float d=v[i]-mu; q+=d*d; }
  q = blockSum256(q, red);
  float rstd = rsqrtf(q*(1.f/1024.f)+EPS);
  #pragma unroll
  for(int i=0;i<4;i++){
    int n=tid+i*256;
    float val=(v[i]-mu)*rstd*gT[n]+bT[n];
    TEmx[bt*1024+n]=val;
    TEb[bt*1024+n]=f2b(val);
  }
}

// ---------------- K2: QKV via MFMA split-K GEMM ----------------
__global__ __launch_bounds__(256) void k2_qkv(const unsigned short* __restrict__ TEb,
    const unsigned short* __restrict__ Wpack2, float* __restrict__ qkv){
  int tid=threadIdx.x; int w=tid>>6, lane=tid&63;
  const int hi=lane>>4, lo=lane&15;
  const int rt=blockIdx.x/18, ct=blockIdx.x-rt*18;
  __shared__ float red[4][16][16];
  f32x4 acc={0.f,0.f,0.f,0.f};
  #pragma unroll
  for(int s=0;s<8;s++){
    int ks=w*8+s;
    bf16x8 af = *(const bf16x8*)&TEb[(rt*16+lo)*1024 + ks*32 + hi*8];
    bf16x8 bf = *(const bf16x8*)&Wpack2[((ct*32+ks)<<9) + lane*8];
    acc = __builtin_amdgcn_mfma_f32_16x16x32_bf16(af, bf, acc, 0,0,0);
  }
  #pragma unroll
  for(int r=0;r<4;r++) red[w][hi*4+r][lo]=acc[r];
  __syncthreads();
  int r16=tid>>4, c16=tid&15;
  float s = red[0][r16][c16]+red[1][r16][c16]+red[2][r16][c16]+red[3][r16][c16];
  qkv[(rt*16+r16)*288 + ct*16 + c16] = s;
}

// ---------------- K3: temporal attn (ctx out as bf16) ----------------
__global__ __launch_bounds__(512) void k3_attn(const float* __restrict__ qkv, const float* __restrict__ res_att,
    float* __restrict__ scores_out, unsigned short* __restrict__ ctxb){
  int b=blockIdx.x; int tid=threadIdx.x;
  __shared__ float sS[432];
  __shared__ float sA[432];
  if(tid<432){
    int h=tid/144; int r=tid-h*144; int q=r/12; int k2=r-q*12;
    const float* Qr=&qkv[(b*12+q)*288 + h*32];
    const float* Kr=&qkv[(b*12+k2)*288 + 96 + h*32];
    float acc=0.f;
    #pragma unroll
    for(int d=0;d<32;d++) acc+=Qr[d]*Kr[d];
    acc = acc*0.17677669529663687f + res_att[(b*3+h)*144 + q*12 + k2];
    sS[h*144+q*12+k2]=acc;
    scores_out[(b*3+h)*144 + q*12 + k2]=acc;
  }
  __syncthreads();
  if(tid<36){
    int h=tid/12, k2=tid-(tid/12)*12;
    float mx=-1e30f;
    for(int q=0;q<12;q++) mx=fmaxf(mx,sS[h*144+q*12+k2]);
    float sum=0.f;
    for(int q=0;q<12;q++){ float e=__expf(sS[h*144+q*12+k2]-mx); sA[h*144+q*12+k2]=e; sum+=e; }
    float inv=1.f/sum;
    for(int q=0;q<12;q++) sA[h*144+q*12+k2]*=inv;
  }
  __syncthreads();
  for(int o=tid;o<1152;o+=512){
    int h=o/384; int r=o-h*384; int q=r/32; int d=r-q*32;
    float acc=0.f;
    #pragma unroll
    for(int k2=0;k2<12;k2++) acc += sA[h*144+q*12+k2]*qkv[(b*12+k2)*288+192+h*32+d];
    ctxb[(b*12+q)*96 + h*32 + d]=f2b(acc);
  }
}

// ---------------- K4a: TATpre = ctx@fcW + TEmx via MFMA (M=192,N=1024,K=96) ----------------
__global__ __launch_bounds__(256) void k4a_mm(const unsigned short* __restrict__ ctxb,
    const unsigned short* __restrict__ fcWB2, const float* __restrict__ TEmx,
    float* __restrict__ TATpre){
  int tid=threadIdx.x; int w=tid>>6, lane=tid&63;
  const int hi=lane>>4, lo=lane&15;
  const int rt=blockIdx.x>>4, cg=blockIdx.x&15;
  const int ct=cg*4+w;
  f32x4 acc={0.f,0.f,0.f,0.f};
  #pragma unroll
  for(int ks=0;ks<3;ks++){
    bf16x8 af = *(const bf16x8*)&ctxb[(rt*16+lo)*96 + ks*32 + hi*8];
    bf16x8 bf = *(const bf16x8*)&fcWB2[((ct*3+ks)<<9) + lane*8];
    acc = __builtin_amdgcn_mfma_f32_16x16x32_bf16(af, bf, acc, 0,0,0);
  }
  #pragma unroll
  for(int r=0;r<4;r++){
    int row = rt*16 + hi*4 + r;
    int coln = ct*16 + lo;
    TATpre[row*1024+coln] = acc[r] + TEmx[row*1024+coln];
  }
}

// ---------------- K4b: per-row LN stats (mu, rstd per bt) ----------------
__global__ __launch_bounds__(256) void k4b_stats(const float* __restrict__ TATpre,
    float* __restrict__ muT, float* __restrict__ rsT){
  int bt=blockIdx.x; int tid=threadIdx.x;
  __shared__ float red[4];
  const float* row=&TATpre[bt*1024];
  float a0=row[tid], a1=row[tid+256], a2=row[tid+512], a3=row[tid+768];
  float s=a0+a1+a2+a3;
  s=blockSum256(s,red);
  float mu=s*(1.f/1024.f);
  float q=(a0-mu)*(a0-mu)+(a1-mu)*(a1-mu)+(a2-mu)*(a2-mu)+(a3-mu)*(a3-mu);
  q=blockSum256(q,red);
  if(tid==0){ muT[bt]=mu; rsT[bt]=rsqrtf(q*(1.f/1024.f)+EPS); }
}

// ---------------- K5: SEmx, 8 rows/block; LN applied on tv load ----------------
__global__ __launch_bounds__(256) void k5_semx(const float* __restrict__ TATpre,
    const float* __restrict__ muT, const float* __restrict__ rsT,
    const float* __restrict__ pre_w,
    const float* __restrict__ pre_b, const float* __restrict__ posS, const float* __restrict__ gS,
    const float* __restrict__ bS, unsigned short* __restrict__ SEb){
  int bn0=blockIdx.x*8; int b=bn0>>10, n0=bn0&1023; int tid=threadIdx.x;
  __shared__ float tv[12][8];
  __shared__ float ps[8][264];
  __shared__ float pq[8][264];
  __shared__ float mur[8], rsr[8];
  if(tid<96){
    int r=tid&7, t=tid>>3;
    int bt=b*12+t;
    tv[t][r]=(TATpre[bt*1024+n0+r]-muT[bt])*rsT[bt];
  }
  __syncthreads();
  const int d0=tid, d1=tid+256;
  float w0[12], w1[12];
  {
    const float4* p0=(const float4*)&pre_w[d0*12];
    float4 a=p0[0], bb=p0[1], c=p0[2];
    w0[0]=a.x;w0[1]=a.y;w0[2]=a.z;w0[3]=a.w; w0[4]=bb.x;w0[5]=bb.y;w0[6]=bb.z;w0[7]=bb.w;
    w0[8]=c.x;w0[9]=c.y;w0[10]=c.z;w0[11]=c.w;
    const float4* p1=(const float4*)&pre_w[d1*12];
    float4 d=p1[0], e=p1[1], f=p1[2];
    w1[0]=d.x;w1[1]=d.y;w1[2]=d.z;w1[3]=d.w; w1[4]=e.x;w1[5]=e.y;w1[6]=e.z;w1[7]=e.w;
    w1[8]=f.x;w1[9]=f.y;w1[10]=f.z;w1[11]=f.w;
  }
  float pb0=pre_b[d0], pb1=pre_b[d1];
  float v0[8], v1[8];
  #pragma unroll
  for(int r=0;r<8;r++){
    float acc0=pb0 + posS[(n0+r)*512+d0];
    float acc1=pb1 + posS[(n0+r)*512+d1];
    #pragma unroll
    for(int t=0;t<12;t++){ float tvv=tv[t][r]; acc0+=tvv*w0[t]; acc1+=tvv*w1[t]; }
    v0[r]=acc0; v1[r]=acc1;
    ps[r][tid]=acc0+acc1;
    pq[r][tid]=acc0*acc0+acc1*acc1;
  }
  __syncthreads();
  {
    int row=tid>>5, l32=tid&31;
    float s=0.f, q=0.f;
    #pragma unroll
    for(int j=0;j<8;j++){ s+=ps[row][l32+j*32]; q+=pq[row][l32+j*32]; }
    #pragma unroll
    for(int o=16;o>=1;o>>=1){ s+=__shfl_xor(s,o,64); q+=__shfl_xor(q,o,64); }
    if(l32==0){
      float mu=s*(1.f/512.f);
      float var=q*(1.f/512.f)-mu*mu;
      mur[row]=mu; rsr[row]=rsqrtf(var+EPS);
    }
  }
  __syncthreads();
  float g0=gS[d0], b0v=bS[d0], g1=gS[d1], b1v=bS[d1];
  #pragma unroll
  for(int r=0;r<8;r++){
    float mu=mur[r], rs=rsr[r];
    SEb[(bn0+r)*512 + d0] = f2b((v0[r]-mu)*rs*g0+b0v);
    SEb[(bn0+r)*512 + d1] = f2b((v1[r]-mu)*rs*g1+b1v);
  }
}

// ---------------- K6: SQ/SK via MFMA GEMM, 16 rows/block, wave = 3 col-tiles ----------------
__global__ __launch_bounds__(256) void k6_sqk(const unsigned short* __restrict__ SEb,
    const unsigned short* __restrict__ Wpack,
    unsigned short* __restrict__ SQb, unsigned short* __restrict__ SKb){
  int tid=threadIdx.x; int w=tid>>6, lane=tid&63;
  const int hi=lane>>4, lo=lane&15;
  const int row0 = blockIdx.x*16;
  f32x4 acc[3];
  #pragma unroll
  for(int i=0;i<3;i++){ acc[i][0]=0.f; acc[i][1]=0.f; acc[i][2]=0.f; acc[i][3]=0.f; }
  for(int ks=0;ks<16;ks++){
    bf16x8 af = *(const bf16x8*)&SEb[(row0+lo)*512 + ks*32 + hi*8];
    #pragma unroll
    for(int j=0;j<3;j++){
      int ct = w*3+j;
      bf16x8 bf = *(const bf16x8*)&Wpack[((ct*16+ks)<<9) + lane*8];
      acc[j] = __builtin_amdgcn_mfma_f32_16x16x32_bf16(af, bf, acc[j], 0,0,0);
    }
  }
  #pragma unroll
  for(int j=0;j<3;j++){
    int ct = w*3+j;
    int c96 = ((ct<6)? ct : ct-6)*16 + lo;
    int kq = c96>>5, d = c96&31;
    unsigned short* dst = (ct<6)? SQb : SKb;
    #pragma unroll
    for(int r=0;r<4;r++){
      int n = row0 + hi*4 + r;
      int b = n>>10, nl = n&1023;
      dst[((b*3+kq)*1024+nl)*32 + d] = f2b(acc[j][r]);
    }
  }
}

// ---------------- K7: whole-x LDS stage, barrier-free chunk loop ----------------
#define SCALE7 0.17677669529663687f
__global__ __launch_bounds__(256) void k7_spatial(const unsigned short* __restrict__ SQb,
    const unsigned short* __restrict__ SKb, const unsigned* __restrict__ mcT,
    const float* __restrict__ x, float* __restrict__ rhsT){
  const int blk0=blockIdx.x;
  const int blk=(blk0&7)*96 + (blk0>>3);      // XCD-chunked: 768 = 8*96, bijective
  const int mt=blk&15, bk=blk>>4;
  const int k=bk%3, b=bk/3;
  const int m0=mt*64;
  const int tid=threadIdx.x;
  const int w=tid>>6, lane=tid&63, g=lane>>4, col=lane&15;

  __shared__ unsigned short xs[16*1024];

  const float* xb = x + b*12288;
  for(int i=tid;i<2048;i+=256) ((unsigned*)xs)[12*512 + i] = 0u;
  for(int i=tid;i<12288;i+=256){
    int n=i/12, t=i-n*12;
    xs[t*1024 + (n ^ ((t&7)<<3))] = f2b(xb[i]);
  }
  __syncthreads();

  const int m_glob = m0 + w*16 + col;
  bf16x8 bfrag = *(const bf16x8*)&SKb[((bk<<10)+m_glob)*32 + g*8];

  f32x4 O = {0.f,0.f,0.f,0.f};
  float mrun=-1e30f, lrun=0.f;

  const unsigned* mrow = mcT + k*1048576 + m_glob*1024;
  const int swz = (col&7)<<3;

  for(int ch=0; ch<8; ++ch){
    const int n0 = ch<<7;

    f32x4 acc[8];
    #pragma unroll
    for(int nt=0;nt<8;nt++){
      bf16x8 afrag = *(const bf16x8*)&SQb[((bk<<10) + n0 + nt*16 + col)*32 + g*8];
      f32x4 z = {0.f,0.f,0.f,0.f};
      acc[nt] = __builtin_amdgcn_mfma_f32_16x16x32_bf16(afrag, bfrag, z, 0,0,0);
    }
    unsigned mcv[8][4];
    #pragma unroll
    for(int nt=0;nt<8;nt++){
      uint4 mv = *(const uint4*)&mrow[n0 + nt*16 + g*4];
      mcv[nt][0]=mv.x; mcv[nt][1]=mv.y; mcv[nt][2]=mv.z; mcv[nt][3]=mv.w;
    }
    float cmax = -1e30f;
    #pragma unroll
    for(int nt=0;nt<8;nt++){
      #pragma unroll
      for(int r=0;r<4;r++){
        float s = acc[nt][r]*SCALE7 + __uint_as_float(mcv[nt][r]<<16);
        acc[nt][r]=s;
        cmax=fmaxf(cmax,s);
      }
    }
    cmax = fmaxf(cmax, __shfl_xor(cmax,16,64));
    cmax = fmaxf(cmax, __shfl_xor(cmax,32,64));
    float mnew = fmaxf(mrun, cmax);
    float alpha = __expf(mrun - mnew);
    float lsum = 0.f;
    unsigned short pb[8][4];
    #pragma unroll
    for(int nt=0;nt<8;nt++){
      #pragma unroll
      for(int r=0;r<4;r++){
        float e = __expf(acc[nt][r] - mnew);
        lsum += e;
        pb[nt][r] = f2b(e * __uint_as_float(mcv[nt][r] & 0xffff0000u));
      }
    }
    lsum += __shfl_xor(lsum,16,64);
    lsum += __shfl_xor(lsum,32,64);
    lrun = lrun*alpha + lsum;
    mrun = mnew;
    O[0]*=alpha; O[1]*=alpha; O[2]*=alpha; O[3]*=alpha;

    #pragma unroll
    for(int c=0;c<4;c++){
      bf16x8 pf;
      #pragma unroll
      for(int j=0;j<4;j++){ pf[j]=(short)pb[2*c][j]; pf[j+4]=(short)pb[2*c+1][j]; }
      int nlo = n0 + c*32 + g*4;
      bf16x4 lo = *(const bf16x4*)&xs[col*1024 + (nlo ^ swz)];
      bf16x4 hi = *(const bf16x4*)&xs[col*1024 + ((nlo+16) ^ swz)];
      bf16x8 ax;
      #pragma unroll
      for(int j=0;j<4;j++){ ax[j]=lo[j]; ax[j+4]=hi[j]; }
      O = __builtin_amdgcn_mfma_f32_16x16x32_bf16(ax, pf, O, 0,0,0);
    }
  }
  float inv = 1.f/lrun;
  #pragma unroll
  for(int r=0;r<4;r++){
    int t = g*4+r;
    if(t<12) rhsT[((bk*12+t)<<10) + m_glob] = O[r]*inv;
  }
}

// ---------------- K9: conv MFMA -> gated bf16 LDS tile -> fc via MFMA -> residual+LN ----
__global__ __launch_bounds__(256) void k9_final(const float* __restrict__ rhsT, const float* __restrict__ theta,
    const unsigned short* __restrict__ Apack, const unsigned short* __restrict__ fcwB,
    const float* __restrict__ g3b, const float* __restrict__ g5b, const float* __restrict__ g7b,
    const float* __restrict__ fcb,
    const float* __restrict__ rw, const float* __restrict__ rb,
    const float* __restrict__ gln, const float* __restrict__ bln,
    const float* __restrict__ x, float* __restrict__ out){
  int bn0=blockIdx.x*8;
  int tid=threadIdx.x;
  const int b=bn0>>10, n0=bn0&1023;

  __shared__ struct { unsigned short Xl[12*8*64]; float rstage[3][12][8]; } P0;
  __shared__ union {
    unsigned short Gl[4*16*8*24];   // [wave][c_loc][g'][tau]
    float XP[8][772];
  } U;
  __shared__ float xres[8][12];
  __shared__ float mu8[8][12], rs8[8][12];

  for(int i=tid;i<288;i+=256){
    int kk=i/96; int rem=i-kk*96; int t=rem>>3; int g=rem&7;
    P0.rstage[kk][t][g]=rhsT[((b*3+kk)*12+t)*1024 + n0 + g];
  }
  for(int i=tid;i<96;i+=256){ int g=i/12, t=i-(i/12)*12; xres[g][t]=x[(bn0+g)*12+t]; }
  __syncthreads();

  {
    int g=tid>>5, icp=tid&31;
    float th0[3], th1[3];
    #pragma unroll
    for(int kk=0;kk<3;kk++){ th0[kk]=theta[kk*64+2*icp]; th1[kk]=theta[kk*64+2*icp+1]; }
    #pragma unroll
    for(int t=0;t<12;t++){
      float r0=P0.rstage[0][t][g], r1=P0.rstage[1][t][g], r2=P0.rstage[2][t][g];
      float a0=fmaxf(r0*th0[0]+r1*th0[1]+r2*th0[2],0.f);
      float a1=fmaxf(r0*th1[0]+r1*th1[1]+r2*th1[2],0.f);
      unsigned pack = (((unsigned)f2b(a1))<<16)|(unsigned)f2b(a0);
      *(unsigned*)((char*)P0.Xl + ((t*8+g)<<7) + ((icp*4) ^ (g<<4))) = pack;
    }
  }
  __syncthreads();

  const int w=tid>>6, lane=tid&63, halfk=lane>>4, colq=lane&15;
  const int gg=colq&7, tau2=colq>>3;
  const int ca = w*16 + halfk*4;
  const char* xlb = (const char*)P0.Xl;
  unsigned short* Glw = &U.Gl[w*3072];

  #define GATE_STORE(ACCA, ACCB, TB) { \
    _Pragma("unroll") \
    for(int r=0;r<4;r++){ \
      float ya=(ACCA)[r], yb=(ACCB)[r]; \
      float e2=__expf(2.f*ya), eb=__expf(yb); \
      float gval=(e2-1.f)*eb*__frcp_rn((e2+1.f)*(eb+1.f)); \
      int c_loc=halfk*4+r; \
      Glw[c_loc*192 + ((gg ^ (c_loc&7))*24) + (TB)+tau2] = f2b(gval); \
    } }

  // ---- group kappa=3 ----
  {
    f32x4 acA[5], acB[5];
    #pragma unroll
    for(int j=0;j<5;j++)
      #pragma unroll
      for(int r=0;r<4;r++){ acA[j][r]=g3b[ca+r]; acB[j][r]=g3b[64+ca+r]; }
    #pragma unroll
    for(int s=0;s<6;s++){
      bf16x8 a0 = *(const bf16x8*)&Apack[((w  )*6 + s)*512 + lane*8];
      bf16x8 a1 = *(const bf16x8*)&Apack[((w+4)*6 + s)*512 + lane*8];
      int dt=s>>1;
      int sl = ((((s&1)*32 + halfk*8)*2) ^ (gg<<4));
      #pragma unroll
      for(int j=0;j<5;j++){
        int t=2*j+tau2+dt;
        bf16x8 bf = *(const bf16x8*)(xlb + ((t*8+gg)<<7) + sl);
        acA[j] = __builtin_amdgcn_mfma_f32_16x16x32_bf16(a0, bf, acA[j], 0,0,0);
        acB[j] = __builtin_amdgcn_mfma_f32_16x16x32_bf16(a1, bf, acB[j], 0,0,0);
      }
    }
    #pragma unroll
    for(int j=0;j<5;j++) GATE_STORE(acA[j], acB[j], 2*j)
  }
  // ---- group kappa=5 ----
  {
    f32x4 acA[4], acB[4];
    #pragma unroll
    for(int j=0;j<4;j++)
      #pragma unroll
      for(int r=0;r<4;r++){ acA[j][r]=g5b[ca+r]; acB[j][r]=g5b[64+ca+r]; }
    #pragma unroll
    for(int s=0;s<10;s++){
      bf16x8 a0 = *(const bf16x8*)&Apack[(48 + (w  )*10 + s)*512 + lane*8];
      bf16x8 a1 = *(const bf16x8*)&Apack[(48 + (w+4)*10 + s)*512 + lane*8];
      int dt=s>>1;
      int sl = ((((s&1)*32 + halfk*8)*2) ^ (gg<<4));
      #pragma unroll
      for(int j=0;j<4;j++){
        int t=2*j+tau2+dt;
        bf16x8 bf = *(const bf16x8*)(xlb + ((t*8+gg)<<7) + sl);
        acA[j] = __builtin_amdgcn_mfma_f32_16x16x32_bf16(a0, bf, acA[j], 0,0,0);
        acB[j] = __builtin_amdgcn_mfma_f32_16x16x32_bf16(a1, bf, acB[j], 0,0,0);
      }
    }
    #pragma unroll
    for(int j=0;j<4;j++) GATE_STORE(acA[j], acB[j], 10+2*j)
  }
  // ---- group kappa=7 ----
  {
    f32x4 acA[3], acB[3];
    #pragma unroll
    for(int j=0;j<3;j++)
      #pragma unroll
      for(int r=0;r<4;r++){ acA[j][r]=g7b[ca+r]; acB[j][r]=g7b[64+ca+r]; }
    #pragma unroll
    for(int s=0;s<14;s++){
      bf16x8 a0 = *(const bf16x8*)&Apack[(128 + (w  )*14 + s)*512 + lane*8];
      bf16x8 a1 = *(const bf16x8*)&Apack[(128 + (w+4)*14 + s)*512 + lane*8];
      int dt=s>>1;
      int sl = ((((s&1)*32 + halfk*8)*2) ^ (gg<<4));
      #pragma unroll
      for(int j=0;j<3;j++){
        int t=2*j+tau2+dt;
        bf16x8 bf = *(const bf16x8*)(xlb + ((t*8+gg)<<7) + sl);
        acA[j] = __builtin_amdgcn_mfma_f32_16x16x32_bf16(a0, bf, acA[j], 0,0,0);
        acB[j] = __builtin_amdgcn_mfma_f32_16x16x32_bf16(a1, bf, acB[j], 0,0,0);
      }
    }
    #pragma unroll
    for(int j=0;j<3;j++) GATE_STORE(acA[j], acB[j], 18+2*j)
  }
  #undef GATE_STORE

  // ---- fc via MFMA ----
  const int tcol = lane&15, hq = lane>>4;
  const int hm = (hq==3)? 0 : hq;
  bf16x8 b2 = *(const bf16x8*)&fcwB[lane*8];
  float fcbv = (tcol<12)? fcb[tcol] : 0.f;
  f32x4 d2[8];
  #pragma unroll
  for(int g=0; g<8; g++){
    bf16x8 a2 = *(const bf16x8*)&Glw[tcol*192 + ((g ^ (tcol&7))*24) + hm*8];
    f32x4 ini = {fcbv, fcbv, fcbv, fcbv};
    d2[g] = __builtin_amdgcn_mfma_f32_16x16x32_bf16(a2, b2, ini, 0,0,0);
  }
  __syncthreads();

  if(tcol<12){
    float rwa[4], rba[4];
    #pragma unroll
    for(int r=0;r<4;r++){ int c=w*16+hq*4+r; rwa[r]=rw[c]; rba[r]=rb[c]; }
    #pragma unroll
    for(int g=0; g<8; g++){
      float xv=xres[g][tcol];
      #pragma unroll
      for(int r=0;r<4;r++){
        int c=w*16+hq*4+r;
        float tv = fmaxf(d2[g][r], 0.f);
        float xr = xv*rwa[r]+rba[r];
        U.XP[g][c*12+tcol] = fmaxf(xr+tv, 0.f);
      }
    }
  }
  __syncthreads();

  if(tid<192){
    int p=tid>>1, h=tid&1;
    int g=p/12, t=p-(p/12)*12;
    float s=0.f;
    for(int c=h*32;c<h*32+32;c++) s+=U.XP[g][c*12+t];
    s += __shfl_xor(s,1,64);
    float mu=s*(1.f/64.f);
    float q=0.f;
    for(int c=h*32;c<h*32+32;c++){float d=U.XP[g][c*12+t]-mu;q+=d*d;}
    q += __shfl_xor(q,1,64);
    if(h==0){ mu8[g][t]=mu; rs8[g][t]=rsqrtf(q*(1.f/64.f)+EPS); }
  }
  __syncthreads();
  for(int o=tid;o<1536;o+=256){
    int g=o/192; int q4=o-g*192;
    int c=q4/3; int tb=(q4-c*3)*4;
    float4 vv = *(const float4*)&U.XP[g][c*12+tb];
    float gl=gln[c], bl=bln[c];
    float4 ov;
    ov.x=(vv.x-mu8[g][tb+0])*rs8[g][tb+0]*gl+bl;
    ov.y=(vv.y-mu8[g][tb+1])*rs8[g][tb+1]*gl+bl;
    ov.z=(vv.z-mu8[g][tb+2])*rs8[g][tb+2]*gl+bl;
    ov.w=(vv.w-mu8[g][tb+3])*rs8[g][tb+3]*gl+bl;
    *(float4*)&out[(long)(bn0+g)*768 + c*12 + tb] = ov;
  }
}

// ---------------- launch ----------------
extern "C" void kernel_launch(void* const* d_in, const int* in_sizes, int n_in,
                              void* d_out, int out_size, void* d_ws, size_t ws_size,
                              hipStream_t stream){
  const float* x    =(const float*)d_in[0];
  const float* res  =(const float*)d_in[1];
  const float* posT =(const float*)d_in[2];
  const float* gT   =(const float*)d_in[3];
  const float* bT   =(const float*)d_in[4];
  const float* wq   =(const float*)d_in[5];
  const float* wk   =(const float*)d_in[6];
  const float* wv   =(const float*)d_in[7];
  const float* fcW  =(const float*)d_in[8];
  const float* prw  =(const float*)d_in[9];
  const float* prb  =(const float*)d_in[10];
  const float* posS =(const float*)d_in[11];
  const float* gS   =(const float*)d_in[12];
  const float* bS   =(const float*)d_in[13];
  const float* swq  =(const float*)d_in[14];
  const float* swk  =(const float*)d_in[15];
  const float* cheb =(const float*)d_in[16];
  const float* adj  =(const float*)d_in[17];
  const float* cmask=(const float*)d_in[18];
  const float* theta=(const float*)d_in[19];
  const float* g3w=(const float*)d_in[20]; const float* g3b=(const float*)d_in[21];
  const float* g5w=(const float*)d_in[22]; const float* g5b=(const float*)d_in[23];
  const float* g7w=(const float*)d_in[24]; const float* g7b=(const float*)d_in[25];
  const float* fcw=(const float*)d_in[26]; const float* fcb=(const float*)d_in[27];
  const float* rw =(const float*)d_in[28]; const float* rb =(const float*)d_in[29];
  const float* gln=(const float*)d_in[30]; const float* bln=(const float*)d_in[31];

  float* outp=(float*)d_out;
  float* scores = outp + 12582912;

  float* wsf=(float*)d_ws;
  float* TEmx = wsf;                          // 196608 f
  float* qkv  = TEmx + 196608;                // 55296 f
  float* TATpre = qkv + 55296;                // 196608 f
  unsigned short* SEb = (unsigned short*)(TATpre + 196608);      // 4194304 f
  unsigned short* SQb = (unsigned short*)((float*)SEb + 4194304); // 786432 f
  unsigned short* SKb = (unsigned short*)((float*)SQb + 786432);  // 786432 f
  unsigned* mcT = (unsigned*)((float*)SKb + 786432);              // 3145728 f
  float* rhsT  = (float*)mcT + 3145728;                           // 589824 f
  unsigned short* Apack = (unsigned short*)(rhsT + 589824);       // 122880 u16
  unsigned short* Wpack = Apack + 122880;                         // 98304 u16
  unsigned short* Wpack2 = Wpack + 98304;                         // 294912 u16
  unsigned short* TEb = Wpack2 + 294912;                          // 196608 u16
  unsigned short* fcwB = TEb + 196608;                            // 512 u16
  unsigned short* ctxb = fcwB + 512;                              // 18432 u16
  unsigned short* fcWB2 = ctxb + 18432;                           // 98304 u16
  float* muT = (float*)(fcWB2 + 98304);                           // 192 f
  float* rsT = muT + 192;                                         // 192 f

  kb0_prep<<<dim3(768),dim3(256),0,stream>>>(adj,cmask,cheb,mcT);
  kprep<<<dim3(301),dim3(256),0,stream>>>(g3w,g5w,g7w,swq,swk,wq,wk,wv,fcw,fcW,
                                          Apack,Wpack,Wpack2,fcwB,fcWB2);
  k1_embedT<<<dim3(192),dim3(256),0,stream>>>(x,posT,gT,bT,TEmx,TEb);
  k2_qkv<<<dim3(216),dim3(256),0,stream>>>(TEb,Wpack2,qkv);
  k3_attn<<<dim3(16),dim3(512),0,stream>>>(qkv,res,scores,ctxb);
  k4a_mm<<<dim3(192),dim3(256),0,stream>>>(ctxb,fcWB2,TEmx,TATpre);
  k4b_stats<<<dim3(192),dim3(256),0,stream>>>(TATpre,muT,rsT);
  k5_semx<<<dim3(2048),dim3(256),0,stream>>>(TATpre,muT,rsT,prw,prb,posS,gS,bS,SEb);
  k6_sqk<<<dim3(1024),dim3(256),0,stream>>>(SEb,Wpack,SQb,SKb);
  k7_spatial<<<dim3(768),dim3(256),0,stream>>>(SQb,SKb,mcT,x,rhsT);
  k9_final<<<dim3(2048),dim3(256),0,stream>>>(rhsT,theta,Apack,fcwB,g3b,g5b,g7b,
                                              fcb,rw,rb,gln,bln,x,outp);
}

// Round 13
// 144.899 us; speedup vs baseline: 10.3757x; 1.0891x over previous
//
#include <hip/hip_runtime.h>
#include <hip/hip_fp16.h>

#define EPS 1e-5f

typedef float f32x4 __attribute__((ext_vector_type(4)));
typedef short bf16x8 __attribute__((ext_vector_type(8)));
typedef short bf16x4 __attribute__((ext_vector_type(4)));

__device__ __forceinline__ unsigned short f2b(float f){
  unsigned u=__float_as_uint(f);
  return (unsigned short)((u + 0x7fffu + ((u>>16)&1u))>>16);
}
__device__ __forceinline__ float b2f(unsigned short h){
  return __uint_as_float(((unsigned)h)<<16);
}

// ---------------- helpers ----------------
__device__ __forceinline__ float blockSum256(float v, float* red){
  #pragma unroll
  for(int o=32;o>0;o>>=1) v += __shfl_down(v,o,64);
  int wid = threadIdx.x>>6;
  if((threadIdx.x&63)==0) red[wid]=v;
  __syncthreads();
  if(threadIdx.x==0) red[0]=red[0]+red[1]+red[2]+red[3];
  __syncthreads();
  float r = red[0];
  __syncthreads();
  return r;
}

// ---------------- KB0: pack mask/cheb TRANSPOSED: mcT[k][m][n] ----------------
__global__ __launch_bounds__(256) void kb0_prep(const float* __restrict__ adj, const float* __restrict__ cmask,
    const float* __restrict__ cheb, unsigned* __restrict__ mcT){
  int blk=blockIdx.x;                 // k*256 + tn*16 + tm
  int k=blk>>8; int rem=blk&255; int tn=rem>>4, tm=rem&15;
  int tid=threadIdx.x;
  __shared__ unsigned tile[64][65];
  const float* chk = cheb + k*1048576;
  const float* cmk = cmask + k*1048576;
  for(int i=tid;i<4096;i+=256){
    int ln=i>>6, lm=i&63;
    int n=tn*64+ln, m=tm*64+lm;
    int nm=n*1024+m;
    tile[ln][lm] = (((unsigned)f2b(chk[nm]))<<16) | (unsigned)f2b(adj[nm]*cmk[nm]);
  }
  __syncthreads();
  unsigned* dst = mcT + k*1048576;
  for(int i=tid;i<4096;i+=256){
    int lm=i>>6, ln=i&63;
    dst[(tm*64+lm)*1024 + tn*64+ln] = tile[ln][lm];
  }
}

// ---------------- KPREP: fused weight packing (Apack | Wpack | Wpack2 | fcwB | fcWB2) ----------------
__global__ __launch_bounds__(256) void kprep(const float* __restrict__ g3w, const float* __restrict__ g5w,
    const float* __restrict__ g7w, const float* __restrict__ swq, const float* __restrict__ swk,
    const float* __restrict__ wq, const float* __restrict__ wk, const float* __restrict__ wv,
    const float* __restrict__ fcw, const float* __restrict__ fcW,
    unsigned short* __restrict__ Apack, unsigned short* __restrict__ Wpack,
    unsigned short* __restrict__ Wpack2, unsigned short* __restrict__ fcwB,
    unsigned short* __restrict__ fcWB2){
  int idx = blockIdx.x*256+threadIdx.x;
  if(idx<15360){                                   // Apack (conv A-frags, bf16)
    int frag=idx>>6, lane=idx&63;
    int rt, s, kappa; const float* W;
    if(frag<48){ rt=frag/6; s=frag-rt*6; kappa=3; W=g3w; }
    else if(frag<128){ int f=frag-48; rt=f/10; s=f-rt*10; kappa=5; W=g5w; }
    else { int f=frag-128; rt=f/14; s=f-rt*14; kappa=7; W=g7w; }
    int c = rt*16 + (lane&15);
    int dt = s>>1, ic0=(s&1)*32 + (lane>>4)*8;
    #pragma unroll
    for(int j=0;j<8;j++) Apack[idx*8+j]=f2b(W[(c*64+ic0+j)*kappa + dt]);
  } else if(idx<27648){                            // Wpack (swq/swk B-frags)
    int id2=idx-15360;
    int frag=id2>>6, lane=id2&63;
    int ct=frag>>4, ks=frag&15;
    const float* W = (ct<6)? swq : swk;
    int c = ((ct<6)? ct : ct-6)*16 + (lane&15);
    int k0 = ks*32 + (lane>>4)*8;
    #pragma unroll
    for(int j=0;j<8;j++) Wpack[id2*8+j]=f2b(W[(k0+j)*96 + c]);
  } else if(idx<64512){                            // Wpack2 (wq|wk|wv B-frags)
    int id2=idx-27648;
    int frag=id2>>6, lane=id2&63;
    int ct=frag>>5, ks=frag&31;
    int cg = ct*16 + (lane&15);
    const float* W; int c;
    if(cg<96){ W=wq; c=cg; } else if(cg<192){ W=wk; c=cg-96; } else { W=wv; c=cg-192; }
    int k0 = ks*32 + (lane>>4)*8;
    #pragma unroll
    for(int j=0;j<8;j++) Wpack2[id2*8+j]=f2b(W[(k0+j)*96 + c]);
  } else if(idx<64576){                            // fcwB (bf16)
    int lane=idx-64512;
    int t=lane&15, hq=lane>>4;
    #pragma unroll
    for(int j=0;j<8;j++){
      int tau=hq*8+j;
      fcwB[lane*8+j] = (tau<24 && t<12) ? f2b(fcw[tau*12+t]) : (unsigned short)0;
    }
  } else if(idx<76864){                            // fcWB2 (fcW B-frags: 64 ct x 3 ks)
    int id3=idx-64576;
    int frag=id3>>6, lane=id3&63;
    int ct=frag/3, ks=frag-ct*3;
    int c = ct*16 + (lane&15);
    int k0 = ks*32 + (lane>>4)*8;
    #pragma unroll
    for(int j=0;j<8;j++) fcWB2[id3*8+j]=f2b(fcW[(k0+j)*1024 + c]);
  }
}

// ---------------- K1: EmbedT (fp32 + bf16 outputs) ----------------
__global__ __launch_bounds__(256) void k1_embedT(const float* __restrict__ x, const float* __restrict__ posT,
    const float* __restrict__ gT, const float* __restrict__ bT, float* __restrict__ TEmx,
    unsigned short* __restrict__ TEb){
  int bt=blockIdx.x; int b=bt/12, t=bt-b*12;
  int tid=threadIdx.x;
  __shared__ float red[4];
  float v[4]; float s=0.f;
  #pragma unroll
  for(int i=0;i<4;i++){ int n=tid+i*256; v[i]=x[(b*1024+n)*12+t]+posT[t*1024+n]; s+=v[i]; }
  s = blockSum256(s, red);
  float mu = s*(1.f/1024.f);
  float q=0.f;
  #pragma unroll
  for(int i=0;i<4;i++){ float d=v[i]-mu; q+=d*d; }
  q = blockSum256(q, red);
  float rstd = rsqrtf(q*(1.f/1024.f)+EPS);
  #pragma unroll
  for(int i=0;i<4;i++){
    int n=tid+i*256;
    float val=(v[i]-mu)*rstd*gT[n]+bT[n];
    TEmx[bt*1024+n]=val;
    TEb[bt*1024+n]=f2b(val);
  }
}

// ---------------- K2: QKV via MFMA split-K GEMM ----------------
__global__ __launch_bounds__(256) void k2_qkv(const unsigned short* __restrict__ TEb,
    const unsigned short* __restrict__ Wpack2, float* __restrict__ qkv){
  int tid=threadIdx.x; int w=tid>>6, lane=tid&63;
  const int hi=lane>>4, lo=lane&15;
  const int rt=blockIdx.x/18, ct=blockIdx.x-rt*18;
  __shared__ float red[4][16][16];
  f32x4 acc={0.f,0.f,0.f,0.f};
  #pragma unroll
  for(int s=0;s<8;s++){
    int ks=w*8+s;
    bf16x8 af = *(const bf16x8*)&TEb[(rt*16+lo)*1024 + ks*32 + hi*8];
    bf16x8 bf = *(const bf16x8*)&Wpack2[((ct*32+ks)<<9) + lane*8];
    acc = __builtin_amdgcn_mfma_f32_16x16x32_bf16(af, bf, acc, 0,0,0);
  }
  #pragma unroll
  for(int r=0;r<4;r++) red[w][hi*4+r][lo]=acc[r];
  __syncthreads();
  int r16=tid>>4, c16=tid&15;
  float s = red[0][r16][c16]+red[1][r16][c16]+red[2][r16][c16]+red[3][r16][c16];
  qkv[(rt*16+r16)*288 + ct*16 + c16] = s;
}

// ---------------- K3 v2: temporal attn, 48 blocks (b,h) ----------------
__global__ __launch_bounds__(256) void k3_attn(const float* __restrict__ qkv, const float* __restrict__ res_att,
    float* __restrict__ scores_out, unsigned short* __restrict__ ctxb){
  int bh=blockIdx.x; int b=bh/3, h=bh-(bh/3)*3;
  int tid=threadIdx.x;
  __shared__ float sS[144];
  __shared__ float sA[144];
  if(tid<144){
    int q=tid/12;
    const float* Qr=&qkv[(b*12+q)*288 + h*32];
    const float* Kr=&qkv[(b*12+(tid-q*12))*288 + 96 + h*32];
    float acc=0.f;
    #pragma unroll
    for(int d=0;d<32;d++) acc+=Qr[d]*Kr[d];
    acc = acc*0.17677669529663687f + res_att[bh*144 + tid];
    sS[tid]=acc;
    scores_out[bh*144 + tid]=acc;
  }
  __syncthreads();
  if(tid<12){
    int k2=tid;
    float mx=-1e30f;
    for(int q=0;q<12;q++) mx=fmaxf(mx,sS[q*12+k2]);
    float sum=0.f;
    for(int q=0;q<12;q++){ float e=__expf(sS[q*12+k2]-mx); sA[q*12+k2]=e; sum+=e; }
    float inv=1.f/sum;
    for(int q=0;q<12;q++) sA[q*12+k2]*=inv;
  }
  __syncthreads();
  for(int o=tid;o<384;o+=256){
    int q=o>>5, d=o&31;
    float acc=0.f;
    #pragma unroll
    for(int k2=0;k2<12;k2++) acc += sA[q*12+k2]*qkv[(b*12+k2)*288+192+h*32+d];
    ctxb[(b*12+q)*96 + h*32 + d]=f2b(acc);
  }
}

// ---------------- K4a: TATpre = ctx@fcW + TEmx via MFMA ----------------
__global__ __launch_bounds__(256) void k4a_mm(const unsigned short* __restrict__ ctxb,
    const unsigned short* __restrict__ fcWB2, const float* __restrict__ TEmx,
    float* __restrict__ TATpre){
  int tid=threadIdx.x; int w=tid>>6, lane=tid&63;
  const int hi=lane>>4, lo=lane&15;
  const int rt=blockIdx.x>>4, cg=blockIdx.x&15;
  const int ct=cg*4+w;
  f32x4 acc={0.f,0.f,0.f,0.f};
  #pragma unroll
  for(int ks=0;ks<3;ks++){
    bf16x8 af = *(const bf16x8*)&ctxb[(rt*16+lo)*96 + ks*32 + hi*8];
    bf16x8 bf = *(const bf16x8*)&fcWB2[((ct*3+ks)<<9) + lane*8];
    acc = __builtin_amdgcn_mfma_f32_16x16x32_bf16(af, bf, acc, 0,0,0);
  }
  #pragma unroll
  for(int r=0;r<4;r++){
    int row = rt*16 + hi*4 + r;
    int coln = ct*16 + lo;
    TATpre[row*1024+coln] = acc[r] + TEmx[row*1024+coln];
  }
}

// ---------------- K4b: per-row LN stats ----------------
__global__ __launch_bounds__(256) void k4b_stats(const float* __restrict__ TATpre,
    float* __restrict__ muT, float* __restrict__ rsT){
  int bt=blockIdx.x; int tid=threadIdx.x;
  __shared__ float red[4];
  const float* row=&TATpre[bt*1024];
  float a0=row[tid], a1=row[tid+256], a2=row[tid+512], a3=row[tid+768];
  float s=a0+a1+a2+a3;
  s=blockSum256(s,red);
  float mu=s*(1.f/1024.f);
  float q=(a0-mu)*(a0-mu)+(a1-mu)*(a1-mu)+(a2-mu)*(a2-mu)+(a3-mu)*(a3-mu);
  q=blockSum256(q,red);
  if(tid==0){ muT[bt]=mu; rsT[bt]=rsqrtf(q*(1.f/1024.f)+EPS); }
}

// ---------------- K5: SEmx, 8 rows/block; LN applied on tv load ----------------
__global__ __launch_bounds__(256) void k5_semx(const float* __restrict__ TATpre,
    const float* __restrict__ muT, const float* __restrict__ rsT,
    const float* __restrict__ pre_w,
    const float* __restrict__ pre_b, const float* __restrict__ posS, const float* __restrict__ gS,
    const float* __restrict__ bS, unsigned short* __restrict__ SEb){
  int bn0=blockIdx.x*8; int b=bn0>>10, n0=bn0&1023; int tid=threadIdx.x;
  __shared__ float tv[12][8];
  __shared__ float ps[8][264];
  __shared__ float pq[8][264];
  __shared__ float mur[8], rsr[8];
  if(tid<96){
    int r=tid&7, t=tid>>3;
    int bt=b*12+t;
    tv[t][r]=(TATpre[bt*1024+n0+r]-muT[bt])*rsT[bt];
  }
  __syncthreads();
  const int d0=tid, d1=tid+256;
  float w0[12], w1[12];
  {
    const float4* p0=(const float4*)&pre_w[d0*12];
    float4 a=p0[0], bb=p0[1], c=p0[2];
    w0[0]=a.x;w0[1]=a.y;w0[2]=a.z;w0[3]=a.w; w0[4]=bb.x;w0[5]=bb.y;w0[6]=bb.z;w0[7]=bb.w;
    w0[8]=c.x;w0[9]=c.y;w0[10]=c.z;w0[11]=c.w;
    const float4* p1=(const float4*)&pre_w[d1*12];
    float4 d=p1[0], e=p1[1], f=p1[2];
    w1[0]=d.x;w1[1]=d.y;w1[2]=d.z;w1[3]=d.w; w1[4]=e.x;w1[5]=e.y;w1[6]=e.z;w1[7]=e.w;
    w1[8]=f.x;w1[9]=f.y;w1[10]=f.z;w1[11]=f.w;
  }
  float pb0=pre_b[d0], pb1=pre_b[d1];
  float v0[8], v1[8];
  #pragma unroll
  for(int r=0;r<8;r++){
    float acc0=pb0 + posS[(n0+r)*512+d0];
    float acc1=pb1 + posS[(n0+r)*512+d1];
    #pragma unroll
    for(int t=0;t<12;t++){ float tvv=tv[t][r]; acc0+=tvv*w0[t]; acc1+=tvv*w1[t]; }
    v0[r]=acc0; v1[r]=acc1;
    ps[r][tid]=acc0+acc1;
    pq[r][tid]=acc0*acc0+acc1*acc1;
  }
  __syncthreads();
  {
    int row=tid>>5, l32=tid&31;
    float s=0.f, q=0.f;
    #pragma unroll
    for(int j=0;j<8;j++){ s+=ps[row][l32+j*32]; q+=pq[row][l32+j*32]; }
    #pragma unroll
    for(int o=16;o>=1;o>>=1){ s+=__shfl_xor(s,o,64); q+=__shfl_xor(q,o,64); }
    if(l32==0){
      float mu=s*(1.f/512.f);
      float var=q*(1.f/512.f)-mu*mu;
      mur[row]=mu; rsr[row]=rsqrtf(var+EPS);
    }
  }
  __syncthreads();
  float g0=gS[d0], b0v=bS[d0], g1=gS[d1], b1v=bS[d1];
  #pragma unroll
  for(int r=0;r<8;r++){
    float mu=mur[r], rs=rsr[r];
    SEb[(bn0+r)*512 + d0] = f2b((v0[r]-mu)*rs*g0+b0v);
    SEb[(bn0+r)*512 + d1] = f2b((v1[r]-mu)*rs*g1+b1v);
  }
}

// ---------------- K6: SQ/SK via MFMA GEMM, 16 rows/block; af prefetch ----------------
__global__ __launch_bounds__(256) void k6_sqk(const unsigned short* __restrict__ SEb,
    const unsigned short* __restrict__ Wpack,
    unsigned short* __restrict__ SQb, unsigned short* __restrict__ SKb){
  int tid=threadIdx.x; int w=tid>>6, lane=tid&63;
  const int hi=lane>>4, lo=lane&15;
  const int row0 = blockIdx.x*16;
  f32x4 acc[3];
  #pragma unroll
  for(int i=0;i<3;i++){ acc[i][0]=0.f; acc[i][1]=0.f; acc[i][2]=0.f; acc[i][3]=0.f; }
  const unsigned short* arow = &SEb[(row0+lo)*512 + hi*8];
  bf16x8 afc = *(const bf16x8*)&arow[0];
  #pragma unroll
  for(int ks=0;ks<16;ks++){
    bf16x8 afn;
    if(ks<15) afn = *(const bf16x8*)&arow[(ks+1)*32];
    #pragma unroll
    for(int j=0;j<3;j++){
      int ct = w*3+j;
      bf16x8 bf = *(const bf16x8*)&Wpack[((ct*16+ks)<<9) + lane*8];
      acc[j] = __builtin_amdgcn_mfma_f32_16x16x32_bf16(afc, bf, acc[j], 0,0,0);
    }
    if(ks<15) afc = afn;
  }
  #pragma unroll
  for(int j=0;j<3;j++){
    int ct = w*3+j;
    int c96 = ((ct<6)? ct : ct-6)*16 + lo;
    int kq = c96>>5, d = c96&31;
    unsigned short* dst = (ct<6)? SQb : SKb;
    #pragma unroll
    for(int r=0;r<4;r++){
      int n = row0 + hi*4 + r;
      int b = n>>10, nl = n&1023;
      dst[((b*3+kq)*1024+nl)*32 + d] = f2b(acc[j][r]);
    }
  }
}

// ---------------- K7: whole-x LDS stage; mask+A-frag register double-buffer ----------------
#define SCALE7 0.17677669529663687f
__global__ __launch_bounds__(256) void k7_spatial(const unsigned short* __restrict__ SQb,
    const unsigned short* __restrict__ SKb, const unsigned* __restrict__ mcT,
    const float* __restrict__ x, float* __restrict__ rhsT){
  const int blk0=blockIdx.x;
  const int blk=(blk0&7)*96 + (blk0>>3);      // XCD-chunked: 768 = 8*96, bijective
  const int mt=blk&15, bk=blk>>4;
  const int k=bk%3, b=bk/3;
  const int m0=mt*64;
  const int tid=threadIdx.x;
  const int w=tid>>6, lane=tid&63, g=lane>>4, col=lane&15;

  __shared__ unsigned short xs[16*1024];

  const float* xb = x + b*12288;
  for(int i=tid;i<2048;i+=256) ((unsigned*)xs)[12*512 + i] = 0u;
  for(int i=tid;i<12288;i+=256){
    int n=i/12, t=i-n*12;
    xs[t*1024 + (n ^ ((t&7)<<3))] = f2b(xb[i]);
  }
  __syncthreads();

  const int m_glob = m0 + w*16 + col;
  bf16x8 bfrag = *(const bf16x8*)&SKb[((bk<<10)+m_glob)*32 + g*8];

  f32x4 O = {0.f,0.f,0.f,0.f};
  float mrun=-1e30f, lrun=0.f;

  const unsigned* mrow = mcT + k*1048576 + m_glob*1024;
  const unsigned short* sqbase = &SQb[((bk<<10)+col)*32 + g*8];
  const int swz = (col&7)<<3;

  // prefetch chunk 0
  uint4 mvc[8]; bf16x8 afc[8];
  #pragma unroll
  for(int nt=0;nt<8;nt++){
    mvc[nt] = *(const uint4*)&mrow[nt*16 + g*4];
    afc[nt] = *(const bf16x8*)&sqbase[(nt*16)*32];
  }

  #pragma unroll
  for(int ch=0; ch<8; ++ch){
    const int n0 = ch<<7;
    uint4 mvn[8]; bf16x8 afn[8];
    #pragma unroll
    for(int nt=0;nt<8;nt++){
      if(ch<7){
        mvn[nt] = *(const uint4*)&mrow[n0+128 + nt*16 + g*4];
        afn[nt] = *(const bf16x8*)&sqbase[(n0+128 + nt*16)*32];
      }
    }

    f32x4 acc[8];
    #pragma unroll
    for(int nt=0;nt<8;nt++){
      f32x4 z = {0.f,0.f,0.f,0.f};
      acc[nt] = __builtin_amdgcn_mfma_f32_16x16x32_bf16(afc[nt], bfrag, z, 0,0,0);
    }
    float cmax = -1e30f;
    #pragma unroll
    for(int nt=0;nt<8;nt++){
      #pragma unroll
      for(int r=0;r<4;r++){
        unsigned mv = (r==0)?mvc[nt].x:((r==1)?mvc[nt].y:((r==2)?mvc[nt].z:mvc[nt].w));
        float s = acc[nt][r]*SCALE7 + __uint_as_float(mv<<16);
        acc[nt][r]=s;
        cmax=fmaxf(cmax,s);
      }
    }
    cmax = fmaxf(cmax, __shfl_xor(cmax,16,64));
    cmax = fmaxf(cmax, __shfl_xor(cmax,32,64));
    float mnew = fmaxf(mrun, cmax);
    float alpha = __expf(mrun - mnew);
    float lsum = 0.f;
    unsigned short pb[8][4];
    #pragma unroll
    for(int nt=0;nt<8;nt++){
      #pragma unroll
      for(int r=0;r<4;r++){
        unsigned mv = (r==0)?mvc[nt].x:((r==1)?mvc[nt].y:((r==2)?mvc[nt].z:mvc[nt].w));
        float e = __expf(acc[nt][r] - mnew);
        lsum += e;
        pb[nt][r] = f2b(e * __uint_as_float(mv & 0xffff0000u));
      }
    }
    lsum += __shfl_xor(lsum,16,64);
    lsum += __shfl_xor(lsum,32,64);
    lrun = lrun*alpha + lsum;
    mrun = mnew;
    O[0]*=alpha; O[1]*=alpha; O[2]*=alpha; O[3]*=alpha;

    #pragma unroll
    for(int c=0;c<4;c++){
      bf16x8 pf;
      #pragma unroll
      for(int j=0;j<4;j++){ pf[j]=(short)pb[2*c][j]; pf[j+4]=(short)pb[2*c+1][j]; }
      int nlo = n0 + c*32 + g*4;
      bf16x4 lo = *(const bf16x4*)&xs[col*1024 + (nlo ^ swz)];
      bf16x4 hi = *(const bf16x4*)&xs[col*1024 + ((nlo+16) ^ swz)];
      bf16x8 ax;
      #pragma unroll
      for(int j=0;j<4;j++){ ax[j]=lo[j]; ax[j+4]=hi[j]; }
      O = __builtin_amdgcn_mfma_f32_16x16x32_bf16(ax, pf, O, 0,0,0);
    }
    #pragma unroll
    for(int nt=0;nt<8;nt++){
      if(ch<7){ mvc[nt]=mvn[nt]; afc[nt]=afn[nt]; }
    }
  }
  float inv = 1.f/lrun;
  #pragma unroll
  for(int r=0;r<4;r++){
    int t = g*4+r;
    if(t<12) rhsT[((bk*12+t)<<10) + m_glob] = O[r]*inv;
  }
}

// ---------------- K9: conv MFMA (A-frag prefetch) -> gated LDS -> fc MFMA -> residual+LN ----
__global__ __launch_bounds__(256) void k9_final(const float* __restrict__ rhsT, const float* __restrict__ theta,
    const unsigned short* __restrict__ Apack, const unsigned short* __restrict__ fcwB,
    const float* __restrict__ g3b, const float* __restrict__ g5b, const float* __restrict__ g7b,
    const float* __restrict__ fcb,
    const float* __restrict__ rw, const float* __restrict__ rb,
    const float* __restrict__ gln, const float* __restrict__ bln,
    const float* __restrict__ x, float* __restrict__ out){
  int bn0=blockIdx.x*8;
  int tid=threadIdx.x;
  const int b=bn0>>10, n0=bn0&1023;

  __shared__ struct { unsigned short Xl[12*8*64]; float rstage[3][12][8]; } P0;
  __shared__ union {
    unsigned short Gl[4*16*8*24];   // [wave][c_loc][g'][tau]
    float XP[8][772];
  } U;
  __shared__ float xres[8][12];
  __shared__ float mu8[8][12], rs8[8][12];

  for(int i=tid;i<288;i+=256){
    int kk=i/96; int rem=i-kk*96; int t=rem>>3; int g=rem&7;
    P0.rstage[kk][t][g]=rhsT[((b*3+kk)*12+t)*1024 + n0 + g];
  }
  for(int i=tid;i<96;i+=256){ int g=i/12, t=i-(i/12)*12; xres[g][t]=x[(bn0+g)*12+t]; }
  __syncthreads();

  {
    int g=tid>>5, icp=tid&31;
    float th0[3], th1[3];
    #pragma unroll
    for(int kk=0;kk<3;kk++){ th0[kk]=theta[kk*64+2*icp]; th1[kk]=theta[kk*64+2*icp+1]; }
    #pragma unroll
    for(int t=0;t<12;t++){
      float r0=P0.rstage[0][t][g], r1=P0.rstage[1][t][g], r2=P0.rstage[2][t][g];
      float a0=fmaxf(r0*th0[0]+r1*th0[1]+r2*th0[2],0.f);
      float a1=fmaxf(r0*th1[0]+r1*th1[1]+r2*th1[2],0.f);
      unsigned pack = (((unsigned)f2b(a1))<<16)|(unsigned)f2b(a0);
      *(unsigned*)((char*)P0.Xl + ((t*8+g)<<7) + ((icp*4) ^ (g<<4))) = pack;
    }
  }
  __syncthreads();

  const int w=tid>>6, lane=tid&63, halfk=lane>>4, colq=lane&15;
  const int gg=colq&7, tau2=colq>>3;
  const int ca = w*16 + halfk*4;
  const char* xlb = (const char*)P0.Xl;
  unsigned short* Glw = &U.Gl[w*3072];

  #define GATE_STORE(ACCA, ACCB, TB) { \
    _Pragma("unroll") \
    for(int r=0;r<4;r++){ \
      float ya=(ACCA)[r], yb=(ACCB)[r]; \
      float e2=__expf(2.f*ya), eb=__expf(yb); \
      float gval=(e2-1.f)*eb*__frcp_rn((e2+1.f)*(eb+1.f)); \
      int c_loc=halfk*4+r; \
      Glw[c_loc*192 + ((gg ^ (c_loc&7))*24) + (TB)+tau2] = f2b(gval); \
    } }

  // ---- group kappa=3 (6 K-steps, 5 col-tiles) ----
  {
    f32x4 acA[5], acB[5];
    #pragma unroll
    for(int j=0;j<5;j++)
      #pragma unroll
      for(int r=0;r<4;r++){ acA[j][r]=g3b[ca+r]; acB[j][r]=g3b[64+ca+r]; }
    const unsigned short* ap0=&Apack[((w  )*6)*512 + lane*8];
    const unsigned short* ap1=&Apack[((w+4)*6)*512 + lane*8];
    bf16x8 a0c=*(const bf16x8*)&ap0[0];
    bf16x8 a1c=*(const bf16x8*)&ap1[0];
    #pragma unroll
    for(int s=0;s<6;s++){
      bf16x8 a0n, a1n;
      if(s<5){ a0n=*(const bf16x8*)&ap0[(s+1)*512]; a1n=*(const bf16x8*)&ap1[(s+1)*512]; }
      int dt=s>>1;
      int sl = ((((s&1)*32 + halfk*8)*2) ^ (gg<<4));
      #pragma unroll
      for(int j=0;j<5;j++){
        int t=2*j+tau2+dt;
        bf16x8 bf = *(const bf16x8*)(xlb + ((t*8+gg)<<7) + sl);
        acA[j] = __builtin_amdgcn_mfma_f32_16x16x32_bf16(a0c, bf, acA[j], 0,0,0);
        acB[j] = __builtin_amdgcn_mfma_f32_16x16x32_bf16(a1c, bf, acB[j], 0,0,0);
      }
      if(s<5){ a0c=a0n; a1c=a1n; }
    }
    #pragma unroll
    for(int j=0;j<5;j++) GATE_STORE(acA[j], acB[j], 2*j)
  }
  // ---- group kappa=5 (10 K-steps, 4 col-tiles) ----
  {
    f32x4 acA[4], acB[4];
    #pragma unroll
    for(int j=0;j<4;j++)
      #pragma unroll
      for(int r=0;r<4;r++){ acA[j][r]=g5b[ca+r]; acB[j][r]=g5b[64+ca+r]; }
    const unsigned short* ap0=&Apack[(48 + (w  )*10)*512 + lane*8];
    const unsigned short* ap1=&Apack[(48 + (w+4)*10)*512 + lane*8];
    bf16x8 a0c=*(const bf16x8*)&ap0[0];
    bf16x8 a1c=*(const bf16x8*)&ap1[0];
    #pragma unroll
    for(int s=0;s<10;s++){
      bf16x8 a0n, a1n;
      if(s<9){ a0n=*(const bf16x8*)&ap0[(s+1)*512]; a1n=*(const bf16x8*)&ap1[(s+1)*512]; }
      int dt=s>>1;
      int sl = ((((s&1)*32 + halfk*8)*2) ^ (gg<<4));
      #pragma unroll
      for(int j=0;j<4;j++){
        int t=2*j+tau2+dt;
        bf16x8 bf = *(const bf16x8*)(xlb + ((t*8+gg)<<7) + sl);
        acA[j] = __builtin_amdgcn_mfma_f32_16x16x32_bf16(a0c, bf, acA[j], 0,0,0);
        acB[j] = __builtin_amdgcn_mfma_f32_16x16x32_bf16(a1c, bf, acB[j], 0,0,0);
      }
      if(s<9){ a0c=a0n; a1c=a1n; }
    }
    #pragma unroll
    for(int j=0;j<4;j++) GATE_STORE(acA[j], acB[j], 10+2*j)
  }
  // ---- group kappa=7 (14 K-steps, 3 col-tiles) ----
  {
    f32x4 acA[3], acB[3];
    #pragma unroll
    for(int j=0;j<3;j++)
      #pragma unroll
      for(int r=0;r<4;r++){ acA[j][r]=g7b[ca+r]; acB[j][r]=g7b[64+ca+r]; }
    const unsigned short* ap0=&Apack[(128 + (w  )*14)*512 + lane*8];
    const unsigned short* ap1=&Apack[(128 + (w+4)*14)*512 + lane*8];
    bf16x8 a0c=*(const bf16x8*)&ap0[0];
    bf16x8 a1c=*(const bf16x8*)&ap1[0];
    #pragma unroll
    for(int s=0;s<14;s++){
      bf16x8 a0n, a1n;
      if(s<13){ a0n=*(const bf16x8*)&ap0[(s+1)*512]; a1n=*(const bf16x8*)&ap1[(s+1)*512]; }
      int dt=s>>1;
      int sl = ((((s&1)*32 + halfk*8)*2) ^ (gg<<4));
      #pragma unroll
      for(int j=0;j<3;j++){
        int t=2*j+tau2+dt;
        bf16x8 bf = *(const bf16x8*)(xlb + ((t*8+gg)<<7) + sl);
        acA[j] = __builtin_amdgcn_mfma_f32_16x16x32_bf16(a0c, bf, acA[j], 0,0,0);
        acB[j] = __builtin_amdgcn_mfma_f32_16x16x32_bf16(a1c, bf, acB[j], 0,0,0);
      }
      if(s<13){ a0c=a0n; a1c=a1n; }
    }
    #pragma unroll
    for(int j=0;j<3;j++) GATE_STORE(acA[j], acB[j], 18+2*j)
  }
  #undef GATE_STORE

  // ---- fc via MFMA ----
  const int tcol = lane&15, hq = lane>>4;
  const int hm = (hq==3)? 0 : hq;
  bf16x8 b2 = *(const bf16x8*)&fcwB[lane*8];
  float fcbv = (tcol<12)? fcb[tcol] : 0.f;
  f32x4 d2[8];
  #pragma unroll
  for(int g=0; g<8; g++){
    bf16x8 a2 = *(const bf16x8*)&Glw[tcol*192 + ((g ^ (tcol&7))*24) + hm*8];
    f32x4 ini = {fcbv, fcbv, fcbv, fcbv};
    d2[g] = __builtin_amdgcn_mfma_f32_16x16x32_bf16(a2, b2, ini, 0,0,0);
  }
  __syncthreads();

  if(tcol<12){
    float rwa[4], rba[4];
    #pragma unroll
    for(int r=0;r<4;r++){ int c=w*16+hq*4+r; rwa[r]=rw[c]; rba[r]=rb[c]; }
    #pragma unroll
    for(int g=0; g<8; g++){
      float xv=xres[g][tcol];
      #pragma unroll
      for(int r=0;r<4;r++){
        int c=w*16+hq*4+r;
        float tv = fmaxf(d2[g][r], 0.f);
        float xr = xv*rwa[r]+rba[r];
        U.XP[g][c*12+tcol] = fmaxf(xr+tv, 0.f);
      }
    }
  }
  __syncthreads();

  if(tid<192){
    int p=tid>>1, h=tid&1;
    int g=p/12, t=p-(p/12)*12;
    float s=0.f;
    for(int c=h*32;c<h*32+32;c++) s+=U.XP[g][c*12+t];
    s += __shfl_xor(s,1,64);
    float mu=s*(1.f/64.f);
    float q=0.f;
    for(int c=h*32;c<h*32+32;c++){float d=U.XP[g][c*12+t]-mu;q+=d*d;}
    q += __shfl_xor(q,1,64);
    if(h==0){ mu8[g][t]=mu; rs8[g][t]=rsqrtf(q*(1.f/64.f)+EPS); }
  }
  __syncthreads();
  for(int o=tid;o<1536;o+=256){
    int g=o/192; int q4=o-g*192;
    int c=q4/3; int tb=(q4-c*3)*4;
    float4 vv = *(const float4*)&U.XP[g][c*12+tb];
    float gl=gln[c], bl=bln[c];
    float4 ov;
    ov.x=(vv.x-mu8[g][tb+0])*rs8[g][tb+0]*gl+bl;
    ov.y=(vv.y-mu8[g][tb+1])*rs8[g][tb+1]*gl+bl;
    ov.z=(vv.z-mu8[g][tb+2])*rs8[g][tb+2]*gl+bl;
    ov.w=(vv.w-mu8[g][tb+3])*rs8[g][tb+3]*gl+bl;
    *(float4*)&out[(long)(bn0+g)*768 + c*12 + tb] = ov;
  }
}

// ---------------- launch ----------------
extern "C" void kernel_launch(void* const* d_in, const int* in_sizes, int n_in,
                              void* d_out, int out_size, void* d_ws, size_t ws_size,
                              hipStream_t stream){
  const float* x    =(const float*)d_in[0];
  const float* res  =(const float*)d_in[1];
  const float* posT =(const float*)d_in[2];
  const float* gT   =(const float*)d_in[3];
  const float* bT   =(const float*)d_in[4];
  const float* wq   =(const float*)d_in[5];
  const float* wk   =(const float*)d_in[6];
  const float* wv   =(const float*)d_in[7];
  const float* fcW  =(const float*)d_in[8];
  const float* prw  =(const float*)d_in[9];
  const float* prb  =(const float*)d_in[10];
  const float* posS =(const float*)d_in[11];
  const float* gS   =(const float*)d_in[12];
  const float* bS   =(const float*)d_in[13];
  const float* swq  =(const float*)d_in[14];
  const float* swk  =(const float*)d_in[15];
  const float* cheb =(const float*)d_in[16];
  const float* adj  =(const float*)d_in[17];
  const float* cmask=(const float*)d_in[18];
  const float* theta=(const float*)d_in[19];
  const float* g3w=(const float*)d_in[20]; const float* g3b=(const float*)d_in[21];
  const float* g5w=(const float*)d_in[22]; const float* g5b=(const float*)d_in[23];
  const float* g7w=(const float*)d_in[24]; const float* g7b=(const float*)d_in[25];
  const float* fcw=(const float*)d_in[26]; const float* fcb=(const float*)d_in[27];
  const float* rw =(const float*)d_in[28]; const float* rb =(const float*)d_in[29];
  const float* gln=(const float*)d_in[30]; const float* bln=(const float*)d_in[31];

  float* outp=(float*)d_out;
  float* scores = outp + 12582912;

  float* wsf=(float*)d_ws;
  float* TEmx = wsf;                          // 196608 f
  float* qkv  = TEmx + 196608;                // 55296 f
  float* TATpre = qkv + 55296;                // 196608 f
  unsigned short* SEb = (unsigned short*)(TATpre + 196608);      // 4194304 f
  unsigned short* SQb = (unsigned short*)((float*)SEb + 4194304); // 786432 f
  unsigned short* SKb = (unsigned short*)((float*)SQb + 786432);  // 786432 f
  unsigned* mcT = (unsigned*)((float*)SKb + 786432);              // 3145728 f
  float* rhsT  = (float*)mcT + 3145728;                           // 589824 f
  unsigned short* Apack = (unsigned short*)(rhsT + 589824);       // 122880 u16
  unsigned short* Wpack = Apack + 122880;                         // 98304 u16
  unsigned short* Wpack2 = Wpack + 98304;                         // 294912 u16
  unsigned short* TEb = Wpack2 + 294912;                          // 196608 u16
  unsigned short* fcwB = TEb + 196608;                            // 512 u16
  unsigned short* ctxb = fcwB + 512;                              // 18432 u16
  unsigned short* fcWB2 = ctxb + 18432;                           // 98304 u16
  float* muT = (float*)(fcWB2 + 98304);                           // 192 f
  float* rsT = muT + 192;                                         // 192 f

  kb0_prep<<<dim3(768),dim3(256),0,stream>>>(adj,cmask,cheb,mcT);
  kprep<<<dim3(301),dim3(256),0,stream>>>(g3w,g5w,g7w,swq,swk,wq,wk,wv,fcw,fcW,
                                          Apack,Wpack,Wpack2,fcwB,fcWB2);
  k1_embedT<<<dim3(192),dim3(256),0,stream>>>(x,posT,gT,bT,TEmx,TEb);
  k2_qkv<<<dim3(216),dim3(256),0,stream>>>(TEb,Wpack2,qkv);
  k3_attn<<<dim3(48),dim3(256),0,stream>>>(qkv,res,scores,ctxb);
  k4a_mm<<<dim3(192),dim3(256),0,stream>>>(ctxb,fcWB2,TEmx,TATpre);
  k4b_stats<<<dim3(192),dim3(256),0,stream>>>(TATpre,muT,rsT);
  k5_semx<<<dim3(2048),dim3(256),0,stream>>>(TATpre,muT,rsT,prw,prb,posS,gS,bS,SEb);
  k6_sqk<<<dim3(1024),dim3(256),0,stream>>>(SEb,Wpack,SQb,SKb);
  k7_spatial<<<dim3(768),dim3(256),0,stream>>>(SQb,SKb,mcT,x,rhsT);
  k9_final<<<dim3(2048),dim3(256),0,stream>>>(rhsT,theta,Apack,fcwB,g3b,g5b,g7b,
                                              fcb,rw,rb,gln,bln,x,outp);
}